// Round 1
// baseline (23177.666 us; speedup 1.0000x reference)
//
#include <hip/hip_runtime.h>
#include <cmath>

// ---------------- problem constants ----------------
#define BB 32          // batch
#define NPTS 8192      // points per cloud
#define NG 128         // groups
#define KNB 32         // neighbors per group
#define LK 32          // len_keep
#define DE 768         // encoder dim
#define DD 512         // decoder dim
#define NLE 12
#define NLD 8

// =====================================================================
// FPS: one block per batch. dmin in LDS, block argmax each step.
// =====================================================================
__global__ __launch_bounds__(1024) void fps_kernel(
    const float* __restrict__ xyz, const int* __restrict__ init,
    int* __restrict__ cent_idx, float* __restrict__ cxyz)
{
#pragma clang fp contract(off)
    const int b = blockIdx.x;
    const float* P = xyz + (size_t)b * NPTS * 3;
    __shared__ float dmin[NPTS];
    __shared__ float rv[1024];
    __shared__ int   ri[1024];
    __shared__ int far_s;
    const int tid = threadIdx.x;
    for (int n = tid; n < NPTS; n += 1024) dmin[n] = 1e10f;
    if (tid == 0) far_s = init[b];
    __syncthreads();
    for (int t = 0; t < NG; ++t) {
        int far = far_s;
        if (tid == 0) {
            cent_idx[b * NG + t] = far;
            cxyz[(b * NG + t) * 3 + 0] = P[far * 3 + 0];
            cxyz[(b * NG + t) * 3 + 1] = P[far * 3 + 1];
            cxyz[(b * NG + t) * 3 + 2] = P[far * 3 + 2];
        }
        float cx = P[far * 3 + 0], cy = P[far * 3 + 1], cz = P[far * 3 + 2];
        float best = -1.0f; int bi = 0;
        for (int n = tid; n < NPTS; n += 1024) {
            float dx = P[n * 3 + 0] - cx;
            float dy = P[n * 3 + 1] - cy;
            float dz = P[n * 3 + 2] - cz;
            float d = dx * dx + dy * dy + dz * dz;
            float dm = dmin[n];
            if (d < dm) dm = d;
            dmin[n] = dm;
            if (dm > best) { best = dm; bi = n; }   // strict > keeps lowest index
        }
        rv[tid] = best; ri[tid] = bi;
        __syncthreads();
        for (int s = 512; s > 0; s >>= 1) {
            if (tid < s) {
                float v2 = rv[tid + s]; int i2 = ri[tid + s];
                if (v2 > rv[tid] || (v2 == rv[tid] && i2 < ri[tid])) { rv[tid] = v2; ri[tid] = i2; }
            }
            __syncthreads();
        }
        if (tid == 0) far_s = ri[0];
        __syncthreads();
    }
}

// =====================================================================
// KNN: one block per (b, m). dist in LDS, 32 rounds of argmin.
// Writes centered neighborhoods gn (B,NG,K,3).
// =====================================================================
__global__ __launch_bounds__(256) void knn_kernel(
    const float* __restrict__ xyz, const float* __restrict__ cxyz,
    float* __restrict__ gn)
{
#pragma clang fp contract(off)
    const int bm = blockIdx.x;
    const int b = bm / NG;
    const float* P = xyz + (size_t)b * NPTS * 3;
    __shared__ float dist[NPTS];
    __shared__ float rv[256];
    __shared__ int   ri[256];
    const int tid = threadIdx.x;
    const float cx = cxyz[bm * 3 + 0], cy = cxyz[bm * 3 + 1], cz = cxyz[bm * 3 + 2];
    const float c2 = cx * cx + cy * cy + cz * cz;
    for (int n = tid; n < NPTS; n += 256) {
        float x = P[n * 3 + 0], y = P[n * 3 + 1], z = P[n * 3 + 2];
        float x2 = x * x + y * y + z * z;
        float dt = cx * x + cy * y + cz * z;
        dist[n] = (c2 + x2) - 2.0f * dt;
    }
    __syncthreads();
    for (int r = 0; r < KNB; ++r) {
        float best = 1e31f; int bi = 1 << 30;
        for (int n = tid; n < NPTS; n += 256) {
            float v = dist[n];
            if (v < best) { best = v; bi = n; }     // strict < keeps lowest index
        }
        rv[tid] = best; ri[tid] = bi;
        __syncthreads();
        for (int s = 128; s > 0; s >>= 1) {
            if (tid < s) {
                float v2 = rv[tid + s]; int i2 = ri[tid + s];
                if (v2 < rv[tid] || (v2 == rv[tid] && i2 < ri[tid])) { rv[tid] = v2; ri[tid] = i2; }
            }
            __syncthreads();
        }
        if (tid == 0) {
            int n = ri[0];
            dist[n] = 1e30f;
            gn[((size_t)bm * KNB + r) * 3 + 0] = P[n * 3 + 0] - cx;
            gn[((size_t)bm * KNB + r) * 3 + 1] = P[n * 3 + 1] - cy;
            gn[((size_t)bm * KNB + r) * 3 + 2] = P[n * 3 + 2] - cz;
        }
        __syncthreads();
    }
}

// =====================================================================
// embed1: (131072,3)@(64,3)^T + bias
// =====================================================================
__global__ void embed1_kernel(const float* __restrict__ gn, const float* __restrict__ w,
                              const float* __restrict__ bias, float* __restrict__ h1)
{
    int i = blockIdx.x * 256 + threadIdx.x;
    if (i >= 131072 * 64) return;
    int r = i >> 6, c = i & 63;
    const float* p = gn + (size_t)r * 3;
    h1[i] = p[0] * w[c * 3 + 0] + p[1] * w[c * 3 + 1] + p[2] * w[c * 3 + 2] + bias[c];
}

// =====================================================================
// column stats (sum, sumsq) in double, atomics to st[0..C) and st[C..2C)
// =====================================================================
template <int C>
__global__ __launch_bounds__(256) void colstats_kernel(const float* __restrict__ X,
                                                       double* __restrict__ st, int Mrows)
{
    constexpr int RL = 256 / C;
    const int c = threadIdx.x % C;
    const int rl = threadIdx.x / C;
    double s = 0.0, s2 = 0.0;
    int rows_per_block = (Mrows + gridDim.x - 1) / gridDim.x;
    int r0 = blockIdx.x * rows_per_block;
    int r1 = min(r0 + rows_per_block, Mrows);
    for (int r = r0 + rl; r < r1; r += RL) {
        float v = X[(size_t)r * C + c];
        s += v; s2 += (double)v * v;
    }
    __shared__ double sh[2][256];
    sh[0][threadIdx.x] = s; sh[1][threadIdx.x] = s2;
    __syncthreads();
    if (rl == 0) {
        for (int j = 1; j < RL; ++j) { s += sh[0][j * C + c]; s2 += sh[1][j * C + c]; }
        atomicAdd(&st[c], s);
        atomicAdd(&st[C + c], s2);
    }
}

__global__ void bn_finalize(const double* __restrict__ st, const float* __restrict__ g,
                            const float* __restrict__ be, float* __restrict__ sc,
                            float* __restrict__ shb, int C)
{
    int c = blockIdx.x * 64 + threadIdx.x;
    if (c >= C) return;
    double m = st[c] / 131072.0;
    double var = st[C + c] / 131072.0 - m * m;
    if (var < 0.0) var = 0.0;
    float rs = rsqrtf((float)var + 1e-5f);
    sc[c] = rs * g[c];
    shb[c] = be[c] - (float)m * rs * g[c];
}

__global__ void bn_apply(float* __restrict__ x, const float* __restrict__ sc,
                         const float* __restrict__ shb, int total, int C, int relu)
{
    int i = blockIdx.x * 256 + threadIdx.x;
    if (i >= total) return;
    int c = i % C;
    float v = x[i] * sc[c] + shb[c];
    if (relu) v = fmaxf(v, 0.0f);
    x[i] = v;
}

// =====================================================================
// embed3 fused: per group, compute h2(32x128)@cw3^T(768x128) pre-BN,
// track per-(g,c) max/min + global channel sum/sumsq (32-copy double atomics)
// =====================================================================
__global__ __launch_bounds__(256) void embed3_pool(
    const float* __restrict__ h2, const float* __restrict__ cw3, const float* __restrict__ cb3,
    float* __restrict__ gmax, float* __restrict__ gmin, double* __restrict__ st3)
{
    const int g = blockIdx.x;  // 0..4095
    __shared__ float hs[32][128];
    for (int i = threadIdx.x; i < 32 * 128; i += 256)
        hs[i >> 7][i & 127] = h2[(size_t)g * 32 * 128 + i];
    __syncthreads();
    double* stp = st3 + (size_t)(g & 31) * 1536;
    for (int c = threadIdx.x; c < 768; c += 256) {
        const float* w = cw3 + (size_t)c * 128;
        const float bb = cb3[c];
        float mx = -1e30f, mn = 1e30f;
        double s = 0.0, s2 = 0.0;
        for (int k = 0; k < 32; ++k) {
            float acc = 0.0f;
            #pragma unroll 8
            for (int d = 0; d < 128; ++d) acc += hs[k][d] * w[d];
            acc += bb;
            mx = fmaxf(mx, acc); mn = fminf(mn, acc);
            s += acc; s2 += (double)acc * acc;
        }
        gmax[(size_t)g * 768 + c] = mx;
        gmin[(size_t)g * 768 + c] = mn;
        atomicAdd(&stp[c], s);
        atomicAdd(&stp[768 + c], s2);
    }
}

__global__ void bn3_finalize(const double* __restrict__ st3, const float* __restrict__ g,
                             const float* __restrict__ be, float* __restrict__ a3,
                             float* __restrict__ c3)
{
    int c = blockIdx.x * 256 + threadIdx.x;
    if (c >= 768) return;
    double s = 0.0, s2 = 0.0;
    for (int p = 0; p < 32; ++p) { s += st3[(size_t)p * 1536 + c]; s2 += st3[(size_t)p * 1536 + 768 + c]; }
    double m = s / 131072.0;
    double var = s2 / 131072.0 - m * m;
    if (var < 0.0) var = 0.0;
    float rs = rsqrtf((float)var + 1e-5f);
    a3[c] = rs * g[c];
    c3[c] = be[c] - (float)m * rs * g[c];
}

// tokens = affine(max/min) ; x = tokens + cxyz@pos_w^T + pos_b
__global__ void tokens_pos(const float* __restrict__ gmax, const float* __restrict__ gmin,
                           const float* __restrict__ a3, const float* __restrict__ c3,
                           const float* __restrict__ cxyz, const float* __restrict__ posw,
                           const float* __restrict__ posb, float* __restrict__ x)
{
    int i = blockIdx.x * 256 + threadIdx.x;
    if (i >= 4096 * 768) return;
    int c = i % 768, g = i / 768;
    float a = a3[c];
    float tok = (a >= 0.0f ? a * gmax[i] : a * gmin[i]) + c3[c];
    float px = cxyz[g * 3 + 0], py = cxyz[g * 3 + 1], pz = cxyz[g * 3 + 2];
    x[i] = tok + px * posw[c * 3 + 0] + py * posw[c * 3 + 1] + pz * posw[c * 3 + 2] + posb[c];
}

__global__ void restore_kernel(const int* __restrict__ shuffle, int* __restrict__ restore)
{
    int j = blockIdx.x * 256 + threadIdx.x;
    if (j >= BB * NG) return;
    int b = j / NG, p = j % NG;
    restore[b * NG + shuffle[j]] = p;
}

__global__ void mask_kernel(const int* __restrict__ restore, float* __restrict__ maskv)
{
    int i = blockIdx.x * 256 + threadIdx.x;
    if (i >= BB * NG) return;
    maskv[i] = (restore[i] < LK) ? 0.0f : 1.0f;
}

__global__ void gather_xk(const float* __restrict__ xfull, const int* __restrict__ shuffle,
                          float* __restrict__ xe)
{
    int i = blockIdx.x * 256 + threadIdx.x;
    if (i >= BB * LK * DE) return;
    int c = i % DE;
    int s = (i / DE) % LK;
    int b = i / (DE * LK);
    xe[i] = xfull[((size_t)b * NG + shuffle[b * NG + s]) * DE + c];
}

__global__ void yd_build(const float* __restrict__ yk, const int* __restrict__ restore,
                         const float* __restrict__ mtok, const float* __restrict__ cxyz,
                         const float* __restrict__ dpw, const float* __restrict__ dpb,
                         float* __restrict__ xd)
{
    int i = blockIdx.x * 256 + threadIdx.x;
    if (i >= BB * NG * DD) return;
    int c = i % DD;
    int g = i / DD;
    int b = g / NG;
    int r = restore[g];
    float base = (r < LK) ? yk[((size_t)b * LK + r) * DD + c] : mtok[c];
    float px = cxyz[g * 3 + 0], py = cxyz[g * 3 + 1], pz = cxyz[g * 3 + 2];
    xd[i] = base + px * dpw[c * 3 + 0] + py * dpw[c * 3 + 1] + pz * dpw[c * 3 + 2] + dpb[c];
}

// =====================================================================
// generic fp32 GEMM: C(M,N) = A(M,K) @ W(N,K)^T + bias  (optional relu)
// 64x64 tile, 256 threads, 4x4 per thread, K-step 16
// =====================================================================
__global__ __launch_bounds__(256) void gemm_bias(
    const float* __restrict__ A, const float* __restrict__ W,
    const float* __restrict__ bias, float* __restrict__ C,
    int M, int N, int K, int relu)
{
    __shared__ float As[16][68];
    __shared__ float Ws[16][68];
    const int tid = threadIdx.x;
    const int tx = tid & 15, ty = tid >> 4;
    const int m0 = blockIdx.y * 64, n0 = blockIdx.x * 64;
    const int lk = tid & 15;   // k within tile
    const int lr = tid >> 4;   // base row 0..15
    float acc[4][4] = {};
    for (int kt = 0; kt < K; kt += 16) {
        #pragma unroll
        for (int j = 0; j < 4; ++j) {
            int m = m0 + lr + 16 * j;
            As[lk][lr + 16 * j] = (m < M) ? A[(size_t)m * K + kt + lk] : 0.0f;
            int n = n0 + lr + 16 * j;
            Ws[lk][lr + 16 * j] = (n < N) ? W[(size_t)n * K + kt + lk] : 0.0f;
        }
        __syncthreads();
        #pragma unroll
        for (int kk = 0; kk < 16; ++kk) {
            float4 av4 = *(const float4*)&As[kk][ty * 4];
            float4 bv4 = *(const float4*)&Ws[kk][tx * 4];
            float av[4] = {av4.x, av4.y, av4.z, av4.w};
            float bv[4] = {bv4.x, bv4.y, bv4.z, bv4.w};
            #pragma unroll
            for (int i = 0; i < 4; ++i)
                #pragma unroll
                for (int j = 0; j < 4; ++j)
                    acc[i][j] += av[i] * bv[j];
        }
        __syncthreads();
    }
    #pragma unroll
    for (int i = 0; i < 4; ++i) {
        int m = m0 + ty * 4 + i;
        if (m >= M) continue;
        #pragma unroll
        for (int j = 0; j < 4; ++j) {
            int n = n0 + tx * 4 + j;
            if (n >= N) continue;
            float v = acc[i][j] + bias[n];
            if (relu) v = fmaxf(v, 0.0f);
            C[(size_t)m * N + n] = v;
        }
    }
}

// =====================================================================
// attention: block per (b, h, q-tile). qkv rows are (b*S+s), width 3*NH*DH
// =====================================================================
template <int S, int DH, int QT, int NH>
__global__ __launch_bounds__(256) void attn_kernel(const float* __restrict__ qkv,
                                                   float* __restrict__ o, float scale)
{
    constexpr int D = NH * DH;
    constexpr int NT = S / QT;
    __shared__ float Ks[S][DH];
    __shared__ float Vs[S][DH];
    __shared__ float Qs[QT][DH];
    __shared__ float P[QT][S];
    const int t = blockIdx.x % NT;
    const int h = (blockIdx.x / NT) % NH;
    const int b = blockIdx.x / (NT * NH);
    const float* base = qkv + (size_t)b * S * 3 * D + h * DH;
    for (int i = threadIdx.x; i < S * DH; i += 256) {
        int s = i / DH, d = i % DH;
        Ks[s][d] = base[(size_t)s * 3 * D + D + d];
        Vs[s][d] = base[(size_t)s * 3 * D + 2 * D + d];
    }
    for (int i = threadIdx.x; i < QT * DH; i += 256) {
        int qi = i / DH, d = i % DH;
        Qs[qi][d] = base[(size_t)(t * QT + qi) * 3 * D + d];
    }
    __syncthreads();
    for (int i = threadIdx.x; i < QT * S; i += 256) {
        int qi = i / S, s = i % S;
        float acc = 0.0f;
        #pragma unroll 8
        for (int d = 0; d < DH; ++d) acc += Qs[qi][d] * Ks[s][d];
        P[qi][s] = acc * scale;
    }
    __syncthreads();
    if (threadIdx.x < QT) {
        int qi = threadIdx.x;
        float mx = -1e30f;
        for (int s = 0; s < S; ++s) mx = fmaxf(mx, P[qi][s]);
        float sum = 0.0f;
        for (int s = 0; s < S; ++s) { float e = expf(P[qi][s] - mx); P[qi][s] = e; sum += e; }
        float inv = 1.0f / sum;
        for (int s = 0; s < S; ++s) P[qi][s] *= inv;
    }
    __syncthreads();
    float* ob = o + (size_t)b * S * D + h * DH;
    for (int i = threadIdx.x; i < QT * DH; i += 256) {
        int qi = i / DH, d = i % DH;
        float acc = 0.0f;
        for (int s = 0; s < S; ++s) acc += P[qi][s] * Vs[s][d];
        ob[(size_t)(t * QT + qi) * D + d] = acc;
    }
}

// =====================================================================
// LayerNorm with residual, in place: x = LN(x + r) * g + b
// =====================================================================
template <int D>
__global__ __launch_bounds__(256) void ln_res(float* __restrict__ x, const float* __restrict__ r,
                                              const float* __restrict__ g, const float* __restrict__ b)
{
    __shared__ float row[D];
    __shared__ float red[256];
    __shared__ float mv[2];
    const size_t off = (size_t)blockIdx.x * D;
    float s = 0.0f;
    for (int i = threadIdx.x; i < D; i += 256) {
        float v = x[off + i] + r[off + i];
        row[i] = v; s += v;
    }
    red[threadIdx.x] = s; __syncthreads();
    for (int st = 128; st > 0; st >>= 1) { if (threadIdx.x < st) red[threadIdx.x] += red[threadIdx.x + st]; __syncthreads(); }
    if (threadIdx.x == 0) mv[0] = red[0] / D;
    __syncthreads();
    float m = mv[0];
    s = 0.0f;
    for (int i = threadIdx.x; i < D; i += 256) { float d = row[i] - m; s += d * d; }
    red[threadIdx.x] = s; __syncthreads();
    for (int st = 128; st > 0; st >>= 1) { if (threadIdx.x < st) red[threadIdx.x] += red[threadIdx.x + st]; __syncthreads(); }
    if (threadIdx.x == 0) mv[1] = red[0] / D;
    __syncthreads();
    float rs = rsqrtf(mv[1] + 1e-5f);
    for (int i = threadIdx.x; i < D; i += 256)
        x[off + i] = (row[i] - m) * rs * g[i] + b[i];
}

// =====================================================================
// loss
// =====================================================================
__global__ __launch_bounds__(128) void loss_l(const float* __restrict__ pred,
                                              const float* __restrict__ target,
                                              const float* __restrict__ maskv,
                                              float* __restrict__ lm)
{
    const int g = blockIdx.x;
    __shared__ float red[128];
    int t = threadIdx.x;
    float s = 0.0f;
    if (t < 96) {
        float d = pred[(size_t)g * 96 + t] - target[(size_t)g * 96 + t];
        s = d * d;
    }
    red[t] = s; __syncthreads();
    for (int st = 64; st > 0; st >>= 1) { if (t < st) red[t] += red[t + st]; __syncthreads(); }
    if (t == 0) lm[g] = (red[0] / 96.0f) * maskv[g];
}

__global__ __launch_bounds__(1024) void loss_final(const float* __restrict__ lm,
                                                   const float* __restrict__ maskv,
                                                   float* __restrict__ out)
{
    __shared__ float r1[1024], r2[1024];
    int t = threadIdx.x;
    float a = 0.0f, b = 0.0f;
    for (int i = t; i < BB * NG; i += 1024) { a += lm[i]; b += maskv[i]; }
    r1[t] = a; r2[t] = b; __syncthreads();
    for (int st = 512; st > 0; st >>= 1) { if (t < st) { r1[t] += r1[t + st]; r2[t] += r2[t + st]; } __syncthreads(); }
    if (t == 0) out[0] = r1[0] / r2[0];
}

// =====================================================================
// host
// =====================================================================
extern "C" void kernel_launch(void* const* d_in, const int* in_sizes, int n_in,
                              void* d_out, int out_size, void* d_ws, size_t ws_size,
                              hipStream_t stream)
{
    (void)in_sizes; (void)n_in; (void)out_size; (void)ws_size;
    const float* xyz        = (const float*)d_in[0];
    const int*   fps_init   = (const int*)d_in[1];
    const int*   ids_shuf   = (const int*)d_in[2];
    const float* cw1 = (const float*)d_in[3];  const float* cb1 = (const float*)d_in[4];
    const float* g1  = (const float*)d_in[5];  const float* be1 = (const float*)d_in[6];
    const float* cw2 = (const float*)d_in[7];  const float* cb2 = (const float*)d_in[8];
    const float* g2  = (const float*)d_in[9];  const float* be2 = (const float*)d_in[10];
    const float* cw3 = (const float*)d_in[11]; const float* cb3 = (const float*)d_in[12];
    const float* g3  = (const float*)d_in[13]; const float* be3 = (const float*)d_in[14];
    const float* posw = (const float*)d_in[15]; const float* posb = (const float*)d_in[16];
    const float* eqw = (const float*)d_in[17]; const float* eqb = (const float*)d_in[18];
    const float* eow = (const float*)d_in[19]; const float* eob = (const float*)d_in[20];
    const float* el1g = (const float*)d_in[21]; const float* el1b = (const float*)d_in[22];
    const float* ef1w = (const float*)d_in[23]; const float* ef1b = (const float*)d_in[24];
    const float* ef2w = (const float*)d_in[25]; const float* ef2b = (const float*)d_in[26];
    const float* el2g = (const float*)d_in[27]; const float* el2b = (const float*)d_in[28];
    const float* dew = (const float*)d_in[29]; const float* deb = (const float*)d_in[30];
    const float* mtok = (const float*)d_in[31];
    const float* dpw = (const float*)d_in[32]; const float* dpb = (const float*)d_in[33];
    const float* dqw = (const float*)d_in[34]; const float* dqb = (const float*)d_in[35];
    const float* dow = (const float*)d_in[36]; const float* dob = (const float*)d_in[37];
    const float* dl1g = (const float*)d_in[38]; const float* dl1b = (const float*)d_in[39];
    const float* df1w = (const float*)d_in[40]; const float* df1b = (const float*)d_in[41];
    const float* df2w = (const float*)d_in[42]; const float* df2b = (const float*)d_in[43];
    const float* dl2g = (const float*)d_in[44]; const float* dl2b = (const float*)d_in[45];
    const float* prw = (const float*)d_in[46]; const float* prb = (const float*)d_in[47];
    float* out = (float*)d_out;
    float* pred = out + 1;
    float* maskv = out + 1 + (size_t)BB * NG * KNB * 3;

    // ---- workspace carve ----
    char* ws = (char*)d_ws;
    size_t off = 0;
    auto alloc = [&](size_t bytes) -> void* {
        void* p = ws + off;
        off = (off + bytes + 255) & ~(size_t)255;
        return p;
    };
    double* st1 = (double*)alloc(128 * 8);
    double* st2 = (double*)alloc(256 * 8);
    double* st3 = (double*)alloc((size_t)32 * 1536 * 8);
    float* sc1 = (float*)alloc(64 * 4);  float* sh1 = (float*)alloc(64 * 4);
    float* sc2 = (float*)alloc(128 * 4); float* sh2 = (float*)alloc(128 * 4);
    float* a3 = (float*)alloc(768 * 4);  float* c3 = (float*)alloc(768 * 4);
    int* centi = (int*)alloc(4096 * 4);
    int* restore = (int*)alloc(4096 * 4);
    float* cxyz = (float*)alloc(12288 * 4);
    float* gn   = (float*)alloc((size_t)393216 * 4);
    float* h1   = (float*)alloc((size_t)8388608 * 4);     // 131072 x 64
    float* h2   = (float*)alloc((size_t)16777216 * 4);    // 131072 x 128
    float* gmax = (float*)alloc((size_t)3145728 * 4);
    float* gmin = (float*)alloc((size_t)3145728 * 4);
    float* xfull = (float*)alloc((size_t)3145728 * 4);    // 4096 x 768 (later enc tmp)
    float* xe   = (float*)alloc((size_t)786432 * 4);      // 1024 x 768
    float* qkve = (float*)alloc((size_t)2359296 * 4);     // 1024 x 2304
    float* oe   = (float*)alloc((size_t)786432 * 4);
    float* fe1  = (float*)alloc((size_t)3145728 * 4);     // 1024 x 3072
    float* yk   = (float*)alloc((size_t)524288 * 4);      // 1024 x 512
    float* xd   = (float*)alloc((size_t)2097152 * 4);     // 4096 x 512
    float* qkvd = (float*)alloc((size_t)6291456 * 4);     // 4096 x 1536
    float* od   = (float*)alloc((size_t)2097152 * 4);
    float* fd1  = (float*)alloc((size_t)8388608 * 4);     // 4096 x 2048
    float* tmpd = (float*)alloc((size_t)2097152 * 4);     // 4096 x 512
    float* lm   = (float*)alloc(4096 * 4);

    // zero the fp64 stats region (st1..st3 contiguous)
    size_t stats_bytes = (size_t)((char*)st3 + (size_t)32 * 1536 * 8 - (char*)st1);
    hipMemsetAsync((void*)st1, 0, stats_bytes, stream);

    auto gemm = [&](const float* A, const float* W, const float* bias, float* Cm,
                    int M, int N, int K, int relu) {
        dim3 grid((N + 63) / 64, (M + 63) / 64);
        gemm_bias<<<grid, 256, 0, stream>>>(A, W, bias, Cm, M, N, K, relu);
    };

    // ---- stage 1: FPS + KNN ----
    fps_kernel<<<BB, 1024, 0, stream>>>(xyz, fps_init, centi, cxyz);
    knn_kernel<<<BB * NG, 256, 0, stream>>>(xyz, cxyz, gn);

    // ---- stage 2: mini-PointNet ----
    embed1_kernel<<<(131072 * 64 + 255) / 256, 256, 0, stream>>>(gn, cw1, cb1, h1);
    colstats_kernel<64><<<256, 256, 0, stream>>>(h1, st1, 131072);
    bn_finalize<<<1, 64, 0, stream>>>(st1, g1, be1, sc1, sh1, 64);
    bn_apply<<<(131072 * 64 + 255) / 256, 256, 0, stream>>>(h1, sc1, sh1, 131072 * 64, 64, 1);
    gemm(h1, cw2, cb2, h2, 131072, 128, 64, 0);
    colstats_kernel<128><<<256, 256, 0, stream>>>(h2, st2, 131072);
    bn_finalize<<<2, 64, 0, stream>>>(st2, g2, be2, sc2, sh2, 128);
    bn_apply<<<(131072 * 128 + 255) / 256, 256, 0, stream>>>(h2, sc2, sh2, 131072 * 128, 128, 1);
    embed3_pool<<<4096, 256, 0, stream>>>(h2, cw3, cb3, gmax, gmin, st3);
    bn3_finalize<<<3, 256, 0, stream>>>(st3, g3, be3, a3, c3);
    tokens_pos<<<(4096 * 768 + 255) / 256, 256, 0, stream>>>(gmax, gmin, a3, c3, cxyz, posw, posb, xfull);

    // ---- stage 3: shuffle / mask ----
    restore_kernel<<<16, 256, 0, stream>>>(ids_shuf, restore);
    mask_kernel<<<16, 256, 0, stream>>>(restore, maskv);
    gather_xk<<<(BB * LK * DE + 255) / 256, 256, 0, stream>>>(xfull, ids_shuf, xe);

    // ---- stage 4: encoder (12 layers) ----
    for (int l = 0; l < NLE; ++l) {
        gemm(xe, eqw + (size_t)l * 3 * DE * DE, eqb + (size_t)l * 3 * DE, qkve, BB * LK, 3 * DE, DE, 0);
        attn_kernel<LK, 64, 32, 12><<<BB * 12, 256, 0, stream>>>(qkve, oe, 0.125f);
        gemm(oe, eow + (size_t)l * DE * DE, eob + (size_t)l * DE, xfull, BB * LK, DE, DE, 0);
        ln_res<DE><<<BB * LK, 256, 0, stream>>>(xe, xfull, el1g + (size_t)l * DE, el1b + (size_t)l * DE);
        gemm(xe, ef1w + (size_t)l * 4 * DE * DE, ef1b + (size_t)l * 4 * DE, fe1, BB * LK, 4 * DE, DE, 1);
        gemm(fe1, ef2w + (size_t)l * DE * 4 * DE, ef2b + (size_t)l * DE, xfull, BB * LK, DE, 4 * DE, 0);
        ln_res<DE><<<BB * LK, 256, 0, stream>>>(xe, xfull, el2g + (size_t)l * DE, el2b + (size_t)l * DE);
    }

    // ---- stage 5: decoder embed + mask tokens ----
    gemm(xe, dew, deb, yk, BB * LK, DD, DE, 0);
    yd_build<<<(BB * NG * DD + 255) / 256, 256, 0, stream>>>(yk, restore, mtok, cxyz, dpw, dpb, xd);

    // ---- stage 6: decoder (8 layers) ----
    const float dsc = (float)(1.0 / sqrt(32.0));
    for (int l = 0; l < NLD; ++l) {
        gemm(xd, dqw + (size_t)l * 3 * DD * DD, dqb + (size_t)l * 3 * DD, qkvd, BB * NG, 3 * DD, DD, 0);
        attn_kernel<NG, 32, 32, 16><<<BB * 16 * (NG / 32), 256, 0, stream>>>(qkvd, od, dsc);
        gemm(od, dow + (size_t)l * DD * DD, dob + (size_t)l * DD, tmpd, BB * NG, DD, DD, 0);
        ln_res<DD><<<BB * NG, 256, 0, stream>>>(xd, tmpd, dl1g + (size_t)l * DD, dl1b + (size_t)l * DD);
        gemm(xd, df1w + (size_t)l * 4 * DD * DD, df1b + (size_t)l * 4 * DD, fd1, BB * NG, 4 * DD, DD, 1);
        gemm(fd1, df2w + (size_t)l * DD * 4 * DD, df2b + (size_t)l * DD, tmpd, BB * NG, DD, 4 * DD, 0);
        ln_res<DD><<<BB * NG, 256, 0, stream>>>(xd, tmpd, dl2g + (size_t)l * DD, dl2b + (size_t)l * DD);
    }

    // ---- stage 7: prediction + loss ----
    gemm(xd, prw, prb, pred, BB * NG, KNB * 3, DD, 0);
    loss_l<<<BB * NG, 128, 0, stream>>>(pred, gn, maskv, lm);
    loss_final<<<1, 1024, 0, stream>>>(lm, maskv, out);
}

// Round 2
// 9092.654 us; speedup vs baseline: 2.5491x; 2.5491x over previous
//
#include <hip/hip_runtime.h>
#include <cmath>

// ---------------- problem constants ----------------
#define BB 32          // batch
#define NPTS 8192      // points per cloud
#define NG 128         // groups
#define KNB 32         // neighbors per group
#define LK 32          // len_keep
#define DE 768         // encoder dim
#define DD 512         // decoder dim
#define NLE 12
#define NLD 8

typedef __bf16 bf16x8 __attribute__((ext_vector_type(8)));
typedef float  f32x4  __attribute__((ext_vector_type(4)));

static __device__ __forceinline__ bf16x8 pack8(float4 a, float4 b) {
    bf16x8 h;
    h[0] = (__bf16)a.x; h[1] = (__bf16)a.y; h[2] = (__bf16)a.z; h[3] = (__bf16)a.w;
    h[4] = (__bf16)b.x; h[5] = (__bf16)b.y; h[6] = (__bf16)b.z; h[7] = (__bf16)b.w;
    return h;
}

// =====================================================================
// FPS: one block per batch. dmin in LDS, block argmax each step.
// =====================================================================
__global__ __launch_bounds__(1024) void fps_kernel(
    const float* __restrict__ xyz, const int* __restrict__ init,
    int* __restrict__ cent_idx, float* __restrict__ cxyz)
{
#pragma clang fp contract(off)
    const int b = blockIdx.x;
    const float* P = xyz + (size_t)b * NPTS * 3;
    __shared__ float dmin[NPTS];
    __shared__ float rv[1024];
    __shared__ int   ri[1024];
    __shared__ int far_s;
    const int tid = threadIdx.x;
    for (int n = tid; n < NPTS; n += 1024) dmin[n] = 1e10f;
    if (tid == 0) far_s = init[b];
    __syncthreads();
    for (int t = 0; t < NG; ++t) {
        int far = far_s;
        if (tid == 0) {
            cent_idx[b * NG + t] = far;
            cxyz[(b * NG + t) * 3 + 0] = P[far * 3 + 0];
            cxyz[(b * NG + t) * 3 + 1] = P[far * 3 + 1];
            cxyz[(b * NG + t) * 3 + 2] = P[far * 3 + 2];
        }
        float cx = P[far * 3 + 0], cy = P[far * 3 + 1], cz = P[far * 3 + 2];
        float best = -1.0f; int bi = 0;
        for (int n = tid; n < NPTS; n += 1024) {
            float dx = P[n * 3 + 0] - cx;
            float dy = P[n * 3 + 1] - cy;
            float dz = P[n * 3 + 2] - cz;
            float d = dx * dx + dy * dy + dz * dz;
            float dm = dmin[n];
            if (d < dm) dm = d;
            dmin[n] = dm;
            if (dm > best) { best = dm; bi = n; }   // strict > keeps lowest index
        }
        rv[tid] = best; ri[tid] = bi;
        __syncthreads();
        for (int s = 512; s > 0; s >>= 1) {
            if (tid < s) {
                float v2 = rv[tid + s]; int i2 = ri[tid + s];
                if (v2 > rv[tid] || (v2 == rv[tid] && i2 < ri[tid])) { rv[tid] = v2; ri[tid] = i2; }
            }
            __syncthreads();
        }
        if (tid == 0) far_s = ri[0];
        __syncthreads();
    }
}

// =====================================================================
// KNN: one block per (b, m). dist in LDS, 32 rounds of argmin.
// =====================================================================
__global__ __launch_bounds__(256) void knn_kernel(
    const float* __restrict__ xyz, const float* __restrict__ cxyz,
    float* __restrict__ gn)
{
#pragma clang fp contract(off)
    const int bm = blockIdx.x;
    const int b = bm / NG;
    const float* P = xyz + (size_t)b * NPTS * 3;
    __shared__ float dist[NPTS];
    __shared__ float rv[256];
    __shared__ int   ri[256];
    const int tid = threadIdx.x;
    const float cx = cxyz[bm * 3 + 0], cy = cxyz[bm * 3 + 1], cz = cxyz[bm * 3 + 2];
    const float c2 = cx * cx + cy * cy + cz * cz;
    for (int n = tid; n < NPTS; n += 256) {
        float x = P[n * 3 + 0], y = P[n * 3 + 1], z = P[n * 3 + 2];
        float x2 = x * x + y * y + z * z;
        float dt = cx * x + cy * y + cz * z;
        dist[n] = (c2 + x2) - 2.0f * dt;
    }
    __syncthreads();
    for (int r = 0; r < KNB; ++r) {
        float best = 1e31f; int bi = 1 << 30;
        for (int n = tid; n < NPTS; n += 256) {
            float v = dist[n];
            if (v < best) { best = v; bi = n; }
        }
        rv[tid] = best; ri[tid] = bi;
        __syncthreads();
        for (int s = 128; s > 0; s >>= 1) {
            if (tid < s) {
                float v2 = rv[tid + s]; int i2 = ri[tid + s];
                if (v2 < rv[tid] || (v2 == rv[tid] && i2 < ri[tid])) { rv[tid] = v2; ri[tid] = i2; }
            }
            __syncthreads();
        }
        if (tid == 0) {
            int n = ri[0];
            dist[n] = 1e30f;
            gn[((size_t)bm * KNB + r) * 3 + 0] = P[n * 3 + 0] - cx;
            gn[((size_t)bm * KNB + r) * 3 + 1] = P[n * 3 + 1] - cy;
            gn[((size_t)bm * KNB + r) * 3 + 2] = P[n * 3 + 2] - cz;
        }
        __syncthreads();
    }
}

// =====================================================================
// embed1: (131072,3)@(64,3)^T + bias
// =====================================================================
__global__ void embed1_kernel(const float* __restrict__ gn, const float* __restrict__ w,
                              const float* __restrict__ bias, float* __restrict__ h1)
{
    int i = blockIdx.x * 256 + threadIdx.x;
    if (i >= 131072 * 64) return;
    int r = i >> 6, c = i & 63;
    const float* p = gn + (size_t)r * 3;
    h1[i] = p[0] * w[c * 3 + 0] + p[1] * w[c * 3 + 1] + p[2] * w[c * 3 + 2] + bias[c];
}

// =====================================================================
// column stats (sum, sumsq) in double
// =====================================================================
template <int C>
__global__ __launch_bounds__(256) void colstats_kernel(const float* __restrict__ X,
                                                       double* __restrict__ st, int Mrows)
{
    constexpr int RL = 256 / C;
    const int c = threadIdx.x % C;
    const int rl = threadIdx.x / C;
    double s = 0.0, s2 = 0.0;
    int rows_per_block = (Mrows + gridDim.x - 1) / gridDim.x;
    int r0 = blockIdx.x * rows_per_block;
    int r1 = min(r0 + rows_per_block, Mrows);
    for (int r = r0 + rl; r < r1; r += RL) {
        float v = X[(size_t)r * C + c];
        s += v; s2 += (double)v * v;
    }
    __shared__ double sh[2][256];
    sh[0][threadIdx.x] = s; sh[1][threadIdx.x] = s2;
    __syncthreads();
    if (rl == 0) {
        for (int j = 1; j < RL; ++j) { s += sh[0][j * C + c]; s2 += sh[1][j * C + c]; }
        atomicAdd(&st[c], s);
        atomicAdd(&st[C + c], s2);
    }
}

__global__ void bn_finalize(const double* __restrict__ st, const float* __restrict__ g,
                            const float* __restrict__ be, float* __restrict__ sc,
                            float* __restrict__ shb, int C)
{
    int c = blockIdx.x * 64 + threadIdx.x;
    if (c >= C) return;
    double m = st[c] / 131072.0;
    double var = st[C + c] / 131072.0 - m * m;
    if (var < 0.0) var = 0.0;
    float rs = rsqrtf((float)var + 1e-5f);
    sc[c] = rs * g[c];
    shb[c] = be[c] - (float)m * rs * g[c];
}

__global__ void bn_apply(float* __restrict__ x, const float* __restrict__ sc,
                         const float* __restrict__ shb, int total, int C, int relu)
{
    int i = blockIdx.x * 256 + threadIdx.x;
    if (i >= total) return;
    int c = i % C;
    float v = x[i] * sc[c] + shb[c];
    if (relu) v = fmaxf(v, 0.0f);
    x[i] = v;
}

// =====================================================================
// bf16 MFMA GEMM: C(M,N) = A(M,K) @ W(N,K)^T + bias (optional relu)
// 128x128 tile, BK=64, 256 thr = 4 waves (2x2), wave = 64x64 (4x4 MFMA 16x16x32)
// LDS XOR-swizzle: chunk ^= (row&7)  (16B chunks within 128B row) -> conflict-free
// =====================================================================
__global__ __launch_bounds__(256) void gemm_mfma(
    const float* __restrict__ A, const float* __restrict__ W,
    const float* __restrict__ bias, float* __restrict__ C,
    int M, int N, int K, int relu)
{
    __shared__ __bf16 As[128 * 64];
    __shared__ __bf16 Ws[128 * 64];
    const int tid = threadIdx.x;
    const int lane = tid & 63;
    const int wave = tid >> 6;
    const int wm = wave >> 1, wn = wave & 1;
    const int m0 = blockIdx.y * 128, n0 = blockIdx.x * 128;

    f32x4 acc[4][4] = {};

    for (int kt = 0; kt < K; kt += 64) {
        #pragma unroll
        for (int j = 0; j < 4; ++j) {
            int c = tid + j * 256;          // chunk 0..1023
            int row = c >> 3, kc = c & 7;
            int dst = row * 64 + ((kc ^ (row & 7)) * 8);
            {
                int m = m0 + row;
                float4 v0 = {0,0,0,0}, v1 = {0,0,0,0};
                if (m < M) {
                    const float* p = A + (size_t)m * K + kt + kc * 8;
                    v0 = *(const float4*)p; v1 = *(const float4*)(p + 4);
                }
                *(bf16x8*)&As[dst] = pack8(v0, v1);
            }
            {
                int n = n0 + row;
                float4 v0 = {0,0,0,0}, v1 = {0,0,0,0};
                if (n < N) {
                    const float* p = W + (size_t)n * K + kt + kc * 8;
                    v0 = *(const float4*)p; v1 = *(const float4*)(p + 4);
                }
                *(bf16x8*)&Ws[dst] = pack8(v0, v1);
            }
        }
        __syncthreads();
        #pragma unroll
        for (int ks = 0; ks < 2; ++ks) {
            bf16x8 af[4], bfr[4];
            #pragma unroll
            for (int i = 0; i < 4; ++i) {
                int rowA = wm * 64 + i * 16 + (lane & 15);
                int kc = ks * 4 + (lane >> 4);
                af[i] = *(bf16x8*)&As[rowA * 64 + ((kc ^ (rowA & 7)) * 8)];
                int rowB = wn * 64 + i * 16 + (lane & 15);
                bfr[i] = *(bf16x8*)&Ws[rowB * 64 + ((kc ^ (rowB & 7)) * 8)];
            }
            #pragma unroll
            for (int i = 0; i < 4; ++i)
                #pragma unroll
                for (int j = 0; j < 4; ++j)
                    acc[i][j] = __builtin_amdgcn_mfma_f32_16x16x32_bf16(af[i], bfr[j], acc[i][j], 0, 0, 0);
        }
        __syncthreads();
    }
    #pragma unroll
    for (int j = 0; j < 4; ++j) {
        int col = n0 + wn * 64 + j * 16 + (lane & 15);
        if (col >= N) continue;
        float bv = bias[col];
        #pragma unroll
        for (int i = 0; i < 4; ++i) {
            #pragma unroll
            for (int r = 0; r < 4; ++r) {
                int rowm = m0 + wm * 64 + i * 16 + (lane >> 4) * 4 + r;
                if (rowm >= M) continue;
                float v = acc[i][j][r] + bv;
                if (relu) v = fmaxf(v, 0.0f);
                C[(size_t)rowm * N + col] = v;
            }
        }
    }
}

// =====================================================================
// embed3 via MFMA: h3(131072,768) = h2(131072,128) @ cw3^T, fused epilogue:
// bias + per-group(32-row) max/min + per-column sum/sumsq (double atomics)
// grid (6, 1024)
// =====================================================================
__global__ __launch_bounds__(256) void embed3_mfma(
    const float* __restrict__ h2, const float* __restrict__ cw3, const float* __restrict__ cb3,
    float* __restrict__ gmax, float* __restrict__ gmin, double* __restrict__ st3)
{
    __shared__ __bf16 As[128 * 64];
    __shared__ __bf16 Ws[128 * 64];
    const int tid = threadIdx.x;
    const int lane = tid & 63;
    const int wave = tid >> 6;
    const int wm = wave >> 1, wn = wave & 1;
    const int m0 = blockIdx.y * 128, n0 = blockIdx.x * 128;

    f32x4 acc[4][4] = {};

    #pragma unroll
    for (int kt = 0; kt < 128; kt += 64) {
        #pragma unroll
        for (int j = 0; j < 4; ++j) {
            int c = tid + j * 256;
            int row = c >> 3, kc = c & 7;
            int dst = row * 64 + ((kc ^ (row & 7)) * 8);
            {
                const float* p = h2 + (size_t)(m0 + row) * 128 + kt + kc * 8;
                *(bf16x8*)&As[dst] = pack8(*(const float4*)p, *(const float4*)(p + 4));
            }
            {
                const float* p = cw3 + (size_t)(n0 + row) * 128 + kt + kc * 8;
                *(bf16x8*)&Ws[dst] = pack8(*(const float4*)p, *(const float4*)(p + 4));
            }
        }
        __syncthreads();
        #pragma unroll
        for (int ks = 0; ks < 2; ++ks) {
            bf16x8 af[4], bfr[4];
            #pragma unroll
            for (int i = 0; i < 4; ++i) {
                int rowA = wm * 64 + i * 16 + (lane & 15);
                int kc = ks * 4 + (lane >> 4);
                af[i] = *(bf16x8*)&As[rowA * 64 + ((kc ^ (rowA & 7)) * 8)];
                int rowB = wn * 64 + i * 16 + (lane & 15);
                bfr[i] = *(bf16x8*)&Ws[rowB * 64 + ((kc ^ (rowB & 7)) * 8)];
            }
            #pragma unroll
            for (int i = 0; i < 4; ++i)
                #pragma unroll
                for (int j = 0; j < 4; ++j)
                    acc[i][j] = __builtin_amdgcn_mfma_f32_16x16x32_bf16(af[i], bfr[j], acc[i][j], 0, 0, 0);
        }
        __syncthreads();
    }

    // epilogue: bias, per-group (32 rows) max/min per column, column stats
    #pragma unroll
    for (int j = 0; j < 4; ++j) {
        int col = n0 + wn * 64 + j * 16 + (lane & 15);
        float bv = cb3[col];
        float stot = 0.0f, s2tot = 0.0f;
        #pragma unroll
        for (int gi = 0; gi < 2; ++gi) {
            float mx = -1e30f, mn = 1e30f, s = 0.0f, s2 = 0.0f;
            #pragma unroll
            for (int ii = 0; ii < 2; ++ii) {
                f32x4 a = acc[gi * 2 + ii][j];
                #pragma unroll
                for (int r = 0; r < 4; ++r) {
                    float v = a[r] + bv;
                    mx = fmaxf(mx, v); mn = fminf(mn, v);
                    s += v; s2 += v * v;
                }
            }
            #pragma unroll
            for (int d = 16; d < 64; d <<= 1) {
                mx = fmaxf(mx, __shfl_xor(mx, d));
                mn = fminf(mn, __shfl_xor(mn, d));
                s  += __shfl_xor(s, d);
                s2 += __shfl_xor(s2, d);
            }
            stot += s; s2tot += s2;
            if (lane < 16) {
                int g = (m0 >> 5) + wm * 2 + gi;
                gmax[(size_t)g * 768 + col] = mx;
                gmin[(size_t)g * 768 + col] = mn;
            }
        }
        if (lane < 16) {
            double* stp = st3 + (size_t)(blockIdx.y & 31) * 1536;
            atomicAdd(&stp[col], (double)stot);
            atomicAdd(&stp[768 + col], (double)s2tot);
        }
    }
}

__global__ void bn3_finalize(const double* __restrict__ st3, const float* __restrict__ g,
                             const float* __restrict__ be, float* __restrict__ a3,
                             float* __restrict__ c3)
{
    int c = blockIdx.x * 256 + threadIdx.x;
    if (c >= 768) return;
    double s = 0.0, s2 = 0.0;
    for (int p = 0; p < 32; ++p) { s += st3[(size_t)p * 1536 + c]; s2 += st3[(size_t)p * 1536 + 768 + c]; }
    double m = s / 131072.0;
    double var = s2 / 131072.0 - m * m;
    if (var < 0.0) var = 0.0;
    float rs = rsqrtf((float)var + 1e-5f);
    a3[c] = rs * g[c];
    c3[c] = be[c] - (float)m * rs * g[c];
}

// tokens = affine(max/min) ; x = tokens + cxyz@pos_w^T + pos_b
__global__ void tokens_pos(const float* __restrict__ gmax, const float* __restrict__ gmin,
                           const float* __restrict__ a3, const float* __restrict__ c3,
                           const float* __restrict__ cxyz, const float* __restrict__ posw,
                           const float* __restrict__ posb, float* __restrict__ x)
{
    int i = blockIdx.x * 256 + threadIdx.x;
    if (i >= 4096 * 768) return;
    int c = i % 768, g = i / 768;
    float a = a3[c];
    float tok = (a >= 0.0f ? a * gmax[i] : a * gmin[i]) + c3[c];
    float px = cxyz[g * 3 + 0], py = cxyz[g * 3 + 1], pz = cxyz[g * 3 + 2];
    x[i] = tok + px * posw[c * 3 + 0] + py * posw[c * 3 + 1] + pz * posw[c * 3 + 2] + posb[c];
}

__global__ void restore_kernel(const int* __restrict__ shuffle, int* __restrict__ restore)
{
    int j = blockIdx.x * 256 + threadIdx.x;
    if (j >= BB * NG) return;
    int b = j / NG, p = j % NG;
    restore[b * NG + shuffle[j]] = p;
}

__global__ void mask_kernel(const int* __restrict__ restore, float* __restrict__ maskv)
{
    int i = blockIdx.x * 256 + threadIdx.x;
    if (i >= BB * NG) return;
    maskv[i] = (restore[i] < LK) ? 0.0f : 1.0f;
}

__global__ void gather_xk(const float* __restrict__ xfull, const int* __restrict__ shuffle,
                          float* __restrict__ xe)
{
    int i = blockIdx.x * 256 + threadIdx.x;
    if (i >= BB * LK * DE) return;
    int c = i % DE;
    int s = (i / DE) % LK;
    int b = i / (DE * LK);
    xe[i] = xfull[((size_t)b * NG + shuffle[b * NG + s]) * DE + c];
}

__global__ void yd_build(const float* __restrict__ yk, const int* __restrict__ restore,
                         const float* __restrict__ mtok, const float* __restrict__ cxyz,
                         const float* __restrict__ dpw, const float* __restrict__ dpb,
                         float* __restrict__ xd)
{
    int i = blockIdx.x * 256 + threadIdx.x;
    if (i >= BB * NG * DD) return;
    int c = i % DD;
    int g = i / DD;
    int b = g / NG;
    int r = restore[g];
    float base = (r < LK) ? yk[((size_t)b * LK + r) * DD + c] : mtok[c];
    float px = cxyz[g * 3 + 0], py = cxyz[g * 3 + 1], pz = cxyz[g * 3 + 2];
    xd[i] = base + px * dpw[c * 3 + 0] + py * dpw[c * 3 + 1] + pz * dpw[c * 3 + 2] + dpb[c];
}

// =====================================================================
// attention: block per (b, h, q-tile)
// =====================================================================
template <int S, int DH, int QT, int NH>
__global__ __launch_bounds__(256) void attn_kernel(const float* __restrict__ qkv,
                                                   float* __restrict__ o, float scale)
{
    constexpr int D = NH * DH;
    constexpr int NT = S / QT;
    __shared__ float Ks[S][DH];
    __shared__ float Vs[S][DH];
    __shared__ float Qs[QT][DH];
    __shared__ float P[QT][S];
    const int t = blockIdx.x % NT;
    const int h = (blockIdx.x / NT) % NH;
    const int b = blockIdx.x / (NT * NH);
    const float* base = qkv + (size_t)b * S * 3 * D + h * DH;
    for (int i = threadIdx.x; i < S * DH; i += 256) {
        int s = i / DH, d = i % DH;
        Ks[s][d] = base[(size_t)s * 3 * D + D + d];
        Vs[s][d] = base[(size_t)s * 3 * D + 2 * D + d];
    }
    for (int i = threadIdx.x; i < QT * DH; i += 256) {
        int qi = i / DH, d = i % DH;
        Qs[qi][d] = base[(size_t)(t * QT + qi) * 3 * D + d];
    }
    __syncthreads();
    for (int i = threadIdx.x; i < QT * S; i += 256) {
        int qi = i / S, s = i % S;
        float acc = 0.0f;
        #pragma unroll 8
        for (int d = 0; d < DH; ++d) acc += Qs[qi][d] * Ks[s][d];
        P[qi][s] = acc * scale;
    }
    __syncthreads();
    if (threadIdx.x < QT) {
        int qi = threadIdx.x;
        float mx = -1e30f;
        for (int s = 0; s < S; ++s) mx = fmaxf(mx, P[qi][s]);
        float sum = 0.0f;
        for (int s = 0; s < S; ++s) { float e = expf(P[qi][s] - mx); P[qi][s] = e; sum += e; }
        float inv = 1.0f / sum;
        for (int s = 0; s < S; ++s) P[qi][s] *= inv;
    }
    __syncthreads();
    float* ob = o + (size_t)b * S * D + h * DH;
    for (int i = threadIdx.x; i < QT * DH; i += 256) {
        int qi = i / DH, d = i % DH;
        float acc = 0.0f;
        for (int s = 0; s < S; ++s) acc += P[qi][s] * Vs[s][d];
        ob[(size_t)(t * QT + qi) * D + d] = acc;
    }
}

// =====================================================================
// LayerNorm with residual, in place: x = LN(x + r) * g + b
// =====================================================================
template <int D>
__global__ __launch_bounds__(256) void ln_res(float* __restrict__ x, const float* __restrict__ r,
                                              const float* __restrict__ g, const float* __restrict__ b)
{
    __shared__ float row[D];
    __shared__ float red[256];
    __shared__ float mv[2];
    const size_t off = (size_t)blockIdx.x * D;
    float s = 0.0f;
    for (int i = threadIdx.x; i < D; i += 256) {
        float v = x[off + i] + r[off + i];
        row[i] = v; s += v;
    }
    red[threadIdx.x] = s; __syncthreads();
    for (int st = 128; st > 0; st >>= 1) { if (threadIdx.x < st) red[threadIdx.x] += red[threadIdx.x + st]; __syncthreads(); }
    if (threadIdx.x == 0) mv[0] = red[0] / D;
    __syncthreads();
    float m = mv[0];
    s = 0.0f;
    for (int i = threadIdx.x; i < D; i += 256) { float d = row[i] - m; s += d * d; }
    red[threadIdx.x] = s; __syncthreads();
    for (int st = 128; st > 0; st >>= 1) { if (threadIdx.x < st) red[threadIdx.x] += red[threadIdx.x + st]; __syncthreads(); }
    if (threadIdx.x == 0) mv[1] = red[0] / D;
    __syncthreads();
    float rs = rsqrtf(mv[1] + 1e-5f);
    for (int i = threadIdx.x; i < D; i += 256)
        x[off + i] = (row[i] - m) * rs * g[i] + b[i];
}

// =====================================================================
// loss
// =====================================================================
__global__ __launch_bounds__(128) void loss_l(const float* __restrict__ pred,
                                              const float* __restrict__ target,
                                              const float* __restrict__ maskv,
                                              float* __restrict__ lm)
{
    const int g = blockIdx.x;
    __shared__ float red[128];
    int t = threadIdx.x;
    float s = 0.0f;
    if (t < 96) {
        float d = pred[(size_t)g * 96 + t] - target[(size_t)g * 96 + t];
        s = d * d;
    }
    red[t] = s; __syncthreads();
    for (int st = 64; st > 0; st >>= 1) { if (t < st) red[t] += red[t + st]; __syncthreads(); }
    if (t == 0) lm[g] = (red[0] / 96.0f) * maskv[g];
}

__global__ __launch_bounds__(1024) void loss_final(const float* __restrict__ lm,
                                                   const float* __restrict__ maskv,
                                                   float* __restrict__ out)
{
    __shared__ float r1[1024], r2[1024];
    int t = threadIdx.x;
    float a = 0.0f, b = 0.0f;
    for (int i = t; i < BB * NG; i += 1024) { a += lm[i]; b += maskv[i]; }
    r1[t] = a; r2[t] = b; __syncthreads();
    for (int st = 512; st > 0; st >>= 1) { if (t < st) { r1[t] += r1[t + st]; r2[t] += r2[t + st]; } __syncthreads(); }
    if (t == 0) out[0] = r1[0] / r2[0];
}

// =====================================================================
// host
// =====================================================================
extern "C" void kernel_launch(void* const* d_in, const int* in_sizes, int n_in,
                              void* d_out, int out_size, void* d_ws, size_t ws_size,
                              hipStream_t stream)
{
    (void)in_sizes; (void)n_in; (void)out_size; (void)ws_size;
    const float* xyz        = (const float*)d_in[0];
    const int*   fps_init   = (const int*)d_in[1];
    const int*   ids_shuf   = (const int*)d_in[2];
    const float* cw1 = (const float*)d_in[3];  const float* cb1 = (const float*)d_in[4];
    const float* g1  = (const float*)d_in[5];  const float* be1 = (const float*)d_in[6];
    const float* cw2 = (const float*)d_in[7];  const float* cb2 = (const float*)d_in[8];
    const float* g2  = (const float*)d_in[9];  const float* be2 = (const float*)d_in[10];
    const float* cw3 = (const float*)d_in[11]; const float* cb3 = (const float*)d_in[12];
    const float* g3  = (const float*)d_in[13]; const float* be3 = (const float*)d_in[14];
    const float* posw = (const float*)d_in[15]; const float* posb = (const float*)d_in[16];
    const float* eqw = (const float*)d_in[17]; const float* eqb = (const float*)d_in[18];
    const float* eow = (const float*)d_in[19]; const float* eob = (const float*)d_in[20];
    const float* el1g = (const float*)d_in[21]; const float* el1b = (const float*)d_in[22];
    const float* ef1w = (const float*)d_in[23]; const float* ef1b = (const float*)d_in[24];
    const float* ef2w = (const float*)d_in[25]; const float* ef2b = (const float*)d_in[26];
    const float* el2g = (const float*)d_in[27]; const float* el2b = (const float*)d_in[28];
    const float* dew = (const float*)d_in[29]; const float* deb = (const float*)d_in[30];
    const float* mtok = (const float*)d_in[31];
    const float* dpw = (const float*)d_in[32]; const float* dpb = (const float*)d_in[33];
    const float* dqw = (const float*)d_in[34]; const float* dqb = (const float*)d_in[35];
    const float* dow = (const float*)d_in[36]; const float* dob = (const float*)d_in[37];
    const float* dl1g = (const float*)d_in[38]; const float* dl1b = (const float*)d_in[39];
    const float* df1w = (const float*)d_in[40]; const float* df1b = (const float*)d_in[41];
    const float* df2w = (const float*)d_in[42]; const float* df2b = (const float*)d_in[43];
    const float* dl2g = (const float*)d_in[44]; const float* dl2b = (const float*)d_in[45];
    const float* prw = (const float*)d_in[46]; const float* prb = (const float*)d_in[47];
    float* out = (float*)d_out;
    float* pred = out + 1;
    float* maskv = out + 1 + (size_t)BB * NG * KNB * 3;

    // ---- workspace carve ----
    char* ws = (char*)d_ws;
    size_t off = 0;
    auto alloc = [&](size_t bytes) -> void* {
        void* p = ws + off;
        off = (off + bytes + 255) & ~(size_t)255;
        return p;
    };
    double* st1 = (double*)alloc(128 * 8);
    double* st2 = (double*)alloc(256 * 8);
    double* st3 = (double*)alloc((size_t)32 * 1536 * 8);
    float* sc1 = (float*)alloc(64 * 4);  float* sh1 = (float*)alloc(64 * 4);
    float* sc2 = (float*)alloc(128 * 4); float* sh2 = (float*)alloc(128 * 4);
    float* a3 = (float*)alloc(768 * 4);  float* c3 = (float*)alloc(768 * 4);
    int* centi = (int*)alloc(4096 * 4);
    int* restore = (int*)alloc(4096 * 4);
    float* cxyz = (float*)alloc(12288 * 4);
    float* gn   = (float*)alloc((size_t)393216 * 4);
    float* h1   = (float*)alloc((size_t)8388608 * 4);     // 131072 x 64
    float* h2   = (float*)alloc((size_t)16777216 * 4);    // 131072 x 128
    float* gmax = (float*)alloc((size_t)3145728 * 4);
    float* gmin = (float*)alloc((size_t)3145728 * 4);
    float* xfull = (float*)alloc((size_t)3145728 * 4);    // 4096 x 768 (also enc tmp)
    float* xe   = (float*)alloc((size_t)786432 * 4);      // 1024 x 768
    float* qkve = (float*)alloc((size_t)2359296 * 4);     // 1024 x 2304
    float* oe   = (float*)alloc((size_t)786432 * 4);
    float* fe1  = (float*)alloc((size_t)3145728 * 4);     // 1024 x 3072
    float* yk   = (float*)alloc((size_t)524288 * 4);      // 1024 x 512
    float* xd   = (float*)alloc((size_t)2097152 * 4);     // 4096 x 512
    float* qkvd = (float*)alloc((size_t)6291456 * 4);     // 4096 x 1536
    float* od   = (float*)alloc((size_t)2097152 * 4);
    float* fd1  = (float*)alloc((size_t)8388608 * 4);     // 4096 x 2048
    float* tmpd = (float*)alloc((size_t)2097152 * 4);     // 4096 x 512
    float* lm   = (float*)alloc(4096 * 4);

    // zero the fp64 stats region (st1..st3 contiguous)
    size_t stats_bytes = (size_t)((char*)st3 + (size_t)32 * 1536 * 8 - (char*)st1);
    hipMemsetAsync((void*)st1, 0, stats_bytes, stream);

    auto gemm = [&](const float* A, const float* W, const float* bias, float* Cm,
                    int M, int N, int K, int relu) {
        dim3 grid((N + 127) / 128, (M + 127) / 128);
        gemm_mfma<<<grid, 256, 0, stream>>>(A, W, bias, Cm, M, N, K, relu);
    };

    // ---- stage 1: FPS + KNN ----
    fps_kernel<<<BB, 1024, 0, stream>>>(xyz, fps_init, centi, cxyz);
    knn_kernel<<<BB * NG, 256, 0, stream>>>(xyz, cxyz, gn);

    // ---- stage 2: mini-PointNet ----
    embed1_kernel<<<(131072 * 64 + 255) / 256, 256, 0, stream>>>(gn, cw1, cb1, h1);
    colstats_kernel<64><<<256, 256, 0, stream>>>(h1, st1, 131072);
    bn_finalize<<<1, 64, 0, stream>>>(st1, g1, be1, sc1, sh1, 64);
    bn_apply<<<(131072 * 64 + 255) / 256, 256, 0, stream>>>(h1, sc1, sh1, 131072 * 64, 64, 1);
    gemm(h1, cw2, cb2, h2, 131072, 128, 64, 0);
    colstats_kernel<128><<<256, 256, 0, stream>>>(h2, st2, 131072);
    bn_finalize<<<2, 64, 0, stream>>>(st2, g2, be2, sc2, sh2, 128);
    bn_apply<<<(131072 * 128 + 255) / 256, 256, 0, stream>>>(h2, sc2, sh2, 131072 * 128, 128, 1);
    embed3_mfma<<<dim3(6, 1024), 256, 0, stream>>>(h2, cw3, cb3, gmax, gmin, st3);
    bn3_finalize<<<3, 256, 0, stream>>>(st3, g3, be3, a3, c3);
    tokens_pos<<<(4096 * 768 + 255) / 256, 256, 0, stream>>>(gmax, gmin, a3, c3, cxyz, posw, posb, xfull);

    // ---- stage 3: shuffle / mask ----
    restore_kernel<<<16, 256, 0, stream>>>(ids_shuf, restore);
    mask_kernel<<<16, 256, 0, stream>>>(restore, maskv);
    gather_xk<<<(BB * LK * DE + 255) / 256, 256, 0, stream>>>(xfull, ids_shuf, xe);

    // ---- stage 4: encoder (12 layers) ----
    for (int l = 0; l < NLE; ++l) {
        gemm(xe, eqw + (size_t)l * 3 * DE * DE, eqb + (size_t)l * 3 * DE, qkve, BB * LK, 3 * DE, DE, 0);
        attn_kernel<LK, 64, 32, 12><<<BB * 12, 256, 0, stream>>>(qkve, oe, 0.125f);
        gemm(oe, eow + (size_t)l * DE * DE, eob + (size_t)l * DE, xfull, BB * LK, DE, DE, 0);
        ln_res<DE><<<BB * LK, 256, 0, stream>>>(xe, xfull, el1g + (size_t)l * DE, el1b + (size_t)l * DE);
        gemm(xe, ef1w + (size_t)l * 4 * DE * DE, ef1b + (size_t)l * 4 * DE, fe1, BB * LK, 4 * DE, DE, 1);
        gemm(fe1, ef2w + (size_t)l * DE * 4 * DE, ef2b + (size_t)l * DE, xfull, BB * LK, DE, 4 * DE, 0);
        ln_res<DE><<<BB * LK, 256, 0, stream>>>(xe, xfull, el2g + (size_t)l * DE, el2b + (size_t)l * DE);
    }

    // ---- stage 5: decoder embed + mask tokens ----
    gemm(xe, dew, deb, yk, BB * LK, DD, DE, 0);
    yd_build<<<(BB * NG * DD + 255) / 256, 256, 0, stream>>>(yk, restore, mtok, cxyz, dpw, dpb, xd);

    // ---- stage 6: decoder (8 layers) ----
    const float dsc = (float)(1.0 / sqrt(32.0));
    for (int l = 0; l < NLD; ++l) {
        gemm(xd, dqw + (size_t)l * 3 * DD * DD, dqb + (size_t)l * 3 * DD, qkvd, BB * NG, 3 * DD, DD, 0);
        attn_kernel<NG, 32, 32, 16><<<BB * 16 * (NG / 32), 256, 0, stream>>>(qkvd, od, dsc);
        gemm(od, dow + (size_t)l * DD * DD, dob + (size_t)l * DD, tmpd, BB * NG, DD, DD, 0);
        ln_res<DD><<<BB * NG, 256, 0, stream>>>(xd, tmpd, dl1g + (size_t)l * DD, dl1b + (size_t)l * DD);
        gemm(xd, df1w + (size_t)l * 4 * DD * DD, df1b + (size_t)l * 4 * DD, fd1, BB * NG, 4 * DD, DD, 1);
        gemm(fd1, df2w + (size_t)l * DD * 4 * DD, df2b + (size_t)l * DD, tmpd, BB * NG, DD, 4 * DD, 0);
        ln_res<DD><<<BB * NG, 256, 0, stream>>>(xd, tmpd, dl2g + (size_t)l * DD, dl2b + (size_t)l * DD);
    }

    // ---- stage 7: prediction + loss ----
    gemm(xd, prw, prb, pred, BB * NG, KNB * 3, DD, 0);
    loss_l<<<BB * NG, 128, 0, stream>>>(pred, gn, maskv, lm);
    loss_final<<<1, 1024, 0, stream>>>(lm, maskv, out);
}

// Round 3
// 4455.265 us; speedup vs baseline: 5.2023x; 2.0409x over previous
//
#include <hip/hip_runtime.h>
#include <cmath>

// ---------------- problem constants ----------------
#define BB 32          // batch
#define NPTS 8192      // points per cloud
#define NG 128         // groups
#define KNB 32         // neighbors per group
#define LK 32          // len_keep
#define DE 768         // encoder dim
#define DD 512         // decoder dim
#define NLE 12
#define NLD 8

typedef __bf16 bf16x8 __attribute__((ext_vector_type(8)));
typedef float  f32x4  __attribute__((ext_vector_type(4)));

static __device__ __forceinline__ bf16x8 pack8(float4 a, float4 b) {
    bf16x8 h;
    h[0] = (__bf16)a.x; h[1] = (__bf16)a.y; h[2] = (__bf16)a.z; h[3] = (__bf16)a.w;
    h[4] = (__bf16)b.x; h[5] = (__bf16)b.y; h[6] = (__bf16)b.z; h[7] = (__bf16)b.w;
    return h;
}

// async global->LDS 16B copy: per-wave, lane l writes ldsbase + l*16
static __device__ __forceinline__ void gload16(const __bf16* g, __bf16* l) {
    __builtin_amdgcn_global_load_lds(
        (const __attribute__((address_space(1))) void*)g,
        (__attribute__((address_space(3))) void*)l,
        16, 0, 0);
}

// =====================================================================
// FPS: one block per batch. points + dmin in LDS, wave-shuffle argmax.
// =====================================================================
__global__ __launch_bounds__(1024) void fps_kernel(
    const float* __restrict__ xyz, const int* __restrict__ init,
    float* __restrict__ cxyz)
{
#pragma clang fp contract(off)
    const int b = blockIdx.x;
    const float* P = xyz + (size_t)b * NPTS * 3;
    __shared__ float px[NPTS], py[NPTS], pz[NPTS];
    __shared__ float dmin[NPTS];
    __shared__ float rv16[16];
    __shared__ int   ri16[16];
    __shared__ int far_s;
    const int tid = threadIdx.x;
    for (int n = tid; n < NPTS; n += 1024) {
        px[n] = P[n * 3 + 0]; py[n] = P[n * 3 + 1]; pz[n] = P[n * 3 + 2];
        dmin[n] = 1e10f;
    }
    if (tid == 0) far_s = init[b];
    __syncthreads();
    for (int t = 0; t < NG; ++t) {
        int far = far_s;
        float cx = px[far], cy = py[far], cz = pz[far];
        if (tid == 0) {
            cxyz[(b * NG + t) * 3 + 0] = cx;
            cxyz[(b * NG + t) * 3 + 1] = cy;
            cxyz[(b * NG + t) * 3 + 2] = cz;
        }
        float best = -1.0f; int bi = 0;
        #pragma unroll
        for (int k = 0; k < 8; ++k) {
            int n = tid + (k << 10);
            float dx = px[n] - cx, dy = py[n] - cy, dz = pz[n] - cz;
            float d = dx * dx + dy * dy + dz * dz;
            float dm = dmin[n];
            if (d < dm) dm = d;
            dmin[n] = dm;
            if (dm > best) { best = dm; bi = n; }   // strict > keeps lowest index
        }
        #pragma unroll
        for (int d = 32; d >= 1; d >>= 1) {
            float v2 = __shfl_down(best, d); int i2 = __shfl_down(bi, d);
            if (v2 > best || (v2 == best && i2 < bi)) { best = v2; bi = i2; }
        }
        if ((tid & 63) == 0) { rv16[tid >> 6] = best; ri16[tid >> 6] = bi; }
        __syncthreads();
        if (tid == 0) {
            float bv = rv16[0]; int bbi = ri16[0];
            for (int w = 1; w < 16; ++w) {
                float v2 = rv16[w]; int i2 = ri16[w];
                if (v2 > bv || (v2 == bv && i2 < bbi)) { bv = v2; bbi = i2; }
            }
            far_s = bbi;
        }
        __syncthreads();
    }
}

// =====================================================================
// KNN: one block per (b,m). dist computed once; per-thread persistent
// (best,idx); per round: wave-shuffle argmin + owner-only rescan.
// =====================================================================
__global__ __launch_bounds__(256) void knn_kernel(
    const float* __restrict__ xyz, const float* __restrict__ cxyz,
    float* __restrict__ gn)
{
#pragma clang fp contract(off)
    const int bm = blockIdx.x;
    const int b = bm / NG;
    const float* P = xyz + (size_t)b * NPTS * 3;
    __shared__ float dist[NPTS];
    __shared__ float rv4[4];
    __shared__ int   ri4[4];
    __shared__ int   order[KNB];
    const int tid = threadIdx.x;
    const float cx = cxyz[bm * 3 + 0], cy = cxyz[bm * 3 + 1], cz = cxyz[bm * 3 + 2];
    const float c2 = cx * cx + cy * cy + cz * cz;
    float best = 1e31f; int bi = 1 << 30;
    #pragma unroll
    for (int j = 0; j < NPTS / 256; ++j) {
        int n = tid + (j << 8);
        float x = P[n * 3 + 0], y = P[n * 3 + 1], z = P[n * 3 + 2];
        float x2 = x * x + y * y + z * z;
        float dt = cx * x + cy * y + cz * z;
        float v = (c2 + x2) - 2.0f * dt;
        dist[n] = v;
        if (v < best) { best = v; bi = n; }        // strict < keeps lowest index
    }
    for (int r = 0; r < KNB; ++r) {
        float v = best; int i = bi;
        #pragma unroll
        for (int d = 32; d >= 1; d >>= 1) {
            float v2 = __shfl_down(v, d); int i2 = __shfl_down(i, d);
            if (v2 < v || (v2 == v && i2 < i)) { v = v2; i = i2; }
        }
        if ((tid & 63) == 0) { rv4[tid >> 6] = v; ri4[tid >> 6] = i; }
        __syncthreads();
        float bv = rv4[0]; int bn = ri4[0];
        #pragma unroll
        for (int w = 1; w < 4; ++w) {
            float v2 = rv4[w]; int i2 = ri4[w];
            if (v2 < bv || (v2 == bv && i2 < bn)) { bv = v2; bn = i2; }
        }
        if (tid == (bn & 255)) {
            order[r] = bn;
            dist[bn] = 1e30f;
            best = 1e31f; bi = 1 << 30;
            #pragma unroll
            for (int j = 0; j < NPTS / 256; ++j) {
                int n = tid + (j << 8);
                float dv = dist[n];
                if (dv < best) { best = dv; bi = n; }
            }
        }
        __syncthreads();
    }
    if (tid < KNB) {
        int n = order[tid];
        gn[((size_t)bm * KNB + tid) * 3 + 0] = P[n * 3 + 0] - cx;
        gn[((size_t)bm * KNB + tid) * 3 + 1] = P[n * 3 + 1] - cy;
        gn[((size_t)bm * KNB + tid) * 3 + 2] = P[n * 3 + 2] - cz;
    }
}

// =====================================================================
// f32 -> bf16 bulk convert (n multiple of 8)
// =====================================================================
__global__ void cvt_bf16_kernel(const float* __restrict__ src, __bf16* __restrict__ dst, int n8)
{
    int i = blockIdx.x * 256 + threadIdx.x;
    if (i >= n8) return;
    const float4* p = (const float4*)(src + (size_t)i * 8);
    *(bf16x8*)(dst + (size_t)i * 8) = pack8(p[0], p[1]);
}

// =====================================================================
// embed1: (131072,3)@(64,3)^T + bias
// =====================================================================
__global__ void embed1_kernel(const float* __restrict__ gn, const float* __restrict__ w,
                              const float* __restrict__ bias, float* __restrict__ h1)
{
    int i = blockIdx.x * 256 + threadIdx.x;
    if (i >= 131072 * 64) return;
    int r = i >> 6, c = i & 63;
    const float* p = gn + (size_t)r * 3;
    h1[i] = p[0] * w[c * 3 + 0] + p[1] * w[c * 3 + 1] + p[2] * w[c * 3 + 2] + bias[c];
}

// =====================================================================
// column stats (sum, sumsq) in double
// =====================================================================
template <int C>
__global__ __launch_bounds__(256) void colstats_kernel(const float* __restrict__ X,
                                                       double* __restrict__ st, int Mrows)
{
    constexpr int RL = 256 / C;
    const int c = threadIdx.x % C;
    const int rl = threadIdx.x / C;
    double s = 0.0, s2 = 0.0;
    int rows_per_block = (Mrows + gridDim.x - 1) / gridDim.x;
    int r0 = blockIdx.x * rows_per_block;
    int r1 = min(r0 + rows_per_block, Mrows);
    for (int r = r0 + rl; r < r1; r += RL) {
        float v = X[(size_t)r * C + c];
        s += v; s2 += (double)v * v;
    }
    __shared__ double sh[2][256];
    sh[0][threadIdx.x] = s; sh[1][threadIdx.x] = s2;
    __syncthreads();
    if (rl == 0) {
        for (int j = 1; j < RL; ++j) { s += sh[0][j * C + c]; s2 += sh[1][j * C + c]; }
        atomicAdd(&st[c], s);
        atomicAdd(&st[C + c], s2);
    }
}

__global__ void bn_finalize(const double* __restrict__ st, const float* __restrict__ g,
                            const float* __restrict__ be, float* __restrict__ sc,
                            float* __restrict__ shb, int C)
{
    int c = blockIdx.x * 64 + threadIdx.x;
    if (c >= C) return;
    double m = st[c] / 131072.0;
    double var = st[C + c] / 131072.0 - m * m;
    if (var < 0.0) var = 0.0;
    float rs = rsqrtf((float)var + 1e-5f);
    sc[c] = rs * g[c];
    shb[c] = be[c] - (float)m * rs * g[c];
}

// BN affine + relu, f32 in -> bf16 out
__global__ void bn_apply_bf16(const float* __restrict__ x, const float* __restrict__ sc,
                              const float* __restrict__ shb, __bf16* __restrict__ y,
                              int total, int C)
{
    int i = blockIdx.x * 256 + threadIdx.x;
    if (i >= total) return;
    int c = i % C;
    float v = x[i] * sc[c] + shb[c];
    v = fmaxf(v, 0.0f);
    y[i] = (__bf16)v;
}

// =====================================================================
// bf16 MFMA GEMM: C(M,N) = A(M,K) @ W(N,K)^T + bias (optional relu)
// A,W bf16 row-major. M%128==0, K%64==0. N%128==0 or guarded (bias/C).
// 128x128 tile, BK=64, 256 thr, double-buffered LDS, global_load_lds
// staging with source pre-swizzle (LDS holds XOR-swizzled layout).
// =====================================================================
#define GEMM_STAGE(Sbuf, KT)                                                    \
    do {                                                                        \
        _Pragma("unroll")                                                       \
        for (int j_ = 0; j_ < 4; ++j_) {                                        \
            int cb_ = j_ * 256 + (wave << 6);                                   \
            int c_ = cb_ + lane;                                                \
            int row_ = c_ >> 3;                                                 \
            int kcs_ = (c_ & 7) ^ (row_ & 7);                                   \
            gload16(A + (size_t)(m0 + row_) * K + (KT) + kcs_ * 8, &As[Sbuf][cb_ * 8]); \
            gload16(W + (size_t)(n0 + row_) * K + (KT) + kcs_ * 8, &Ws[Sbuf][cb_ * 8]); \
        }                                                                       \
    } while (0)

#define GEMM_COMPUTE(Sbuf)                                                      \
    do {                                                                        \
        _Pragma("unroll")                                                       \
        for (int ks = 0; ks < 2; ++ks) {                                        \
            bf16x8 af[4], bfr[4];                                               \
            _Pragma("unroll")                                                   \
            for (int i = 0; i < 4; ++i) {                                       \
                int rowA = wm * 64 + i * 16 + (lane & 15);                      \
                int kc = ks * 4 + (lane >> 4);                                  \
                af[i] = *(bf16x8*)&As[Sbuf][rowA * 64 + ((kc ^ (rowA & 7)) * 8)]; \
                int rowB = wn * 64 + i * 16 + (lane & 15);                      \
                bfr[i] = *(bf16x8*)&Ws[Sbuf][rowB * 64 + ((kc ^ (rowB & 7)) * 8)]; \
            }                                                                   \
            _Pragma("unroll")                                                   \
            for (int i = 0; i < 4; ++i)                                         \
                _Pragma("unroll")                                               \
                for (int j = 0; j < 4; ++j)                                     \
                    acc[i][j] = __builtin_amdgcn_mfma_f32_16x16x32_bf16(af[i], bfr[j], acc[i][j], 0, 0, 0); \
        }                                                                       \
    } while (0)

__global__ __launch_bounds__(256) void gemm_bf16(
    const __bf16* __restrict__ A, const __bf16* __restrict__ W,
    const float* __restrict__ bias, float* __restrict__ Cf, __bf16* __restrict__ Cb,
    int M, int N, int K, int relu)
{
    __shared__ __bf16 As[2][128 * 64];
    __shared__ __bf16 Ws[2][128 * 64];
    const int tid = threadIdx.x;
    const int lane = tid & 63;
    const int wave = tid >> 6;
    const int wm = wave >> 1, wn = wave & 1;
    const int m0 = blockIdx.y * 128, n0 = blockIdx.x * 128;
    (void)M;

    f32x4 acc[4][4] = {};

    GEMM_STAGE(0, 0);
    asm volatile("s_waitcnt vmcnt(0)" ::: "memory");
    __syncthreads();
    const int nt = K >> 6;
    int cur = 0;
    for (int t = 0; t < nt; ++t) {
        if (t + 1 < nt) GEMM_STAGE(cur ^ 1, (t + 1) << 6);
        GEMM_COMPUTE(cur);
        asm volatile("s_waitcnt vmcnt(0)" ::: "memory");
        __syncthreads();
        cur ^= 1;
    }

    #pragma unroll
    for (int j = 0; j < 4; ++j) {
        int col = n0 + wn * 64 + j * 16 + (lane & 15);
        if (col >= N) continue;
        float bv = bias[col];
        #pragma unroll
        for (int i = 0; i < 4; ++i) {
            #pragma unroll
            for (int r = 0; r < 4; ++r) {
                int rowm = m0 + wm * 64 + i * 16 + (lane >> 4) * 4 + r;
                float v = acc[i][j][r] + bv;
                if (relu) v = fmaxf(v, 0.0f);
                if (Cf) Cf[(size_t)rowm * N + col] = v;
                if (Cb) Cb[(size_t)rowm * N + col] = (__bf16)v;
            }
        }
    }
}

// =====================================================================
// embed3 via MFMA: (131072,768) = h2b(131072,128) @ cw3b^T, fused epilogue:
// bias + per-group(32-row) max/min + per-column sum/sumsq. grid (6,1024)
// =====================================================================
__global__ __launch_bounds__(256) void embed3_mfma(
    const __bf16* __restrict__ A, const __bf16* __restrict__ W,
    const float* __restrict__ cb3,
    float* __restrict__ gmax, float* __restrict__ gmin, double* __restrict__ st3)
{
    __shared__ __bf16 As[2][128 * 64];
    __shared__ __bf16 Ws[2][128 * 64];
    const int tid = threadIdx.x;
    const int lane = tid & 63;
    const int wave = tid >> 6;
    const int wm = wave >> 1, wn = wave & 1;
    const int m0 = blockIdx.y * 128, n0 = blockIdx.x * 128;
    const int K = 128;

    f32x4 acc[4][4] = {};

    GEMM_STAGE(0, 0);
    asm volatile("s_waitcnt vmcnt(0)" ::: "memory");
    __syncthreads();
    GEMM_STAGE(1, 64);
    GEMM_COMPUTE(0);
    asm volatile("s_waitcnt vmcnt(0)" ::: "memory");
    __syncthreads();
    GEMM_COMPUTE(1);

    // epilogue: bias, per-group (32 rows) max/min per column, column stats
    #pragma unroll
    for (int j = 0; j < 4; ++j) {
        int col = n0 + wn * 64 + j * 16 + (lane & 15);
        float bv = cb3[col];
        float stot = 0.0f, s2tot = 0.0f;
        #pragma unroll
        for (int gi = 0; gi < 2; ++gi) {
            float mx = -1e30f, mn = 1e30f, s = 0.0f, s2 = 0.0f;
            #pragma unroll
            for (int ii = 0; ii < 2; ++ii) {
                f32x4 a = acc[gi * 2 + ii][j];
                #pragma unroll
                for (int r = 0; r < 4; ++r) {
                    float v = a[r] + bv;
                    mx = fmaxf(mx, v); mn = fminf(mn, v);
                    s += v; s2 += v * v;
                }
            }
            #pragma unroll
            for (int d = 16; d < 64; d <<= 1) {
                mx = fmaxf(mx, __shfl_xor(mx, d));
                mn = fminf(mn, __shfl_xor(mn, d));
                s  += __shfl_xor(s, d);
                s2 += __shfl_xor(s2, d);
            }
            stot += s; s2tot += s2;
            if (lane < 16) {
                int g = (m0 >> 5) + wm * 2 + gi;
                gmax[(size_t)g * 768 + col] = mx;
                gmin[(size_t)g * 768 + col] = mn;
            }
        }
        if (lane < 16) {
            double* stp = st3 + (size_t)(blockIdx.y & 31) * 1536;
            atomicAdd(&stp[col], (double)stot);
            atomicAdd(&stp[768 + col], (double)s2tot);
        }
    }
}

__global__ void bn3_finalize(const double* __restrict__ st3, const float* __restrict__ g,
                             const float* __restrict__ be, float* __restrict__ a3,
                             float* __restrict__ c3)
{
    int c = blockIdx.x * 256 + threadIdx.x;
    if (c >= 768) return;
    double s = 0.0, s2 = 0.0;
    for (int p = 0; p < 32; ++p) { s += st3[(size_t)p * 1536 + c]; s2 += st3[(size_t)p * 1536 + 768 + c]; }
    double m = s / 131072.0;
    double var = s2 / 131072.0 - m * m;
    if (var < 0.0) var = 0.0;
    float rs = rsqrtf((float)var + 1e-5f);
    a3[c] = rs * g[c];
    c3[c] = be[c] - (float)m * rs * g[c];
}

// tokens = affine(max/min) ; x = tokens + cxyz@pos_w^T + pos_b
__global__ void tokens_pos(const float* __restrict__ gmax, const float* __restrict__ gmin,
                           const float* __restrict__ a3, const float* __restrict__ c3,
                           const float* __restrict__ cxyz, const float* __restrict__ posw,
                           const float* __restrict__ posb, float* __restrict__ x)
{
    int i = blockIdx.x * 256 + threadIdx.x;
    if (i >= 4096 * 768) return;
    int c = i % 768, g = i / 768;
    float a = a3[c];
    float tok = (a >= 0.0f ? a * gmax[i] : a * gmin[i]) + c3[c];
    float px = cxyz[g * 3 + 0], py = cxyz[g * 3 + 1], pz = cxyz[g * 3 + 2];
    x[i] = tok + px * posw[c * 3 + 0] + py * posw[c * 3 + 1] + pz * posw[c * 3 + 2] + posb[c];
}

__global__ void restore_kernel(const int* __restrict__ shuffle, int* __restrict__ restore)
{
    int j = blockIdx.x * 256 + threadIdx.x;
    if (j >= BB * NG) return;
    int b = j / NG, p = j % NG;
    restore[b * NG + shuffle[j]] = p;
}

__global__ void mask_kernel(const int* __restrict__ restore, float* __restrict__ maskv)
{
    int i = blockIdx.x * 256 + threadIdx.x;
    if (i >= BB * NG) return;
    maskv[i] = (restore[i] < LK) ? 0.0f : 1.0f;
}

__global__ void gather_xk(const float* __restrict__ xfull, const int* __restrict__ shuffle,
                          float* __restrict__ xe, __bf16* __restrict__ xeb)
{
    int i = blockIdx.x * 256 + threadIdx.x;
    if (i >= BB * LK * DE) return;
    int c = i % DE;
    int s = (i / DE) % LK;
    int b = i / (DE * LK);
    float v = xfull[((size_t)b * NG + shuffle[b * NG + s]) * DE + c];
    xe[i] = v;
    xeb[i] = (__bf16)v;
}

__global__ void yd_build(const float* __restrict__ yk, const int* __restrict__ restore,
                         const float* __restrict__ mtok, const float* __restrict__ cxyz,
                         const float* __restrict__ dpw, const float* __restrict__ dpb,
                         float* __restrict__ xd, __bf16* __restrict__ xdb)
{
    int i = blockIdx.x * 256 + threadIdx.x;
    if (i >= BB * NG * DD) return;
    int c = i % DD;
    int g = i / DD;
    int b = g / NG;
    int r = restore[g];
    float base = (r < LK) ? yk[((size_t)b * LK + r) * DD + c] : mtok[c];
    float px = cxyz[g * 3 + 0], py = cxyz[g * 3 + 1], pz = cxyz[g * 3 + 2];
    float v = base + px * dpw[c * 3 + 0] + py * dpw[c * 3 + 1] + pz * dpw[c * 3 + 2] + dpb[c];
    xd[i] = v;
    xdb[i] = (__bf16)v;
}

// =====================================================================
// attention: block per (b, h, q-tile). f32 in, bf16 out.
// =====================================================================
template <int S, int DH, int QT, int NH>
__global__ __launch_bounds__(256) void attn_kernel(const float* __restrict__ qkv,
                                                   __bf16* __restrict__ o, float scale)
{
    constexpr int D = NH * DH;
    constexpr int NT = S / QT;
    __shared__ float Ks[S][DH];
    __shared__ float Vs[S][DH];
    __shared__ float Qs[QT][DH];
    __shared__ float P[QT][S];
    const int t = blockIdx.x % NT;
    const int h = (blockIdx.x / NT) % NH;
    const int b = blockIdx.x / (NT * NH);
    const float* base = qkv + (size_t)b * S * 3 * D + h * DH;
    for (int i = threadIdx.x; i < S * DH; i += 256) {
        int s = i / DH, d = i % DH;
        Ks[s][d] = base[(size_t)s * 3 * D + D + d];
        Vs[s][d] = base[(size_t)s * 3 * D + 2 * D + d];
    }
    for (int i = threadIdx.x; i < QT * DH; i += 256) {
        int qi = i / DH, d = i % DH;
        Qs[qi][d] = base[(size_t)(t * QT + qi) * 3 * D + d];
    }
    __syncthreads();
    for (int i = threadIdx.x; i < QT * S; i += 256) {
        int qi = i / S, s = i % S;
        float acc = 0.0f;
        #pragma unroll 8
        for (int d = 0; d < DH; ++d) acc += Qs[qi][d] * Ks[s][d];
        P[qi][s] = acc * scale;
    }
    __syncthreads();
    if (threadIdx.x < QT) {
        int qi = threadIdx.x;
        float mx = -1e30f;
        for (int s = 0; s < S; ++s) mx = fmaxf(mx, P[qi][s]);
        float sum = 0.0f;
        for (int s = 0; s < S; ++s) { float e = expf(P[qi][s] - mx); P[qi][s] = e; sum += e; }
        float inv = 1.0f / sum;
        for (int s = 0; s < S; ++s) P[qi][s] *= inv;
    }
    __syncthreads();
    __bf16* ob = o + (size_t)b * S * D + h * DH;
    for (int i = threadIdx.x; i < QT * DH; i += 256) {
        int qi = i / DH, d = i % DH;
        float acc = 0.0f;
        for (int s = 0; s < S; ++s) acc += P[qi][s] * Vs[s][d];
        ob[(size_t)(t * QT + qi) * D + d] = (__bf16)acc;
    }
}

// =====================================================================
// LayerNorm with residual, in place: x = LN(x + r) * g + b ; bf16 copy out
// =====================================================================
template <int D>
__global__ __launch_bounds__(256) void ln_res(float* __restrict__ x, const float* __restrict__ r,
                                              const float* __restrict__ g, const float* __restrict__ b,
                                              __bf16* __restrict__ xb)
{
    __shared__ float row[D];
    __shared__ float red[256];
    __shared__ float mv[2];
    const size_t off = (size_t)blockIdx.x * D;
    float s = 0.0f;
    for (int i = threadIdx.x; i < D; i += 256) {
        float v = x[off + i] + r[off + i];
        row[i] = v; s += v;
    }
    red[threadIdx.x] = s; __syncthreads();
    for (int st = 128; st > 0; st >>= 1) { if (threadIdx.x < st) red[threadIdx.x] += red[threadIdx.x + st]; __syncthreads(); }
    if (threadIdx.x == 0) mv[0] = red[0] / D;
    __syncthreads();
    float m = mv[0];
    s = 0.0f;
    for (int i = threadIdx.x; i < D; i += 256) { float d = row[i] - m; s += d * d; }
    red[threadIdx.x] = s; __syncthreads();
    for (int st = 128; st > 0; st >>= 1) { if (threadIdx.x < st) red[threadIdx.x] += red[threadIdx.x + st]; __syncthreads(); }
    if (threadIdx.x == 0) mv[1] = red[0] / D;
    __syncthreads();
    float rs = rsqrtf(mv[1] + 1e-5f);
    for (int i = threadIdx.x; i < D; i += 256) {
        float v = (row[i] - m) * rs * g[i] + b[i];
        x[off + i] = v;
        xb[off + i] = (__bf16)v;
    }
}

// =====================================================================
// loss
// =====================================================================
__global__ __launch_bounds__(128) void loss_l(const float* __restrict__ pred,
                                              const float* __restrict__ target,
                                              const float* __restrict__ maskv,
                                              float* __restrict__ lm)
{
    const int g = blockIdx.x;
    __shared__ float red[128];
    int t = threadIdx.x;
    float s = 0.0f;
    if (t < 96) {
        float d = pred[(size_t)g * 96 + t] - target[(size_t)g * 96 + t];
        s = d * d;
    }
    red[t] = s; __syncthreads();
    for (int st = 64; st > 0; st >>= 1) { if (t < st) red[t] += red[t + st]; __syncthreads(); }
    if (t == 0) lm[g] = (red[0] / 96.0f) * maskv[g];
}

__global__ __launch_bounds__(1024) void loss_final(const float* __restrict__ lm,
                                                   const float* __restrict__ maskv,
                                                   float* __restrict__ out)
{
    __shared__ float r1[1024], r2[1024];
    int t = threadIdx.x;
    float a = 0.0f, b = 0.0f;
    for (int i = t; i < BB * NG; i += 1024) { a += lm[i]; b += maskv[i]; }
    r1[t] = a; r2[t] = b; __syncthreads();
    for (int st = 512; st > 0; st >>= 1) { if (t < st) { r1[t] += r1[t + st]; r2[t] += r2[t + st]; } __syncthreads(); }
    if (t == 0) out[0] = r1[0] / r2[0];
}

// =====================================================================
// host
// =====================================================================
extern "C" void kernel_launch(void* const* d_in, const int* in_sizes, int n_in,
                              void* d_out, int out_size, void* d_ws, size_t ws_size,
                              hipStream_t stream)
{
    (void)in_sizes; (void)n_in; (void)out_size; (void)ws_size;
    const float* xyz        = (const float*)d_in[0];
    const int*   fps_init   = (const int*)d_in[1];
    const int*   ids_shuf   = (const int*)d_in[2];
    const float* cw1 = (const float*)d_in[3];  const float* cb1 = (const float*)d_in[4];
    const float* g1  = (const float*)d_in[5];  const float* be1 = (const float*)d_in[6];
    const float* cw2 = (const float*)d_in[7];  const float* cb2 = (const float*)d_in[8];
    const float* g2  = (const float*)d_in[9];  const float* be2 = (const float*)d_in[10];
    const float* cw3 = (const float*)d_in[11]; const float* cb3 = (const float*)d_in[12];
    const float* g3  = (const float*)d_in[13]; const float* be3 = (const float*)d_in[14];
    const float* posw = (const float*)d_in[15]; const float* posb = (const float*)d_in[16];
    const float* eqw = (const float*)d_in[17]; const float* eqb = (const float*)d_in[18];
    const float* eow = (const float*)d_in[19]; const float* eob = (const float*)d_in[20];
    const float* el1g = (const float*)d_in[21]; const float* el1b = (const float*)d_in[22];
    const float* ef1w = (const float*)d_in[23]; const float* ef1b = (const float*)d_in[24];
    const float* ef2w = (const float*)d_in[25]; const float* ef2b = (const float*)d_in[26];
    const float* el2g = (const float*)d_in[27]; const float* el2b = (const float*)d_in[28];
    const float* dew = (const float*)d_in[29]; const float* deb = (const float*)d_in[30];
    const float* mtok = (const float*)d_in[31];
    const float* dpw = (const float*)d_in[32]; const float* dpb = (const float*)d_in[33];
    const float* dqw = (const float*)d_in[34]; const float* dqb = (const float*)d_in[35];
    const float* dow = (const float*)d_in[36]; const float* dob = (const float*)d_in[37];
    const float* dl1g = (const float*)d_in[38]; const float* dl1b = (const float*)d_in[39];
    const float* df1w = (const float*)d_in[40]; const float* df1b = (const float*)d_in[41];
    const float* df2w = (const float*)d_in[42]; const float* df2b = (const float*)d_in[43];
    const float* dl2g = (const float*)d_in[44]; const float* dl2b = (const float*)d_in[45];
    const float* prw = (const float*)d_in[46]; const float* prb = (const float*)d_in[47];
    float* out = (float*)d_out;
    float* pred = out + 1;
    float* maskv = out + 1 + (size_t)BB * NG * KNB * 3;

    // ---- workspace carve ----
    char* ws = (char*)d_ws;
    size_t off = 0;
    auto alloc = [&](size_t bytes) -> void* {
        void* p = ws + off;
        off = (off + bytes + 255) & ~(size_t)255;
        return p;
    };
    // persistent small / mid buffers
    double* st1 = (double*)alloc(128 * 8);
    double* st2 = (double*)alloc(256 * 8);
    double* st3 = (double*)alloc((size_t)32 * 1536 * 8);
    float* sc1 = (float*)alloc(64 * 4);  float* sh1 = (float*)alloc(64 * 4);
    float* sc2 = (float*)alloc(128 * 4); float* sh2 = (float*)alloc(128 * 4);
    float* a3 = (float*)alloc(768 * 4);  float* c3 = (float*)alloc(768 * 4);
    int* restore = (int*)alloc(4096 * 4);
    float* cxyz = (float*)alloc(12288 * 4);
    float* gn   = (float*)alloc((size_t)393216 * 4);
    __bf16* cw2b = (__bf16*)alloc((size_t)128 * 64 * 2);
    __bf16* cw3b = (__bf16*)alloc((size_t)768 * 128 * 2);
    float* xfull = (float*)alloc((size_t)4096 * 768 * 4);
    float* xe    = (float*)alloc((size_t)1024 * 768 * 4);
    __bf16* xeb  = (__bf16*)alloc((size_t)1024 * 768 * 2);
    float* qkve  = (float*)alloc((size_t)1024 * 2304 * 4);
    __bf16* oeb  = (__bf16*)alloc((size_t)1024 * 768 * 2);
    __bf16* fe1b = (__bf16*)alloc((size_t)1024 * 3072 * 2);
    float* yk    = (float*)alloc((size_t)1024 * 512 * 4);
    float* xd    = (float*)alloc((size_t)4096 * 512 * 4);
    __bf16* xdb  = (__bf16*)alloc((size_t)4096 * 512 * 2);
    float* qkvd  = (float*)alloc((size_t)4096 * 1536 * 4);
    __bf16* odb  = (__bf16*)alloc((size_t)4096 * 512 * 2);
    __bf16* fd1b = (__bf16*)alloc((size_t)4096 * 2048 * 2);
    float* tmpd  = (float*)alloc((size_t)4096 * 512 * 4);
    float* lm    = (float*)alloc(4096 * 4);

    // bf16 weight region (converted AFTER stage 2; aliased by stage-2 temps)
    __bf16* eqwb  = (__bf16*)alloc((size_t)NLE * 3 * DE * DE * 2);   // 42.5 MB
    __bf16* eowb  = (__bf16*)alloc((size_t)NLE * DE * DE * 2);       // 14.2 MB
    __bf16* ef1wb = (__bf16*)alloc((size_t)NLE * 4 * DE * DE * 2);   // 56.6 MB
    __bf16* ef2wb = (__bf16*)alloc((size_t)NLE * 4 * DE * DE * 2);   // 56.6 MB
    __bf16* dewb  = (__bf16*)alloc((size_t)DD * DE * 2);
    __bf16* dqwb  = (__bf16*)alloc((size_t)NLD * 3 * DD * DD * 2);   // 12.6 MB
    __bf16* dowb  = (__bf16*)alloc((size_t)NLD * DD * DD * 2);
    __bf16* df1wb = (__bf16*)alloc((size_t)NLD * 4 * DD * DD * 2);   // 16.8 MB
    __bf16* df2wb = (__bf16*)alloc((size_t)NLD * 4 * DD * DD * 2);   // 16.8 MB
    __bf16* prwb  = (__bf16*)alloc((size_t)128 * 512 * 2);           // padded 96->128 rows

    // stage-2 temps alias the weight region (weights converted after last use)
    char* U = (char*)eqwb;
    float*  h1   = (float*)U;                                   // 131072x64 f32 (33.6MB)
    __bf16* h1b  = (__bf16*)(U + (size_t)33554432);             // 16.8MB
    float*  h2   = (float*)(U + (size_t)50331648);              // 131072x128 f32 (67.1MB)
    __bf16* h2b  = (__bf16*)(U + (size_t)117440512);            // 33.6MB
    float*  gmax = (float*)(U + (size_t)150994944);             // 12.6MB
    float*  gmin = (float*)(U + (size_t)163577856);             // 12.6MB

    // zero the fp64 stats region (st1..st3 contiguous)
    size_t stats_bytes = (size_t)((char*)st3 + (size_t)32 * 1536 * 8 - (char*)st1);
    hipMemsetAsync((void*)st1, 0, stats_bytes, stream);

    auto cvt = [&](const float* src, __bf16* dst, size_t n) {
        int n8 = (int)(n / 8);
        cvt_bf16_kernel<<<(n8 + 255) / 256, 256, 0, stream>>>(src, dst, n8);
    };
    auto gemm = [&](const __bf16* A, const __bf16* W, const float* bias,
                    float* Cf, __bf16* Cb, int M, int N, int K, int relu) {
        dim3 grid((N + 127) / 128, M / 128);
        gemm_bf16<<<grid, 256, 0, stream>>>(A, W, bias, Cf, Cb, M, N, K, relu);
    };

    // small weights needed during stage 2 (persistent area)
    cvt(cw2, cw2b, 128 * 64);
    cvt(cw3, cw3b, 768 * 128);

    // ---- stage 1: FPS + KNN ----
    fps_kernel<<<BB, 1024, 0, stream>>>(xyz, fps_init, cxyz);
    knn_kernel<<<BB * NG, 256, 0, stream>>>(xyz, cxyz, gn);

    // ---- stage 2: mini-PointNet ----
    embed1_kernel<<<(131072 * 64 + 255) / 256, 256, 0, stream>>>(gn, cw1, cb1, h1);
    colstats_kernel<64><<<256, 256, 0, stream>>>(h1, st1, 131072);
    bn_finalize<<<1, 64, 0, stream>>>(st1, g1, be1, sc1, sh1, 64);
    bn_apply_bf16<<<(131072 * 64 + 255) / 256, 256, 0, stream>>>(h1, sc1, sh1, h1b, 131072 * 64, 64);
    gemm(h1b, cw2b, cb2, h2, nullptr, 131072, 128, 64, 0);
    colstats_kernel<128><<<256, 256, 0, stream>>>(h2, st2, 131072);
    bn_finalize<<<2, 64, 0, stream>>>(st2, g2, be2, sc2, sh2, 128);
    bn_apply_bf16<<<(131072 * 128 + 255) / 256, 256, 0, stream>>>(h2, sc2, sh2, h2b, 131072 * 128, 128);
    embed3_mfma<<<dim3(6, 1024), 256, 0, stream>>>(h2b, cw3b, cb3, gmax, gmin, st3);
    bn3_finalize<<<3, 256, 0, stream>>>(st3, g3, be3, a3, c3);
    tokens_pos<<<(4096 * 768 + 255) / 256, 256, 0, stream>>>(gmax, gmin, a3, c3, cxyz, posw, posb, xfull);

    // ---- stage 3: shuffle / mask ----
    restore_kernel<<<16, 256, 0, stream>>>(ids_shuf, restore);
    mask_kernel<<<16, 256, 0, stream>>>(restore, maskv);
    gather_xk<<<(BB * LK * DE + 255) / 256, 256, 0, stream>>>(xfull, ids_shuf, xe, xeb);

    // ---- weight conversion (after stage-2 temps are dead) ----
    cvt(eqw,  eqwb,  (size_t)NLE * 3 * DE * DE);
    cvt(eow,  eowb,  (size_t)NLE * DE * DE);
    cvt(ef1w, ef1wb, (size_t)NLE * 4 * DE * DE);
    cvt(ef2w, ef2wb, (size_t)NLE * 4 * DE * DE);
    cvt(dew,  dewb,  (size_t)DD * DE);
    cvt(dqw,  dqwb,  (size_t)NLD * 3 * DD * DD);
    cvt(dow,  dowb,  (size_t)NLD * DD * DD);
    cvt(df1w, df1wb, (size_t)NLD * 4 * DD * DD);
    cvt(df2w, df2wb, (size_t)NLD * 4 * DD * DD);
    cvt(prw,  prwb,  (size_t)96 * 512);
    hipMemsetAsync((void*)(prwb + (size_t)96 * 512), 0, (size_t)32 * 512 * 2, stream);

    // ---- stage 4: encoder (12 layers) ----
    for (int l = 0; l < NLE; ++l) {
        gemm(xeb, eqwb + (size_t)l * 3 * DE * DE, eqb + (size_t)l * 3 * DE, qkve, nullptr, 1024, 3 * DE, DE, 0);
        attn_kernel<LK, 64, 32, 12><<<BB * 12, 256, 0, stream>>>(qkve, oeb, 0.125f);
        gemm(oeb, eowb + (size_t)l * DE * DE, eob + (size_t)l * DE, xfull, nullptr, 1024, DE, DE, 0);
        ln_res<DE><<<BB * LK, 256, 0, stream>>>(xe, xfull, el1g + (size_t)l * DE, el1b + (size_t)l * DE, xeb);
        gemm(xeb, ef1wb + (size_t)l * 4 * DE * DE, ef1b + (size_t)l * 4 * DE, nullptr, fe1b, 1024, 4 * DE, DE, 1);
        gemm(fe1b, ef2wb + (size_t)l * DE * 4 * DE, ef2b + (size_t)l * DE, xfull, nullptr, 1024, DE, 4 * DE, 0);
        ln_res<DE><<<BB * LK, 256, 0, stream>>>(xe, xfull, el2g + (size_t)l * DE, el2b + (size_t)l * DE, xeb);
    }

    // ---- stage 5: decoder embed + mask tokens ----
    gemm(xeb, dewb, deb, yk, nullptr, 1024, DD, DE, 0);
    yd_build<<<(BB * NG * DD + 255) / 256, 256, 0, stream>>>(yk, restore, mtok, cxyz, dpw, dpb, xd, xdb);

    // ---- stage 6: decoder (8 layers) ----
    const float dsc = (float)(1.0 / sqrt(32.0));
    for (int l = 0; l < NLD; ++l) {
        gemm(xdb, dqwb + (size_t)l * 3 * DD * DD, dqb + (size_t)l * 3 * DD, qkvd, nullptr, 4096, 3 * DD, DD, 0);
        attn_kernel<NG, 32, 32, 16><<<BB * 16 * (NG / 32), 256, 0, stream>>>(qkvd, odb, dsc);
        gemm(odb, dowb + (size_t)l * DD * DD, dob + (size_t)l * DD, tmpd, nullptr, 4096, DD, DD, 0);
        ln_res<DD><<<BB * NG, 256, 0, stream>>>(xd, tmpd, dl1g + (size_t)l * DD, dl1b + (size_t)l * DD, xdb);
        gemm(xdb, df1wb + (size_t)l * 4 * DD * DD, df1b + (size_t)l * 4 * DD, nullptr, fd1b, 4096, 4 * DD, DD, 1);
        gemm(fd1b, df2wb + (size_t)l * DD * 4 * DD, df2b + (size_t)l * DD, tmpd, nullptr, 4096, DD, 4 * DD, 0);
        ln_res<DD><<<BB * NG, 256, 0, stream>>>(xd, tmpd, dl2g + (size_t)l * DD, dl2b + (size_t)l * DD, xdb);
    }

    // ---- stage 7: prediction + loss ----
    gemm(xdb, prwb, prb, pred, nullptr, 4096, 96, 512, 0);
    loss_l<<<BB * NG, 128, 0, stream>>>(pred, gn, maskv, lm);
    loss_final<<<1, 1024, 0, stream>>>(lm, maskv, out);
}

// Round 4
// 4343.823 us; speedup vs baseline: 5.3358x; 1.0257x over previous
//
#include <hip/hip_runtime.h>
#include <cmath>

// ---------------- problem constants ----------------
#define BB 32          // batch
#define NPTS 8192      // points per cloud
#define NG 128         // groups
#define KNB 32         // neighbors per group
#define LK 32          // len_keep
#define DE 768         // encoder dim
#define DD 512         // decoder dim
#define NLE 12
#define NLD 8

typedef __bf16 bf16x8 __attribute__((ext_vector_type(8)));
typedef float  f32x4  __attribute__((ext_vector_type(4)));

static __device__ __forceinline__ bf16x8 pack8(float4 a, float4 b) {
    bf16x8 h;
    h[0] = (__bf16)a.x; h[1] = (__bf16)a.y; h[2] = (__bf16)a.z; h[3] = (__bf16)a.w;
    h[4] = (__bf16)b.x; h[5] = (__bf16)b.y; h[6] = (__bf16)b.z; h[7] = (__bf16)b.w;
    return h;
}

// async global->LDS 16B copy: per-wave, lane l writes ldsbase + l*16
static __device__ __forceinline__ void gload16(const __bf16* g, __bf16* l) {
    __builtin_amdgcn_global_load_lds(
        (const __attribute__((address_space(1))) void*)g,
        (__attribute__((address_space(3))) void*)l,
        16, 0, 0);
}

// =====================================================================
// FPS: one block per batch, 256 threads. Points in LDS, dmin in REGISTERS
// (32 pts/thread), wave-shuffle argmax, redundant cross-wave reduce.
// =====================================================================
__global__ __launch_bounds__(256) void fps_kernel(
    const float* __restrict__ xyz, const int* __restrict__ init,
    float* __restrict__ cxyz)
{
#pragma clang fp contract(off)
    const int b = blockIdx.x;
    const float* P = xyz + (size_t)b * NPTS * 3;
    __shared__ float px[NPTS], py[NPTS], pz[NPTS];
    __shared__ float rv4[4];
    __shared__ int   ri4[4];
    const int tid = threadIdx.x;
    float dmin[32];
    for (int n = tid; n < NPTS; n += 256) {
        px[n] = P[n * 3 + 0]; py[n] = P[n * 3 + 1]; pz[n] = P[n * 3 + 2];
    }
    #pragma unroll
    for (int k = 0; k < 32; ++k) dmin[k] = 1e10f;
    int far = init[b];
    __syncthreads();
    for (int t = 0; t < NG; ++t) {
        float cx = px[far], cy = py[far], cz = pz[far];
        if (tid == 0) {
            cxyz[(b * NG + t) * 3 + 0] = cx;
            cxyz[(b * NG + t) * 3 + 1] = cy;
            cxyz[(b * NG + t) * 3 + 2] = cz;
        }
        float best = -1.0f; int bi = 0;
        #pragma unroll
        for (int k = 0; k < 32; ++k) {
            int n = tid + (k << 8);
            float dx = px[n] - cx, dy = py[n] - cy, dz = pz[n] - cz;
            float d = dx * dx + dy * dy + dz * dz;
            float dm = dmin[k];
            if (d < dm) dm = d;
            dmin[k] = dm;
            if (dm > best) { best = dm; bi = n; }   // strict > keeps lowest index
        }
        #pragma unroll
        for (int d = 32; d >= 1; d >>= 1) {
            float v2 = __shfl_down(best, d); int i2 = __shfl_down(bi, d);
            if (v2 > best || (v2 == best && i2 < bi)) { best = v2; bi = i2; }
        }
        if ((tid & 63) == 0) { rv4[tid >> 6] = best; ri4[tid >> 6] = bi; }
        __syncthreads();
        float bv = rv4[0]; int bbi = ri4[0];
        #pragma unroll
        for (int w = 1; w < 4; ++w) {
            float v2 = rv4[w]; int i2 = ri4[w];
            if (v2 > bv || (v2 == bv && i2 < bbi)) { bv = v2; bbi = i2; }
        }
        far = bbi;                   // all threads compute identical result
        __syncthreads();             // WAR protect rv4/ri4
    }
}

// =====================================================================
// KNN: one block per (b,m). dist computed once; per-thread persistent
// (best,idx); per round: wave-shuffle argmin + owner-only rescan.
// =====================================================================
__global__ __launch_bounds__(256) void knn_kernel(
    const float* __restrict__ xyz, const float* __restrict__ cxyz,
    float* __restrict__ gn)
{
#pragma clang fp contract(off)
    const int bm = blockIdx.x;
    const int b = bm / NG;
    const float* P = xyz + (size_t)b * NPTS * 3;
    __shared__ float dist[NPTS];
    __shared__ float rv4[4];
    __shared__ int   ri4[4];
    __shared__ int   order[KNB];
    const int tid = threadIdx.x;
    const float cx = cxyz[bm * 3 + 0], cy = cxyz[bm * 3 + 1], cz = cxyz[bm * 3 + 2];
    const float c2 = cx * cx + cy * cy + cz * cz;
    float best = 1e31f; int bi = 1 << 30;
    #pragma unroll
    for (int j = 0; j < NPTS / 256; ++j) {
        int n = tid + (j << 8);
        float x = P[n * 3 + 0], y = P[n * 3 + 1], z = P[n * 3 + 2];
        float x2 = x * x + y * y + z * z;
        float dt = cx * x + cy * y + cz * z;
        float v = (c2 + x2) - 2.0f * dt;
        dist[n] = v;
        if (v < best) { best = v; bi = n; }        // strict < keeps lowest index
    }
    for (int r = 0; r < KNB; ++r) {
        float v = best; int i = bi;
        #pragma unroll
        for (int d = 32; d >= 1; d >>= 1) {
            float v2 = __shfl_down(v, d); int i2 = __shfl_down(i, d);
            if (v2 < v || (v2 == v && i2 < i)) { v = v2; i = i2; }
        }
        if ((tid & 63) == 0) { rv4[tid >> 6] = v; ri4[tid >> 6] = i; }
        __syncthreads();
        float bv = rv4[0]; int bn = ri4[0];
        #pragma unroll
        for (int w = 1; w < 4; ++w) {
            float v2 = rv4[w]; int i2 = ri4[w];
            if (v2 < bv || (v2 == bv && i2 < bn)) { bv = v2; bn = i2; }
        }
        if (tid == (bn & 255)) {
            order[r] = bn;
            dist[bn] = 1e30f;
            best = 1e31f; bi = 1 << 30;
            #pragma unroll
            for (int j = 0; j < NPTS / 256; ++j) {
                int n = tid + (j << 8);
                float dv = dist[n];
                if (dv < best) { best = dv; bi = n; }
            }
        }
        __syncthreads();
    }
    if (tid < KNB) {
        int n = order[tid];
        gn[((size_t)bm * KNB + tid) * 3 + 0] = P[n * 3 + 0] - cx;
        gn[((size_t)bm * KNB + tid) * 3 + 1] = P[n * 3 + 1] - cy;
        gn[((size_t)bm * KNB + tid) * 3 + 2] = P[n * 3 + 2] - cz;
    }
}

// =====================================================================
// f32 -> bf16 bulk convert (n multiple of 8)
// =====================================================================
__global__ void cvt_bf16_kernel(const float* __restrict__ src, __bf16* __restrict__ dst, int n8)
{
    int i = blockIdx.x * 256 + threadIdx.x;
    if (i >= n8) return;
    const float4* p = (const float4*)(src + (size_t)i * 8);
    *(bf16x8*)(dst + (size_t)i * 8) = pack8(p[0], p[1]);
}

// =====================================================================
// embed1: (131072,3)@(64,3)^T + bias
// =====================================================================
__global__ void embed1_kernel(const float* __restrict__ gn, const float* __restrict__ w,
                              const float* __restrict__ bias, float* __restrict__ h1)
{
    int i = blockIdx.x * 256 + threadIdx.x;
    if (i >= 131072 * 64) return;
    int r = i >> 6, c = i & 63;
    const float* p = gn + (size_t)r * 3;
    h1[i] = p[0] * w[c * 3 + 0] + p[1] * w[c * 3 + 1] + p[2] * w[c * 3 + 2] + bias[c];
}

// =====================================================================
// column stats (sum, sumsq) in double
// =====================================================================
template <int C>
__global__ __launch_bounds__(256) void colstats_kernel(const float* __restrict__ X,
                                                       double* __restrict__ st, int Mrows)
{
    constexpr int RL = 256 / C;
    const int c = threadIdx.x % C;
    const int rl = threadIdx.x / C;
    double s = 0.0, s2 = 0.0;
    int rows_per_block = (Mrows + gridDim.x - 1) / gridDim.x;
    int r0 = blockIdx.x * rows_per_block;
    int r1 = min(r0 + rows_per_block, Mrows);
    for (int r = r0 + rl; r < r1; r += RL) {
        float v = X[(size_t)r * C + c];
        s += v; s2 += (double)v * v;
    }
    __shared__ double sh[2][256];
    sh[0][threadIdx.x] = s; sh[1][threadIdx.x] = s2;
    __syncthreads();
    if (rl == 0) {
        for (int j = 1; j < RL; ++j) { s += sh[0][j * C + c]; s2 += sh[1][j * C + c]; }
        atomicAdd(&st[c], s);
        atomicAdd(&st[C + c], s2);
    }
}

__global__ void bn_finalize(const double* __restrict__ st, const float* __restrict__ g,
                            const float* __restrict__ be, float* __restrict__ sc,
                            float* __restrict__ shb, int C)
{
    int c = blockIdx.x * 64 + threadIdx.x;
    if (c >= C) return;
    double m = st[c] / 131072.0;
    double var = st[C + c] / 131072.0 - m * m;
    if (var < 0.0) var = 0.0;
    float rs = rsqrtf((float)var + 1e-5f);
    sc[c] = rs * g[c];
    shb[c] = be[c] - (float)m * rs * g[c];
}

// BN affine + relu, f32 in -> bf16 out
__global__ void bn_apply_bf16(const float* __restrict__ x, const float* __restrict__ sc,
                              const float* __restrict__ shb, __bf16* __restrict__ y,
                              int total, int C)
{
    int i = blockIdx.x * 256 + threadIdx.x;
    if (i >= total) return;
    int c = i % C;
    float v = x[i] * sc[c] + shb[c];
    v = fmaxf(v, 0.0f);
    y[i] = (__bf16)v;
}

// =====================================================================
// bf16 MFMA GEMM: C(M,N) = A(M,K) @ W(N,K)^T + bias (optional relu)
// BN=128, BK=64, 256 thr, double-buffered LDS, global_load_lds staging,
// source pre-swizzle + XOR-swizzled ds_read. BM templated (64 or 128).
// =====================================================================
template <int BM, int WM, int WN>
__global__ __launch_bounds__(256) void gemm_bf16(
    const __bf16* __restrict__ A, const __bf16* __restrict__ W,
    const float* __restrict__ bias, float* __restrict__ Cf, __bf16* __restrict__ Cb,
    int M, int N, int K, int relu)
{
    constexpr int MR = BM / WM / 16;      // m-frags per wave
    constexpr int NR = 128 / WN / 16;     // n-frags per wave
    constexpr int CA = BM * 8 / 256;      // A 16B-chunks per thread
    __shared__ __bf16 As[2][BM * 64];
    __shared__ __bf16 Ws[2][128 * 64];
    const int tid = threadIdx.x;
    const int lane = tid & 63;
    const int wave = tid >> 6;
    const int wm = wave / WN, wn = wave % WN;
    const int m0 = blockIdx.y * BM, n0 = blockIdx.x * 128;
    (void)M;

    f32x4 acc[MR][NR] = {};

    auto stage = [&](int buf, int kt) {
        #pragma unroll
        for (int j = 0; j < CA; ++j) {
            int cb = j * 256 + (wave << 6);
            int c  = cb + lane;
            int row = c >> 3;
            int kcs = (c & 7) ^ (row & 7);
            gload16(A + (size_t)(m0 + row) * K + kt + kcs * 8, &As[buf][cb * 8]);
        }
        #pragma unroll
        for (int j = 0; j < 4; ++j) {
            int cb = j * 256 + (wave << 6);
            int c  = cb + lane;
            int row = c >> 3;
            int kcs = (c & 7) ^ (row & 7);
            gload16(W + (size_t)(n0 + row) * K + kt + kcs * 8, &Ws[buf][cb * 8]);
        }
    };
    auto compute = [&](int buf) {
        #pragma unroll
        for (int ks = 0; ks < 2; ++ks) {
            bf16x8 af[MR], bfr[NR];
            int kc = ks * 4 + (lane >> 4);
            #pragma unroll
            for (int i = 0; i < MR; ++i) {
                int rowA = wm * (BM / WM) + i * 16 + (lane & 15);
                af[i] = *(bf16x8*)&As[buf][rowA * 64 + ((kc ^ (rowA & 7)) * 8)];
            }
            #pragma unroll
            for (int j = 0; j < NR; ++j) {
                int rowB = wn * (128 / WN) + j * 16 + (lane & 15);
                bfr[j] = *(bf16x8*)&Ws[buf][rowB * 64 + ((kc ^ (rowB & 7)) * 8)];
            }
            #pragma unroll
            for (int i = 0; i < MR; ++i)
                #pragma unroll
                for (int j = 0; j < NR; ++j)
                    acc[i][j] = __builtin_amdgcn_mfma_f32_16x16x32_bf16(af[i], bfr[j], acc[i][j], 0, 0, 0);
        }
    };

    stage(0, 0);
    asm volatile("s_waitcnt vmcnt(0)" ::: "memory");
    __syncthreads();
    const int nt = K >> 6;
    int cur = 0;
    for (int t = 0; t < nt; ++t) {
        if (t + 1 < nt) stage(cur ^ 1, (t + 1) << 6);
        compute(cur);
        asm volatile("s_waitcnt vmcnt(0)" ::: "memory");
        __syncthreads();
        cur ^= 1;
    }

    #pragma unroll
    for (int j = 0; j < NR; ++j) {
        int col = n0 + wn * (128 / WN) + j * 16 + (lane & 15);
        if (col >= N) continue;
        float bv = bias[col];
        #pragma unroll
        for (int i = 0; i < MR; ++i) {
            #pragma unroll
            for (int r = 0; r < 4; ++r) {
                int rowm = m0 + wm * (BM / WM) + i * 16 + (lane >> 4) * 4 + r;
                float v = acc[i][j][r] + bv;
                if (relu) v = fmaxf(v, 0.0f);
                if (Cf) Cf[(size_t)rowm * N + col] = v;
                if (Cb) Cb[(size_t)rowm * N + col] = (__bf16)v;
            }
        }
    }
}

// =====================================================================
// embed3 via MFMA: (131072,768) = h2b(131072,128) @ cw3b^T, fused epilogue:
// bias + per-group(32-row) max/min + per-column sum/sumsq. grid (6,1024)
// =====================================================================
__global__ __launch_bounds__(256) void embed3_mfma(
    const __bf16* __restrict__ A, const __bf16* __restrict__ W,
    const float* __restrict__ cb3,
    float* __restrict__ gmax, float* __restrict__ gmin, double* __restrict__ st3)
{
    __shared__ __bf16 As[2][128 * 64];
    __shared__ __bf16 Ws[2][128 * 64];
    const int tid = threadIdx.x;
    const int lane = tid & 63;
    const int wave = tid >> 6;
    const int wm = wave >> 1, wn = wave & 1;
    const int m0 = blockIdx.y * 128, n0 = blockIdx.x * 128;
    const int K = 128;

    f32x4 acc[4][4] = {};

    auto stage = [&](int buf, int kt) {
        #pragma unroll
        for (int j = 0; j < 4; ++j) {
            int cb = j * 256 + (wave << 6);
            int c  = cb + lane;
            int row = c >> 3;
            int kcs = (c & 7) ^ (row & 7);
            gload16(A + (size_t)(m0 + row) * K + kt + kcs * 8, &As[buf][cb * 8]);
            gload16(W + (size_t)(n0 + row) * K + kt + kcs * 8, &Ws[buf][cb * 8]);
        }
    };
    auto compute = [&](int buf) {
        #pragma unroll
        for (int ks = 0; ks < 2; ++ks) {
            bf16x8 af[4], bfr[4];
            int kc = ks * 4 + (lane >> 4);
            #pragma unroll
            for (int i = 0; i < 4; ++i) {
                int rowA = wm * 64 + i * 16 + (lane & 15);
                af[i] = *(bf16x8*)&As[buf][rowA * 64 + ((kc ^ (rowA & 7)) * 8)];
                int rowB = wn * 64 + i * 16 + (lane & 15);
                bfr[i] = *(bf16x8*)&Ws[buf][rowB * 64 + ((kc ^ (rowB & 7)) * 8)];
            }
            #pragma unroll
            for (int i = 0; i < 4; ++i)
                #pragma unroll
                for (int j = 0; j < 4; ++j)
                    acc[i][j] = __builtin_amdgcn_mfma_f32_16x16x32_bf16(af[i], bfr[j], acc[i][j], 0, 0, 0);
        }
    };

    stage(0, 0);
    asm volatile("s_waitcnt vmcnt(0)" ::: "memory");
    __syncthreads();
    stage(1, 64);
    compute(0);
    asm volatile("s_waitcnt vmcnt(0)" ::: "memory");
    __syncthreads();
    compute(1);

    #pragma unroll
    for (int j = 0; j < 4; ++j) {
        int col = n0 + wn * 64 + j * 16 + (lane & 15);
        float bv = cb3[col];
        float stot = 0.0f, s2tot = 0.0f;
        #pragma unroll
        for (int gi = 0; gi < 2; ++gi) {
            float mx = -1e30f, mn = 1e30f, s = 0.0f, s2 = 0.0f;
            #pragma unroll
            for (int ii = 0; ii < 2; ++ii) {
                f32x4 a = acc[gi * 2 + ii][j];
                #pragma unroll
                for (int r = 0; r < 4; ++r) {
                    float v = a[r] + bv;
                    mx = fmaxf(mx, v); mn = fminf(mn, v);
                    s += v; s2 += v * v;
                }
            }
            #pragma unroll
            for (int d = 16; d < 64; d <<= 1) {
                mx = fmaxf(mx, __shfl_xor(mx, d));
                mn = fminf(mn, __shfl_xor(mn, d));
                s  += __shfl_xor(s, d);
                s2 += __shfl_xor(s2, d);
            }
            stot += s; s2tot += s2;
            if (lane < 16) {
                int g = (m0 >> 5) + wm * 2 + gi;
                gmax[(size_t)g * 768 + col] = mx;
                gmin[(size_t)g * 768 + col] = mn;
            }
        }
        if (lane < 16) {
            double* stp = st3 + (size_t)(blockIdx.y & 31) * 1536;
            atomicAdd(&stp[col], (double)stot);
            atomicAdd(&stp[768 + col], (double)s2tot);
        }
    }
}

__global__ void bn3_finalize(const double* __restrict__ st3, const float* __restrict__ g,
                             const float* __restrict__ be, float* __restrict__ a3,
                             float* __restrict__ c3)
{
    int c = blockIdx.x * 256 + threadIdx.x;
    if (c >= 768) return;
    double s = 0.0, s2 = 0.0;
    for (int p = 0; p < 32; ++p) { s += st3[(size_t)p * 1536 + c]; s2 += st3[(size_t)p * 1536 + 768 + c]; }
    double m = s / 131072.0;
    double var = s2 / 131072.0 - m * m;
    if (var < 0.0) var = 0.0;
    float rs = rsqrtf((float)var + 1e-5f);
    a3[c] = rs * g[c];
    c3[c] = be[c] - (float)m * rs * g[c];
}

// tokens = affine(max/min) ; x = tokens + cxyz@pos_w^T + pos_b
__global__ void tokens_pos(const float* __restrict__ gmax, const float* __restrict__ gmin,
                           const float* __restrict__ a3, const float* __restrict__ c3,
                           const float* __restrict__ cxyz, const float* __restrict__ posw,
                           const float* __restrict__ posb, float* __restrict__ x)
{
    int i = blockIdx.x * 256 + threadIdx.x;
    if (i >= 4096 * 768) return;
    int c = i % 768, g = i / 768;
    float a = a3[c];
    float tok = (a >= 0.0f ? a * gmax[i] : a * gmin[i]) + c3[c];
    float px = cxyz[g * 3 + 0], py = cxyz[g * 3 + 1], pz = cxyz[g * 3 + 2];
    x[i] = tok + px * posw[c * 3 + 0] + py * posw[c * 3 + 1] + pz * posw[c * 3 + 2] + posb[c];
}

__global__ void restore_kernel(const int* __restrict__ shuffle, int* __restrict__ restore)
{
    int j = blockIdx.x * 256 + threadIdx.x;
    if (j >= BB * NG) return;
    int b = j / NG, p = j % NG;
    restore[b * NG + shuffle[j]] = p;
}

__global__ void mask_kernel(const int* __restrict__ restore, float* __restrict__ maskv)
{
    int i = blockIdx.x * 256 + threadIdx.x;
    if (i >= BB * NG) return;
    maskv[i] = (restore[i] < LK) ? 0.0f : 1.0f;
}

__global__ void gather_xk(const float* __restrict__ xfull, const int* __restrict__ shuffle,
                          float* __restrict__ xe, __bf16* __restrict__ xeb)
{
    int i = blockIdx.x * 256 + threadIdx.x;
    if (i >= BB * LK * DE) return;
    int c = i % DE;
    int s = (i / DE) % LK;
    int b = i / (DE * LK);
    float v = xfull[((size_t)b * NG + shuffle[b * NG + s]) * DE + c];
    xe[i] = v;
    xeb[i] = (__bf16)v;
}

__global__ void yd_build(const float* __restrict__ yk, const int* __restrict__ restore,
                         const float* __restrict__ mtok, const float* __restrict__ cxyz,
                         const float* __restrict__ dpw, const float* __restrict__ dpb,
                         float* __restrict__ xd, __bf16* __restrict__ xdb)
{
    int i = blockIdx.x * 256 + threadIdx.x;
    if (i >= BB * NG * DD) return;
    int c = i % DD;
    int g = i / DD;
    int b = g / NG;
    int r = restore[g];
    float base = (r < LK) ? yk[((size_t)b * LK + r) * DD + c] : mtok[c];
    float px = cxyz[g * 3 + 0], py = cxyz[g * 3 + 1], pz = cxyz[g * 3 + 2];
    float v = base + px * dpw[c * 3 + 0] + py * dpw[c * 3 + 1] + pz * dpw[c * 3 + 2] + dpb[c];
    xd[i] = v;
    xdb[i] = (__bf16)v;
}

// =====================================================================
// attention: block per (b, h, q-tile). f32 in, bf16 out.
// =====================================================================
template <int S, int DH, int QT, int NH>
__global__ __launch_bounds__(256) void attn_kernel(const float* __restrict__ qkv,
                                                   __bf16* __restrict__ o, float scale)
{
    constexpr int D = NH * DH;
    constexpr int NT = S / QT;
    __shared__ float Ks[S][DH];
    __shared__ float Vs[S][DH];
    __shared__ float Qs[QT][DH];
    __shared__ float P[QT][S];
    const int t = blockIdx.x % NT;
    const int h = (blockIdx.x / NT) % NH;
    const int b = blockIdx.x / (NT * NH);
    const float* base = qkv + (size_t)b * S * 3 * D + h * DH;
    for (int i = threadIdx.x; i < S * DH; i += 256) {
        int s = i / DH, d = i % DH;
        Ks[s][d] = base[(size_t)s * 3 * D + D + d];
        Vs[s][d] = base[(size_t)s * 3 * D + 2 * D + d];
    }
    for (int i = threadIdx.x; i < QT * DH; i += 256) {
        int qi = i / DH, d = i % DH;
        Qs[qi][d] = base[(size_t)(t * QT + qi) * 3 * D + d];
    }
    __syncthreads();
    for (int i = threadIdx.x; i < QT * S; i += 256) {
        int qi = i / S, s = i % S;
        float acc = 0.0f;
        #pragma unroll 8
        for (int d = 0; d < DH; ++d) acc += Qs[qi][d] * Ks[s][d];
        P[qi][s] = acc * scale;
    }
    __syncthreads();
    if (threadIdx.x < QT) {
        int qi = threadIdx.x;
        float mx = -1e30f;
        for (int s = 0; s < S; ++s) mx = fmaxf(mx, P[qi][s]);
        float sum = 0.0f;
        for (int s = 0; s < S; ++s) { float e = expf(P[qi][s] - mx); P[qi][s] = e; sum += e; }
        float inv = 1.0f / sum;
        for (int s = 0; s < S; ++s) P[qi][s] *= inv;
    }
    __syncthreads();
    __bf16* ob = o + (size_t)b * S * D + h * DH;
    for (int i = threadIdx.x; i < QT * DH; i += 256) {
        int qi = i / DH, d = i % DH;
        float acc = 0.0f;
        for (int s = 0; s < S; ++s) acc += P[qi][s] * Vs[s][d];
        ob[(size_t)(t * QT + qi) * D + d] = (__bf16)acc;
    }
}

// =====================================================================
// LayerNorm with residual, in place: x = LN(x + r) * g + b ; bf16 copy out
// =====================================================================
template <int D>
__global__ __launch_bounds__(256) void ln_res(float* __restrict__ x, const float* __restrict__ r,
                                              const float* __restrict__ g, const float* __restrict__ b,
                                              __bf16* __restrict__ xb)
{
    __shared__ float row[D];
    __shared__ float red[256];
    __shared__ float mv[2];
    const size_t off = (size_t)blockIdx.x * D;
    float s = 0.0f;
    for (int i = threadIdx.x; i < D; i += 256) {
        float v = x[off + i] + r[off + i];
        row[i] = v; s += v;
    }
    red[threadIdx.x] = s; __syncthreads();
    for (int st = 128; st > 0; st >>= 1) { if (threadIdx.x < st) red[threadIdx.x] += red[threadIdx.x + st]; __syncthreads(); }
    if (threadIdx.x == 0) mv[0] = red[0] / D;
    __syncthreads();
    float m = mv[0];
    s = 0.0f;
    for (int i = threadIdx.x; i < D; i += 256) { float d = row[i] - m; s += d * d; }
    red[threadIdx.x] = s; __syncthreads();
    for (int st = 128; st > 0; st >>= 1) { if (threadIdx.x < st) red[threadIdx.x] += red[threadIdx.x + st]; __syncthreads(); }
    if (threadIdx.x == 0) mv[1] = red[0] / D;
    __syncthreads();
    float rs = rsqrtf(mv[1] + 1e-5f);
    for (int i = threadIdx.x; i < D; i += 256) {
        float v = (row[i] - m) * rs * g[i] + b[i];
        x[off + i] = v;
        xb[off + i] = (__bf16)v;
    }
}

// =====================================================================
// loss
// =====================================================================
__global__ __launch_bounds__(128) void loss_l(const float* __restrict__ pred,
                                              const float* __restrict__ target,
                                              const float* __restrict__ maskv,
                                              float* __restrict__ lm)
{
    const int g = blockIdx.x;
    __shared__ float red[128];
    int t = threadIdx.x;
    float s = 0.0f;
    if (t < 96) {
        float d = pred[(size_t)g * 96 + t] - target[(size_t)g * 96 + t];
        s = d * d;
    }
    red[t] = s; __syncthreads();
    for (int st = 64; st > 0; st >>= 1) { if (t < st) red[t] += red[t + st]; __syncthreads(); }
    if (t == 0) lm[g] = (red[0] / 96.0f) * maskv[g];
}

__global__ __launch_bounds__(1024) void loss_final(const float* __restrict__ lm,
                                                   const float* __restrict__ maskv,
                                                   float* __restrict__ out)
{
    __shared__ float r1[1024], r2[1024];
    int t = threadIdx.x;
    float a = 0.0f, b = 0.0f;
    for (int i = t; i < BB * NG; i += 1024) { a += lm[i]; b += maskv[i]; }
    r1[t] = a; r2[t] = b; __syncthreads();
    for (int st = 512; st > 0; st >>= 1) { if (t < st) { r1[t] += r1[t + st]; r2[t] += r2[t + st]; } __syncthreads(); }
    if (t == 0) out[0] = r1[0] / r2[0];
}

// =====================================================================
// host
// =====================================================================
extern "C" void kernel_launch(void* const* d_in, const int* in_sizes, int n_in,
                              void* d_out, int out_size, void* d_ws, size_t ws_size,
                              hipStream_t stream)
{
    (void)in_sizes; (void)n_in; (void)out_size; (void)ws_size;
    const float* xyz        = (const float*)d_in[0];
    const int*   fps_init   = (const int*)d_in[1];
    const int*   ids_shuf   = (const int*)d_in[2];
    const float* cw1 = (const float*)d_in[3];  const float* cb1 = (const float*)d_in[4];
    const float* g1  = (const float*)d_in[5];  const float* be1 = (const float*)d_in[6];
    const float* cw2 = (const float*)d_in[7];  const float* cb2 = (const float*)d_in[8];
    const float* g2  = (const float*)d_in[9];  const float* be2 = (const float*)d_in[10];
    const float* cw3 = (const float*)d_in[11]; const float* cb3 = (const float*)d_in[12];
    const float* g3  = (const float*)d_in[13]; const float* be3 = (const float*)d_in[14];
    const float* posw = (const float*)d_in[15]; const float* posb = (const float*)d_in[16];
    const float* eqw = (const float*)d_in[17]; const float* eqb = (const float*)d_in[18];
    const float* eow = (const float*)d_in[19]; const float* eob = (const float*)d_in[20];
    const float* el1g = (const float*)d_in[21]; const float* el1b = (const float*)d_in[22];
    const float* ef1w = (const float*)d_in[23]; const float* ef1b = (const float*)d_in[24];
    const float* ef2w = (const float*)d_in[25]; const float* ef2b = (const float*)d_in[26];
    const float* el2g = (const float*)d_in[27]; const float* el2b = (const float*)d_in[28];
    const float* dew = (const float*)d_in[29]; const float* deb = (const float*)d_in[30];
    const float* mtok = (const float*)d_in[31];
    const float* dpw = (const float*)d_in[32]; const float* dpb = (const float*)d_in[33];
    const float* dqw = (const float*)d_in[34]; const float* dqb = (const float*)d_in[35];
    const float* dow = (const float*)d_in[36]; const float* dob = (const float*)d_in[37];
    const float* dl1g = (const float*)d_in[38]; const float* dl1b = (const float*)d_in[39];
    const float* df1w = (const float*)d_in[40]; const float* df1b = (const float*)d_in[41];
    const float* df2w = (const float*)d_in[42]; const float* df2b = (const float*)d_in[43];
    const float* dl2g = (const float*)d_in[44]; const float* dl2b = (const float*)d_in[45];
    const float* prw = (const float*)d_in[46]; const float* prb = (const float*)d_in[47];
    float* out = (float*)d_out;
    float* pred = out + 1;
    float* maskv = out + 1 + (size_t)BB * NG * KNB * 3;

    // ---- workspace carve ----
    char* ws = (char*)d_ws;
    size_t off = 0;
    auto alloc = [&](size_t bytes) -> void* {
        void* p = ws + off;
        off = (off + bytes + 255) & ~(size_t)255;
        return p;
    };
    double* st1 = (double*)alloc(128 * 8);
    double* st2 = (double*)alloc(256 * 8);
    double* st3 = (double*)alloc((size_t)32 * 1536 * 8);
    float* sc1 = (float*)alloc(64 * 4);  float* sh1 = (float*)alloc(64 * 4);
    float* sc2 = (float*)alloc(128 * 4); float* sh2 = (float*)alloc(128 * 4);
    float* a3 = (float*)alloc(768 * 4);  float* c3 = (float*)alloc(768 * 4);
    int* restore = (int*)alloc(4096 * 4);
    float* cxyz = (float*)alloc(12288 * 4);
    float* gn   = (float*)alloc((size_t)393216 * 4);
    __bf16* cw2b = (__bf16*)alloc((size_t)128 * 64 * 2);
    __bf16* cw3b = (__bf16*)alloc((size_t)768 * 128 * 2);
    float* xfull = (float*)alloc((size_t)4096 * 768 * 4);
    float* xe    = (float*)alloc((size_t)1024 * 768 * 4);
    __bf16* xeb  = (__bf16*)alloc((size_t)1024 * 768 * 2);
    float* qkve  = (float*)alloc((size_t)1024 * 2304 * 4);
    __bf16* oeb  = (__bf16*)alloc((size_t)1024 * 768 * 2);
    __bf16* fe1b = (__bf16*)alloc((size_t)1024 * 3072 * 2);
    float* yk    = (float*)alloc((size_t)1024 * 512 * 4);
    float* xd    = (float*)alloc((size_t)4096 * 512 * 4);
    __bf16* xdb  = (__bf16*)alloc((size_t)4096 * 512 * 2);
    float* qkvd  = (float*)alloc((size_t)4096 * 1536 * 4);
    __bf16* odb  = (__bf16*)alloc((size_t)4096 * 512 * 2);
    __bf16* fd1b = (__bf16*)alloc((size_t)4096 * 2048 * 2);
    float* tmpd  = (float*)alloc((size_t)4096 * 512 * 4);
    float* lm    = (float*)alloc(4096 * 4);

    __bf16* eqwb  = (__bf16*)alloc((size_t)NLE * 3 * DE * DE * 2);
    __bf16* eowb  = (__bf16*)alloc((size_t)NLE * DE * DE * 2);
    __bf16* ef1wb = (__bf16*)alloc((size_t)NLE * 4 * DE * DE * 2);
    __bf16* ef2wb = (__bf16*)alloc((size_t)NLE * 4 * DE * DE * 2);
    __bf16* dewb  = (__bf16*)alloc((size_t)DD * DE * 2);
    __bf16* dqwb  = (__bf16*)alloc((size_t)NLD * 3 * DD * DD * 2);
    __bf16* dowb  = (__bf16*)alloc((size_t)NLD * DD * DD * 2);
    __bf16* df1wb = (__bf16*)alloc((size_t)NLD * 4 * DD * DD * 2);
    __bf16* df2wb = (__bf16*)alloc((size_t)NLD * 4 * DD * DD * 2);
    __bf16* prwb  = (__bf16*)alloc((size_t)128 * 512 * 2);

    char* U = (char*)eqwb;
    float*  h1   = (float*)U;
    __bf16* h1b  = (__bf16*)(U + (size_t)33554432);
    float*  h2   = (float*)(U + (size_t)50331648);
    __bf16* h2b  = (__bf16*)(U + (size_t)117440512);
    float*  gmax = (float*)(U + (size_t)150994944);
    float*  gmin = (float*)(U + (size_t)163577856);

    size_t stats_bytes = (size_t)((char*)st3 + (size_t)32 * 1536 * 8 - (char*)st1);
    hipMemsetAsync((void*)st1, 0, stats_bytes, stream);

    auto cvt = [&](const float* src, __bf16* dst, size_t n) {
        int n8 = (int)(n / 8);
        cvt_bf16_kernel<<<(n8 + 255) / 256, 256, 0, stream>>>(src, dst, n8);
    };
    auto gemm = [&](const __bf16* A, const __bf16* Wt, const float* bias,
                    float* Cf, __bf16* Cb, int M, int N, int K, int relu) {
        int nb128 = ((N + 127) / 128) * (M / 128);
        if (nb128 < 256) {
            dim3 grid((N + 127) / 128, M / 64);
            gemm_bf16<64, 1, 4><<<grid, 256, 0, stream>>>(A, Wt, bias, Cf, Cb, M, N, K, relu);
        } else {
            dim3 grid((N + 127) / 128, M / 128);
            gemm_bf16<128, 2, 2><<<grid, 256, 0, stream>>>(A, Wt, bias, Cf, Cb, M, N, K, relu);
        }
    };

    cvt(cw2, cw2b, 128 * 64);
    cvt(cw3, cw3b, 768 * 128);

    // ---- stage 1: FPS + KNN ----
    fps_kernel<<<BB, 256, 0, stream>>>(xyz, fps_init, cxyz);
    knn_kernel<<<BB * NG, 256, 0, stream>>>(xyz, cxyz, gn);

    // ---- stage 2: mini-PointNet ----
    embed1_kernel<<<(131072 * 64 + 255) / 256, 256, 0, stream>>>(gn, cw1, cb1, h1);
    colstats_kernel<64><<<256, 256, 0, stream>>>(h1, st1, 131072);
    bn_finalize<<<1, 64, 0, stream>>>(st1, g1, be1, sc1, sh1, 64);
    bn_apply_bf16<<<(131072 * 64 + 255) / 256, 256, 0, stream>>>(h1, sc1, sh1, h1b, 131072 * 64, 64);
    gemm(h1b, cw2b, cb2, h2, nullptr, 131072, 128, 64, 0);
    colstats_kernel<128><<<256, 256, 0, stream>>>(h2, st2, 131072);
    bn_finalize<<<2, 64, 0, stream>>>(st2, g2, be2, sc2, sh2, 128);
    bn_apply_bf16<<<(131072 * 128 + 255) / 256, 256, 0, stream>>>(h2, sc2, sh2, h2b, 131072 * 128, 128);
    embed3_mfma<<<dim3(6, 1024), 256, 0, stream>>>(h2b, cw3b, cb3, gmax, gmin, st3);
    bn3_finalize<<<3, 256, 0, stream>>>(st3, g3, be3, a3, c3);
    tokens_pos<<<(4096 * 768 + 255) / 256, 256, 0, stream>>>(gmax, gmin, a3, c3, cxyz, posw, posb, xfull);

    // ---- stage 3: shuffle / mask ----
    restore_kernel<<<16, 256, 0, stream>>>(ids_shuf, restore);
    mask_kernel<<<16, 256, 0, stream>>>(restore, maskv);
    gather_xk<<<(BB * LK * DE + 255) / 256, 256, 0, stream>>>(xfull, ids_shuf, xe, xeb);

    // ---- weight conversion (after stage-2 temps are dead) ----
    cvt(eqw,  eqwb,  (size_t)NLE * 3 * DE * DE);
    cvt(eow,  eowb,  (size_t)NLE * DE * DE);
    cvt(ef1w, ef1wb, (size_t)NLE * 4 * DE * DE);
    cvt(ef2w, ef2wb, (size_t)NLE * 4 * DE * DE);
    cvt(dew,  dewb,  (size_t)DD * DE);
    cvt(dqw,  dqwb,  (size_t)NLD * 3 * DD * DD);
    cvt(dow,  dowb,  (size_t)NLD * DD * DD);
    cvt(df1w, df1wb, (size_t)NLD * 4 * DD * DD);
    cvt(df2w, df2wb, (size_t)NLD * 4 * DD * DD);
    cvt(prw,  prwb,  (size_t)96 * 512);
    hipMemsetAsync((void*)(prwb + (size_t)96 * 512), 0, (size_t)32 * 512 * 2, stream);

    // ---- stage 4: encoder (12 layers) ----
    for (int l = 0; l < NLE; ++l) {
        gemm(xeb, eqwb + (size_t)l * 3 * DE * DE, eqb + (size_t)l * 3 * DE, qkve, nullptr, 1024, 3 * DE, DE, 0);
        attn_kernel<LK, 64, 32, 12><<<BB * 12, 256, 0, stream>>>(qkve, oeb, 0.125f);
        gemm(oeb, eowb + (size_t)l * DE * DE, eob + (size_t)l * DE, xfull, nullptr, 1024, DE, DE, 0);
        ln_res<DE><<<BB * LK, 256, 0, stream>>>(xe, xfull, el1g + (size_t)l * DE, el1b + (size_t)l * DE, xeb);
        gemm(xeb, ef1wb + (size_t)l * 4 * DE * DE, ef1b + (size_t)l * 4 * DE, nullptr, fe1b, 1024, 4 * DE, DE, 1);
        gemm(fe1b, ef2wb + (size_t)l * DE * 4 * DE, ef2b + (size_t)l * DE, xfull, nullptr, 1024, DE, 4 * DE, 0);
        ln_res<DE><<<BB * LK, 256, 0, stream>>>(xe, xfull, el2g + (size_t)l * DE, el2b + (size_t)l * DE, xeb);
    }

    // ---- stage 5: decoder embed + mask tokens ----
    gemm(xeb, dewb, deb, yk, nullptr, 1024, DD, DE, 0);
    yd_build<<<(BB * NG * DD + 255) / 256, 256, 0, stream>>>(yk, restore, mtok, cxyz, dpw, dpb, xd, xdb);

    // ---- stage 6: decoder (8 layers) ----
    const float dsc = (float)(1.0 / sqrt(32.0));
    for (int l = 0; l < NLD; ++l) {
        gemm(xdb, dqwb + (size_t)l * 3 * DD * DD, dqb + (size_t)l * 3 * DD, qkvd, nullptr, 4096, 3 * DD, DD, 0);
        attn_kernel<NG, 32, 32, 16><<<BB * 16 * (NG / 32), 256, 0, stream>>>(qkvd, odb, dsc);
        gemm(odb, dowb + (size_t)l * DD * DD, dob + (size_t)l * DD, tmpd, nullptr, 4096, DD, DD, 0);
        ln_res<DD><<<BB * NG, 256, 0, stream>>>(xd, tmpd, dl1g + (size_t)l * DD, dl1b + (size_t)l * DD, xdb);
        gemm(xdb, df1wb + (size_t)l * 4 * DD * DD, df1b + (size_t)l * 4 * DD, nullptr, fd1b, 4096, 4 * DD, DD, 1);
        gemm(fd1b, df2wb + (size_t)l * DD * 4 * DD, df2b + (size_t)l * DD, tmpd, nullptr, 4096, DD, 4 * DD, 0);
        ln_res<DD><<<BB * NG, 256, 0, stream>>>(xd, tmpd, dl2g + (size_t)l * DD, dl2b + (size_t)l * DD, xdb);
    }

    // ---- stage 7: prediction + loss ----
    gemm(xdb, prwb, prb, pred, nullptr, 4096, 96, 512, 0);
    loss_l<<<BB * NG, 128, 0, stream>>>(pred, gn, maskv, lm);
    loss_final<<<1, 1024, 0, stream>>>(lm, maskv, out);
}

// Round 5
// 4223.226 us; speedup vs baseline: 5.4881x; 1.0286x over previous
//
#include <hip/hip_runtime.h>
#include <cmath>

// ---------------- problem constants ----------------
#define BB 32          // batch
#define NPTS 8192      // points per cloud
#define NG 128         // groups
#define KNB 32         // neighbors per group
#define LK 32          // len_keep
#define DE 768         // encoder dim
#define DD 512         // decoder dim
#define NLE 12
#define NLD 8

typedef __bf16 bf16x8 __attribute__((ext_vector_type(8)));
typedef float  f32x4  __attribute__((ext_vector_type(4)));

#define WAITV(N) asm volatile("s_waitcnt vmcnt(" #N ")" ::: "memory")

static __device__ __forceinline__ bf16x8 pack8(float4 a, float4 b) {
    bf16x8 h;
    h[0] = (__bf16)a.x; h[1] = (__bf16)a.y; h[2] = (__bf16)a.z; h[3] = (__bf16)a.w;
    h[4] = (__bf16)b.x; h[5] = (__bf16)b.y; h[6] = (__bf16)b.z; h[7] = (__bf16)b.w;
    return h;
}

// async global->LDS 16B copy: per-wave, lane l writes ldsbase + l*16
static __device__ __forceinline__ void gload16(const __bf16* g, __bf16* l) {
    __builtin_amdgcn_global_load_lds(
        (const __attribute__((address_space(1))) void*)g,
        (__attribute__((address_space(3))) void*)l,
        16, 0, 0);
}

// =====================================================================
// FPS: one block per batch, 256 threads. Points in LDS, dmin in REGISTERS
// (32 pts/thread), wave-shuffle argmax, redundant cross-wave reduce.
// =====================================================================
__global__ __launch_bounds__(256) void fps_kernel(
    const float* __restrict__ xyz, const int* __restrict__ init,
    float* __restrict__ cxyz)
{
#pragma clang fp contract(off)
    const int b = blockIdx.x;
    const float* P = xyz + (size_t)b * NPTS * 3;
    __shared__ float px[NPTS], py[NPTS], pz[NPTS];
    __shared__ float rv4[4];
    __shared__ int   ri4[4];
    const int tid = threadIdx.x;
    float dmin[32];
    for (int n = tid; n < NPTS; n += 256) {
        px[n] = P[n * 3 + 0]; py[n] = P[n * 3 + 1]; pz[n] = P[n * 3 + 2];
    }
    #pragma unroll
    for (int k = 0; k < 32; ++k) dmin[k] = 1e10f;
    int far = init[b];
    __syncthreads();
    for (int t = 0; t < NG; ++t) {
        float cx = px[far], cy = py[far], cz = pz[far];
        if (tid == 0) {
            cxyz[(b * NG + t) * 3 + 0] = cx;
            cxyz[(b * NG + t) * 3 + 1] = cy;
            cxyz[(b * NG + t) * 3 + 2] = cz;
        }
        float best = -1.0f; int bi = 0;
        #pragma unroll
        for (int k = 0; k < 32; ++k) {
            int n = tid + (k << 8);
            float dx = px[n] - cx, dy = py[n] - cy, dz = pz[n] - cz;
            float d = dx * dx + dy * dy + dz * dz;
            float dm = dmin[k];
            if (d < dm) dm = d;
            dmin[k] = dm;
            if (dm > best) { best = dm; bi = n; }   // strict > keeps lowest index
        }
        #pragma unroll
        for (int d = 32; d >= 1; d >>= 1) {
            float v2 = __shfl_down(best, d); int i2 = __shfl_down(bi, d);
            if (v2 > best || (v2 == best && i2 < bi)) { best = v2; bi = i2; }
        }
        if ((tid & 63) == 0) { rv4[tid >> 6] = best; ri4[tid >> 6] = bi; }
        __syncthreads();
        float bv = rv4[0]; int bbi = ri4[0];
        #pragma unroll
        for (int w = 1; w < 4; ++w) {
            float v2 = rv4[w]; int i2 = ri4[w];
            if (v2 > bv || (v2 == bv && i2 < bbi)) { bv = v2; bbi = i2; }
        }
        far = bbi;                   // all threads compute identical result
        __syncthreads();             // WAR protect rv4/ri4
    }
}

// =====================================================================
// KNN: one block per (b,m). Per-thread 32 dists in REGISTERS with
// incrementally-maintained (best,idx); per round: wave-shuffle argmin +
// cross-wave 4-way reduce; owner does register rescan (no LDS dist).
// =====================================================================
__global__ __launch_bounds__(256) void knn_kernel(
    const float* __restrict__ xyz, const float* __restrict__ cxyz,
    float* __restrict__ gn)
{
#pragma clang fp contract(off)
    const int bm = blockIdx.x;
    const int b = bm / NG;
    const float* P = xyz + (size_t)b * NPTS * 3;
    __shared__ float rv4[4];
    __shared__ int   ri4[4];
    __shared__ int   order[KNB];
    const int tid = threadIdx.x;
    const float cx = cxyz[bm * 3 + 0], cy = cxyz[bm * 3 + 1], cz = cxyz[bm * 3 + 2];
    const float c2 = cx * cx + cy * cy + cz * cz;
    float d[32];
    float best = 1e31f; int bi = 1 << 30;
    #pragma unroll
    for (int j = 0; j < 32; ++j) {
        int n = tid + (j << 8);
        float x = P[n * 3 + 0], y = P[n * 3 + 1], z = P[n * 3 + 2];
        float x2 = x * x + y * y + z * z;
        float dt = cx * x + cy * y + cz * z;
        float v = (c2 + x2) - 2.0f * dt;
        d[j] = v;
        if (v < best) { best = v; bi = n; }        // strict < keeps lowest index
    }
    for (int r = 0; r < KNB; ++r) {
        float v = best; int i = bi;
        #pragma unroll
        for (int dd = 32; dd >= 1; dd >>= 1) {
            float v2 = __shfl_down(v, dd); int i2 = __shfl_down(i, dd);
            if (v2 < v || (v2 == v && i2 < i)) { v = v2; i = i2; }
        }
        if ((tid & 63) == 0) { rv4[tid >> 6] = v; ri4[tid >> 6] = i; }
        __syncthreads();
        float bv = rv4[0]; int bn = ri4[0];
        #pragma unroll
        for (int w = 1; w < 4; ++w) {
            float v2 = rv4[w]; int i2 = ri4[w];
            if (v2 < bv || (v2 == bv && i2 < bn)) { bv = v2; bn = i2; }
        }
        if (tid == 0) order[r] = bn;
        if ((bn & 255) == tid) {
            // owner: remove selected element (static index) and rescan regs
            int sj = bn >> 8;
            best = 1e31f; bi = 1 << 30;
            #pragma unroll
            for (int j = 0; j < 32; ++j) {
                float vv = (j == sj) ? 1e30f : d[j];
                d[j] = vv;
                if (vv < best) { best = vv; bi = tid + (j << 8); }
            }
        }
        __syncthreads();
    }
    if (tid < KNB) {
        int n = order[tid];
        gn[((size_t)bm * KNB + tid) * 3 + 0] = P[n * 3 + 0] - cx;
        gn[((size_t)bm * KNB + tid) * 3 + 1] = P[n * 3 + 1] - cy;
        gn[((size_t)bm * KNB + tid) * 3 + 2] = P[n * 3 + 2] - cz;
    }
}

// =====================================================================
// f32 -> bf16 bulk convert (n multiple of 8)
// =====================================================================
__global__ void cvt_bf16_kernel(const float* __restrict__ src, __bf16* __restrict__ dst, int n8)
{
    int i = blockIdx.x * 256 + threadIdx.x;
    if (i >= n8) return;
    const float4* p = (const float4*)(src + (size_t)i * 8);
    *(bf16x8*)(dst + (size_t)i * 8) = pack8(p[0], p[1]);
}

// =====================================================================
// embed1: (131072,3)@(64,3)^T + bias
// =====================================================================
__global__ void embed1_kernel(const float* __restrict__ gn, const float* __restrict__ w,
                              const float* __restrict__ bias, float* __restrict__ h1)
{
    int i = blockIdx.x * 256 + threadIdx.x;
    if (i >= 131072 * 64) return;
    int r = i >> 6, c = i & 63;
    const float* p = gn + (size_t)r * 3;
    h1[i] = p[0] * w[c * 3 + 0] + p[1] * w[c * 3 + 1] + p[2] * w[c * 3 + 2] + bias[c];
}

// =====================================================================
// column stats (sum, sumsq) in double
// =====================================================================
template <int C>
__global__ __launch_bounds__(256) void colstats_kernel(const float* __restrict__ X,
                                                       double* __restrict__ st, int Mrows)
{
    constexpr int RL = 256 / C;
    const int c = threadIdx.x % C;
    const int rl = threadIdx.x / C;
    double s = 0.0, s2 = 0.0;
    int rows_per_block = (Mrows + gridDim.x - 1) / gridDim.x;
    int r0 = blockIdx.x * rows_per_block;
    int r1 = min(r0 + rows_per_block, Mrows);
    for (int r = r0 + rl; r < r1; r += RL) {
        float v = X[(size_t)r * C + c];
        s += v; s2 += (double)v * v;
    }
    __shared__ double sh[2][256];
    sh[0][threadIdx.x] = s; sh[1][threadIdx.x] = s2;
    __syncthreads();
    if (rl == 0) {
        for (int j = 1; j < RL; ++j) { s += sh[0][j * C + c]; s2 += sh[1][j * C + c]; }
        atomicAdd(&st[c], s);
        atomicAdd(&st[C + c], s2);
    }
}

__global__ void bn_finalize(const double* __restrict__ st, const float* __restrict__ g,
                            const float* __restrict__ be, float* __restrict__ sc,
                            float* __restrict__ shb, int C)
{
    int c = blockIdx.x * 64 + threadIdx.x;
    if (c >= C) return;
    double m = st[c] / 131072.0;
    double var = st[C + c] / 131072.0 - m * m;
    if (var < 0.0) var = 0.0;
    float rs = rsqrtf((float)var + 1e-5f);
    sc[c] = rs * g[c];
    shb[c] = be[c] - (float)m * rs * g[c];
}

// BN affine + relu, f32 in -> bf16 out
__global__ void bn_apply_bf16(const float* __restrict__ x, const float* __restrict__ sc,
                              const float* __restrict__ shb, __bf16* __restrict__ y,
                              int total, int C)
{
    int i = blockIdx.x * 256 + threadIdx.x;
    if (i >= total) return;
    int c = i % C;
    float v = x[i] * sc[c] + shb[c];
    v = fmaxf(v, 0.0f);
    y[i] = (__bf16)v;
}

// =====================================================================
// bf16 MFMA GEMM: C(M,N) = A(M,K) @ W(N,K)^T + bias (optional relu)
// BN=128, BK=64, 256 thr, DEPTH-buffered LDS, global_load_lds staging,
// counted vmcnt pipeline (never drains to 0 mid-loop at depth 3).
// Per-wave loads per stage: L = BM*8/256 + 4 (BM=64 -> 6, BM=128 -> 8).
// =====================================================================
template <int BM, int WM, int WN, int DEPTH>
__global__ __launch_bounds__(256) void gemm_bf16(
    const __bf16* __restrict__ A, const __bf16* __restrict__ W,
    const float* __restrict__ bias, float* __restrict__ Cf, __bf16* __restrict__ Cb,
    int M, int N, int K, int relu)
{
    constexpr int MR = BM / WM / 16;      // m-frags per wave
    constexpr int NR = 128 / WN / 16;     // n-frags per wave
    constexpr int CA = BM * 8 / 256;      // A 16B-chunks per thread
    __shared__ __bf16 As[DEPTH][BM * 64];
    __shared__ __bf16 Ws[DEPTH][128 * 64];
    const int tid = threadIdx.x;
    const int lane = tid & 63;
    const int wave = tid >> 6;
    const int wm = wave / WN, wn = wave % WN;
    const int m0 = blockIdx.y * BM, n0 = blockIdx.x * 128;
    (void)M;

    f32x4 acc[MR][NR] = {};

    auto stage = [&](int buf, int kt) {
        #pragma unroll
        for (int j = 0; j < CA; ++j) {
            int cb = j * 256 + (wave << 6);
            int c  = cb + lane;
            int row = c >> 3;
            int kcs = (c & 7) ^ (row & 7);
            gload16(A + (size_t)(m0 + row) * K + kt + kcs * 8, &As[buf][cb * 8]);
        }
        #pragma unroll
        for (int j = 0; j < 4; ++j) {
            int cb = j * 256 + (wave << 6);
            int c  = cb + lane;
            int row = c >> 3;
            int kcs = (c & 7) ^ (row & 7);
            gload16(W + (size_t)(n0 + row) * K + kt + kcs * 8, &Ws[buf][cb * 8]);
        }
    };
    auto compute = [&](int buf) {
        #pragma unroll
        for (int ks = 0; ks < 2; ++ks) {
            bf16x8 af[MR], bfr[NR];
            int kc = ks * 4 + (lane >> 4);
            #pragma unroll
            for (int i = 0; i < MR; ++i) {
                int rowA = wm * (BM / WM) + i * 16 + (lane & 15);
                af[i] = *(bf16x8*)&As[buf][rowA * 64 + ((kc ^ (rowA & 7)) * 8)];
            }
            #pragma unroll
            for (int j = 0; j < NR; ++j) {
                int rowB = wn * (128 / WN) + j * 16 + (lane & 15);
                bfr[j] = *(bf16x8*)&Ws[buf][rowB * 64 + ((kc ^ (rowB & 7)) * 8)];
            }
            #pragma unroll
            for (int i = 0; i < MR; ++i)
                #pragma unroll
                for (int j = 0; j < NR; ++j)
                    acc[i][j] = __builtin_amdgcn_mfma_f32_16x16x32_bf16(af[i], bfr[j], acc[i][j], 0, 0, 0);
        }
    };

    const int nt = K >> 6;
    stage(0, 0);
    if (DEPTH > 1 && nt > 1) stage(1, 64);
    if (DEPTH > 2 && nt > 2) stage(2, 128);
    for (int t = 0; t < nt; ++t) {
        int ahead = min(nt - 1, t + DEPTH - 1) - t;   // stages outstanding after t's done
        if (ahead >= 2)      { if constexpr (BM == 64) WAITV(12); else WAITV(16); }
        else if (ahead == 1) { if constexpr (BM == 64) WAITV(6);  else WAITV(8); }
        else                 WAITV(0);
        __syncthreads();
        compute(t % DEPTH);
        if (t + DEPTH < nt) {
            __syncthreads();
            stage(t % DEPTH, (t + DEPTH) << 6);
        }
    }

    #pragma unroll
    for (int j = 0; j < NR; ++j) {
        int col = n0 + wn * (128 / WN) + j * 16 + (lane & 15);
        if (col >= N) continue;
        float bv = bias[col];
        #pragma unroll
        for (int i = 0; i < MR; ++i) {
            #pragma unroll
            for (int r = 0; r < 4; ++r) {
                int rowm = m0 + wm * (BM / WM) + i * 16 + (lane >> 4) * 4 + r;
                float v = acc[i][j][r] + bv;
                if (relu) v = fmaxf(v, 0.0f);
                if (Cf) Cf[(size_t)rowm * N + col] = v;
                if (Cb) Cb[(size_t)rowm * N + col] = (__bf16)v;
            }
        }
    }
}

// =====================================================================
// embed3 via MFMA: (131072,768) = h2b(131072,128) @ cw3b^T, fused epilogue:
// bias + per-group(32-row) max/min + per-column sum/sumsq. grid (6,1024)
// =====================================================================
__global__ __launch_bounds__(256) void embed3_mfma(
    const __bf16* __restrict__ A, const __bf16* __restrict__ W,
    const float* __restrict__ cb3,
    float* __restrict__ gmax, float* __restrict__ gmin, double* __restrict__ st3)
{
    __shared__ __bf16 As[2][128 * 64];
    __shared__ __bf16 Ws[2][128 * 64];
    const int tid = threadIdx.x;
    const int lane = tid & 63;
    const int wave = tid >> 6;
    const int wm = wave >> 1, wn = wave & 1;
    const int m0 = blockIdx.y * 128, n0 = blockIdx.x * 128;
    const int K = 128;

    f32x4 acc[4][4] = {};

    auto stage = [&](int buf, int kt) {
        #pragma unroll
        for (int j = 0; j < 4; ++j) {
            int cb = j * 256 + (wave << 6);
            int c  = cb + lane;
            int row = c >> 3;
            int kcs = (c & 7) ^ (row & 7);
            gload16(A + (size_t)(m0 + row) * K + kt + kcs * 8, &As[buf][cb * 8]);
            gload16(W + (size_t)(n0 + row) * K + kt + kcs * 8, &Ws[buf][cb * 8]);
        }
    };
    auto compute = [&](int buf) {
        #pragma unroll
        for (int ks = 0; ks < 2; ++ks) {
            bf16x8 af[4], bfr[4];
            int kc = ks * 4 + (lane >> 4);
            #pragma unroll
            for (int i = 0; i < 4; ++i) {
                int rowA = wm * 64 + i * 16 + (lane & 15);
                af[i] = *(bf16x8*)&As[buf][rowA * 64 + ((kc ^ (rowA & 7)) * 8)];
                int rowB = wn * 64 + i * 16 + (lane & 15);
                bfr[i] = *(bf16x8*)&Ws[buf][rowB * 64 + ((kc ^ (rowB & 7)) * 8)];
            }
            #pragma unroll
            for (int i = 0; i < 4; ++i)
                #pragma unroll
                for (int j = 0; j < 4; ++j)
                    acc[i][j] = __builtin_amdgcn_mfma_f32_16x16x32_bf16(af[i], bfr[j], acc[i][j], 0, 0, 0);
        }
    };

    stage(0, 0);
    stage(1, 64);
    WAITV(8);              // buf0's 8 per-wave loads done; buf1 in flight
    __syncthreads();
    compute(0);
    WAITV(0);
    __syncthreads();
    compute(1);

    #pragma unroll
    for (int j = 0; j < 4; ++j) {
        int col = n0 + wn * 64 + j * 16 + (lane & 15);
        float bv = cb3[col];
        float stot = 0.0f, s2tot = 0.0f;
        #pragma unroll
        for (int gi = 0; gi < 2; ++gi) {
            float mx = -1e30f, mn = 1e30f, s = 0.0f, s2 = 0.0f;
            #pragma unroll
            for (int ii = 0; ii < 2; ++ii) {
                f32x4 a = acc[gi * 2 + ii][j];
                #pragma unroll
                for (int r = 0; r < 4; ++r) {
                    float v = a[r] + bv;
                    mx = fmaxf(mx, v); mn = fminf(mn, v);
                    s += v; s2 += v * v;
                }
            }
            #pragma unroll
            for (int d = 16; d < 64; d <<= 1) {
                mx = fmaxf(mx, __shfl_xor(mx, d));
                mn = fminf(mn, __shfl_xor(mn, d));
                s  += __shfl_xor(s, d);
                s2 += __shfl_xor(s2, d);
            }
            stot += s; s2tot += s2;
            if (lane < 16) {
                int g = (m0 >> 5) + wm * 2 + gi;
                gmax[(size_t)g * 768 + col] = mx;
                gmin[(size_t)g * 768 + col] = mn;
            }
        }
        if (lane < 16) {
            double* stp = st3 + (size_t)(blockIdx.y & 31) * 1536;
            atomicAdd(&stp[col], (double)stot);
            atomicAdd(&stp[768 + col], (double)s2tot);
        }
    }
}

__global__ void bn3_finalize(const double* __restrict__ st3, const float* __restrict__ g,
                             const float* __restrict__ be, float* __restrict__ a3,
                             float* __restrict__ c3)
{
    int c = blockIdx.x * 256 + threadIdx.x;
    if (c >= 768) return;
    double s = 0.0, s2 = 0.0;
    for (int p = 0; p < 32; ++p) { s += st3[(size_t)p * 1536 + c]; s2 += st3[(size_t)p * 1536 + 768 + c]; }
    double m = s / 131072.0;
    double var = s2 / 131072.0 - m * m;
    if (var < 0.0) var = 0.0;
    float rs = rsqrtf((float)var + 1e-5f);
    a3[c] = rs * g[c];
    c3[c] = be[c] - (float)m * rs * g[c];
}

// tokens = affine(max/min) ; x = tokens + cxyz@pos_w^T + pos_b
__global__ void tokens_pos(const float* __restrict__ gmax, const float* __restrict__ gmin,
                           const float* __restrict__ a3, const float* __restrict__ c3,
                           const float* __restrict__ cxyz, const float* __restrict__ posw,
                           const float* __restrict__ posb, float* __restrict__ x)
{
    int i = blockIdx.x * 256 + threadIdx.x;
    if (i >= 4096 * 768) return;
    int c = i % 768, g = i / 768;
    float a = a3[c];
    float tok = (a >= 0.0f ? a * gmax[i] : a * gmin[i]) + c3[c];
    float px = cxyz[g * 3 + 0], py = cxyz[g * 3 + 1], pz = cxyz[g * 3 + 2];
    x[i] = tok + px * posw[c * 3 + 0] + py * posw[c * 3 + 1] + pz * posw[c * 3 + 2] + posb[c];
}

__global__ void restore_kernel(const int* __restrict__ shuffle, int* __restrict__ restore)
{
    int j = blockIdx.x * 256 + threadIdx.x;
    if (j >= BB * NG) return;
    int b = j / NG, p = j % NG;
    restore[b * NG + shuffle[j]] = p;
}

__global__ void mask_kernel(const int* __restrict__ restore, float* __restrict__ maskv)
{
    int i = blockIdx.x * 256 + threadIdx.x;
    if (i >= BB * NG) return;
    maskv[i] = (restore[i] < LK) ? 0.0f : 1.0f;
}

__global__ void gather_xk(const float* __restrict__ xfull, const int* __restrict__ shuffle,
                          float* __restrict__ xe, __bf16* __restrict__ xeb)
{
    int i = blockIdx.x * 256 + threadIdx.x;
    if (i >= BB * LK * DE) return;
    int c = i % DE;
    int s = (i / DE) % LK;
    int b = i / (DE * LK);
    float v = xfull[((size_t)b * NG + shuffle[b * NG + s]) * DE + c];
    xe[i] = v;
    xeb[i] = (__bf16)v;
}

__global__ void yd_build(const float* __restrict__ yk, const int* __restrict__ restore,
                         const float* __restrict__ mtok, const float* __restrict__ cxyz,
                         const float* __restrict__ dpw, const float* __restrict__ dpb,
                         float* __restrict__ xd, __bf16* __restrict__ xdb)
{
    int i = blockIdx.x * 256 + threadIdx.x;
    if (i >= BB * NG * DD) return;
    int c = i % DD;
    int g = i / DD;
    int b = g / NG;
    int r = restore[g];
    float base = (r < LK) ? yk[((size_t)b * LK + r) * DD + c] : mtok[c];
    float px = cxyz[g * 3 + 0], py = cxyz[g * 3 + 1], pz = cxyz[g * 3 + 2];
    float v = base + px * dpw[c * 3 + 0] + py * dpw[c * 3 + 1] + pz * dpw[c * 3 + 2] + dpb[c];
    xd[i] = v;
    xdb[i] = (__bf16)v;
}

// =====================================================================
// attention: block per (b, h, q-tile). f32 in, bf16 out.
// =====================================================================
template <int S, int DH, int QT, int NH>
__global__ __launch_bounds__(256) void attn_kernel(const float* __restrict__ qkv,
                                                   __bf16* __restrict__ o, float scale)
{
    constexpr int D = NH * DH;
    constexpr int NT = S / QT;
    __shared__ float Ks[S][DH];
    __shared__ float Vs[S][DH];
    __shared__ float Qs[QT][DH];
    __shared__ float P[QT][S];
    const int t = blockIdx.x % NT;
    const int h = (blockIdx.x / NT) % NH;
    const int b = blockIdx.x / (NT * NH);
    const float* base = qkv + (size_t)b * S * 3 * D + h * DH;
    for (int i = threadIdx.x; i < S * DH; i += 256) {
        int s = i / DH, d = i % DH;
        Ks[s][d] = base[(size_t)s * 3 * D + D + d];
        Vs[s][d] = base[(size_t)s * 3 * D + 2 * D + d];
    }
    for (int i = threadIdx.x; i < QT * DH; i += 256) {
        int qi = i / DH, d = i % DH;
        Qs[qi][d] = base[(size_t)(t * QT + qi) * 3 * D + d];
    }
    __syncthreads();
    for (int i = threadIdx.x; i < QT * S; i += 256) {
        int qi = i / S, s = i % S;
        float acc = 0.0f;
        #pragma unroll 8
        for (int d = 0; d < DH; ++d) acc += Qs[qi][d] * Ks[s][d];
        P[qi][s] = acc * scale;
    }
    __syncthreads();
    if (threadIdx.x < QT) {
        int qi = threadIdx.x;
        float mx = -1e30f;
        for (int s = 0; s < S; ++s) mx = fmaxf(mx, P[qi][s]);
        float sum = 0.0f;
        for (int s = 0; s < S; ++s) { float e = expf(P[qi][s] - mx); P[qi][s] = e; sum += e; }
        float inv = 1.0f / sum;
        for (int s = 0; s < S; ++s) P[qi][s] *= inv;
    }
    __syncthreads();
    __bf16* ob = o + (size_t)b * S * D + h * DH;
    for (int i = threadIdx.x; i < QT * DH; i += 256) {
        int qi = i / DH, d = i % DH;
        float acc = 0.0f;
        for (int s = 0; s < S; ++s) acc += P[qi][s] * Vs[s][d];
        ob[(size_t)(t * QT + qi) * D + d] = (__bf16)acc;
    }
}

// =====================================================================
// LayerNorm with residual, in place: x = LN(x + r) * g + b ; bf16 copy out
// =====================================================================
template <int D>
__global__ __launch_bounds__(256) void ln_res(float* __restrict__ x, const float* __restrict__ r,
                                              const float* __restrict__ g, const float* __restrict__ b,
                                              __bf16* __restrict__ xb)
{
    __shared__ float row[D];
    __shared__ float red[256];
    __shared__ float mv[2];
    const size_t off = (size_t)blockIdx.x * D;
    float s = 0.0f;
    for (int i = threadIdx.x; i < D; i += 256) {
        float v = x[off + i] + r[off + i];
        row[i] = v; s += v;
    }
    red[threadIdx.x] = s; __syncthreads();
    for (int st = 128; st > 0; st >>= 1) { if (threadIdx.x < st) red[threadIdx.x] += red[threadIdx.x + st]; __syncthreads(); }
    if (threadIdx.x == 0) mv[0] = red[0] / D;
    __syncthreads();
    float m = mv[0];
    s = 0.0f;
    for (int i = threadIdx.x; i < D; i += 256) { float d = row[i] - m; s += d * d; }
    red[threadIdx.x] = s; __syncthreads();
    for (int st = 128; st > 0; st >>= 1) { if (threadIdx.x < st) red[threadIdx.x] += red[threadIdx.x + st]; __syncthreads(); }
    if (threadIdx.x == 0) mv[1] = red[0] / D;
    __syncthreads();
    float rs = rsqrtf(mv[1] + 1e-5f);
    for (int i = threadIdx.x; i < D; i += 256) {
        float v = (row[i] - m) * rs * g[i] + b[i];
        x[off + i] = v;
        xb[off + i] = (__bf16)v;
    }
}

// =====================================================================
// loss
// =====================================================================
__global__ __launch_bounds__(128) void loss_l(const float* __restrict__ pred,
                                              const float* __restrict__ target,
                                              const float* __restrict__ maskv,
                                              float* __restrict__ lm)
{
    const int g = blockIdx.x;
    __shared__ float red[128];
    int t = threadIdx.x;
    float s = 0.0f;
    if (t < 96) {
        float d = pred[(size_t)g * 96 + t] - target[(size_t)g * 96 + t];
        s = d * d;
    }
    red[t] = s; __syncthreads();
    for (int st = 64; st > 0; st >>= 1) { if (t < st) red[t] += red[t + st]; __syncthreads(); }
    if (t == 0) lm[g] = (red[0] / 96.0f) * maskv[g];
}

__global__ __launch_bounds__(1024) void loss_final(const float* __restrict__ lm,
                                                   const float* __restrict__ maskv,
                                                   float* __restrict__ out)
{
    __shared__ float r1[1024], r2[1024];
    int t = threadIdx.x;
    float a = 0.0f, b = 0.0f;
    for (int i = t; i < BB * NG; i += 1024) { a += lm[i]; b += maskv[i]; }
    r1[t] = a; r2[t] = b; __syncthreads();
    for (int st = 512; st > 0; st >>= 1) { if (t < st) { r1[t] += r1[t + st]; r2[t] += r2[t + st]; } __syncthreads(); }
    if (t == 0) out[0] = r1[0] / r2[0];
}

// =====================================================================
// host
// =====================================================================
extern "C" void kernel_launch(void* const* d_in, const int* in_sizes, int n_in,
                              void* d_out, int out_size, void* d_ws, size_t ws_size,
                              hipStream_t stream)
{
    (void)in_sizes; (void)n_in; (void)out_size; (void)ws_size;
    const float* xyz        = (const float*)d_in[0];
    const int*   fps_init   = (const int*)d_in[1];
    const int*   ids_shuf   = (const int*)d_in[2];
    const float* cw1 = (const float*)d_in[3];  const float* cb1 = (const float*)d_in[4];
    const float* g1  = (const float*)d_in[5];  const float* be1 = (const float*)d_in[6];
    const float* cw2 = (const float*)d_in[7];  const float* cb2 = (const float*)d_in[8];
    const float* g2  = (const float*)d_in[9];  const float* be2 = (const float*)d_in[10];
    const float* cw3 = (const float*)d_in[11]; const float* cb3 = (const float*)d_in[12];
    const float* g3  = (const float*)d_in[13]; const float* be3 = (const float*)d_in[14];
    const float* posw = (const float*)d_in[15]; const float* posb = (const float*)d_in[16];
    const float* eqw = (const float*)d_in[17]; const float* eqb = (const float*)d_in[18];
    const float* eow = (const float*)d_in[19]; const float* eob = (const float*)d_in[20];
    const float* el1g = (const float*)d_in[21]; const float* el1b = (const float*)d_in[22];
    const float* ef1w = (const float*)d_in[23]; const float* ef1b = (const float*)d_in[24];
    const float* ef2w = (const float*)d_in[25]; const float* ef2b = (const float*)d_in[26];
    const float* el2g = (const float*)d_in[27]; const float* el2b = (const float*)d_in[28];
    const float* dew = (const float*)d_in[29]; const float* deb = (const float*)d_in[30];
    const float* mtok = (const float*)d_in[31];
    const float* dpw = (const float*)d_in[32]; const float* dpb = (const float*)d_in[33];
    const float* dqw = (const float*)d_in[34]; const float* dqb = (const float*)d_in[35];
    const float* dow = (const float*)d_in[36]; const float* dob = (const float*)d_in[37];
    const float* dl1g = (const float*)d_in[38]; const float* dl1b = (const float*)d_in[39];
    const float* df1w = (const float*)d_in[40]; const float* df1b = (const float*)d_in[41];
    const float* df2w = (const float*)d_in[42]; const float* df2b = (const float*)d_in[43];
    const float* dl2g = (const float*)d_in[44]; const float* dl2b = (const float*)d_in[45];
    const float* prw = (const float*)d_in[46]; const float* prb = (const float*)d_in[47];
    float* out = (float*)d_out;
    float* pred = out + 1;
    float* maskv = out + 1 + (size_t)BB * NG * KNB * 3;

    // ---- workspace carve ----
    char* ws = (char*)d_ws;
    size_t off = 0;
    auto alloc = [&](size_t bytes) -> void* {
        void* p = ws + off;
        off = (off + bytes + 255) & ~(size_t)255;
        return p;
    };
    double* st1 = (double*)alloc(128 * 8);
    double* st2 = (double*)alloc(256 * 8);
    double* st3 = (double*)alloc((size_t)32 * 1536 * 8);
    float* sc1 = (float*)alloc(64 * 4);  float* sh1 = (float*)alloc(64 * 4);
    float* sc2 = (float*)alloc(128 * 4); float* sh2 = (float*)alloc(128 * 4);
    float* a3 = (float*)alloc(768 * 4);  float* c3 = (float*)alloc(768 * 4);
    int* restore = (int*)alloc(4096 * 4);
    float* cxyz = (float*)alloc(12288 * 4);
    float* gn   = (float*)alloc((size_t)393216 * 4);
    __bf16* cw2b = (__bf16*)alloc((size_t)128 * 64 * 2);
    __bf16* cw3b = (__bf16*)alloc((size_t)768 * 128 * 2);
    float* xfull = (float*)alloc((size_t)4096 * 768 * 4);
    float* xe    = (float*)alloc((size_t)1024 * 768 * 4);
    __bf16* xeb  = (__bf16*)alloc((size_t)1024 * 768 * 2);
    float* qkve  = (float*)alloc((size_t)1024 * 2304 * 4);
    __bf16* oeb  = (__bf16*)alloc((size_t)1024 * 768 * 2);
    __bf16* fe1b = (__bf16*)alloc((size_t)1024 * 3072 * 2);
    float* yk    = (float*)alloc((size_t)1024 * 512 * 4);
    float* xd    = (float*)alloc((size_t)4096 * 512 * 4);
    __bf16* xdb  = (__bf16*)alloc((size_t)4096 * 512 * 2);
    float* qkvd  = (float*)alloc((size_t)4096 * 1536 * 4);
    __bf16* odb  = (__bf16*)alloc((size_t)4096 * 512 * 2);
    __bf16* fd1b = (__bf16*)alloc((size_t)4096 * 2048 * 2);
    float* tmpd  = (float*)alloc((size_t)4096 * 512 * 4);
    float* lm    = (float*)alloc(4096 * 4);

    __bf16* eqwb  = (__bf16*)alloc((size_t)NLE * 3 * DE * DE * 2);
    __bf16* eowb  = (__bf16*)alloc((size_t)NLE * DE * DE * 2);
    __bf16* ef1wb = (__bf16*)alloc((size_t)NLE * 4 * DE * DE * 2);
    __bf16* ef2wb = (__bf16*)alloc((size_t)NLE * 4 * DE * DE * 2);
    __bf16* dewb  = (__bf16*)alloc((size_t)DD * DE * 2);
    __bf16* dqwb  = (__bf16*)alloc((size_t)NLD * 3 * DD * DD * 2);
    __bf16* dowb  = (__bf16*)alloc((size_t)NLD * DD * DD * 2);
    __bf16* df1wb = (__bf16*)alloc((size_t)NLD * 4 * DD * DD * 2);
    __bf16* df2wb = (__bf16*)alloc((size_t)NLD * 4 * DD * DD * 2);
    __bf16* prwb  = (__bf16*)alloc((size_t)128 * 512 * 2);

    char* U = (char*)eqwb;
    float*  h1   = (float*)U;
    __bf16* h1b  = (__bf16*)(U + (size_t)33554432);
    float*  h2   = (float*)(U + (size_t)50331648);
    __bf16* h2b  = (__bf16*)(U + (size_t)117440512);
    float*  gmax = (float*)(U + (size_t)150994944);
    float*  gmin = (float*)(U + (size_t)163577856);

    size_t stats_bytes = (size_t)((char*)st3 + (size_t)32 * 1536 * 8 - (char*)st1);
    hipMemsetAsync((void*)st1, 0, stats_bytes, stream);

    auto cvt = [&](const float* src, __bf16* dst, size_t n) {
        int n8 = (int)(n / 8);
        cvt_bf16_kernel<<<(n8 + 255) / 256, 256, 0, stream>>>(src, dst, n8);
    };
    auto gemm = [&](const __bf16* A, const __bf16* Wt, const float* bias,
                    float* Cf, __bf16* Cb, int M, int N, int K, int relu) {
        int nb128 = ((N + 127) / 128) * (M / 128);
        if (nb128 < 256) {
            dim3 grid((N + 127) / 128, M / 64);
            gemm_bf16<64, 1, 4, 3><<<grid, 256, 0, stream>>>(A, Wt, bias, Cf, Cb, M, N, K, relu);
        } else {
            dim3 grid((N + 127) / 128, M / 128);
            gemm_bf16<128, 2, 2, 2><<<grid, 256, 0, stream>>>(A, Wt, bias, Cf, Cb, M, N, K, relu);
        }
    };

    cvt(cw2, cw2b, 128 * 64);
    cvt(cw3, cw3b, 768 * 128);

    // ---- stage 1: FPS + KNN ----
    fps_kernel<<<BB, 256, 0, stream>>>(xyz, fps_init, cxyz);
    knn_kernel<<<BB * NG, 256, 0, stream>>>(xyz, cxyz, gn);

    // ---- stage 2: mini-PointNet ----
    embed1_kernel<<<(131072 * 64 + 255) / 256, 256, 0, stream>>>(gn, cw1, cb1, h1);
    colstats_kernel<64><<<256, 256, 0, stream>>>(h1, st1, 131072);
    bn_finalize<<<1, 64, 0, stream>>>(st1, g1, be1, sc1, sh1, 64);
    bn_apply_bf16<<<(131072 * 64 + 255) / 256, 256, 0, stream>>>(h1, sc1, sh1, h1b, 131072 * 64, 64);
    gemm(h1b, cw2b, cb2, h2, nullptr, 131072, 128, 64, 0);
    colstats_kernel<128><<<256, 256, 0, stream>>>(h2, st2, 131072);
    bn_finalize<<<2, 64, 0, stream>>>(st2, g2, be2, sc2, sh2, 128);
    bn_apply_bf16<<<(131072 * 128 + 255) / 256, 256, 0, stream>>>(h2, sc2, sh2, h2b, 131072 * 128, 128);
    embed3_mfma<<<dim3(6, 1024), 256, 0, stream>>>(h2b, cw3b, cb3, gmax, gmin, st3);
    bn3_finalize<<<3, 256, 0, stream>>>(st3, g3, be3, a3, c3);
    tokens_pos<<<(4096 * 768 + 255) / 256, 256, 0, stream>>>(gmax, gmin, a3, c3, cxyz, posw, posb, xfull);

    // ---- stage 3: shuffle / mask ----
    restore_kernel<<<16, 256, 0, stream>>>(ids_shuf, restore);
    mask_kernel<<<16, 256, 0, stream>>>(restore, maskv);
    gather_xk<<<(BB * LK * DE + 255) / 256, 256, 0, stream>>>(xfull, ids_shuf, xe, xeb);

    // ---- weight conversion (after stage-2 temps are dead) ----
    cvt(eqw,  eqwb,  (size_t)NLE * 3 * DE * DE);
    cvt(eow,  eowb,  (size_t)NLE * DE * DE);
    cvt(ef1w, ef1wb, (size_t)NLE * 4 * DE * DE);
    cvt(ef2w, ef2wb, (size_t)NLE * 4 * DE * DE);
    cvt(dew,  dewb,  (size_t)DD * DE);
    cvt(dqw,  dqwb,  (size_t)NLD * 3 * DD * DD);
    cvt(dow,  dowb,  (size_t)NLD * DD * DD);
    cvt(df1w, df1wb, (size_t)NLD * 4 * DD * DD);
    cvt(df2w, df2wb, (size_t)NLD * 4 * DD * DD);
    cvt(prw,  prwb,  (size_t)96 * 512);
    hipMemsetAsync((void*)(prwb + (size_t)96 * 512), 0, (size_t)32 * 512 * 2, stream);

    // ---- stage 4: encoder (12 layers) ----
    for (int l = 0; l < NLE; ++l) {
        gemm(xeb, eqwb + (size_t)l * 3 * DE * DE, eqb + (size_t)l * 3 * DE, qkve, nullptr, 1024, 3 * DE, DE, 0);
        attn_kernel<LK, 64, 32, 12><<<BB * 12, 256, 0, stream>>>(qkve, oeb, 0.125f);
        gemm(oeb, eowb + (size_t)l * DE * DE, eob + (size_t)l * DE, xfull, nullptr, 1024, DE, DE, 0);
        ln_res<DE><<<BB * LK, 256, 0, stream>>>(xe, xfull, el1g + (size_t)l * DE, el1b + (size_t)l * DE, xeb);
        gemm(xeb, ef1wb + (size_t)l * 4 * DE * DE, ef1b + (size_t)l * 4 * DE, nullptr, fe1b, 1024, 4 * DE, DE, 1);
        gemm(fe1b, ef2wb + (size_t)l * DE * 4 * DE, ef2b + (size_t)l * DE, xfull, nullptr, 1024, DE, 4 * DE, 0);
        ln_res<DE><<<BB * LK, 256, 0, stream>>>(xe, xfull, el2g + (size_t)l * DE, el2b + (size_t)l * DE, xeb);
    }

    // ---- stage 5: decoder embed + mask tokens ----
    gemm(xeb, dewb, deb, yk, nullptr, 1024, DD, DE, 0);
    yd_build<<<(BB * NG * DD + 255) / 256, 256, 0, stream>>>(yk, restore, mtok, cxyz, dpw, dpb, xd, xdb);

    // ---- stage 6: decoder (8 layers) ----
    const float dsc = (float)(1.0 / sqrt(32.0));
    for (int l = 0; l < NLD; ++l) {
        gemm(xdb, dqwb + (size_t)l * 3 * DD * DD, dqb + (size_t)l * 3 * DD, qkvd, nullptr, 4096, 3 * DD, DD, 0);
        attn_kernel<NG, 32, 32, 16><<<BB * 16 * (NG / 32), 256, 0, stream>>>(qkvd, odb, dsc);
        gemm(odb, dowb + (size_t)l * DD * DD, dob + (size_t)l * DD, tmpd, nullptr, 4096, DD, DD, 0);
        ln_res<DD><<<BB * NG, 256, 0, stream>>>(xd, tmpd, dl1g + (size_t)l * DD, dl1b + (size_t)l * DD, xdb);
        gemm(xdb, df1wb + (size_t)l * 4 * DD * DD, df1b + (size_t)l * 4 * DD, nullptr, fd1b, 4096, 4 * DD, DD, 1);
        gemm(fd1b, df2wb + (size_t)l * DD * 4 * DD, df2b + (size_t)l * DD, tmpd, nullptr, 4096, DD, 4 * DD, 0);
        ln_res<DD><<<BB * NG, 256, 0, stream>>>(xd, tmpd, dl2g + (size_t)l * DD, dl2b + (size_t)l * DD, xdb);
    }

    // ---- stage 7: prediction + loss ----
    gemm(xdb, prwb, prb, pred, nullptr, 4096, 96, 512, 0);
    loss_l<<<BB * NG, 128, 0, stream>>>(pred, gn, maskv, lm);
    loss_final<<<1, 1024, 0, stream>>>(lm, maskv, out);
}

// Round 6
// 3898.700 us; speedup vs baseline: 5.9450x; 1.0832x over previous
//
#include <hip/hip_runtime.h>
#include <cmath>

// ---------------- problem constants ----------------
#define BB 32          // batch
#define NPTS 8192      // points per cloud
#define NG 128         // groups
#define KNB 32         // neighbors per group
#define LK 32          // len_keep
#define DE 768         // encoder dim
#define DD 512         // decoder dim
#define NLE 12
#define NLD 8

typedef __bf16 bf16x8 __attribute__((ext_vector_type(8)));
typedef float  f32x4  __attribute__((ext_vector_type(4)));

#define WAITV(N) asm volatile("s_waitcnt vmcnt(" #N ")" ::: "memory")

static __device__ __forceinline__ bf16x8 pack8(float4 a, float4 b) {
    bf16x8 h;
    h[0] = (__bf16)a.x; h[1] = (__bf16)a.y; h[2] = (__bf16)a.z; h[3] = (__bf16)a.w;
    h[4] = (__bf16)b.x; h[5] = (__bf16)b.y; h[6] = (__bf16)b.z; h[7] = (__bf16)b.w;
    return h;
}

// async global->LDS 16B copy: per-wave, lane l writes ldsbase + l*16
static __device__ __forceinline__ void gload16(const __bf16* g, __bf16* l) {
    __builtin_amdgcn_global_load_lds(
        (const __attribute__((address_space(1))) void*)g,
        (__attribute__((address_space(3))) void*)l,
        16, 0, 0);
}

// =====================================================================
// FPS: one block per batch, 256 threads. Point coords AND dmin in
// REGISTERS (32 pts/thread); LDS copy only for centroid broadcast.
// (dist,idx) packed in u64 -> single-compare argmax; ONE barrier/step
// via parity-double-buffered reduce slots.
// =====================================================================
__global__ __launch_bounds__(256, 1) void fps_kernel(
    const float* __restrict__ xyz, const int* __restrict__ init,
    float* __restrict__ cxyz)
{
#pragma clang fp contract(off)
    const int b = blockIdx.x;
    const float* P = xyz + (size_t)b * NPTS * 3;
    __shared__ float pxs[NPTS], pys[NPTS], pzs[NPTS];
    __shared__ unsigned long long red[2][4];
    const int tid = threadIdx.x;
    float x[32], y[32], z[32], dmin[32];
    #pragma unroll
    for (int k = 0; k < 32; ++k) {
        int n = tid + (k << 8);
        float xx = P[n * 3 + 0], yy = P[n * 3 + 1], zz = P[n * 3 + 2];
        x[k] = xx; y[k] = yy; z[k] = zz;
        pxs[n] = xx; pys[n] = yy; pzs[n] = zz;
        dmin[k] = 1e10f;
    }
    int far = init[b];
    __syncthreads();
    for (int t = 0; t < NG; ++t) {
        float cx = pxs[far], cy = pys[far], cz = pzs[far];
        if (tid == 0) {
            cxyz[(b * NG + t) * 3 + 0] = cx;
            cxyz[(b * NG + t) * 3 + 1] = cy;
            cxyz[(b * NG + t) * 3 + 2] = cz;
        }
        unsigned long long key = 0ull;
        #pragma unroll
        for (int k = 0; k < 32; ++k) {
            float dx = x[k] - cx, dy = y[k] - cy, dz = z[k] - cz;
            float d = dx * dx + dy * dy + dz * dz;
            float dm = dmin[k];
            if (d < dm) dm = d;
            dmin[k] = dm;
            // non-negative floats are order-isomorphic to their bit patterns;
            // (8191-n) low word -> max key == max dist, lowest index on tie
            unsigned long long kk = ((unsigned long long)__float_as_uint(dm) << 32)
                                  | (unsigned)(8191 - (tid + (k << 8)));
            if (kk > key) key = kk;
        }
        #pragma unroll
        for (int d = 32; d >= 1; d >>= 1) {
            unsigned long long k2 = __shfl_down(key, d);
            if (k2 > key) key = k2;
        }
        if ((tid & 63) == 0) red[t & 1][tid >> 6] = key;
        __syncthreads();
        unsigned long long kb = red[t & 1][0];
        #pragma unroll
        for (int w = 1; w < 4; ++w) {
            unsigned long long k2 = red[t & 1][w];
            if (k2 > kb) kb = k2;
        }
        far = 8191 - (int)(kb & 0xFFFFFFFFu);   // identical in all threads
    }
}

// =====================================================================
// KNN: one block per (b,m). Per-thread 32 dists in REGISTERS with
// incrementally-maintained (best,idx); per round: wave-shuffle argmin +
// cross-wave 4-way reduce; owner does register rescan (no LDS dist).
// =====================================================================
__global__ __launch_bounds__(256) void knn_kernel(
    const float* __restrict__ xyz, const float* __restrict__ cxyz,
    float* __restrict__ gn)
{
#pragma clang fp contract(off)
    const int bm = blockIdx.x;
    const int b = bm / NG;
    const float* P = xyz + (size_t)b * NPTS * 3;
    __shared__ float rv4[4];
    __shared__ int   ri4[4];
    __shared__ int   order[KNB];
    const int tid = threadIdx.x;
    const float cx = cxyz[bm * 3 + 0], cy = cxyz[bm * 3 + 1], cz = cxyz[bm * 3 + 2];
    const float c2 = cx * cx + cy * cy + cz * cz;
    float d[32];
    float best = 1e31f; int bi = 1 << 30;
    #pragma unroll
    for (int j = 0; j < 32; ++j) {
        int n = tid + (j << 8);
        float x = P[n * 3 + 0], y = P[n * 3 + 1], z = P[n * 3 + 2];
        float x2 = x * x + y * y + z * z;
        float dt = cx * x + cy * y + cz * z;
        float v = (c2 + x2) - 2.0f * dt;
        d[j] = v;
        if (v < best) { best = v; bi = n; }        // strict < keeps lowest index
    }
    for (int r = 0; r < KNB; ++r) {
        float v = best; int i = bi;
        #pragma unroll
        for (int dd = 32; dd >= 1; dd >>= 1) {
            float v2 = __shfl_down(v, dd); int i2 = __shfl_down(i, dd);
            if (v2 < v || (v2 == v && i2 < i)) { v = v2; i = i2; }
        }
        if ((tid & 63) == 0) { rv4[tid >> 6] = v; ri4[tid >> 6] = i; }
        __syncthreads();
        float bv = rv4[0]; int bn = ri4[0];
        #pragma unroll
        for (int w = 1; w < 4; ++w) {
            float v2 = rv4[w]; int i2 = ri4[w];
            if (v2 < bv || (v2 == bv && i2 < bn)) { bv = v2; bn = i2; }
        }
        if (tid == 0) order[r] = bn;
        if ((bn & 255) == tid) {
            int sj = bn >> 8;
            best = 1e31f; bi = 1 << 30;
            #pragma unroll
            for (int j = 0; j < 32; ++j) {
                float vv = (j == sj) ? 1e30f : d[j];
                d[j] = vv;
                if (vv < best) { best = vv; bi = tid + (j << 8); }
            }
        }
        __syncthreads();
    }
    if (tid < KNB) {
        int n = order[tid];
        gn[((size_t)bm * KNB + tid) * 3 + 0] = P[n * 3 + 0] - cx;
        gn[((size_t)bm * KNB + tid) * 3 + 1] = P[n * 3 + 1] - cy;
        gn[((size_t)bm * KNB + tid) * 3 + 2] = P[n * 3 + 2] - cz;
    }
}

// =====================================================================
// f32 -> bf16 bulk convert (n multiple of 8)
// =====================================================================
__global__ void cvt_bf16_kernel(const float* __restrict__ src, __bf16* __restrict__ dst, int n8)
{
    int i = blockIdx.x * 256 + threadIdx.x;
    if (i >= n8) return;
    const float4* p = (const float4*)(src + (size_t)i * 8);
    *(bf16x8*)(dst + (size_t)i * 8) = pack8(p[0], p[1]);
}

// =====================================================================
// embed1: (131072,3)@(64,3)^T + bias
// =====================================================================
__global__ void embed1_kernel(const float* __restrict__ gn, const float* __restrict__ w,
                              const float* __restrict__ bias, float* __restrict__ h1)
{
    int i = blockIdx.x * 256 + threadIdx.x;
    if (i >= 131072 * 64) return;
    int r = i >> 6, c = i & 63;
    const float* p = gn + (size_t)r * 3;
    h1[i] = p[0] * w[c * 3 + 0] + p[1] * w[c * 3 + 1] + p[2] * w[c * 3 + 2] + bias[c];
}

// =====================================================================
// column stats (sum, sumsq) in double
// =====================================================================
template <int C>
__global__ __launch_bounds__(256) void colstats_kernel(const float* __restrict__ X,
                                                       double* __restrict__ st, int Mrows)
{
    constexpr int RL = 256 / C;
    const int c = threadIdx.x % C;
    const int rl = threadIdx.x / C;
    double s = 0.0, s2 = 0.0;
    int rows_per_block = (Mrows + gridDim.x - 1) / gridDim.x;
    int r0 = blockIdx.x * rows_per_block;
    int r1 = min(r0 + rows_per_block, Mrows);
    for (int r = r0 + rl; r < r1; r += RL) {
        float v = X[(size_t)r * C + c];
        s += v; s2 += (double)v * v;
    }
    __shared__ double sh[2][256];
    sh[0][threadIdx.x] = s; sh[1][threadIdx.x] = s2;
    __syncthreads();
    if (rl == 0) {
        for (int j = 1; j < RL; ++j) { s += sh[0][j * C + c]; s2 += sh[1][j * C + c]; }
        atomicAdd(&st[c], s);
        atomicAdd(&st[C + c], s2);
    }
}

__global__ void bn_finalize(const double* __restrict__ st, const float* __restrict__ g,
                            const float* __restrict__ be, float* __restrict__ sc,
                            float* __restrict__ shb, int C)
{
    int c = blockIdx.x * 64 + threadIdx.x;
    if (c >= C) return;
    double m = st[c] / 131072.0;
    double var = st[C + c] / 131072.0 - m * m;
    if (var < 0.0) var = 0.0;
    float rs = rsqrtf((float)var + 1e-5f);
    sc[c] = rs * g[c];
    shb[c] = be[c] - (float)m * rs * g[c];
}

// BN affine + relu, f32 in -> bf16 out
__global__ void bn_apply_bf16(const float* __restrict__ x, const float* __restrict__ sc,
                              const float* __restrict__ shb, __bf16* __restrict__ y,
                              int total, int C)
{
    int i = blockIdx.x * 256 + threadIdx.x;
    if (i >= total) return;
    int c = i % C;
    float v = x[i] * sc[c] + shb[c];
    v = fmaxf(v, 0.0f);
    y[i] = (__bf16)v;
}

// =====================================================================
// bf16 MFMA GEMM: C(M,N) = A(M,K) @ W(N,K)^T + bias (optional relu)
// BN=128, BK=64, 256 thr, global_load_lds staging, counted vmcnt.
// DEPTH==3: single-barrier/K-step 3-buffer pipeline (stage issues before
// compute under the same barrier; buffer reuse protected by the barrier).
// DEPTH==2: two-barrier double-buffer (for the 128-tile, keeps 2 blk/CU).
// Per-wave loads per stage: L = BM*8/256/... (BM=64 -> 6, BM=128 -> 8).
// =====================================================================
template <int BM, int WM, int WN, int DEPTH>
__global__ __launch_bounds__(256) void gemm_bf16(
    const __bf16* __restrict__ A, const __bf16* __restrict__ W,
    const float* __restrict__ bias, float* __restrict__ Cf, __bf16* __restrict__ Cb,
    int M, int N, int K, int relu)
{
    constexpr int MR = BM / WM / 16;      // m-frags per wave
    constexpr int NR = 128 / WN / 16;     // n-frags per wave
    constexpr int CA = BM * 8 / 256;      // A 16B-chunks per thread
    __shared__ __bf16 As[DEPTH][BM * 64];
    __shared__ __bf16 Ws[DEPTH][128 * 64];
    const int tid = threadIdx.x;
    const int lane = tid & 63;
    const int wave = tid >> 6;
    const int wm = wave / WN, wn = wave % WN;
    const int m0 = blockIdx.y * BM, n0 = blockIdx.x * 128;
    (void)M;

    f32x4 acc[MR][NR] = {};

    auto stage = [&](int buf, int kt) {
        #pragma unroll
        for (int j = 0; j < CA; ++j) {
            int cb = j * 256 + (wave << 6);
            int c  = cb + lane;
            int row = c >> 3;
            int kcs = (c & 7) ^ (row & 7);
            gload16(A + (size_t)(m0 + row) * K + kt + kcs * 8, &As[buf][cb * 8]);
        }
        #pragma unroll
        for (int j = 0; j < 4; ++j) {
            int cb = j * 256 + (wave << 6);
            int c  = cb + lane;
            int row = c >> 3;
            int kcs = (c & 7) ^ (row & 7);
            gload16(W + (size_t)(n0 + row) * K + kt + kcs * 8, &Ws[buf][cb * 8]);
        }
    };
    auto compute = [&](int buf) {
        #pragma unroll
        for (int ks = 0; ks < 2; ++ks) {
            bf16x8 af[MR], bfr[NR];
            int kc = ks * 4 + (lane >> 4);
            #pragma unroll
            for (int i = 0; i < MR; ++i) {
                int rowA = wm * (BM / WM) + i * 16 + (lane & 15);
                af[i] = *(bf16x8*)&As[buf][rowA * 64 + ((kc ^ (rowA & 7)) * 8)];
            }
            #pragma unroll
            for (int j = 0; j < NR; ++j) {
                int rowB = wn * (128 / WN) + j * 16 + (lane & 15);
                bfr[j] = *(bf16x8*)&Ws[buf][rowB * 64 + ((kc ^ (rowB & 7)) * 8)];
            }
            #pragma unroll
            for (int i = 0; i < MR; ++i)
                #pragma unroll
                for (int j = 0; j < NR; ++j)
                    acc[i][j] = __builtin_amdgcn_mfma_f32_16x16x32_bf16(af[i], bfr[j], acc[i][j], 0, 0, 0);
        }
    };

    const int nt = K >> 6;
    if constexpr (DEPTH == 3) {
        // single barrier per K-step: WAITV; barrier; stage(t+2); compute(t)
        stage(0, 0);
        if (nt > 1) stage(1, 64);
        for (int t = 0; t < nt; ++t) {
            if (t < nt - 1) { if constexpr (BM == 64) WAITV(6); else WAITV(8); }
            else            WAITV(0);
            __syncthreads();   // tile t visible to all; all done with buf (t+2)%3
            if (t + 2 < nt) stage((t + 2) % 3, (t + 2) << 6);
            compute(t % 3);
        }
    } else {
        // DEPTH==2: two barriers per K-step
        stage(0, 0);
        if (nt > 1) stage(1, 64);
        for (int t = 0; t < nt; ++t) {
            if (t < nt - 1) { if constexpr (BM == 64) WAITV(6); else WAITV(8); }
            else            WAITV(0);
            __syncthreads();
            compute(t % 2);
            if (t + 2 < nt + 0 || t + 2 == nt) { }
            if (t + 2 <= nt - 1) {
                __syncthreads();
                stage(t % 2, (t + 2) << 6);
            }
        }
    }

    #pragma unroll
    for (int j = 0; j < NR; ++j) {
        int col = n0 + wn * (128 / WN) + j * 16 + (lane & 15);
        if (col >= N) continue;
        float bv = bias[col];
        #pragma unroll
        for (int i = 0; i < MR; ++i) {
            #pragma unroll
            for (int r = 0; r < 4; ++r) {
                int rowm = m0 + wm * (BM / WM) + i * 16 + (lane >> 4) * 4 + r;
                float v = acc[i][j][r] + bv;
                if (relu) v = fmaxf(v, 0.0f);
                if (Cf) Cf[(size_t)rowm * N + col] = v;
                if (Cb) Cb[(size_t)rowm * N + col] = (__bf16)v;
            }
        }
    }
}

// =====================================================================
// embed3 via MFMA: (131072,768) = h2b(131072,128) @ cw3b^T, fused epilogue:
// bias + per-group(32-row) max/min + per-column sum/sumsq. grid (6,1024)
// =====================================================================
__global__ __launch_bounds__(256) void embed3_mfma(
    const __bf16* __restrict__ A, const __bf16* __restrict__ W,
    const float* __restrict__ cb3,
    float* __restrict__ gmax, float* __restrict__ gmin, double* __restrict__ st3)
{
    __shared__ __bf16 As[2][128 * 64];
    __shared__ __bf16 Ws[2][128 * 64];
    const int tid = threadIdx.x;
    const int lane = tid & 63;
    const int wave = tid >> 6;
    const int wm = wave >> 1, wn = wave & 1;
    const int m0 = blockIdx.y * 128, n0 = blockIdx.x * 128;
    const int K = 128;

    f32x4 acc[4][4] = {};

    auto stage = [&](int buf, int kt) {
        #pragma unroll
        for (int j = 0; j < 4; ++j) {
            int cb = j * 256 + (wave << 6);
            int c  = cb + lane;
            int row = c >> 3;
            int kcs = (c & 7) ^ (row & 7);
            gload16(A + (size_t)(m0 + row) * K + kt + kcs * 8, &As[buf][cb * 8]);
            gload16(W + (size_t)(n0 + row) * K + kt + kcs * 8, &Ws[buf][cb * 8]);
        }
    };
    auto compute = [&](int buf) {
        #pragma unroll
        for (int ks = 0; ks < 2; ++ks) {
            bf16x8 af[4], bfr[4];
            int kc = ks * 4 + (lane >> 4);
            #pragma unroll
            for (int i = 0; i < 4; ++i) {
                int rowA = wm * 64 + i * 16 + (lane & 15);
                af[i] = *(bf16x8*)&As[buf][rowA * 64 + ((kc ^ (rowA & 7)) * 8)];
                int rowB = wn * 64 + i * 16 + (lane & 15);
                bfr[i] = *(bf16x8*)&Ws[buf][rowB * 64 + ((kc ^ (rowB & 7)) * 8)];
            }
            #pragma unroll
            for (int i = 0; i < 4; ++i)
                #pragma unroll
                for (int j = 0; j < 4; ++j)
                    acc[i][j] = __builtin_amdgcn_mfma_f32_16x16x32_bf16(af[i], bfr[j], acc[i][j], 0, 0, 0);
        }
    };

    stage(0, 0);
    stage(1, 64);
    WAITV(8);
    __syncthreads();
    compute(0);
    WAITV(0);
    __syncthreads();
    compute(1);

    #pragma unroll
    for (int j = 0; j < 4; ++j) {
        int col = n0 + wn * 64 + j * 16 + (lane & 15);
        float bv = cb3[col];
        float stot = 0.0f, s2tot = 0.0f;
        #pragma unroll
        for (int gi = 0; gi < 2; ++gi) {
            float mx = -1e30f, mn = 1e30f, s = 0.0f, s2 = 0.0f;
            #pragma unroll
            for (int ii = 0; ii < 2; ++ii) {
                f32x4 a = acc[gi * 2 + ii][j];
                #pragma unroll
                for (int r = 0; r < 4; ++r) {
                    float v = a[r] + bv;
                    mx = fmaxf(mx, v); mn = fminf(mn, v);
                    s += v; s2 += v * v;
                }
            }
            #pragma unroll
            for (int d = 16; d < 64; d <<= 1) {
                mx = fmaxf(mx, __shfl_xor(mx, d));
                mn = fminf(mn, __shfl_xor(mn, d));
                s  += __shfl_xor(s, d);
                s2 += __shfl_xor(s2, d);
            }
            stot += s; s2tot += s2;
            if (lane < 16) {
                int g = (m0 >> 5) + wm * 2 + gi;
                gmax[(size_t)g * 768 + col] = mx;
                gmin[(size_t)g * 768 + col] = mn;
            }
        }
        if (lane < 16) {
            double* stp = st3 + (size_t)(blockIdx.y & 31) * 1536;
            atomicAdd(&stp[col], (double)stot);
            atomicAdd(&stp[768 + col], (double)s2tot);
        }
    }
}

__global__ void bn3_finalize(const double* __restrict__ st3, const float* __restrict__ g,
                             const float* __restrict__ be, float* __restrict__ a3,
                             float* __restrict__ c3)
{
    int c = blockIdx.x * 256 + threadIdx.x;
    if (c >= 768) return;
    double s = 0.0, s2 = 0.0;
    for (int p = 0; p < 32; ++p) { s += st3[(size_t)p * 1536 + c]; s2 += st3[(size_t)p * 1536 + 768 + c]; }
    double m = s / 131072.0;
    double var = s2 / 131072.0 - m * m;
    if (var < 0.0) var = 0.0;
    float rs = rsqrtf((float)var + 1e-5f);
    a3[c] = rs * g[c];
    c3[c] = be[c] - (float)m * rs * g[c];
}

// tokens = affine(max/min) ; x = tokens + cxyz@pos_w^T + pos_b
__global__ void tokens_pos(const float* __restrict__ gmax, const float* __restrict__ gmin,
                           const float* __restrict__ a3, const float* __restrict__ c3,
                           const float* __restrict__ cxyz, const float* __restrict__ posw,
                           const float* __restrict__ posb, float* __restrict__ x)
{
    int i = blockIdx.x * 256 + threadIdx.x;
    if (i >= 4096 * 768) return;
    int c = i % 768, g = i / 768;
    float a = a3[c];
    float tok = (a >= 0.0f ? a * gmax[i] : a * gmin[i]) + c3[c];
    float px = cxyz[g * 3 + 0], py = cxyz[g * 3 + 1], pz = cxyz[g * 3 + 2];
    x[i] = tok + px * posw[c * 3 + 0] + py * posw[c * 3 + 1] + pz * posw[c * 3 + 2] + posb[c];
}

__global__ void restore_kernel(const int* __restrict__ shuffle, int* __restrict__ restore)
{
    int j = blockIdx.x * 256 + threadIdx.x;
    if (j >= BB * NG) return;
    int b = j / NG, p = j % NG;
    restore[b * NG + shuffle[j]] = p;
}

__global__ void mask_kernel(const int* __restrict__ restore, float* __restrict__ maskv)
{
    int i = blockIdx.x * 256 + threadIdx.x;
    if (i >= BB * NG) return;
    maskv[i] = (restore[i] < LK) ? 0.0f : 1.0f;
}

__global__ void gather_xk(const float* __restrict__ xfull, const int* __restrict__ shuffle,
                          float* __restrict__ xe, __bf16* __restrict__ xeb)
{
    int i = blockIdx.x * 256 + threadIdx.x;
    if (i >= BB * LK * DE) return;
    int c = i % DE;
    int s = (i / DE) % LK;
    int b = i / (DE * LK);
    float v = xfull[((size_t)b * NG + shuffle[b * NG + s]) * DE + c];
    xe[i] = v;
    xeb[i] = (__bf16)v;
}

__global__ void yd_build(const float* __restrict__ yk, const int* __restrict__ restore,
                         const float* __restrict__ mtok, const float* __restrict__ cxyz,
                         const float* __restrict__ dpw, const float* __restrict__ dpb,
                         float* __restrict__ xd, __bf16* __restrict__ xdb)
{
    int i = blockIdx.x * 256 + threadIdx.x;
    if (i >= BB * NG * DD) return;
    int c = i % DD;
    int g = i / DD;
    int b = g / NG;
    int r = restore[g];
    float base = (r < LK) ? yk[((size_t)b * LK + r) * DD + c] : mtok[c];
    float px = cxyz[g * 3 + 0], py = cxyz[g * 3 + 1], pz = cxyz[g * 3 + 2];
    float v = base + px * dpw[c * 3 + 0] + py * dpw[c * 3 + 1] + pz * dpw[c * 3 + 2] + dpb[c];
    xd[i] = v;
    xdb[i] = (__bf16)v;
}

// =====================================================================
// attention: block per (b, h, q-tile). f32 in, bf16 out.
// softmax wave-parallel: 8 lanes per q-row, shfl_xor reduce.
// =====================================================================
template <int S, int DH, int QT, int NH>
__global__ __launch_bounds__(256) void attn_kernel(const float* __restrict__ qkv,
                                                   __bf16* __restrict__ o, float scale)
{
    constexpr int D = NH * DH;
    constexpr int NT = S / QT;
    constexpr int CH = S / 8;          // cols per lane in softmax
    __shared__ float Ks[S][DH];
    __shared__ float Vs[S][DH];
    __shared__ float Qs[QT][DH];
    __shared__ float P[QT][S];
    const int t = blockIdx.x % NT;
    const int h = (blockIdx.x / NT) % NH;
    const int b = blockIdx.x / (NT * NH);
    const float* base = qkv + (size_t)b * S * 3 * D + h * DH;
    for (int i = threadIdx.x; i < S * DH; i += 256) {
        int s = i / DH, d = i % DH;
        Ks[s][d] = base[(size_t)s * 3 * D + D + d];
        Vs[s][d] = base[(size_t)s * 3 * D + 2 * D + d];
    }
    for (int i = threadIdx.x; i < QT * DH; i += 256) {
        int qi = i / DH, d = i % DH;
        Qs[qi][d] = base[(size_t)(t * QT + qi) * 3 * D + d];
    }
    __syncthreads();
    for (int i = threadIdx.x; i < QT * S; i += 256) {
        int qi = i / S, s = i % S;
        float acc = 0.0f;
        #pragma unroll 8
        for (int d = 0; d < DH; ++d) acc += Qs[qi][d] * Ks[s][d];
        P[qi][s] = acc * scale;
    }
    __syncthreads();
    {
        int qi = threadIdx.x >> 3;        // 32 rows, 8 lanes each
        int sub = threadIdx.x & 7;
        float mx = -1e30f;
        #pragma unroll
        for (int j = 0; j < CH; ++j) mx = fmaxf(mx, P[qi][sub * CH + j]);
        #pragma unroll
        for (int d = 4; d >= 1; d >>= 1) mx = fmaxf(mx, __shfl_xor(mx, d));
        float sum = 0.0f;
        #pragma unroll
        for (int j = 0; j < CH; ++j) {
            float e = expf(P[qi][sub * CH + j] - mx);
            P[qi][sub * CH + j] = e;
            sum += e;
        }
        #pragma unroll
        for (int d = 4; d >= 1; d >>= 1) sum += __shfl_xor(sum, d);
        float inv = 1.0f / sum;
        #pragma unroll
        for (int j = 0; j < CH; ++j) P[qi][sub * CH + j] *= inv;
    }
    __syncthreads();
    __bf16* ob = o + (size_t)b * S * D + h * DH;
    for (int i = threadIdx.x; i < QT * DH; i += 256) {
        int qi = i / DH, d = i % DH;
        float acc = 0.0f;
        for (int s = 0; s < S; ++s) acc += P[qi][s] * Vs[s][d];
        ob[(size_t)(t * QT + qi) * D + d] = (__bf16)acc;
    }
}

// =====================================================================
// LayerNorm with residual, in place: x = LN(x + r) * g + b ; bf16 copy.
// Register-resident row, one-pass sum/sumsq, single barrier.
// =====================================================================
template <int D>
__global__ __launch_bounds__(256) void ln_res(float* __restrict__ x, const float* __restrict__ r,
                                              const float* __restrict__ g, const float* __restrict__ b,
                                              __bf16* __restrict__ xb)
{
    constexpr int J = D / 256;
    __shared__ float pr[2][4];
    const size_t off = (size_t)blockIdx.x * D;
    const int tid = threadIdx.x;
    float vals[J];
    float s = 0.0f, s2 = 0.0f;
    #pragma unroll
    for (int j = 0; j < J; ++j) {
        int i = tid + j * 256;
        float v = x[off + i] + r[off + i];
        vals[j] = v; s += v; s2 += v * v;
    }
    #pragma unroll
    for (int d = 32; d >= 1; d >>= 1) { s += __shfl_down(s, d); s2 += __shfl_down(s2, d); }
    if ((tid & 63) == 0) { pr[0][tid >> 6] = s; pr[1][tid >> 6] = s2; }
    __syncthreads();
    float st = pr[0][0] + pr[0][1] + pr[0][2] + pr[0][3];
    float s2t = pr[1][0] + pr[1][1] + pr[1][2] + pr[1][3];
    float m = st / D;
    float var = s2t / D - m * m;
    if (var < 0.0f) var = 0.0f;
    float rs = rsqrtf(var + 1e-5f);
    #pragma unroll
    for (int j = 0; j < J; ++j) {
        int i = tid + j * 256;
        float v = (vals[j] - m) * rs * g[i] + b[i];
        x[off + i] = v;
        xb[off + i] = (__bf16)v;
    }
}

// =====================================================================
// loss
// =====================================================================
__global__ __launch_bounds__(128) void loss_l(const float* __restrict__ pred,
                                              const float* __restrict__ target,
                                              const float* __restrict__ maskv,
                                              float* __restrict__ lm)
{
    const int g = blockIdx.x;
    __shared__ float red[128];
    int t = threadIdx.x;
    float s = 0.0f;
    if (t < 96) {
        float d = pred[(size_t)g * 96 + t] - target[(size_t)g * 96 + t];
        s = d * d;
    }
    red[t] = s; __syncthreads();
    for (int st = 64; st > 0; st >>= 1) { if (t < st) red[t] += red[t + st]; __syncthreads(); }
    if (t == 0) lm[g] = (red[0] / 96.0f) * maskv[g];
}

__global__ __launch_bounds__(1024) void loss_final(const float* __restrict__ lm,
                                                   const float* __restrict__ maskv,
                                                   float* __restrict__ out)
{
    __shared__ float r1[1024], r2[1024];
    int t = threadIdx.x;
    float a = 0.0f, b = 0.0f;
    for (int i = t; i < BB * NG; i += 1024) { a += lm[i]; b += maskv[i]; }
    r1[t] = a; r2[t] = b; __syncthreads();
    for (int st = 512; st > 0; st >>= 1) { if (t < st) { r1[t] += r1[t + st]; r2[t] += r2[t + st]; } __syncthreads(); }
    if (t == 0) out[0] = r1[0] / r2[0];
}

// =====================================================================
// host
// =====================================================================
extern "C" void kernel_launch(void* const* d_in, const int* in_sizes, int n_in,
                              void* d_out, int out_size, void* d_ws, size_t ws_size,
                              hipStream_t stream)
{
    (void)in_sizes; (void)n_in; (void)out_size; (void)ws_size;
    const float* xyz        = (const float*)d_in[0];
    const int*   fps_init   = (const int*)d_in[1];
    const int*   ids_shuf   = (const int*)d_in[2];
    const float* cw1 = (const float*)d_in[3];  const float* cb1 = (const float*)d_in[4];
    const float* g1  = (const float*)d_in[5];  const float* be1 = (const float*)d_in[6];
    const float* cw2 = (const float*)d_in[7];  const float* cb2 = (const float*)d_in[8];
    const float* g2  = (const float*)d_in[9];  const float* be2 = (const float*)d_in[10];
    const float* cw3 = (const float*)d_in[11]; const float* cb3 = (const float*)d_in[12];
    const float* g3  = (const float*)d_in[13]; const float* be3 = (const float*)d_in[14];
    const float* posw = (const float*)d_in[15]; const float* posb = (const float*)d_in[16];
    const float* eqw = (const float*)d_in[17]; const float* eqb = (const float*)d_in[18];
    const float* eow = (const float*)d_in[19]; const float* eob = (const float*)d_in[20];
    const float* el1g = (const float*)d_in[21]; const float* el1b = (const float*)d_in[22];
    const float* ef1w = (const float*)d_in[23]; const float* ef1b = (const float*)d_in[24];
    const float* ef2w = (const float*)d_in[25]; const float* ef2b = (const float*)d_in[26];
    const float* el2g = (const float*)d_in[27]; const float* el2b = (const float*)d_in[28];
    const float* dew = (const float*)d_in[29]; const float* deb = (const float*)d_in[30];
    const float* mtok = (const float*)d_in[31];
    const float* dpw = (const float*)d_in[32]; const float* dpb = (const float*)d_in[33];
    const float* dqw = (const float*)d_in[34]; const float* dqb = (const float*)d_in[35];
    const float* dow = (const float*)d_in[36]; const float* dob = (const float*)d_in[37];
    const float* dl1g = (const float*)d_in[38]; const float* dl1b = (const float*)d_in[39];
    const float* df1w = (const float*)d_in[40]; const float* df1b = (const float*)d_in[41];
    const float* df2w = (const float*)d_in[42]; const float* df2b = (const float*)d_in[43];
    const float* dl2g = (const float*)d_in[44]; const float* dl2b = (const float*)d_in[45];
    const float* prw = (const float*)d_in[46]; const float* prb = (const float*)d_in[47];
    float* out = (float*)d_out;
    float* pred = out + 1;
    float* maskv = out + 1 + (size_t)BB * NG * KNB * 3;

    // ---- workspace carve ----
    char* ws = (char*)d_ws;
    size_t off = 0;
    auto alloc = [&](size_t bytes) -> void* {
        void* p = ws + off;
        off = (off + bytes + 255) & ~(size_t)255;
        return p;
    };
    double* st1 = (double*)alloc(128 * 8);
    double* st2 = (double*)alloc(256 * 8);
    double* st3 = (double*)alloc((size_t)32 * 1536 * 8);
    float* sc1 = (float*)alloc(64 * 4);  float* sh1 = (float*)alloc(64 * 4);
    float* sc2 = (float*)alloc(128 * 4); float* sh2 = (float*)alloc(128 * 4);
    float* a3 = (float*)alloc(768 * 4);  float* c3 = (float*)alloc(768 * 4);
    int* restore = (int*)alloc(4096 * 4);
    float* cxyz = (float*)alloc(12288 * 4);
    float* gn   = (float*)alloc((size_t)393216 * 4);
    __bf16* cw2b = (__bf16*)alloc((size_t)128 * 64 * 2);
    __bf16* cw3b = (__bf16*)alloc((size_t)768 * 128 * 2);
    float* xfull = (float*)alloc((size_t)4096 * 768 * 4);
    float* xe    = (float*)alloc((size_t)1024 * 768 * 4);
    __bf16* xeb  = (__bf16*)alloc((size_t)1024 * 768 * 2);
    float* qkve  = (float*)alloc((size_t)1024 * 2304 * 4);
    __bf16* oeb  = (__bf16*)alloc((size_t)1024 * 768 * 2);
    __bf16* fe1b = (__bf16*)alloc((size_t)1024 * 3072 * 2);
    float* yk    = (float*)alloc((size_t)1024 * 512 * 4);
    float* xd    = (float*)alloc((size_t)4096 * 512 * 4);
    __bf16* xdb  = (__bf16*)alloc((size_t)4096 * 512 * 2);
    float* qkvd  = (float*)alloc((size_t)4096 * 1536 * 4);
    __bf16* odb  = (__bf16*)alloc((size_t)4096 * 512 * 2);
    __bf16* fd1b = (__bf16*)alloc((size_t)4096 * 2048 * 2);
    float* tmpd  = (float*)alloc((size_t)4096 * 512 * 4);
    float* lm    = (float*)alloc(4096 * 4);

    __bf16* eqwb  = (__bf16*)alloc((size_t)NLE * 3 * DE * DE * 2);
    __bf16* eowb  = (__bf16*)alloc((size_t)NLE * DE * DE * 2);
    __bf16* ef1wb = (__bf16*)alloc((size_t)NLE * 4 * DE * DE * 2);
    __bf16* ef2wb = (__bf16*)alloc((size_t)NLE * 4 * DE * DE * 2);
    __bf16* dewb  = (__bf16*)alloc((size_t)DD * DE * 2);
    __bf16* dqwb  = (__bf16*)alloc((size_t)NLD * 3 * DD * DD * 2);
    __bf16* dowb  = (__bf16*)alloc((size_t)NLD * DD * DD * 2);
    __bf16* df1wb = (__bf16*)alloc((size_t)NLD * 4 * DD * DD * 2);
    __bf16* df2wb = (__bf16*)alloc((size_t)NLD * 4 * DD * DD * 2);
    __bf16* prwb  = (__bf16*)alloc((size_t)128 * 512 * 2);

    char* U = (char*)eqwb;
    float*  h1   = (float*)U;
    __bf16* h1b  = (__bf16*)(U + (size_t)33554432);
    float*  h2   = (float*)(U + (size_t)50331648);
    __bf16* h2b  = (__bf16*)(U + (size_t)117440512);
    float*  gmax = (float*)(U + (size_t)150994944);
    float*  gmin = (float*)(U + (size_t)163577856);

    size_t stats_bytes = (size_t)((char*)st3 + (size_t)32 * 1536 * 8 - (char*)st1);
    hipMemsetAsync((void*)st1, 0, stats_bytes, stream);

    auto cvt = [&](const float* src, __bf16* dst, size_t n) {
        int n8 = (int)(n / 8);
        cvt_bf16_kernel<<<(n8 + 255) / 256, 256, 0, stream>>>(src, dst, n8);
    };
    auto gemm = [&](const __bf16* A, const __bf16* Wt, const float* bias,
                    float* Cf, __bf16* Cb, int M, int N, int K, int relu) {
        int nb128 = ((N + 127) / 128) * (M / 128);
        if (nb128 < 256) {
            dim3 grid((N + 127) / 128, M / 64);
            gemm_bf16<64, 1, 4, 3><<<grid, 256, 0, stream>>>(A, Wt, bias, Cf, Cb, M, N, K, relu);
        } else {
            dim3 grid((N + 127) / 128, M / 128);
            gemm_bf16<128, 2, 2, 2><<<grid, 256, 0, stream>>>(A, Wt, bias, Cf, Cb, M, N, K, relu);
        }
    };

    cvt(cw2, cw2b, 128 * 64);
    cvt(cw3, cw3b, 768 * 128);

    // ---- stage 1: FPS + KNN ----
    fps_kernel<<<BB, 256, 0, stream>>>(xyz, fps_init, cxyz);
    knn_kernel<<<BB * NG, 256, 0, stream>>>(xyz, cxyz, gn);

    // ---- stage 2: mini-PointNet ----
    embed1_kernel<<<(131072 * 64 + 255) / 256, 256, 0, stream>>>(gn, cw1, cb1, h1);
    colstats_kernel<64><<<256, 256, 0, stream>>>(h1, st1, 131072);
    bn_finalize<<<1, 64, 0, stream>>>(st1, g1, be1, sc1, sh1, 64);
    bn_apply_bf16<<<(131072 * 64 + 255) / 256, 256, 0, stream>>>(h1, sc1, sh1, h1b, 131072 * 64, 64);
    gemm(h1b, cw2b, cb2, h2, nullptr, 131072, 128, 64, 0);
    colstats_kernel<128><<<256, 256, 0, stream>>>(h2, st2, 131072);
    bn_finalize<<<2, 64, 0, stream>>>(st2, g2, be2, sc2, sh2, 128);
    bn_apply_bf16<<<(131072 * 128 + 255) / 256, 256, 0, stream>>>(h2, sc2, sh2, h2b, 131072 * 128, 128);
    embed3_mfma<<<dim3(6, 1024), 256, 0, stream>>>(h2b, cw3b, cb3, gmax, gmin, st3);
    bn3_finalize<<<3, 256, 0, stream>>>(st3, g3, be3, a3, c3);
    tokens_pos<<<(4096 * 768 + 255) / 256, 256, 0, stream>>>(gmax, gmin, a3, c3, cxyz, posw, posb, xfull);

    // ---- stage 3: shuffle / mask ----
    restore_kernel<<<16, 256, 0, stream>>>(ids_shuf, restore);
    mask_kernel<<<16, 256, 0, stream>>>(restore, maskv);
    gather_xk<<<(BB * LK * DE + 255) / 256, 256, 0, stream>>>(xfull, ids_shuf, xe, xeb);

    // ---- weight conversion (after stage-2 temps are dead) ----
    cvt(eqw,  eqwb,  (size_t)NLE * 3 * DE * DE);
    cvt(eow,  eowb,  (size_t)NLE * DE * DE);
    cvt(ef1w, ef1wb, (size_t)NLE * 4 * DE * DE);
    cvt(ef2w, ef2wb, (size_t)NLE * 4 * DE * DE);
    cvt(dew,  dewb,  (size_t)DD * DE);
    cvt(dqw,  dqwb,  (size_t)NLD * 3 * DD * DD);
    cvt(dow,  dowb,  (size_t)NLD * DD * DD);
    cvt(df1w, df1wb, (size_t)NLD * 4 * DD * DD);
    cvt(df2w, df2wb, (size_t)NLD * 4 * DD * DD);
    cvt(prw,  prwb,  (size_t)96 * 512);
    hipMemsetAsync((void*)(prwb + (size_t)96 * 512), 0, (size_t)32 * 512 * 2, stream);

    // ---- stage 4: encoder (12 layers) ----
    for (int l = 0; l < NLE; ++l) {
        gemm(xeb, eqwb + (size_t)l * 3 * DE * DE, eqb + (size_t)l * 3 * DE, qkve, nullptr, 1024, 3 * DE, DE, 0);
        attn_kernel<LK, 64, 32, 12><<<BB * 12, 256, 0, stream>>>(qkve, oeb, 0.125f);
        gemm(oeb, eowb + (size_t)l * DE * DE, eob + (size_t)l * DE, xfull, nullptr, 1024, DE, DE, 0);
        ln_res<DE><<<BB * LK, 256, 0, stream>>>(xe, xfull, el1g + (size_t)l * DE, el1b + (size_t)l * DE, xeb);
        gemm(xeb, ef1wb + (size_t)l * 4 * DE * DE, ef1b + (size_t)l * 4 * DE, nullptr, fe1b, 1024, 4 * DE, DE, 1);
        gemm(fe1b, ef2wb + (size_t)l * DE * 4 * DE, ef2b + (size_t)l * DE, xfull, nullptr, 1024, DE, 4 * DE, 0);
        ln_res<DE><<<BB * LK, 256, 0, stream>>>(xe, xfull, el2g + (size_t)l * DE, el2b + (size_t)l * DE, xeb);
    }

    // ---- stage 5: decoder embed + mask tokens ----
    gemm(xeb, dewb, deb, yk, nullptr, 1024, DD, DE, 0);
    yd_build<<<(BB * NG * DD + 255) / 256, 256, 0, stream>>>(yk, restore, mtok, cxyz, dpw, dpb, xd, xdb);

    // ---- stage 6: decoder (8 layers) ----
    const float dsc = (float)(1.0 / sqrt(32.0));
    for (int l = 0; l < NLD; ++l) {
        gemm(xdb, dqwb + (size_t)l * 3 * DD * DD, dqb + (size_t)l * 3 * DD, qkvd, nullptr, 4096, 3 * DD, DD, 0);
        attn_kernel<NG, 32, 32, 16><<<BB * 16 * (NG / 32), 256, 0, stream>>>(qkvd, odb, dsc);
        gemm(odb, dowb + (size_t)l * DD * DD, dob + (size_t)l * DD, tmpd, nullptr, 4096, DD, DD, 0);
        ln_res<DD><<<BB * NG, 256, 0, stream>>>(xd, tmpd, dl1g + (size_t)l * DD, dl1b + (size_t)l * DD, xdb);
        gemm(xdb, df1wb + (size_t)l * 4 * DD * DD, df1b + (size_t)l * 4 * DD, nullptr, fd1b, 4096, 4 * DD, DD, 1);
        gemm(fd1b, df2wb + (size_t)l * DD * 4 * DD, df2b + (size_t)l * DD, tmpd, nullptr, 4096, DD, 4 * DD, 0);
        ln_res<DD><<<BB * NG, 256, 0, stream>>>(xd, tmpd, dl2g + (size_t)l * DD, dl2b + (size_t)l * DD, xdb);
    }

    // ---- stage 7: prediction + loss ----
    gemm(xdb, prwb, prb, pred, nullptr, 4096, 96, 512, 0);
    loss_l<<<BB * NG, 128, 0, stream>>>(pred, gn, maskv, lm);
    loss_final<<<1, 1024, 0, stream>>>(lm, maskv, out);
}

// Round 7
// 2779.386 us; speedup vs baseline: 8.3391x; 1.4027x over previous
//
#include <hip/hip_runtime.h>
#include <cmath>

// ---------------- problem constants ----------------
#define BB 32          // batch
#define NPTS 8192      // points per cloud
#define NG 128         // groups
#define KNB 32         // neighbors per group
#define LK 32          // len_keep
#define DE 768         // encoder dim
#define DD 512         // decoder dim
#define NLE 12
#define NLD 8

typedef __bf16 bf16x8 __attribute__((ext_vector_type(8)));
typedef float  f32x4  __attribute__((ext_vector_type(4)));
typedef unsigned long long u64;

#define WAITV(N) asm volatile("s_waitcnt vmcnt(" #N ")" ::: "memory")

static __device__ __forceinline__ bf16x8 pack8(float4 a, float4 b) {
    bf16x8 h;
    h[0] = (__bf16)a.x; h[1] = (__bf16)a.y; h[2] = (__bf16)a.z; h[3] = (__bf16)a.w;
    h[4] = (__bf16)b.x; h[5] = (__bf16)b.y; h[6] = (__bf16)b.z; h[7] = (__bf16)b.w;
    return h;
}

// async global->LDS 16B copy: per-wave, lane l writes ldsbase + l*16
static __device__ __forceinline__ void gload16(const __bf16* g, __bf16* l) {
    __builtin_amdgcn_global_load_lds(
        (const __attribute__((address_space(1))) void*)g,
        (__attribute__((address_space(3))) void*)l,
        16, 0, 0);
}

// monotone float -> uint map (total order preserved, handles negatives)
static __device__ __forceinline__ unsigned fkey(float f) {
    unsigned u = __float_as_uint(f);
    return ((int)u < 0) ? ~u : (u | 0x80000000u);
}

// =====================================================================
// FPS: one block per batch, 256 threads. Point coords AND dmin in
// REGISTERS (32 pts/thread); LDS copy only for centroid broadcast.
// =====================================================================
__global__ __launch_bounds__(256, 1) void fps_kernel(
    const float* __restrict__ xyz, const int* __restrict__ init,
    float* __restrict__ cxyz)
{
#pragma clang fp contract(off)
    const int b = blockIdx.x;
    const float* P = xyz + (size_t)b * NPTS * 3;
    __shared__ float pxs[NPTS], pys[NPTS], pzs[NPTS];
    __shared__ u64 red[2][4];
    const int tid = threadIdx.x;
    float x[32], y[32], z[32], dmin[32];
    #pragma unroll
    for (int k = 0; k < 32; ++k) {
        int n = tid + (k << 8);
        float xx = P[n * 3 + 0], yy = P[n * 3 + 1], zz = P[n * 3 + 2];
        x[k] = xx; y[k] = yy; z[k] = zz;
        pxs[n] = xx; pys[n] = yy; pzs[n] = zz;
        dmin[k] = 1e10f;
    }
    int far = init[b];
    __syncthreads();
    for (int t = 0; t < NG; ++t) {
        float cx = pxs[far], cy = pys[far], cz = pzs[far];
        if (tid == 0) {
            cxyz[(b * NG + t) * 3 + 0] = cx;
            cxyz[(b * NG + t) * 3 + 1] = cy;
            cxyz[(b * NG + t) * 3 + 2] = cz;
        }
        u64 key = 0ull;
        #pragma unroll
        for (int k = 0; k < 32; ++k) {
            float dx = x[k] - cx, dy = y[k] - cy, dz = z[k] - cz;
            float d = dx * dx + dy * dy + dz * dz;
            float dm = dmin[k];
            if (d < dm) dm = d;
            dmin[k] = dm;
            u64 kk = ((u64)__float_as_uint(dm) << 32) | (unsigned)(8191 - (tid + (k << 8)));
            if (kk > key) key = kk;
        }
        #pragma unroll
        for (int d = 32; d >= 1; d >>= 1) {
            u64 k2 = __shfl_down(key, d);
            if (k2 > key) key = k2;
        }
        if ((tid & 63) == 0) red[t & 1][tid >> 6] = key;
        __syncthreads();
        u64 kb = red[t & 1][0];
        #pragma unroll
        for (int w = 1; w < 4; ++w) {
            u64 k2 = red[t & 1][w];
            if (k2 > kb) kb = k2;
        }
        far = 8191 - (int)(kb & 0xFFFFFFFFu);
    }
}

// =====================================================================
// KNN: one block per (b,m). Phase 1: each wave privately selects its own
// sorted top-32 (pure wave shuffles, NO barriers). Phase 2: wave 0 ranks
// the 128 candidates (u64 keys) and scatters order[rank]. 2 barriers total.
// Global top-32 is a subset of the union of per-wave top-32s (each point
// belongs to exactly one wave).
// =====================================================================
__global__ __launch_bounds__(256) void knn_kernel(
    const float* __restrict__ xyz, const float* __restrict__ cxyz,
    float* __restrict__ gn)
{
#pragma clang fp contract(off)
    const int bm = blockIdx.x;
    const int b = bm / NG;
    const float* P = xyz + (size_t)b * NPTS * 3;
    __shared__ u64 cand[128];
    __shared__ int order[KNB];
    const int tid = threadIdx.x;
    const int wv = tid >> 6, lane = tid & 63;
    const float cx = cxyz[bm * 3 + 0], cy = cxyz[bm * 3 + 1], cz = cxyz[bm * 3 + 2];
    const float c2 = cx * cx + cy * cy + cz * cz;
    float d[32];
    float best = 1e31f; int bi = 1 << 30;
    #pragma unroll
    for (int j = 0; j < 32; ++j) {
        int n = tid + (j << 8);
        float x = P[n * 3 + 0], y = P[n * 3 + 1], z = P[n * 3 + 2];
        float x2 = x * x + y * y + z * z;
        float dt = cx * x + cy * y + cz * z;
        float v = (c2 + x2) - 2.0f * dt;
        d[j] = v;
        if (v < best) { best = v; bi = n; }        // strict < keeps lowest index
    }
    // phase 1: 32 wave-local rounds, no block barriers
    for (int r = 0; r < KNB; ++r) {
        float v = best; int i = bi;
        #pragma unroll
        for (int dd = 32; dd >= 1; dd >>= 1) {
            float v2 = __shfl_down(v, dd); int i2 = __shfl_down(i, dd);
            if (v2 < v || (v2 == v && i2 < i)) { v = v2; i = i2; }
        }
        v = __shfl(v, 0); i = __shfl(i, 0);        // broadcast wave winner
        if (lane == 0)
            cand[wv * 32 + r] = ((u64)fkey(v) << 32) | (unsigned)i;
        if ((i & 255) == tid) {
            int sj = i >> 8;
            best = 1e31f; bi = 1 << 30;
            #pragma unroll
            for (int j = 0; j < 32; ++j) {
                float vv = (j == sj) ? 1e30f : d[j];
                d[j] = vv;
                if (vv < best) { best = vv; bi = tid + (j << 8); }
            }
        }
    }
    __syncthreads();
    // phase 2: wave 0 ranks 128 candidates (keys distinct since idx distinct)
    if (wv == 0) {
        u64 my0 = cand[lane], my1 = cand[lane + 64];
        int r0 = 0, r1 = 0;
        #pragma unroll 16
        for (int j = 0; j < 128; ++j) {
            u64 k = cand[j];
            r0 += (k < my0); r1 += (k < my1);
        }
        if (r0 < KNB) order[r0] = (int)(my0 & 0xFFFFFFFFu);
        if (r1 < KNB) order[r1] = (int)(my1 & 0xFFFFFFFFu);
    }
    __syncthreads();
    if (tid < KNB) {
        int n = order[tid];
        gn[((size_t)bm * KNB + tid) * 3 + 0] = P[n * 3 + 0] - cx;
        gn[((size_t)bm * KNB + tid) * 3 + 1] = P[n * 3 + 1] - cy;
        gn[((size_t)bm * KNB + tid) * 3 + 2] = P[n * 3 + 2] - cz;
    }
}

// =====================================================================
// f32 -> bf16 bulk convert (n multiple of 8)
// =====================================================================
__global__ void cvt_bf16_kernel(const float* __restrict__ src, __bf16* __restrict__ dst, int n8)
{
    int i = blockIdx.x * 256 + threadIdx.x;
    if (i >= n8) return;
    const float4* p = (const float4*)(src + (size_t)i * 8);
    *(bf16x8*)(dst + (size_t)i * 8) = pack8(p[0], p[1]);
}

// =====================================================================
// embed1: (131072,3)@(64,3)^T + bias
// =====================================================================
__global__ void embed1_kernel(const float* __restrict__ gn, const float* __restrict__ w,
                              const float* __restrict__ bias, float* __restrict__ h1)
{
    int i = blockIdx.x * 256 + threadIdx.x;
    if (i >= 131072 * 64) return;
    int r = i >> 6, c = i & 63;
    const float* p = gn + (size_t)r * 3;
    h1[i] = p[0] * w[c * 3 + 0] + p[1] * w[c * 3 + 1] + p[2] * w[c * 3 + 2] + bias[c];
}

// =====================================================================
// column stats (sum, sumsq) in double
// =====================================================================
template <int C>
__global__ __launch_bounds__(256) void colstats_kernel(const float* __restrict__ X,
                                                       double* __restrict__ st, int Mrows)
{
    constexpr int RL = 256 / C;
    const int c = threadIdx.x % C;
    const int rl = threadIdx.x / C;
    double s = 0.0, s2 = 0.0;
    int rows_per_block = (Mrows + gridDim.x - 1) / gridDim.x;
    int r0 = blockIdx.x * rows_per_block;
    int r1 = min(r0 + rows_per_block, Mrows);
    for (int r = r0 + rl; r < r1; r += RL) {
        float v = X[(size_t)r * C + c];
        s += v; s2 += (double)v * v;
    }
    __shared__ double sh[2][256];
    sh[0][threadIdx.x] = s; sh[1][threadIdx.x] = s2;
    __syncthreads();
    if (rl == 0) {
        for (int j = 1; j < RL; ++j) { s += sh[0][j * C + c]; s2 += sh[1][j * C + c]; }
        atomicAdd(&st[c], s);
        atomicAdd(&st[C + c], s2);
    }
}

__global__ void bn_finalize(const double* __restrict__ st, const float* __restrict__ g,
                            const float* __restrict__ be, float* __restrict__ sc,
                            float* __restrict__ shb, int C)
{
    int c = blockIdx.x * 64 + threadIdx.x;
    if (c >= C) return;
    double m = st[c] / 131072.0;
    double var = st[C + c] / 131072.0 - m * m;
    if (var < 0.0) var = 0.0;
    float rs = rsqrtf((float)var + 1e-5f);
    sc[c] = rs * g[c];
    shb[c] = be[c] - (float)m * rs * g[c];
}

// BN affine + relu, f32 in -> bf16 out
__global__ void bn_apply_bf16(const float* __restrict__ x, const float* __restrict__ sc,
                              const float* __restrict__ shb, __bf16* __restrict__ y,
                              int total, int C)
{
    int i = blockIdx.x * 256 + threadIdx.x;
    if (i >= total) return;
    int c = i % C;
    float v = x[i] * sc[c] + shb[c];
    v = fmaxf(v, 0.0f);
    y[i] = (__bf16)v;
}

// =====================================================================
// bf16 MFMA GEMM with split-K: C_partial[sk](M,N) = A(M, chunk) @ W^T + bias
// grid.z = SK; chunk k-range = [sk*Kc, (sk+1)*Kc); bias applied at sk==0.
// BN=128, BK=64, 256 thr, global_load_lds staging, counted vmcnt.
// DEPTH==3: single-barrier/K-step 3-buffer pipeline. DEPTH==2: 2-barrier.
// =====================================================================
template <int BM, int WM, int WN, int DEPTH>
__global__ __launch_bounds__(256) void gemm_bf16(
    const __bf16* __restrict__ A, const __bf16* __restrict__ W,
    const float* __restrict__ bias, float* __restrict__ Cf, __bf16* __restrict__ Cb,
    int M, int N, int K, int Kc, int relu)
{
    constexpr int MR = BM / WM / 16;
    constexpr int NR = 128 / WN / 16;
    constexpr int CA = BM * 8 / 256;
    __shared__ __bf16 As[DEPTH][BM * 64];
    __shared__ __bf16 Ws[DEPTH][128 * 64];
    const int tid = threadIdx.x;
    const int lane = tid & 63;
    const int wave = tid >> 6;
    const int wm = wave / WN, wn = wave % WN;
    const int m0 = blockIdx.y * BM, n0 = blockIdx.x * 128;
    const int kb = blockIdx.z * Kc;

    f32x4 acc[MR][NR] = {};

    auto stage = [&](int buf, int kt) {
        #pragma unroll
        for (int j = 0; j < CA; ++j) {
            int cb = j * 256 + (wave << 6);
            int c  = cb + lane;
            int row = c >> 3;
            int kcs = (c & 7) ^ (row & 7);
            gload16(A + (size_t)(m0 + row) * K + kb + kt + kcs * 8, &As[buf][cb * 8]);
        }
        #pragma unroll
        for (int j = 0; j < 4; ++j) {
            int cb = j * 256 + (wave << 6);
            int c  = cb + lane;
            int row = c >> 3;
            int kcs = (c & 7) ^ (row & 7);
            gload16(W + (size_t)(n0 + row) * K + kb + kt + kcs * 8, &Ws[buf][cb * 8]);
        }
    };
    auto compute = [&](int buf) {
        #pragma unroll
        for (int ks = 0; ks < 2; ++ks) {
            bf16x8 af[MR], bfr[NR];
            int kc = ks * 4 + (lane >> 4);
            #pragma unroll
            for (int i = 0; i < MR; ++i) {
                int rowA = wm * (BM / WM) + i * 16 + (lane & 15);
                af[i] = *(bf16x8*)&As[buf][rowA * 64 + ((kc ^ (rowA & 7)) * 8)];
            }
            #pragma unroll
            for (int j = 0; j < NR; ++j) {
                int rowB = wn * (128 / WN) + j * 16 + (lane & 15);
                bfr[j] = *(bf16x8*)&Ws[buf][rowB * 64 + ((kc ^ (rowB & 7)) * 8)];
            }
            #pragma unroll
            for (int i = 0; i < MR; ++i)
                #pragma unroll
                for (int j = 0; j < NR; ++j)
                    acc[i][j] = __builtin_amdgcn_mfma_f32_16x16x32_bf16(af[i], bfr[j], acc[i][j], 0, 0, 0);
        }
    };

    const int nt = Kc >> 6;
    if constexpr (DEPTH == 3) {
        stage(0, 0);
        if (nt > 1) stage(1, 64);
        for (int t = 0; t < nt; ++t) {
            if (t < nt - 1) { if constexpr (BM == 64) WAITV(6); else WAITV(8); }
            else            WAITV(0);
            __syncthreads();
            if (t + 2 < nt) stage((t + 2) % 3, (t + 2) << 6);
            compute(t % 3);
        }
    } else {
        stage(0, 0);
        if (nt > 1) stage(1, 64);
        for (int t = 0; t < nt; ++t) {
            if (t < nt - 1) { if constexpr (BM == 64) WAITV(6); else WAITV(8); }
            else            WAITV(0);
            __syncthreads();
            compute(t % 2);
            if (t + 2 <= nt - 1) {
                __syncthreads();
                stage(t % 2, (t + 2) << 6);
            }
        }
    }

    float* Co = Cf ? Cf + (size_t)blockIdx.z * M * N : nullptr;
    #pragma unroll
    for (int j = 0; j < NR; ++j) {
        int col = n0 + wn * (128 / WN) + j * 16 + (lane & 15);
        if (col >= N) continue;
        float bv = (blockIdx.z == 0) ? bias[col] : 0.0f;
        #pragma unroll
        for (int i = 0; i < MR; ++i) {
            #pragma unroll
            for (int r = 0; r < 4; ++r) {
                int rowm = m0 + wm * (BM / WM) + i * 16 + (lane >> 4) * 4 + r;
                float v = acc[i][j][r] + bv;
                if (relu) v = fmaxf(v, 0.0f);
                if (Co) Co[(size_t)rowm * N + col] = v;
                if (Cb) Cb[(size_t)rowm * N + col] = (__bf16)v;
            }
        }
    }
}

// =====================================================================
// embed3 via MFMA: fused epilogue (bias + group max/min + column stats)
// =====================================================================
__global__ __launch_bounds__(256) void embed3_mfma(
    const __bf16* __restrict__ A, const __bf16* __restrict__ W,
    const float* __restrict__ cb3,
    float* __restrict__ gmax, float* __restrict__ gmin, double* __restrict__ st3)
{
    __shared__ __bf16 As[2][128 * 64];
    __shared__ __bf16 Ws[2][128 * 64];
    const int tid = threadIdx.x;
    const int lane = tid & 63;
    const int wave = tid >> 6;
    const int wm = wave >> 1, wn = wave & 1;
    const int m0 = blockIdx.y * 128, n0 = blockIdx.x * 128;
    const int K = 128;

    f32x4 acc[4][4] = {};

    auto stage = [&](int buf, int kt) {
        #pragma unroll
        for (int j = 0; j < 4; ++j) {
            int cb = j * 256 + (wave << 6);
            int c  = cb + lane;
            int row = c >> 3;
            int kcs = (c & 7) ^ (row & 7);
            gload16(A + (size_t)(m0 + row) * K + kt + kcs * 8, &As[buf][cb * 8]);
            gload16(W + (size_t)(n0 + row) * K + kt + kcs * 8, &Ws[buf][cb * 8]);
        }
    };
    auto compute = [&](int buf) {
        #pragma unroll
        for (int ks = 0; ks < 2; ++ks) {
            bf16x8 af[4], bfr[4];
            int kc = ks * 4 + (lane >> 4);
            #pragma unroll
            for (int i = 0; i < 4; ++i) {
                int rowA = wm * 64 + i * 16 + (lane & 15);
                af[i] = *(bf16x8*)&As[buf][rowA * 64 + ((kc ^ (rowA & 7)) * 8)];
                int rowB = wn * 64 + i * 16 + (lane & 15);
                bfr[i] = *(bf16x8*)&Ws[buf][rowB * 64 + ((kc ^ (rowB & 7)) * 8)];
            }
            #pragma unroll
            for (int i = 0; i < 4; ++i)
                #pragma unroll
                for (int j = 0; j < 4; ++j)
                    acc[i][j] = __builtin_amdgcn_mfma_f32_16x16x32_bf16(af[i], bfr[j], acc[i][j], 0, 0, 0);
        }
    };

    stage(0, 0);
    stage(1, 64);
    WAITV(8);
    __syncthreads();
    compute(0);
    WAITV(0);
    __syncthreads();
    compute(1);

    #pragma unroll
    for (int j = 0; j < 4; ++j) {
        int col = n0 + wn * 64 + j * 16 + (lane & 15);
        float bv = cb3[col];
        float stot = 0.0f, s2tot = 0.0f;
        #pragma unroll
        for (int gi = 0; gi < 2; ++gi) {
            float mx = -1e30f, mn = 1e30f, s = 0.0f, s2 = 0.0f;
            #pragma unroll
            for (int ii = 0; ii < 2; ++ii) {
                f32x4 a = acc[gi * 2 + ii][j];
                #pragma unroll
                for (int r = 0; r < 4; ++r) {
                    float v = a[r] + bv;
                    mx = fmaxf(mx, v); mn = fminf(mn, v);
                    s += v; s2 += v * v;
                }
            }
            #pragma unroll
            for (int d = 16; d < 64; d <<= 1) {
                mx = fmaxf(mx, __shfl_xor(mx, d));
                mn = fminf(mn, __shfl_xor(mn, d));
                s  += __shfl_xor(s, d);
                s2 += __shfl_xor(s2, d);
            }
            stot += s; s2tot += s2;
            if (lane < 16) {
                int g = (m0 >> 5) + wm * 2 + gi;
                gmax[(size_t)g * 768 + col] = mx;
                gmin[(size_t)g * 768 + col] = mn;
            }
        }
        if (lane < 16) {
            double* stp = st3 + (size_t)(blockIdx.y & 31) * 1536;
            atomicAdd(&stp[col], (double)stot);
            atomicAdd(&stp[768 + col], (double)s2tot);
        }
    }
}

__global__ void bn3_finalize(const double* __restrict__ st3, const float* __restrict__ g,
                             const float* __restrict__ be, float* __restrict__ a3,
                             float* __restrict__ c3)
{
    int c = blockIdx.x * 256 + threadIdx.x;
    if (c >= 768) return;
    double s = 0.0, s2 = 0.0;
    for (int p = 0; p < 32; ++p) { s += st3[(size_t)p * 1536 + c]; s2 += st3[(size_t)p * 1536 + 768 + c]; }
    double m = s / 131072.0;
    double var = s2 / 131072.0 - m * m;
    if (var < 0.0) var = 0.0;
    float rs = rsqrtf((float)var + 1e-5f);
    a3[c] = rs * g[c];
    c3[c] = be[c] - (float)m * rs * g[c];
}

// tokens = affine(max/min) ; x = tokens + cxyz@pos_w^T + pos_b
__global__ void tokens_pos(const float* __restrict__ gmax, const float* __restrict__ gmin,
                           const float* __restrict__ a3, const float* __restrict__ c3,
                           const float* __restrict__ cxyz, const float* __restrict__ posw,
                           const float* __restrict__ posb, float* __restrict__ x)
{
    int i = blockIdx.x * 256 + threadIdx.x;
    if (i >= 4096 * 768) return;
    int c = i % 768, g = i / 768;
    float a = a3[c];
    float tok = (a >= 0.0f ? a * gmax[i] : a * gmin[i]) + c3[c];
    float px = cxyz[g * 3 + 0], py = cxyz[g * 3 + 1], pz = cxyz[g * 3 + 2];
    x[i] = tok + px * posw[c * 3 + 0] + py * posw[c * 3 + 1] + pz * posw[c * 3 + 2] + posb[c];
}

// restore + mask fused (both scatter through shuffle[j])
__global__ void restore_kernel(const int* __restrict__ shuffle, int* __restrict__ restore,
                               float* __restrict__ maskv)
{
    int j = blockIdx.x * 256 + threadIdx.x;
    if (j >= BB * NG) return;
    int b = j / NG, p = j % NG;
    int dst = b * NG + shuffle[j];
    restore[dst] = p;
    maskv[dst] = (p < LK) ? 0.0f : 1.0f;
}

__global__ void gather_xk(const float* __restrict__ xfull, const int* __restrict__ shuffle,
                          float* __restrict__ xe, __bf16* __restrict__ xeb)
{
    int i = blockIdx.x * 256 + threadIdx.x;
    if (i >= BB * LK * DE) return;
    int c = i % DE;
    int s = (i / DE) % LK;
    int b = i / (DE * LK);
    float v = xfull[((size_t)b * NG + shuffle[b * NG + s]) * DE + c];
    xe[i] = v;
    xeb[i] = (__bf16)v;
}

// yd = (kept ? sum of 4 yk partials : mtok) + cxyz@dpw^T + dpb
__global__ void yd_build(const float* __restrict__ ykp, const int* __restrict__ restore,
                         const float* __restrict__ mtok, const float* __restrict__ cxyz,
                         const float* __restrict__ dpw, const float* __restrict__ dpb,
                         float* __restrict__ xd, __bf16* __restrict__ xdb)
{
    const size_t PS = (size_t)1024 * DD;
    int i = blockIdx.x * 256 + threadIdx.x;
    if (i >= BB * NG * DD) return;
    int c = i % DD;
    int g = i / DD;
    int b = g / NG;
    int r = restore[g];
    float base;
    if (r < LK) {
        size_t o = (size_t)(b * LK + r) * DD + c;
        base = ykp[o] + ykp[PS + o] + ykp[2 * PS + o] + ykp[3 * PS + o];
    } else {
        base = mtok[c];
    }
    float px = cxyz[g * 3 + 0], py = cxyz[g * 3 + 1], pz = cxyz[g * 3 + 2];
    float v = base + px * dpw[c * 3 + 0] + py * dpw[c * 3 + 1] + pz * dpw[c * 3 + 2] + dpb[c];
    xd[i] = v;
    xdb[i] = (__bf16)v;
}

// =====================================================================
// attention: block per (b, h, q-tile). f32 in, bf16 out. float4 LDS ops,
// padded rows; softmax wave-parallel (8 lanes/row).
// =====================================================================
template <int S, int DH, int QT, int NH>
__global__ __launch_bounds__(256) void attn_kernel(const float* __restrict__ qkv,
                                                   __bf16* __restrict__ o, float scale)
{
    constexpr int D = NH * DH;
    constexpr int NT = S / QT;
    constexpr int DH4 = DH / 4;
    constexpr int KW = DH + 4;         // padded row stride (floats)
    constexpr int PS = S + 4;
    constexpr int CH = S / 8;
    __shared__ float Ks[S][KW];
    __shared__ float Vs[S][KW];
    __shared__ float Qs[QT][KW];
    __shared__ float Pb[QT][PS];
    const int t = blockIdx.x % NT;
    const int h = (blockIdx.x / NT) % NH;
    const int b = blockIdx.x / (NT * NH);
    const float* base = qkv + (size_t)b * S * 3 * D + h * DH;
    for (int i = threadIdx.x; i < S * DH4; i += 256) {
        int s = i / DH4, d4 = (i % DH4) * 4;
        *(float4*)&Ks[s][d4] = *(const float4*)&base[(size_t)s * 3 * D + D + d4];
        *(float4*)&Vs[s][d4] = *(const float4*)&base[(size_t)s * 3 * D + 2 * D + d4];
    }
    for (int i = threadIdx.x; i < QT * DH4; i += 256) {
        int qi = i / DH4, d4 = (i % DH4) * 4;
        *(float4*)&Qs[qi][d4] = *(const float4*)&base[(size_t)(t * QT + qi) * 3 * D + d4];
    }
    __syncthreads();
    for (int i = threadIdx.x; i < QT * S; i += 256) {
        int qi = i / S, s = i % S;
        float acc = 0.0f;
        #pragma unroll
        for (int d4 = 0; d4 < DH; d4 += 4) {
            float4 q = *(float4*)&Qs[qi][d4];
            float4 k = *(float4*)&Ks[s][d4];
            acc += q.x * k.x + q.y * k.y + q.z * k.z + q.w * k.w;
        }
        Pb[qi][s] = acc * scale;
    }
    __syncthreads();
    {
        int qi = threadIdx.x >> 3;        // 32 rows, 8 lanes each
        int sub = threadIdx.x & 7;
        float mx = -1e30f;
        #pragma unroll
        for (int j = 0; j < CH; ++j) mx = fmaxf(mx, Pb[qi][sub * CH + j]);
        #pragma unroll
        for (int d = 4; d >= 1; d >>= 1) mx = fmaxf(mx, __shfl_xor(mx, d));
        float sum = 0.0f;
        #pragma unroll
        for (int j = 0; j < CH; ++j) {
            float e = expf(Pb[qi][sub * CH + j] - mx);
            Pb[qi][sub * CH + j] = e;
            sum += e;
        }
        #pragma unroll
        for (int d = 4; d >= 1; d >>= 1) sum += __shfl_xor(sum, d);
        float inv = 1.0f / sum;
        #pragma unroll
        for (int j = 0; j < CH; ++j) Pb[qi][sub * CH + j] *= inv;
    }
    __syncthreads();
    __bf16* ob = o + (size_t)b * S * D + h * DH;
    for (int i = threadIdx.x; i < QT * DH4; i += 256) {
        int qi = i / DH4, d4 = (i % DH4) * 4;
        float4 acc = {0, 0, 0, 0};
        for (int s = 0; s < S; ++s) {
            float p = Pb[qi][s];
            float4 v = *(float4*)&Vs[s][d4];
            acc.x += p * v.x; acc.y += p * v.y; acc.z += p * v.z; acc.w += p * v.w;
        }
        __bf16 o4[4] = {(__bf16)acc.x, (__bf16)acc.y, (__bf16)acc.z, (__bf16)acc.w};
        *(ushort4*)&ob[(size_t)(t * QT + qi) * D + d4] = *(ushort4*)o4;
    }
}

// =====================================================================
// LayerNorm with residual (optionally summing SK split-K partials):
// x = LN(x + sum_partials) * g + b ; bf16 copy out.
// =====================================================================
template <int D, int SK>
__global__ __launch_bounds__(256) void ln_res(float* __restrict__ x, const float* __restrict__ part,
                                              size_t pstride,
                                              const float* __restrict__ g, const float* __restrict__ b,
                                              __bf16* __restrict__ xb)
{
    constexpr int J = D / 256;
    __shared__ float pr[2][4];
    const size_t off = (size_t)blockIdx.x * D;
    const int tid = threadIdx.x;
    float vals[J];
    float s = 0.0f, s2 = 0.0f;
    #pragma unroll
    for (int j = 0; j < J; ++j) {
        int i = tid + j * 256;
        float v = x[off + i];
        #pragma unroll
        for (int sk = 0; sk < SK; ++sk) v += part[(size_t)sk * pstride + off + i];
        vals[j] = v; s += v; s2 += v * v;
    }
    #pragma unroll
    for (int d = 32; d >= 1; d >>= 1) { s += __shfl_down(s, d); s2 += __shfl_down(s2, d); }
    if ((tid & 63) == 0) { pr[0][tid >> 6] = s; pr[1][tid >> 6] = s2; }
    __syncthreads();
    float st = pr[0][0] + pr[0][1] + pr[0][2] + pr[0][3];
    float s2t = pr[1][0] + pr[1][1] + pr[1][2] + pr[1][3];
    float m = st / D;
    float var = s2t / D - m * m;
    if (var < 0.0f) var = 0.0f;
    float rs = rsqrtf(var + 1e-5f);
    #pragma unroll
    for (int j = 0; j < J; ++j) {
        int i = tid + j * 256;
        float v = (vals[j] - m) * rs * g[i] + b[i];
        x[off + i] = v;
        xb[off + i] = (__bf16)v;
    }
}

// =====================================================================
// loss
// =====================================================================
__global__ __launch_bounds__(128) void loss_l(const float* __restrict__ pred,
                                              const float* __restrict__ target,
                                              const float* __restrict__ maskv,
                                              float* __restrict__ lm)
{
    const int g = blockIdx.x;
    __shared__ float red[128];
    int t = threadIdx.x;
    float s = 0.0f;
    if (t < 96) {
        float d = pred[(size_t)g * 96 + t] - target[(size_t)g * 96 + t];
        s = d * d;
    }
    red[t] = s; __syncthreads();
    for (int st = 64; st > 0; st >>= 1) { if (t < st) red[t] += red[t + st]; __syncthreads(); }
    if (t == 0) lm[g] = (red[0] / 96.0f) * maskv[g];
}

__global__ __launch_bounds__(1024) void loss_final(const float* __restrict__ lm,
                                                   const float* __restrict__ maskv,
                                                   float* __restrict__ out)
{
    __shared__ float r1[1024], r2[1024];
    int t = threadIdx.x;
    float a = 0.0f, b = 0.0f;
    for (int i = t; i < BB * NG; i += 1024) { a += lm[i]; b += maskv[i]; }
    r1[t] = a; r2[t] = b; __syncthreads();
    for (int st = 512; st > 0; st >>= 1) { if (t < st) { r1[t] += r1[t + st]; r2[t] += r2[t + st]; } __syncthreads(); }
    if (t == 0) out[0] = r1[0] / r2[0];
}

// =====================================================================
// host
// =====================================================================
extern "C" void kernel_launch(void* const* d_in, const int* in_sizes, int n_in,
                              void* d_out, int out_size, void* d_ws, size_t ws_size,
                              hipStream_t stream)
{
    (void)in_sizes; (void)n_in; (void)out_size; (void)ws_size;
    const float* xyz        = (const float*)d_in[0];
    const int*   fps_init   = (const int*)d_in[1];
    const int*   ids_shuf   = (const int*)d_in[2];
    const float* cw1 = (const float*)d_in[3];  const float* cb1 = (const float*)d_in[4];
    const float* g1  = (const float*)d_in[5];  const float* be1 = (const float*)d_in[6];
    const float* cw2 = (const float*)d_in[7];  const float* cb2 = (const float*)d_in[8];
    const float* g2  = (const float*)d_in[9];  const float* be2 = (const float*)d_in[10];
    const float* cw3 = (const float*)d_in[11]; const float* cb3 = (const float*)d_in[12];
    const float* g3  = (const float*)d_in[13]; const float* be3 = (const float*)d_in[14];
    const float* posw = (const float*)d_in[15]; const float* posb = (const float*)d_in[16];
    const float* eqw = (const float*)d_in[17]; const float* eqb = (const float*)d_in[18];
    const float* eow = (const float*)d_in[19]; const float* eob = (const float*)d_in[20];
    const float* el1g = (const float*)d_in[21]; const float* el1b = (const float*)d_in[22];
    const float* ef1w = (const float*)d_in[23]; const float* ef1b = (const float*)d_in[24];
    const float* ef2w = (const float*)d_in[25]; const float* ef2b = (const float*)d_in[26];
    const float* el2g = (const float*)d_in[27]; const float* el2b = (const float*)d_in[28];
    const float* dew = (const float*)d_in[29]; const float* deb = (const float*)d_in[30];
    const float* mtok = (const float*)d_in[31];
    const float* dpw = (const float*)d_in[32]; const float* dpb = (const float*)d_in[33];
    const float* dqw = (const float*)d_in[34]; const float* dqb = (const float*)d_in[35];
    const float* dow = (const float*)d_in[36]; const float* dob = (const float*)d_in[37];
    const float* dl1g = (const float*)d_in[38]; const float* dl1b = (const float*)d_in[39];
    const float* df1w = (const float*)d_in[40]; const float* df1b = (const float*)d_in[41];
    const float* df2w = (const float*)d_in[42]; const float* df2b = (const float*)d_in[43];
    const float* dl2g = (const float*)d_in[44]; const float* dl2b = (const float*)d_in[45];
    const float* prw = (const float*)d_in[46]; const float* prb = (const float*)d_in[47];
    float* out = (float*)d_out;
    float* pred = out + 1;
    float* maskv = out + 1 + (size_t)BB * NG * KNB * 3;

    // ---- workspace carve ----
    char* ws = (char*)d_ws;
    size_t off = 0;
    auto alloc = [&](size_t bytes) -> void* {
        void* p = ws + off;
        off = (off + bytes + 255) & ~(size_t)255;
        return p;
    };
    double* st1 = (double*)alloc(128 * 8);
    double* st2 = (double*)alloc(256 * 8);
    double* st3 = (double*)alloc((size_t)32 * 1536 * 8);
    float* sc1 = (float*)alloc(64 * 4);  float* sh1 = (float*)alloc(64 * 4);
    float* sc2 = (float*)alloc(128 * 4); float* sh2 = (float*)alloc(128 * 4);
    float* a3 = (float*)alloc(768 * 4);  float* c3 = (float*)alloc(768 * 4);
    int* restore = (int*)alloc(4096 * 4);
    float* cxyz = (float*)alloc(12288 * 4);
    float* gn   = (float*)alloc((size_t)393216 * 4);
    __bf16* cw2b = (__bf16*)alloc((size_t)128 * 64 * 2);
    __bf16* cw3b = (__bf16*)alloc((size_t)768 * 128 * 2);
    float* xfull = (float*)alloc((size_t)4096 * 768 * 4);   // also 4x(1024x768) partials
    float* xe    = (float*)alloc((size_t)1024 * 768 * 4);
    __bf16* xeb  = (__bf16*)alloc((size_t)1024 * 768 * 2);
    float* qkve  = (float*)alloc((size_t)1024 * 2304 * 4);  // also 4x(1024x512) dew partials
    __bf16* oeb  = (__bf16*)alloc((size_t)1024 * 768 * 2);
    __bf16* fe1b = (__bf16*)alloc((size_t)1024 * 3072 * 2);
    float* xd    = (float*)alloc((size_t)4096 * 512 * 4);
    __bf16* xdb  = (__bf16*)alloc((size_t)4096 * 512 * 2);
    float* qkvd  = (float*)alloc((size_t)4096 * 1536 * 4);  // also 2x(4096x512) partials
    __bf16* odb  = (__bf16*)alloc((size_t)4096 * 512 * 2);
    __bf16* fd1b = (__bf16*)alloc((size_t)4096 * 2048 * 2);
    float* lm    = (float*)alloc(4096 * 4);

    __bf16* eqwb  = (__bf16*)alloc((size_t)NLE * 3 * DE * DE * 2);
    __bf16* eowb  = (__bf16*)alloc((size_t)NLE * DE * DE * 2);
    __bf16* ef1wb = (__bf16*)alloc((size_t)NLE * 4 * DE * DE * 2);
    __bf16* ef2wb = (__bf16*)alloc((size_t)NLE * 4 * DE * DE * 2);
    __bf16* dewb  = (__bf16*)alloc((size_t)DD * DE * 2);
    __bf16* dqwb  = (__bf16*)alloc((size_t)NLD * 3 * DD * DD * 2);
    __bf16* dowb  = (__bf16*)alloc((size_t)NLD * DD * DD * 2);
    __bf16* df1wb = (__bf16*)alloc((size_t)NLD * 4 * DD * DD * 2);
    __bf16* df2wb = (__bf16*)alloc((size_t)NLD * 4 * DD * DD * 2);
    __bf16* prwb  = (__bf16*)alloc((size_t)128 * 512 * 2);

    char* U = (char*)eqwb;
    float*  h1   = (float*)U;
    __bf16* h1b  = (__bf16*)(U + (size_t)33554432);
    float*  h2   = (float*)(U + (size_t)50331648);
    __bf16* h2b  = (__bf16*)(U + (size_t)117440512);
    float*  gmax = (float*)(U + (size_t)150994944);
    float*  gmin = (float*)(U + (size_t)163577856);

    size_t stats_bytes = (size_t)((char*)st3 + (size_t)32 * 1536 * 8 - (char*)st1);
    hipMemsetAsync((void*)st1, 0, stats_bytes, stream);

    auto cvt = [&](const float* src, __bf16* dst, size_t n) {
        int n8 = (int)(n / 8);
        cvt_bf16_kernel<<<(n8 + 255) / 256, 256, 0, stream>>>(src, dst, n8);
    };
    // non-split gemm (auto tile select)
    auto gemm = [&](const __bf16* A, const __bf16* Wt, const float* bias,
                    float* Cf, __bf16* Cb, int M, int N, int K, int relu) {
        int nb128 = ((N + 127) / 128) * (M / 128);
        if (nb128 < 256) {
            dim3 grid((N + 127) / 128, M / 64, 1);
            gemm_bf16<64, 1, 4, 3><<<grid, 256, 0, stream>>>(A, Wt, bias, Cf, Cb, M, N, K, K, relu);
        } else {
            dim3 grid((N + 127) / 128, M / 128, 1);
            gemm_bf16<128, 2, 2, 2><<<grid, 256, 0, stream>>>(A, Wt, bias, Cf, Cb, M, N, K, K, relu);
        }
    };
    // split-K gemm (BM=64 path), partials at Cf + sk*M*N
    auto gemmSK = [&](const __bf16* A, const __bf16* Wt, const float* bias,
                      float* Cf, int M, int N, int K, int SK) {
        dim3 grid((N + 127) / 128, M / 64, SK);
        gemm_bf16<64, 1, 4, 3><<<grid, 256, 0, stream>>>(A, Wt, bias, Cf, nullptr, M, N, K, K / SK, 0);
    };

    cvt(cw2, cw2b, 128 * 64);
    cvt(cw3, cw3b, 768 * 128);

    // ---- stage 1: FPS + KNN ----
    fps_kernel<<<BB, 256, 0, stream>>>(xyz, fps_init, cxyz);
    knn_kernel<<<BB * NG, 256, 0, stream>>>(xyz, cxyz, gn);

    // ---- stage 2: mini-PointNet ----
    embed1_kernel<<<(131072 * 64 + 255) / 256, 256, 0, stream>>>(gn, cw1, cb1, h1);
    colstats_kernel<64><<<256, 256, 0, stream>>>(h1, st1, 131072);
    bn_finalize<<<1, 64, 0, stream>>>(st1, g1, be1, sc1, sh1, 64);
    bn_apply_bf16<<<(131072 * 64 + 255) / 256, 256, 0, stream>>>(h1, sc1, sh1, h1b, 131072 * 64, 64);
    gemm(h1b, cw2b, cb2, h2, nullptr, 131072, 128, 64, 0);
    colstats_kernel<128><<<256, 256, 0, stream>>>(h2, st2, 131072);
    bn_finalize<<<2, 64, 0, stream>>>(st2, g2, be2, sc2, sh2, 128);
    bn_apply_bf16<<<(131072 * 128 + 255) / 256, 256, 0, stream>>>(h2, sc2, sh2, h2b, 131072 * 128, 128);
    embed3_mfma<<<dim3(6, 1024), 256, 0, stream>>>(h2b, cw3b, cb3, gmax, gmin, st3);
    bn3_finalize<<<3, 256, 0, stream>>>(st3, g3, be3, a3, c3);
    tokens_pos<<<(4096 * 768 + 255) / 256, 256, 0, stream>>>(gmax, gmin, a3, c3, cxyz, posw, posb, xfull);

    // ---- stage 3: shuffle / mask ----
    restore_kernel<<<16, 256, 0, stream>>>(ids_shuf, restore, maskv);
    gather_xk<<<(BB * LK * DE + 255) / 256, 256, 0, stream>>>(xfull, ids_shuf, xe, xeb);

    // ---- weight conversion (after stage-2 temps are dead) ----
    cvt(eqw,  eqwb,  (size_t)NLE * 3 * DE * DE);
    cvt(eow,  eowb,  (size_t)NLE * DE * DE);
    cvt(ef1w, ef1wb, (size_t)NLE * 4 * DE * DE);
    cvt(ef2w, ef2wb, (size_t)NLE * 4 * DE * DE);
    cvt(dew,  dewb,  (size_t)DD * DE);
    cvt(dqw,  dqwb,  (size_t)NLD * 3 * DD * DD);
    cvt(dow,  dowb,  (size_t)NLD * DD * DD);
    cvt(df1w, df1wb, (size_t)NLD * 4 * DD * DD);
    cvt(df2w, df2wb, (size_t)NLD * 4 * DD * DD);
    cvt(prw,  prwb,  (size_t)96 * 512);
    hipMemsetAsync((void*)(prwb + (size_t)96 * 512), 0, (size_t)32 * 512 * 2, stream);

    const size_t PSE = (size_t)1024 * DE;   // encoder partial stride
    const size_t PSD = (size_t)4096 * DD;   // decoder partial stride

    // ---- stage 4: encoder (12 layers) ----
    for (int l = 0; l < NLE; ++l) {
        gemm(xeb, eqwb + (size_t)l * 3 * DE * DE, eqb + (size_t)l * 3 * DE, qkve, nullptr, 1024, 3 * DE, DE, 0);
        attn_kernel<LK, 64, 32, 12><<<BB * 12, 256, 0, stream>>>(qkve, oeb, 0.125f);
        gemmSK(oeb, eowb + (size_t)l * DE * DE, eob + (size_t)l * DE, xfull, 1024, DE, DE, 4);
        ln_res<DE, 4><<<BB * LK, 256, 0, stream>>>(xe, xfull, PSE, el1g + (size_t)l * DE, el1b + (size_t)l * DE, xeb);
        gemm(xeb, ef1wb + (size_t)l * 4 * DE * DE, ef1b + (size_t)l * 4 * DE, nullptr, fe1b, 1024, 4 * DE, DE, 1);
        gemmSK(fe1b, ef2wb + (size_t)l * DE * 4 * DE, ef2b + (size_t)l * DE, xfull, 1024, DE, 4 * DE, 4);
        ln_res<DE, 4><<<BB * LK, 256, 0, stream>>>(xe, xfull, PSE, el2g + (size_t)l * DE, el2b + (size_t)l * DE, xeb);
    }

    // ---- stage 5: decoder embed + mask tokens ----
    gemmSK(xeb, dewb, deb, qkve, 1024, DD, DE, 4);
    yd_build<<<(BB * NG * DD + 255) / 256, 256, 0, stream>>>(qkve, restore, mtok, cxyz, dpw, dpb, xd, xdb);

    // ---- stage 6: decoder (8 layers) ----
    const float dsc = (float)(1.0 / sqrt(32.0));
    for (int l = 0; l < NLD; ++l) {
        gemm(xdb, dqwb + (size_t)l * 3 * DD * DD, dqb + (size_t)l * 3 * DD, qkvd, nullptr, 4096, 3 * DD, DD, 0);
        attn_kernel<NG, 32, 32, 16><<<BB * 16 * (NG / 32), 256, 0, stream>>>(qkvd, odb, dsc);
        gemmSK(odb, dowb + (size_t)l * DD * DD, dob + (size_t)l * DD, qkvd, 4096, DD, DD, 2);
        ln_res<DD, 2><<<BB * NG, 256, 0, stream>>>(xd, qkvd, PSD, dl1g + (size_t)l * DD, dl1b + (size_t)l * DD, xdb);
        gemm(xdb, df1wb + (size_t)l * 4 * DD * DD, df1b + (size_t)l * 4 * DD, nullptr, fd1b, 4096, 4 * DD, DD, 1);
        gemmSK(fd1b, df2wb + (size_t)l * DD * 4 * DD, df2b + (size_t)l * DD, qkvd, 4096, DD, 4 * DD, 2);
        ln_res<DD, 2><<<BB * NG, 256, 0, stream>>>(xd, qkvd, PSD, dl2g + (size_t)l * DD, dl2b + (size_t)l * DD, xdb);
    }

    // ---- stage 7: prediction + loss ----
    gemm(xdb, prwb, prb, pred, nullptr, 4096, 96, 512, 0);
    loss_l<<<BB * NG, 128, 0, stream>>>(pred, gn, maskv, lm);
    loss_final<<<1, 1024, 0, stream>>>(lm, maskv, out);
}

// Round 8
// 2618.359 us; speedup vs baseline: 8.8520x; 1.0615x over previous
//
#include <hip/hip_runtime.h>
#include <cmath>

// ---------------- problem constants ----------------
#define BB 32          // batch
#define NPTS 8192      // points per cloud
#define NG 128         // groups
#define KNB 32         // neighbors per group
#define LK 32          // len_keep
#define DE 768         // encoder dim
#define DD 512         // decoder dim
#define NLE 12
#define NLD 8

typedef __bf16 bf16x8 __attribute__((ext_vector_type(8)));
typedef float  f32x4  __attribute__((ext_vector_type(4)));
typedef unsigned long long u64;

#define WAITV(N) asm volatile("s_waitcnt vmcnt(" #N ")" ::: "memory")

static __device__ __forceinline__ bf16x8 pack8(float4 a, float4 b) {
    bf16x8 h;
    h[0] = (__bf16)a.x; h[1] = (__bf16)a.y; h[2] = (__bf16)a.z; h[3] = (__bf16)a.w;
    h[4] = (__bf16)b.x; h[5] = (__bf16)b.y; h[6] = (__bf16)b.z; h[7] = (__bf16)b.w;
    return h;
}

// async global->LDS 16B copy: per-wave, lane l writes ldsbase + l*16
static __device__ __forceinline__ void gload16(const __bf16* g, __bf16* l) {
    __builtin_amdgcn_global_load_lds(
        (const __attribute__((address_space(1))) void*)g,
        (__attribute__((address_space(3))) void*)l,
        16, 0, 0);
}

// monotone float -> uint map (total order preserved, handles negatives)
static __device__ __forceinline__ unsigned fkey(float f) {
    unsigned u = __float_as_uint(f);
    return ((int)u < 0) ? ~u : (u | 0x80000000u);
}

// =====================================================================
// FPS: one block per batch, 256 threads. Point coords AND dmin in
// REGISTERS (32 pts/thread); LDS copy only for centroid broadcast.
// =====================================================================
__global__ __launch_bounds__(256, 1) void fps_kernel(
    const float* __restrict__ xyz, const int* __restrict__ init,
    float* __restrict__ cxyz)
{
#pragma clang fp contract(off)
    const int b = blockIdx.x;
    const float* P = xyz + (size_t)b * NPTS * 3;
    __shared__ float pxs[NPTS], pys[NPTS], pzs[NPTS];
    __shared__ u64 red[2][4];
    const int tid = threadIdx.x;
    float x[32], y[32], z[32], dmin[32];
    #pragma unroll
    for (int k = 0; k < 32; ++k) {
        int n = tid + (k << 8);
        float xx = P[n * 3 + 0], yy = P[n * 3 + 1], zz = P[n * 3 + 2];
        x[k] = xx; y[k] = yy; z[k] = zz;
        pxs[n] = xx; pys[n] = yy; pzs[n] = zz;
        dmin[k] = 1e10f;
    }
    int far = init[b];
    __syncthreads();
    for (int t = 0; t < NG; ++t) {
        float cx = pxs[far], cy = pys[far], cz = pzs[far];
        if (tid == 0) {
            cxyz[(b * NG + t) * 3 + 0] = cx;
            cxyz[(b * NG + t) * 3 + 1] = cy;
            cxyz[(b * NG + t) * 3 + 2] = cz;
        }
        u64 key = 0ull;
        #pragma unroll
        for (int k = 0; k < 32; ++k) {
            float dx = x[k] - cx, dy = y[k] - cy, dz = z[k] - cz;
            float d = dx * dx + dy * dy + dz * dz;
            float dm = dmin[k];
            if (d < dm) dm = d;
            dmin[k] = dm;
            u64 kk = ((u64)__float_as_uint(dm) << 32) | (unsigned)(8191 - (tid + (k << 8)));
            if (kk > key) key = kk;
        }
        #pragma unroll
        for (int d = 32; d >= 1; d >>= 1) {
            u64 k2 = __shfl_down(key, d);
            if (k2 > key) key = k2;
        }
        if ((tid & 63) == 0) red[t & 1][tid >> 6] = key;
        __syncthreads();
        u64 kb = red[t & 1][0];
        #pragma unroll
        for (int w = 1; w < 4; ++w) {
            u64 k2 = red[t & 1][w];
            if (k2 > kb) kb = k2;
        }
        far = 8191 - (int)(kb & 0xFFFFFFFFu);
    }
}

// =====================================================================
// KNN: one block per (b,m). Threshold + rank selection:
//  - per-lane min key (during dist calc)
//  - per-wave bitonic sort of 64 lane-min keys -> T_w = 32nd smallest
//  - block threshold T = min_w T_w  (>=32 keys <= T; top-32 subset)
//  - emit candidates <= T to LDS (prefix-scan slots), rank by counting
//  - fallback to exact 32-round extraction if candidates overflow
// Keys are u64 (fkey(dist), idx): ascending = smallest dist, lowest idx.
// =====================================================================
__global__ __launch_bounds__(256) void knn_kernel(
    const float* __restrict__ xyz, const float* __restrict__ cxyz,
    float* __restrict__ gn)
{
#pragma clang fp contract(off)
    const int bm = blockIdx.x;
    const int b = bm / NG;
    const float* P = xyz + (size_t)b * NPTS * 3;
    __shared__ u64 cand[512];
    __shared__ u64 tmins[4];
    __shared__ int wcnt[4];
    __shared__ int order[KNB];
    const int tid = threadIdx.x;
    const int wv = tid >> 6, lane = tid & 63;
    const float cx = cxyz[bm * 3 + 0], cy = cxyz[bm * 3 + 1], cz = cxyz[bm * 3 + 2];
    const float c2 = cx * cx + cy * cy + cz * cz;
    unsigned fk[32];
    float bestf = 1e31f; int bi = 1 << 30;
    #pragma unroll
    for (int j = 0; j < 32; ++j) {
        int n = tid + (j << 8);
        float x = P[n * 3 + 0], y = P[n * 3 + 1], z = P[n * 3 + 2];
        float x2 = x * x + y * y + z * z;
        float dt = cx * x + cy * y + cz * z;
        float v = (c2 + x2) - 2.0f * dt;
        fk[j] = fkey(v);
        if (v < bestf) { bestf = v; bi = n; }      // strict < keeps lowest index
    }
    // per-lane min key
    u64 mk = ((u64)fkey(bestf) << 32) | (unsigned)bi;
    // bitonic sort of 64 lane-min keys (ascending across lanes)
    {
        u64 v = mk;
        #pragma unroll
        for (int k = 2; k <= 64; k <<= 1) {
            #pragma unroll
            for (int j = k >> 1; j > 0; j >>= 1) {
                u64 o = __shfl_xor(v, j);
                bool up = ((lane & k) == 0);
                bool lower = ((lane & j) == 0);
                u64 mn = (v < o) ? v : o;
                u64 mx = (v < o) ? o : v;
                v = (up == lower) ? mn : mx;
            }
        }
        u64 Tw = __shfl(v, 31);                    // 32nd smallest lane-min
        if (lane == 0) tmins[wv] = Tw;
    }
    __syncthreads();
    u64 T = tmins[0];
    #pragma unroll
    for (int w = 1; w < 4; ++w) { u64 k2 = tmins[w]; if (k2 < T) T = k2; }
    // count my candidates <= T
    int c = 0;
    #pragma unroll
    for (int j = 0; j < 32; ++j) {
        u64 key = ((u64)fk[j] << 32) | (unsigned)(tid + (j << 8));
        c += (key <= T) ? 1 : 0;
    }
    // wave inclusive scan
    int s = c;
    #pragma unroll
    for (int d = 1; d < 64; d <<= 1) {
        int t2 = __shfl_up(s, d);
        if (lane >= d) s += t2;
    }
    int excl = s - c;
    if (lane == 63) wcnt[wv] = s;
    __syncthreads();
    int base = 0;
    for (int w = 0; w < wv; ++w) base += wcnt[w];
    int etot = wcnt[0] + wcnt[1] + wcnt[2] + wcnt[3];

    if (etot <= 512) {
        // emit candidates
        int pos = base + excl;
        #pragma unroll
        for (int j = 0; j < 32; ++j) {
            u64 key = ((u64)fk[j] << 32) | (unsigned)(tid + (j << 8));
            if (key <= T) cand[pos++] = key;
        }
        __syncthreads();
        // rank candidates (keys distinct -> ranks 0..etot-1 unique; etot>=32)
        for (int si = tid; si < etot; si += 256) {
            u64 my = cand[si];
            int r = 0;
            for (int j2 = 0; j2 < etot; ++j2) r += (cand[j2] < my) ? 1 : 0;
            if (r < KNB) order[r] = (int)(my & 0xFFFFFFFFu);
        }
        __syncthreads();
    } else {
        // fallback: exact 32-round extraction (pathological tie overflow)
        u64 bk = ~0ull;
        #pragma unroll
        for (int j = 0; j < 32; ++j) {
            u64 key = ((u64)fk[j] << 32) | (unsigned)(tid + (j << 8));
            if (key < bk) bk = key;
        }
        for (int r = 0; r < KNB; ++r) {
            u64 kk = bk;
            #pragma unroll
            for (int dd = 32; dd >= 1; dd >>= 1) {
                u64 k2 = __shfl_down(kk, dd);
                if (k2 < kk) kk = k2;
            }
            if (lane == 0) cand[(r & 1) * 4 + wv] = kk;
            __syncthreads();
            u64 kb = cand[(r & 1) * 4 + 0];
            #pragma unroll
            for (int w = 1; w < 4; ++w) { u64 k2 = cand[(r & 1) * 4 + w]; if (k2 < kb) kb = k2; }
            if (tid == 0) order[r] = (int)(kb & 0xFFFFFFFFu);
            if ((int)(kb & 255u) == tid) {
                int sj = (int)((kb & 0xFFFFFFFFu) >> 8);
                #pragma unroll
                for (int j = 0; j < 32; ++j) if (j == sj) fk[j] = 0xFFFFFFFFu;
                bk = ~0ull;
                #pragma unroll
                for (int j = 0; j < 32; ++j) {
                    u64 key = ((u64)fk[j] << 32) | (unsigned)(tid + (j << 8));
                    if (key < bk) bk = key;
                }
            }
            __syncthreads();
        }
    }
    if (tid < KNB) {
        int n = order[tid];
        gn[((size_t)bm * KNB + tid) * 3 + 0] = P[n * 3 + 0] - cx;
        gn[((size_t)bm * KNB + tid) * 3 + 1] = P[n * 3 + 1] - cy;
        gn[((size_t)bm * KNB + tid) * 3 + 2] = P[n * 3 + 2] - cz;
    }
}

// =====================================================================
// f32 -> bf16 bulk convert (n multiple of 8)
// =====================================================================
__global__ void cvt_bf16_kernel(const float* __restrict__ src, __bf16* __restrict__ dst, int n8)
{
    int i = blockIdx.x * 256 + threadIdx.x;
    if (i >= n8) return;
    const float4* p = (const float4*)(src + (size_t)i * 8);
    *(bf16x8*)(dst + (size_t)i * 8) = pack8(p[0], p[1]);
}

// multi-segment convert: one dispatch for all big weights
struct CvtTab {
    const float* src[10];
    __bf16* dst[10];
    int cum[11];     // cumulative n8 boundaries, cum[0]=0
};
__global__ void cvt_multi_kernel(CvtTab t)
{
    int i = blockIdx.x * 256 + threadIdx.x;
    if (i >= t.cum[10]) return;
    int seg = 0;
    #pragma unroll
    for (int k = 1; k < 10; ++k) seg += (i >= t.cum[k]) ? 1 : 0;
    int local = i - t.cum[seg];
    const float4* p = (const float4*)(t.src[seg] + (size_t)local * 8);
    *(bf16x8*)(t.dst[seg] + (size_t)local * 8) = pack8(p[0], p[1]);
}

// =====================================================================
// embed1: (131072,3)@(64,3)^T + bias
// =====================================================================
__global__ void embed1_kernel(const float* __restrict__ gn, const float* __restrict__ w,
                              const float* __restrict__ bias, float* __restrict__ h1)
{
    int i = blockIdx.x * 256 + threadIdx.x;
    if (i >= 131072 * 64) return;
    int r = i >> 6, c = i & 63;
    const float* p = gn + (size_t)r * 3;
    h1[i] = p[0] * w[c * 3 + 0] + p[1] * w[c * 3 + 1] + p[2] * w[c * 3 + 2] + bias[c];
}

// =====================================================================
// column stats (sum, sumsq) in double
// =====================================================================
template <int C>
__global__ __launch_bounds__(256) void colstats_kernel(const float* __restrict__ X,
                                                       double* __restrict__ st, int Mrows)
{
    constexpr int RL = 256 / C;
    const int c = threadIdx.x % C;
    const int rl = threadIdx.x / C;
    double s = 0.0, s2 = 0.0;
    int rows_per_block = (Mrows + gridDim.x - 1) / gridDim.x;
    int r0 = blockIdx.x * rows_per_block;
    int r1 = min(r0 + rows_per_block, Mrows);
    for (int r = r0 + rl; r < r1; r += RL) {
        float v = X[(size_t)r * C + c];
        s += v; s2 += (double)v * v;
    }
    __shared__ double sh[2][256];
    sh[0][threadIdx.x] = s; sh[1][threadIdx.x] = s2;
    __syncthreads();
    if (rl == 0) {
        for (int j = 1; j < RL; ++j) { s += sh[0][j * C + c]; s2 += sh[1][j * C + c]; }
        atomicAdd(&st[c], s);
        atomicAdd(&st[C + c], s2);
    }
}

__global__ void bn_finalize(const double* __restrict__ st, const float* __restrict__ g,
                            const float* __restrict__ be, float* __restrict__ sc,
                            float* __restrict__ shb, int C)
{
    int c = blockIdx.x * 64 + threadIdx.x;
    if (c >= C) return;
    double m = st[c] / 131072.0;
    double var = st[C + c] / 131072.0 - m * m;
    if (var < 0.0) var = 0.0;
    float rs = rsqrtf((float)var + 1e-5f);
    sc[c] = rs * g[c];
    shb[c] = be[c] - (float)m * rs * g[c];
}

// BN affine + relu, f32 in -> bf16 out
__global__ void bn_apply_bf16(const float* __restrict__ x, const float* __restrict__ sc,
                              const float* __restrict__ shb, __bf16* __restrict__ y,
                              int total, int C)
{
    int i = blockIdx.x * 256 + threadIdx.x;
    if (i >= total) return;
    int c = i % C;
    float v = x[i] * sc[c] + shb[c];
    v = fmaxf(v, 0.0f);
    y[i] = (__bf16)v;
}

// =====================================================================
// bf16 MFMA GEMM with split-K: C_partial[sk](M,N) = A(M, chunk) @ W^T + bias
// grid.z = SK; chunk k-range = [sk*Kc, (sk+1)*Kc); bias applied at sk==0.
// BN=128, BK=64, 256 thr, global_load_lds staging, counted vmcnt.
// DEPTH==3: single-barrier/K-step 3-buffer pipeline. DEPTH==2: 2-barrier.
// =====================================================================
template <int BM, int WM, int WN, int DEPTH>
__global__ __launch_bounds__(256) void gemm_bf16(
    const __bf16* __restrict__ A, const __bf16* __restrict__ W,
    const float* __restrict__ bias, float* __restrict__ Cf, __bf16* __restrict__ Cb,
    int M, int N, int K, int Kc, int relu)
{
    constexpr int MR = BM / WM / 16;
    constexpr int NR = 128 / WN / 16;
    constexpr int CA = BM * 8 / 256;
    __shared__ __bf16 As[DEPTH][BM * 64];
    __shared__ __bf16 Ws[DEPTH][128 * 64];
    const int tid = threadIdx.x;
    const int lane = tid & 63;
    const int wave = tid >> 6;
    const int wm = wave / WN, wn = wave % WN;
    const int m0 = blockIdx.y * BM, n0 = blockIdx.x * 128;
    const int kb = blockIdx.z * Kc;

    f32x4 acc[MR][NR] = {};

    auto stage = [&](int buf, int kt) {
        #pragma unroll
        for (int j = 0; j < CA; ++j) {
            int cb = j * 256 + (wave << 6);
            int c  = cb + lane;
            int row = c >> 3;
            int kcs = (c & 7) ^ (row & 7);
            gload16(A + (size_t)(m0 + row) * K + kb + kt + kcs * 8, &As[buf][cb * 8]);
        }
        #pragma unroll
        for (int j = 0; j < 4; ++j) {
            int cb = j * 256 + (wave << 6);
            int c  = cb + lane;
            int row = c >> 3;
            int kcs = (c & 7) ^ (row & 7);
            gload16(W + (size_t)(n0 + row) * K + kb + kt + kcs * 8, &Ws[buf][cb * 8]);
        }
    };
    auto compute = [&](int buf) {
        #pragma unroll
        for (int ks = 0; ks < 2; ++ks) {
            bf16x8 af[MR], bfr[NR];
            int kc = ks * 4 + (lane >> 4);
            #pragma unroll
            for (int i = 0; i < MR; ++i) {
                int rowA = wm * (BM / WM) + i * 16 + (lane & 15);
                af[i] = *(bf16x8*)&As[buf][rowA * 64 + ((kc ^ (rowA & 7)) * 8)];
            }
            #pragma unroll
            for (int j = 0; j < NR; ++j) {
                int rowB = wn * (128 / WN) + j * 16 + (lane & 15);
                bfr[j] = *(bf16x8*)&Ws[buf][rowB * 64 + ((kc ^ (rowB & 7)) * 8)];
            }
            #pragma unroll
            for (int i = 0; i < MR; ++i)
                #pragma unroll
                for (int j = 0; j < NR; ++j)
                    acc[i][j] = __builtin_amdgcn_mfma_f32_16x16x32_bf16(af[i], bfr[j], acc[i][j], 0, 0, 0);
        }
    };

    const int nt = Kc >> 6;
    if constexpr (DEPTH == 3) {
        stage(0, 0);
        if (nt > 1) stage(1, 64);
        for (int t = 0; t < nt; ++t) {
            if (t < nt - 1) { if constexpr (BM == 64) WAITV(6); else WAITV(8); }
            else            WAITV(0);
            __syncthreads();
            if (t + 2 < nt) stage((t + 2) % 3, (t + 2) << 6);
            compute(t % 3);
        }
    } else {
        stage(0, 0);
        if (nt > 1) stage(1, 64);
        for (int t = 0; t < nt; ++t) {
            if (t < nt - 1) { if constexpr (BM == 64) WAITV(6); else WAITV(8); }
            else            WAITV(0);
            __syncthreads();
            compute(t % 2);
            if (t + 2 <= nt - 1) {
                __syncthreads();
                stage(t % 2, (t + 2) << 6);
            }
        }
    }

    float* Co = Cf ? Cf + (size_t)blockIdx.z * M * N : nullptr;
    #pragma unroll
    for (int j = 0; j < NR; ++j) {
        int col = n0 + wn * (128 / WN) + j * 16 + (lane & 15);
        if (col >= N) continue;
        float bv = (blockIdx.z == 0) ? bias[col] : 0.0f;
        #pragma unroll
        for (int i = 0; i < MR; ++i) {
            #pragma unroll
            for (int r = 0; r < 4; ++r) {
                int rowm = m0 + wm * (BM / WM) + i * 16 + (lane >> 4) * 4 + r;
                float v = acc[i][j][r] + bv;
                if (relu) v = fmaxf(v, 0.0f);
                if (Co) Co[(size_t)rowm * N + col] = v;
                if (Cb) Cb[(size_t)rowm * N + col] = (__bf16)v;
            }
        }
    }
}

// =====================================================================
// embed3 via MFMA: fused epilogue (bias + group max/min + column stats)
// =====================================================================
__global__ __launch_bounds__(256) void embed3_mfma(
    const __bf16* __restrict__ A, const __bf16* __restrict__ W,
    const float* __restrict__ cb3,
    float* __restrict__ gmax, float* __restrict__ gmin, double* __restrict__ st3)
{
    __shared__ __bf16 As[2][128 * 64];
    __shared__ __bf16 Ws[2][128 * 64];
    const int tid = threadIdx.x;
    const int lane = tid & 63;
    const int wave = tid >> 6;
    const int wm = wave >> 1, wn = wave & 1;
    const int m0 = blockIdx.y * 128, n0 = blockIdx.x * 128;
    const int K = 128;

    f32x4 acc[4][4] = {};

    auto stage = [&](int buf, int kt) {
        #pragma unroll
        for (int j = 0; j < 4; ++j) {
            int cb = j * 256 + (wave << 6);
            int c  = cb + lane;
            int row = c >> 3;
            int kcs = (c & 7) ^ (row & 7);
            gload16(A + (size_t)(m0 + row) * K + kt + kcs * 8, &As[buf][cb * 8]);
            gload16(W + (size_t)(n0 + row) * K + kt + kcs * 8, &Ws[buf][cb * 8]);
        }
    };
    auto compute = [&](int buf) {
        #pragma unroll
        for (int ks = 0; ks < 2; ++ks) {
            bf16x8 af[4], bfr[4];
            int kc = ks * 4 + (lane >> 4);
            #pragma unroll
            for (int i = 0; i < 4; ++i) {
                int rowA = wm * 64 + i * 16 + (lane & 15);
                af[i] = *(bf16x8*)&As[buf][rowA * 64 + ((kc ^ (rowA & 7)) * 8)];
                int rowB = wn * 64 + i * 16 + (lane & 15);
                bfr[i] = *(bf16x8*)&Ws[buf][rowB * 64 + ((kc ^ (rowB & 7)) * 8)];
            }
            #pragma unroll
            for (int i = 0; i < 4; ++i)
                #pragma unroll
                for (int j = 0; j < 4; ++j)
                    acc[i][j] = __builtin_amdgcn_mfma_f32_16x16x32_bf16(af[i], bfr[j], acc[i][j], 0, 0, 0);
        }
    };

    stage(0, 0);
    stage(1, 64);
    WAITV(8);
    __syncthreads();
    compute(0);
    WAITV(0);
    __syncthreads();
    compute(1);

    #pragma unroll
    for (int j = 0; j < 4; ++j) {
        int col = n0 + wn * 64 + j * 16 + (lane & 15);
        float bv = cb3[col];
        float stot = 0.0f, s2tot = 0.0f;
        #pragma unroll
        for (int gi = 0; gi < 2; ++gi) {
            float mx = -1e30f, mn = 1e30f, s = 0.0f, s2 = 0.0f;
            #pragma unroll
            for (int ii = 0; ii < 2; ++ii) {
                f32x4 a = acc[gi * 2 + ii][j];
                #pragma unroll
                for (int r = 0; r < 4; ++r) {
                    float v = a[r] + bv;
                    mx = fmaxf(mx, v); mn = fminf(mn, v);
                    s += v; s2 += v * v;
                }
            }
            #pragma unroll
            for (int d = 16; d < 64; d <<= 1) {
                mx = fmaxf(mx, __shfl_xor(mx, d));
                mn = fminf(mn, __shfl_xor(mn, d));
                s  += __shfl_xor(s, d);
                s2 += __shfl_xor(s2, d);
            }
            stot += s; s2tot += s2;
            if (lane < 16) {
                int g = (m0 >> 5) + wm * 2 + gi;
                gmax[(size_t)g * 768 + col] = mx;
                gmin[(size_t)g * 768 + col] = mn;
            }
        }
        if (lane < 16) {
            double* stp = st3 + (size_t)(blockIdx.y & 31) * 1536;
            atomicAdd(&stp[col], (double)stot);
            atomicAdd(&stp[768 + col], (double)s2tot);
        }
    }
}

__global__ void bn3_finalize(const double* __restrict__ st3, const float* __restrict__ g,
                             const float* __restrict__ be, float* __restrict__ a3,
                             float* __restrict__ c3)
{
    int c = blockIdx.x * 256 + threadIdx.x;
    if (c >= 768) return;
    double s = 0.0, s2 = 0.0;
    for (int p = 0; p < 32; ++p) { s += st3[(size_t)p * 1536 + c]; s2 += st3[(size_t)p * 1536 + 768 + c]; }
    double m = s / 131072.0;
    double var = s2 / 131072.0 - m * m;
    if (var < 0.0) var = 0.0;
    float rs = rsqrtf((float)var + 1e-5f);
    a3[c] = rs * g[c];
    c3[c] = be[c] - (float)m * rs * g[c];
}

// tokens = affine(max/min) ; x = tokens + cxyz@pos_w^T + pos_b
__global__ void tokens_pos(const float* __restrict__ gmax, const float* __restrict__ gmin,
                           const float* __restrict__ a3, const float* __restrict__ c3,
                           const float* __restrict__ cxyz, const float* __restrict__ posw,
                           const float* __restrict__ posb, float* __restrict__ x)
{
    int i = blockIdx.x * 256 + threadIdx.x;
    if (i >= 4096 * 768) return;
    int c = i % 768, g = i / 768;
    float a = a3[c];
    float tok = (a >= 0.0f ? a * gmax[i] : a * gmin[i]) + c3[c];
    float px = cxyz[g * 3 + 0], py = cxyz[g * 3 + 1], pz = cxyz[g * 3 + 2];
    x[i] = tok + px * posw[c * 3 + 0] + py * posw[c * 3 + 1] + pz * posw[c * 3 + 2] + posb[c];
}

// restore + mask fused (both scatter through shuffle[j])
__global__ void restore_kernel(const int* __restrict__ shuffle, int* __restrict__ restore,
                               float* __restrict__ maskv)
{
    int j = blockIdx.x * 256 + threadIdx.x;
    if (j >= BB * NG) return;
    int b = j / NG, p = j % NG;
    int dst = b * NG + shuffle[j];
    restore[dst] = p;
    maskv[dst] = (p < LK) ? 0.0f : 1.0f;
}

__global__ void gather_xk(const float* __restrict__ xfull, const int* __restrict__ shuffle,
                          float* __restrict__ xe, __bf16* __restrict__ xeb)
{
    int i = blockIdx.x * 256 + threadIdx.x;
    if (i >= BB * LK * DE) return;
    int c = i % DE;
    int s = (i / DE) % LK;
    int b = i / (DE * LK);
    float v = xfull[((size_t)b * NG + shuffle[b * NG + s]) * DE + c];
    xe[i] = v;
    xeb[i] = (__bf16)v;
}

// yd = (kept ? sum of 4 yk partials : mtok) + cxyz@dpw^T + dpb
__global__ void yd_build(const float* __restrict__ ykp, const int* __restrict__ restore,
                         const float* __restrict__ mtok, const float* __restrict__ cxyz,
                         const float* __restrict__ dpw, const float* __restrict__ dpb,
                         float* __restrict__ xd, __bf16* __restrict__ xdb)
{
    const size_t PS = (size_t)1024 * DD;
    int i = blockIdx.x * 256 + threadIdx.x;
    if (i >= BB * NG * DD) return;
    int c = i % DD;
    int g = i / DD;
    int b = g / NG;
    int r = restore[g];
    float base;
    if (r < LK) {
        size_t o = (size_t)(b * LK + r) * DD + c;
        base = ykp[o] + ykp[PS + o] + ykp[2 * PS + o] + ykp[3 * PS + o];
    } else {
        base = mtok[c];
    }
    float px = cxyz[g * 3 + 0], py = cxyz[g * 3 + 1], pz = cxyz[g * 3 + 2];
    float v = base + px * dpw[c * 3 + 0] + py * dpw[c * 3 + 1] + pz * dpw[c * 3 + 2] + dpb[c];
    xd[i] = v;
    xdb[i] = (__bf16)v;
}

// =====================================================================
// attention: block per (b, h, q-tile). f32 in, bf16 out. float4 LDS ops,
// padded rows; softmax wave-parallel (8 lanes/row).
// =====================================================================
template <int S, int DH, int QT, int NH>
__global__ __launch_bounds__(256) void attn_kernel(const float* __restrict__ qkv,
                                                   __bf16* __restrict__ o, float scale)
{
    constexpr int D = NH * DH;
    constexpr int NT = S / QT;
    constexpr int DH4 = DH / 4;
    constexpr int KW = DH + 4;
    constexpr int PS = S + 4;
    constexpr int CH = S / 8;
    __shared__ float Ks[S][KW];
    __shared__ float Vs[S][KW];
    __shared__ float Qs[QT][KW];
    __shared__ float Pb[QT][PS];
    const int t = blockIdx.x % NT;
    const int h = (blockIdx.x / NT) % NH;
    const int b = blockIdx.x / (NT * NH);
    const float* base = qkv + (size_t)b * S * 3 * D + h * DH;
    for (int i = threadIdx.x; i < S * DH4; i += 256) {
        int s = i / DH4, d4 = (i % DH4) * 4;
        *(float4*)&Ks[s][d4] = *(const float4*)&base[(size_t)s * 3 * D + D + d4];
        *(float4*)&Vs[s][d4] = *(const float4*)&base[(size_t)s * 3 * D + 2 * D + d4];
    }
    for (int i = threadIdx.x; i < QT * DH4; i += 256) {
        int qi = i / DH4, d4 = (i % DH4) * 4;
        *(float4*)&Qs[qi][d4] = *(const float4*)&base[(size_t)(t * QT + qi) * 3 * D + d4];
    }
    __syncthreads();
    for (int i = threadIdx.x; i < QT * S; i += 256) {
        int qi = i / S, s = i % S;
        float acc = 0.0f;
        #pragma unroll
        for (int d4 = 0; d4 < DH; d4 += 4) {
            float4 q = *(float4*)&Qs[qi][d4];
            float4 k = *(float4*)&Ks[s][d4];
            acc += q.x * k.x + q.y * k.y + q.z * k.z + q.w * k.w;
        }
        Pb[qi][s] = acc * scale;
    }
    __syncthreads();
    {
        int qi = threadIdx.x >> 3;
        int sub = threadIdx.x & 7;
        float mx = -1e30f;
        #pragma unroll
        for (int j = 0; j < CH; ++j) mx = fmaxf(mx, Pb[qi][sub * CH + j]);
        #pragma unroll
        for (int d = 4; d >= 1; d >>= 1) mx = fmaxf(mx, __shfl_xor(mx, d));
        float sum = 0.0f;
        #pragma unroll
        for (int j = 0; j < CH; ++j) {
            float e = expf(Pb[qi][sub * CH + j] - mx);
            Pb[qi][sub * CH + j] = e;
            sum += e;
        }
        #pragma unroll
        for (int d = 4; d >= 1; d >>= 1) sum += __shfl_xor(sum, d);
        float inv = 1.0f / sum;
        #pragma unroll
        for (int j = 0; j < CH; ++j) Pb[qi][sub * CH + j] *= inv;
    }
    __syncthreads();
    __bf16* ob = o + (size_t)b * S * D + h * DH;
    for (int i = threadIdx.x; i < QT * DH4; i += 256) {
        int qi = i / DH4, d4 = (i % DH4) * 4;
        float4 acc = {0, 0, 0, 0};
        for (int s = 0; s < S; ++s) {
            float p = Pb[qi][s];
            float4 v = *(float4*)&Vs[s][d4];
            acc.x += p * v.x; acc.y += p * v.y; acc.z += p * v.z; acc.w += p * v.w;
        }
        __bf16 o4[4] = {(__bf16)acc.x, (__bf16)acc.y, (__bf16)acc.z, (__bf16)acc.w};
        *(ushort4*)&ob[(size_t)(t * QT + qi) * D + d4] = *(ushort4*)o4;
    }
}

// =====================================================================
// LayerNorm with residual (optionally summing SK split-K partials):
// x = LN(x + sum_partials) * g + b ; bf16 copy out.
// =====================================================================
template <int D, int SK>
__global__ __launch_bounds__(256) void ln_res(float* __restrict__ x, const float* __restrict__ part,
                                              size_t pstride,
                                              const float* __restrict__ g, const float* __restrict__ b,
                                              __bf16* __restrict__ xb)
{
    constexpr int J = D / 256;
    __shared__ float pr[2][4];
    const size_t off = (size_t)blockIdx.x * D;
    const int tid = threadIdx.x;
    float vals[J];
    float s = 0.0f, s2 = 0.0f;
    #pragma unroll
    for (int j = 0; j < J; ++j) {
        int i = tid + j * 256;
        float v = x[off + i];
        #pragma unroll
        for (int sk = 0; sk < SK; ++sk) v += part[(size_t)sk * pstride + off + i];
        vals[j] = v; s += v; s2 += v * v;
    }
    #pragma unroll
    for (int d = 32; d >= 1; d >>= 1) { s += __shfl_down(s, d); s2 += __shfl_down(s2, d); }
    if ((tid & 63) == 0) { pr[0][tid >> 6] = s; pr[1][tid >> 6] = s2; }
    __syncthreads();
    float st = pr[0][0] + pr[0][1] + pr[0][2] + pr[0][3];
    float s2t = pr[1][0] + pr[1][1] + pr[1][2] + pr[1][3];
    float m = st / D;
    float var = s2t / D - m * m;
    if (var < 0.0f) var = 0.0f;
    float rs = rsqrtf(var + 1e-5f);
    #pragma unroll
    for (int j = 0; j < J; ++j) {
        int i = tid + j * 256;
        float v = (vals[j] - m) * rs * g[i] + b[i];
        x[off + i] = v;
        xb[off + i] = (__bf16)v;
    }
}

// =====================================================================
// loss
// =====================================================================
__global__ __launch_bounds__(128) void loss_l(const float* __restrict__ pred,
                                              const float* __restrict__ target,
                                              const float* __restrict__ maskv,
                                              float* __restrict__ lm)
{
    const int g = blockIdx.x;
    __shared__ float red[128];
    int t = threadIdx.x;
    float s = 0.0f;
    if (t < 96) {
        float d = pred[(size_t)g * 96 + t] - target[(size_t)g * 96 + t];
        s = d * d;
    }
    red[t] = s; __syncthreads();
    for (int st = 64; st > 0; st >>= 1) { if (t < st) red[t] += red[t + st]; __syncthreads(); }
    if (t == 0) lm[g] = (red[0] / 96.0f) * maskv[g];
}

__global__ __launch_bounds__(1024) void loss_final(const float* __restrict__ lm,
                                                   const float* __restrict__ maskv,
                                                   float* __restrict__ out)
{
    __shared__ float r1[1024], r2[1024];
    int t = threadIdx.x;
    float a = 0.0f, b = 0.0f;
    for (int i = t; i < BB * NG; i += 1024) { a += lm[i]; b += maskv[i]; }
    r1[t] = a; r2[t] = b; __syncthreads();
    for (int st = 512; st > 0; st >>= 1) { if (t < st) { r1[t] += r1[t + st]; r2[t] += r2[t + st]; } __syncthreads(); }
    if (t == 0) out[0] = r1[0] / r2[0];
}

// =====================================================================
// host
// =====================================================================
extern "C" void kernel_launch(void* const* d_in, const int* in_sizes, int n_in,
                              void* d_out, int out_size, void* d_ws, size_t ws_size,
                              hipStream_t stream)
{
    (void)in_sizes; (void)n_in; (void)out_size; (void)ws_size;
    const float* xyz        = (const float*)d_in[0];
    const int*   fps_init   = (const int*)d_in[1];
    const int*   ids_shuf   = (const int*)d_in[2];
    const float* cw1 = (const float*)d_in[3];  const float* cb1 = (const float*)d_in[4];
    const float* g1  = (const float*)d_in[5];  const float* be1 = (const float*)d_in[6];
    const float* cw2 = (const float*)d_in[7];  const float* cb2 = (const float*)d_in[8];
    const float* g2  = (const float*)d_in[9];  const float* be2 = (const float*)d_in[10];
    const float* cw3 = (const float*)d_in[11]; const float* cb3 = (const float*)d_in[12];
    const float* g3  = (const float*)d_in[13]; const float* be3 = (const float*)d_in[14];
    const float* posw = (const float*)d_in[15]; const float* posb = (const float*)d_in[16];
    const float* eqw = (const float*)d_in[17]; const float* eqb = (const float*)d_in[18];
    const float* eow = (const float*)d_in[19]; const float* eob = (const float*)d_in[20];
    const float* el1g = (const float*)d_in[21]; const float* el1b = (const float*)d_in[22];
    const float* ef1w = (const float*)d_in[23]; const float* ef1b = (const float*)d_in[24];
    const float* ef2w = (const float*)d_in[25]; const float* ef2b = (const float*)d_in[26];
    const float* el2g = (const float*)d_in[27]; const float* el2b = (const float*)d_in[28];
    const float* dew = (const float*)d_in[29]; const float* deb = (const float*)d_in[30];
    const float* mtok = (const float*)d_in[31];
    const float* dpw = (const float*)d_in[32]; const float* dpb = (const float*)d_in[33];
    const float* dqw = (const float*)d_in[34]; const float* dqb = (const float*)d_in[35];
    const float* dow = (const float*)d_in[36]; const float* dob = (const float*)d_in[37];
    const float* dl1g = (const float*)d_in[38]; const float* dl1b = (const float*)d_in[39];
    const float* df1w = (const float*)d_in[40]; const float* df1b = (const float*)d_in[41];
    const float* df2w = (const float*)d_in[42]; const float* df2b = (const float*)d_in[43];
    const float* dl2g = (const float*)d_in[44]; const float* dl2b = (const float*)d_in[45];
    const float* prw = (const float*)d_in[46]; const float* prb = (const float*)d_in[47];
    float* out = (float*)d_out;
    float* pred = out + 1;
    float* maskv = out + 1 + (size_t)BB * NG * KNB * 3;

    // ---- workspace carve ----
    char* ws = (char*)d_ws;
    size_t off = 0;
    auto alloc = [&](size_t bytes) -> void* {
        void* p = ws + off;
        off = (off + bytes + 255) & ~(size_t)255;
        return p;
    };
    double* st1 = (double*)alloc(128 * 8);
    double* st2 = (double*)alloc(256 * 8);
    double* st3 = (double*)alloc((size_t)32 * 1536 * 8);
    float* sc1 = (float*)alloc(64 * 4);  float* sh1 = (float*)alloc(64 * 4);
    float* sc2 = (float*)alloc(128 * 4); float* sh2 = (float*)alloc(128 * 4);
    float* a3 = (float*)alloc(768 * 4);  float* c3 = (float*)alloc(768 * 4);
    int* restore = (int*)alloc(4096 * 4);
    float* cxyz = (float*)alloc(12288 * 4);
    float* gn   = (float*)alloc((size_t)393216 * 4);
    __bf16* cw2b = (__bf16*)alloc((size_t)128 * 64 * 2);
    __bf16* cw3b = (__bf16*)alloc((size_t)768 * 128 * 2);
    float* xfull = (float*)alloc((size_t)4096 * 768 * 4);   // also 4x(1024x768) partials
    float* xe    = (float*)alloc((size_t)1024 * 768 * 4);
    __bf16* xeb  = (__bf16*)alloc((size_t)1024 * 768 * 2);
    float* qkve  = (float*)alloc((size_t)1024 * 2304 * 4);  // also 4x(1024x512) dew partials
    __bf16* oeb  = (__bf16*)alloc((size_t)1024 * 768 * 2);
    __bf16* fe1b = (__bf16*)alloc((size_t)1024 * 3072 * 2);
    float* xd    = (float*)alloc((size_t)4096 * 512 * 4);
    __bf16* xdb  = (__bf16*)alloc((size_t)4096 * 512 * 2);
    float* qkvd  = (float*)alloc((size_t)4096 * 1536 * 4);  // also 2x(4096x512) partials
    __bf16* odb  = (__bf16*)alloc((size_t)4096 * 512 * 2);
    __bf16* fd1b = (__bf16*)alloc((size_t)4096 * 2048 * 2);
    float* lm    = (float*)alloc(4096 * 4);

    __bf16* eqwb  = (__bf16*)alloc((size_t)NLE * 3 * DE * DE * 2);
    __bf16* eowb  = (__bf16*)alloc((size_t)NLE * DE * DE * 2);
    __bf16* ef1wb = (__bf16*)alloc((size_t)NLE * 4 * DE * DE * 2);
    __bf16* ef2wb = (__bf16*)alloc((size_t)NLE * 4 * DE * DE * 2);
    __bf16* dewb  = (__bf16*)alloc((size_t)DD * DE * 2);
    __bf16* dqwb  = (__bf16*)alloc((size_t)NLD * 3 * DD * DD * 2);
    __bf16* dowb  = (__bf16*)alloc((size_t)NLD * DD * DD * 2);
    __bf16* df1wb = (__bf16*)alloc((size_t)NLD * 4 * DD * DD * 2);
    __bf16* df2wb = (__bf16*)alloc((size_t)NLD * 4 * DD * DD * 2);
    __bf16* prwb  = (__bf16*)alloc((size_t)128 * 512 * 2);

    char* U = (char*)eqwb;
    float*  h1   = (float*)U;
    __bf16* h1b  = (__bf16*)(U + (size_t)33554432);
    float*  h2   = (float*)(U + (size_t)50331648);
    __bf16* h2b  = (__bf16*)(U + (size_t)117440512);
    float*  gmax = (float*)(U + (size_t)150994944);
    float*  gmin = (float*)(U + (size_t)163577856);

    size_t stats_bytes = (size_t)((char*)st3 + (size_t)32 * 1536 * 8 - (char*)st1);
    hipMemsetAsync((void*)st1, 0, stats_bytes, stream);

    auto cvt = [&](const float* src, __bf16* dst, size_t n) {
        int n8 = (int)(n / 8);
        cvt_bf16_kernel<<<(n8 + 255) / 256, 256, 0, stream>>>(src, dst, n8);
    };
    // non-split gemm (auto tile select)
    auto gemm = [&](const __bf16* A, const __bf16* Wt, const float* bias,
                    float* Cf, __bf16* Cb, int M, int N, int K, int relu) {
        int nb128 = ((N + 127) / 128) * (M / 128);
        if (nb128 < 256) {
            dim3 grid((N + 127) / 128, M / 64, 1);
            gemm_bf16<64, 1, 4, 3><<<grid, 256, 0, stream>>>(A, Wt, bias, Cf, Cb, M, N, K, K, relu);
        } else {
            dim3 grid((N + 127) / 128, M / 128, 1);
            gemm_bf16<128, 2, 2, 2><<<grid, 256, 0, stream>>>(A, Wt, bias, Cf, Cb, M, N, K, K, relu);
        }
    };
    // split-K gemm (BM=64 path), partials at Cf + sk*M*N
    auto gemmSK = [&](const __bf16* A, const __bf16* Wt, const float* bias,
                      float* Cf, int M, int N, int K, int SK) {
        dim3 grid((N + 127) / 128, M / 64, SK);
        gemm_bf16<64, 1, 4, 3><<<grid, 256, 0, stream>>>(A, Wt, bias, Cf, nullptr, M, N, K, K / SK, 0);
    };

    cvt(cw2, cw2b, 128 * 64);
    cvt(cw3, cw3b, 768 * 128);

    // ---- stage 1: FPS + KNN ----
    fps_kernel<<<BB, 256, 0, stream>>>(xyz, fps_init, cxyz);
    knn_kernel<<<BB * NG, 256, 0, stream>>>(xyz, cxyz, gn);

    // ---- stage 2: mini-PointNet ----
    embed1_kernel<<<(131072 * 64 + 255) / 256, 256, 0, stream>>>(gn, cw1, cb1, h1);
    colstats_kernel<64><<<256, 256, 0, stream>>>(h1, st1, 131072);
    bn_finalize<<<1, 64, 0, stream>>>(st1, g1, be1, sc1, sh1, 64);
    bn_apply_bf16<<<(131072 * 64 + 255) / 256, 256, 0, stream>>>(h1, sc1, sh1, h1b, 131072 * 64, 64);
    gemm(h1b, cw2b, cb2, h2, nullptr, 131072, 128, 64, 0);
    colstats_kernel<128><<<256, 256, 0, stream>>>(h2, st2, 131072);
    bn_finalize<<<2, 64, 0, stream>>>(st2, g2, be2, sc2, sh2, 128);
    bn_apply_bf16<<<(131072 * 128 + 255) / 256, 256, 0, stream>>>(h2, sc2, sh2, h2b, 131072 * 128, 128);
    embed3_mfma<<<dim3(6, 1024), 256, 0, stream>>>(h2b, cw3b, cb3, gmax, gmin, st3);
    bn3_finalize<<<3, 256, 0, stream>>>(st3, g3, be3, a3, c3);
    tokens_pos<<<(4096 * 768 + 255) / 256, 256, 0, stream>>>(gmax, gmin, a3, c3, cxyz, posw, posb, xfull);

    // ---- stage 3: shuffle / mask ----
    restore_kernel<<<16, 256, 0, stream>>>(ids_shuf, restore, maskv);
    gather_xk<<<(BB * LK * DE + 255) / 256, 256, 0, stream>>>(xfull, ids_shuf, xe, xeb);

    // ---- weight conversion: single dispatch (after stage-2 temps dead) ----
    {
        CvtTab t;
        const float* srcs[10] = {eqw, eow, ef1w, ef2w, dew, dqw, dow, df1w, df2w, prw};
        __bf16* dsts[10] = {eqwb, eowb, ef1wb, ef2wb, dewb, dqwb, dowb, df1wb, df2wb, prwb};
        size_t ns[10] = {
            (size_t)NLE * 3 * DE * DE, (size_t)NLE * DE * DE,
            (size_t)NLE * 4 * DE * DE, (size_t)NLE * 4 * DE * DE,
            (size_t)DD * DE,
            (size_t)NLD * 3 * DD * DD, (size_t)NLD * DD * DD,
            (size_t)NLD * 4 * DD * DD, (size_t)NLD * 4 * DD * DD,
            (size_t)96 * 512
        };
        int cum = 0;
        t.cum[0] = 0;
        for (int k = 0; k < 10; ++k) {
            t.src[k] = srcs[k]; t.dst[k] = dsts[k];
            cum += (int)(ns[k] / 8);
            t.cum[k + 1] = cum;
        }
        cvt_multi_kernel<<<(cum + 255) / 256, 256, 0, stream>>>(t);
        hipMemsetAsync((void*)(prwb + (size_t)96 * 512), 0, (size_t)32 * 512 * 2, stream);
    }

    const size_t PSE = (size_t)1024 * DE;   // encoder partial stride
    const size_t PSD = (size_t)4096 * DD;   // decoder partial stride

    // ---- stage 4: encoder (12 layers) ----
    for (int l = 0; l < NLE; ++l) {
        gemm(xeb, eqwb + (size_t)l * 3 * DE * DE, eqb + (size_t)l * 3 * DE, qkve, nullptr, 1024, 3 * DE, DE, 0);
        attn_kernel<LK, 64, 32, 12><<<BB * 12, 256, 0, stream>>>(qkve, oeb, 0.125f);
        gemmSK(oeb, eowb + (size_t)l * DE * DE, eob + (size_t)l * DE, xfull, 1024, DE, DE, 4);
        ln_res<DE, 4><<<BB * LK, 256, 0, stream>>>(xe, xfull, PSE, el1g + (size_t)l * DE, el1b + (size_t)l * DE, xeb);
        gemm(xeb, ef1wb + (size_t)l * 4 * DE * DE, ef1b + (size_t)l * 4 * DE, nullptr, fe1b, 1024, 4 * DE, DE, 1);
        gemmSK(fe1b, ef2wb + (size_t)l * DE * 4 * DE, ef2b + (size_t)l * DE, xfull, 1024, DE, 4 * DE, 4);
        ln_res<DE, 4><<<BB * LK, 256, 0, stream>>>(xe, xfull, PSE, el2g + (size_t)l * DE, el2b + (size_t)l * DE, xeb);
    }

    // ---- stage 5: decoder embed + mask tokens ----
    gemmSK(xeb, dewb, deb, qkve, 1024, DD, DE, 4);
    yd_build<<<(BB * NG * DD + 255) / 256, 256, 0, stream>>>(qkve, restore, mtok, cxyz, dpw, dpb, xd, xdb);

    // ---- stage 6: decoder (8 layers) ----
    const float dsc = (float)(1.0 / sqrt(32.0));
    for (int l = 0; l < NLD; ++l) {
        gemm(xdb, dqwb + (size_t)l * 3 * DD * DD, dqb + (size_t)l * 3 * DD, qkvd, nullptr, 4096, 3 * DD, DD, 0);
        attn_kernel<NG, 32, 32, 16><<<BB * 16 * (NG / 32), 256, 0, stream>>>(qkvd, odb, dsc);
        gemmSK(odb, dowb + (size_t)l * DD * DD, dob + (size_t)l * DD, qkvd, 4096, DD, DD, 2);
        ln_res<DD, 2><<<BB * NG, 256, 0, stream>>>(xd, qkvd, PSD, dl1g + (size_t)l * DD, dl1b + (size_t)l * DD, xdb);
        gemm(xdb, df1wb + (size_t)l * 4 * DD * DD, df1b + (size_t)l * 4 * DD, nullptr, fd1b, 4096, 4 * DD, DD, 1);
        gemmSK(fd1b, df2wb + (size_t)l * DD * 4 * DD, df2b + (size_t)l * DD, qkvd, 4096, DD, 4 * DD, 2);
        ln_res<DD, 2><<<BB * NG, 256, 0, stream>>>(xd, qkvd, PSD, dl2g + (size_t)l * DD, dl2b + (size_t)l * DD, xdb);
    }

    // ---- stage 7: prediction + loss ----
    gemm(xdb, prwb, prb, pred, nullptr, 4096, 96, 512, 0);
    loss_l<<<BB * NG, 128, 0, stream>>>(pred, gn, maskv, lm);
    loss_final<<<1, 1024, 0, stream>>>(lm, maskv, out);
}

// Round 9
// 2419.242 us; speedup vs baseline: 9.5806x; 1.0823x over previous
//
#include <hip/hip_runtime.h>
#include <cmath>

// ---------------- problem constants ----------------
#define BB 32          // batch
#define NPTS 8192      // points per cloud
#define NG 128         // groups
#define KNB 32         // neighbors per group
#define LK 32          // len_keep
#define DE 768         // encoder dim
#define DD 512         // decoder dim
#define NLE 12
#define NLD 8

typedef __bf16 bf16x8 __attribute__((ext_vector_type(8)));
typedef float  f32x4  __attribute__((ext_vector_type(4)));
typedef unsigned long long u64;

#define WAITV(N) asm volatile("s_waitcnt vmcnt(" #N ")" ::: "memory")

static __device__ __forceinline__ bf16x8 pack8(float4 a, float4 b) {
    bf16x8 h;
    h[0] = (__bf16)a.x; h[1] = (__bf16)a.y; h[2] = (__bf16)a.z; h[3] = (__bf16)a.w;
    h[4] = (__bf16)b.x; h[5] = (__bf16)b.y; h[6] = (__bf16)b.z; h[7] = (__bf16)b.w;
    return h;
}

// async global->LDS 16B copy: per-wave, lane l writes ldsbase + l*16
static __device__ __forceinline__ void gload16(const __bf16* g, __bf16* l) {
    __builtin_amdgcn_global_load_lds(
        (const __attribute__((address_space(1))) void*)g,
        (__attribute__((address_space(3))) void*)l,
        16, 0, 0);
}

// monotone float -> uint map (total order preserved, handles negatives)
static __device__ __forceinline__ unsigned fkey(float f) {
    unsigned u = __float_as_uint(f);
    return ((int)u < 0) ? ~u : (u | 0x80000000u);
}

// =====================================================================
// FPS: one block per batch, 512 threads, 16 pts/thread in registers.
// float argmax in loop (strict > keeps lowest idx), u64 pack once,
// single barrier/step via parity-double-buffered reduce slots.
// =====================================================================
__global__ __launch_bounds__(512, 1) void fps_kernel(
    const float* __restrict__ xyz, const int* __restrict__ init,
    float* __restrict__ cxyz)
{
#pragma clang fp contract(off)
    const int b = blockIdx.x;
    const float* P = xyz + (size_t)b * NPTS * 3;
    __shared__ float pxs[NPTS], pys[NPTS], pzs[NPTS];
    __shared__ u64 red[2][8];
    const int tid = threadIdx.x;
    float x[16], y[16], z[16], dmin[16];
    #pragma unroll
    for (int k = 0; k < 16; ++k) {
        int n = tid + (k << 9);
        float xx = P[n * 3 + 0], yy = P[n * 3 + 1], zz = P[n * 3 + 2];
        x[k] = xx; y[k] = yy; z[k] = zz;
        pxs[n] = xx; pys[n] = yy; pzs[n] = zz;
        dmin[k] = 1e10f;
    }
    int far = init[b];
    __syncthreads();
    for (int t = 0; t < NG; ++t) {
        float cx = pxs[far], cy = pys[far], cz = pzs[far];
        if (tid == 0) {
            cxyz[(b * NG + t) * 3 + 0] = cx;
            cxyz[(b * NG + t) * 3 + 1] = cy;
            cxyz[(b * NG + t) * 3 + 2] = cz;
        }
        float best = -1.0f; int bi = 0;
        #pragma unroll
        for (int k = 0; k < 16; ++k) {
            int n = tid + (k << 9);
            float dx = x[k] - cx, dy = y[k] - cy, dz = z[k] - cz;
            float d = dx * dx + dy * dy + dz * dz;
            float dm = dmin[k];
            if (d < dm) dm = d;
            dmin[k] = dm;
            if (dm > best) { best = dm; bi = n; }   // strict > keeps lowest index
        }
        u64 key = ((u64)__float_as_uint(best) << 32) | (unsigned)(8191 - bi);
        #pragma unroll
        for (int d = 32; d >= 1; d >>= 1) {
            u64 k2 = __shfl_down(key, d);
            if (k2 > key) key = k2;
        }
        if ((tid & 63) == 0) red[t & 1][tid >> 6] = key;
        __syncthreads();
        u64 kb = red[t & 1][0];
        #pragma unroll
        for (int w = 1; w < 8; ++w) {
            u64 k2 = red[t & 1][w];
            if (k2 > kb) kb = k2;
        }
        far = 8191 - (int)(kb & 0xFFFFFFFFu);
    }
}

// =====================================================================
// KNN: threshold + rank selection (R8, unchanged).
// =====================================================================
__global__ __launch_bounds__(256) void knn_kernel(
    const float* __restrict__ xyz, const float* __restrict__ cxyz,
    float* __restrict__ gn)
{
#pragma clang fp contract(off)
    const int bm = blockIdx.x;
    const int b = bm / NG;
    const float* P = xyz + (size_t)b * NPTS * 3;
    __shared__ u64 cand[512];
    __shared__ u64 tmins[4];
    __shared__ int wcnt[4];
    __shared__ int order[KNB];
    const int tid = threadIdx.x;
    const int wv = tid >> 6, lane = tid & 63;
    const float cx = cxyz[bm * 3 + 0], cy = cxyz[bm * 3 + 1], cz = cxyz[bm * 3 + 2];
    const float c2 = cx * cx + cy * cy + cz * cz;
    unsigned fk[32];
    float bestf = 1e31f; int bi = 1 << 30;
    #pragma unroll
    for (int j = 0; j < 32; ++j) {
        int n = tid + (j << 8);
        float x = P[n * 3 + 0], y = P[n * 3 + 1], z = P[n * 3 + 2];
        float x2 = x * x + y * y + z * z;
        float dt = cx * x + cy * y + cz * z;
        float v = (c2 + x2) - 2.0f * dt;
        fk[j] = fkey(v);
        if (v < bestf) { bestf = v; bi = n; }
    }
    u64 mk = ((u64)fkey(bestf) << 32) | (unsigned)bi;
    {
        u64 v = mk;
        #pragma unroll
        for (int k = 2; k <= 64; k <<= 1) {
            #pragma unroll
            for (int j = k >> 1; j > 0; j >>= 1) {
                u64 o = __shfl_xor(v, j);
                bool up = ((lane & k) == 0);
                bool lower = ((lane & j) == 0);
                u64 mn = (v < o) ? v : o;
                u64 mx = (v < o) ? o : v;
                v = (up == lower) ? mn : mx;
            }
        }
        u64 Tw = __shfl(v, 31);
        if (lane == 0) tmins[wv] = Tw;
    }
    __syncthreads();
    u64 T = tmins[0];
    #pragma unroll
    for (int w = 1; w < 4; ++w) { u64 k2 = tmins[w]; if (k2 < T) T = k2; }
    int c = 0;
    #pragma unroll
    for (int j = 0; j < 32; ++j) {
        u64 key = ((u64)fk[j] << 32) | (unsigned)(tid + (j << 8));
        c += (key <= T) ? 1 : 0;
    }
    int s = c;
    #pragma unroll
    for (int d = 1; d < 64; d <<= 1) {
        int t2 = __shfl_up(s, d);
        if (lane >= d) s += t2;
    }
    int excl = s - c;
    if (lane == 63) wcnt[wv] = s;
    __syncthreads();
    int base = 0;
    for (int w = 0; w < wv; ++w) base += wcnt[w];
    int etot = wcnt[0] + wcnt[1] + wcnt[2] + wcnt[3];

    if (etot <= 512) {
        int pos = base + excl;
        #pragma unroll
        for (int j = 0; j < 32; ++j) {
            u64 key = ((u64)fk[j] << 32) | (unsigned)(tid + (j << 8));
            if (key <= T) cand[pos++] = key;
        }
        __syncthreads();
        for (int si = tid; si < etot; si += 256) {
            u64 my = cand[si];
            int r = 0;
            for (int j2 = 0; j2 < etot; ++j2) r += (cand[j2] < my) ? 1 : 0;
            if (r < KNB) order[r] = (int)(my & 0xFFFFFFFFu);
        }
        __syncthreads();
    } else {
        u64 bk = ~0ull;
        #pragma unroll
        for (int j = 0; j < 32; ++j) {
            u64 key = ((u64)fk[j] << 32) | (unsigned)(tid + (j << 8));
            if (key < bk) bk = key;
        }
        for (int r = 0; r < KNB; ++r) {
            u64 kk = bk;
            #pragma unroll
            for (int dd = 32; dd >= 1; dd >>= 1) {
                u64 k2 = __shfl_down(kk, dd);
                if (k2 < kk) kk = k2;
            }
            if (lane == 0) cand[(r & 1) * 4 + wv] = kk;
            __syncthreads();
            u64 kb = cand[(r & 1) * 4 + 0];
            #pragma unroll
            for (int w = 1; w < 4; ++w) { u64 k2 = cand[(r & 1) * 4 + w]; if (k2 < kb) kb = k2; }
            if (tid == 0) order[r] = (int)(kb & 0xFFFFFFFFu);
            if ((int)(kb & 255u) == tid) {
                int sj = (int)((kb & 0xFFFFFFFFu) >> 8);
                #pragma unroll
                for (int j = 0; j < 32; ++j) if (j == sj) fk[j] = 0xFFFFFFFFu;
                bk = ~0ull;
                #pragma unroll
                for (int j = 0; j < 32; ++j) {
                    u64 key = ((u64)fk[j] << 32) | (unsigned)(tid + (j << 8));
                    if (key < bk) bk = key;
                }
            }
            __syncthreads();
        }
    }
    if (tid < KNB) {
        int n = order[tid];
        gn[((size_t)bm * KNB + tid) * 3 + 0] = P[n * 3 + 0] - cx;
        gn[((size_t)bm * KNB + tid) * 3 + 1] = P[n * 3 + 1] - cy;
        gn[((size_t)bm * KNB + tid) * 3 + 2] = P[n * 3 + 2] - cz;
    }
}

// =====================================================================
// f32 -> bf16 bulk convert
// =====================================================================
__global__ void cvt_bf16_kernel(const float* __restrict__ src, __bf16* __restrict__ dst, int n8)
{
    int i = blockIdx.x * 256 + threadIdx.x;
    if (i >= n8) return;
    const float4* p = (const float4*)(src + (size_t)i * 8);
    *(bf16x8*)(dst + (size_t)i * 8) = pack8(p[0], p[1]);
}

struct CvtTab {
    const float* src[10];
    __bf16* dst[10];
    int cum[11];
};
__global__ void cvt_multi_kernel(CvtTab t)
{
    int i = blockIdx.x * 256 + threadIdx.x;
    if (i >= t.cum[10]) return;
    int seg = 0;
    #pragma unroll
    for (int k = 1; k < 10; ++k) seg += (i >= t.cum[k]) ? 1 : 0;
    int local = i - t.cum[seg];
    const float4* p = (const float4*)(t.src[seg] + (size_t)local * 8);
    *(bf16x8*)(t.dst[seg] + (size_t)local * 8) = pack8(p[0], p[1]);
}

// =====================================================================
// embed1
// =====================================================================
__global__ void embed1_kernel(const float* __restrict__ gn, const float* __restrict__ w,
                              const float* __restrict__ bias, float* __restrict__ h1)
{
    int i = blockIdx.x * 256 + threadIdx.x;
    if (i >= 131072 * 64) return;
    int r = i >> 6, c = i & 63;
    const float* p = gn + (size_t)r * 3;
    h1[i] = p[0] * w[c * 3 + 0] + p[1] * w[c * 3 + 1] + p[2] * w[c * 3 + 2] + bias[c];
}

// =====================================================================
// column stats
// =====================================================================
template <int C>
__global__ __launch_bounds__(256) void colstats_kernel(const float* __restrict__ X,
                                                       double* __restrict__ st, int Mrows)
{
    constexpr int RL = 256 / C;
    const int c = threadIdx.x % C;
    const int rl = threadIdx.x / C;
    double s = 0.0, s2 = 0.0;
    int rows_per_block = (Mrows + gridDim.x - 1) / gridDim.x;
    int r0 = blockIdx.x * rows_per_block;
    int r1 = min(r0 + rows_per_block, Mrows);
    for (int r = r0 + rl; r < r1; r += RL) {
        float v = X[(size_t)r * C + c];
        s += v; s2 += (double)v * v;
    }
    __shared__ double sh[2][256];
    sh[0][threadIdx.x] = s; sh[1][threadIdx.x] = s2;
    __syncthreads();
    if (rl == 0) {
        for (int j = 1; j < RL; ++j) { s += sh[0][j * C + c]; s2 += sh[1][j * C + c]; }
        atomicAdd(&st[c], s);
        atomicAdd(&st[C + c], s2);
    }
}

__global__ void bn_finalize(const double* __restrict__ st, const float* __restrict__ g,
                            const float* __restrict__ be, float* __restrict__ sc,
                            float* __restrict__ shb, int C)
{
    int c = blockIdx.x * 64 + threadIdx.x;
    if (c >= C) return;
    double m = st[c] / 131072.0;
    double var = st[C + c] / 131072.0 - m * m;
    if (var < 0.0) var = 0.0;
    float rs = rsqrtf((float)var + 1e-5f);
    sc[c] = rs * g[c];
    shb[c] = be[c] - (float)m * rs * g[c];
}

__global__ void bn_apply_bf16(const float* __restrict__ x, const float* __restrict__ sc,
                              const float* __restrict__ shb, __bf16* __restrict__ y,
                              int total, int C)
{
    int i = blockIdx.x * 256 + threadIdx.x;
    if (i >= total) return;
    int c = i % C;
    float v = x[i] * sc[c] + shb[c];
    v = fmaxf(v, 0.0f);
    y[i] = (__bf16)v;
}

// =====================================================================
// bf16 MFMA GEMM with split-K (R8, unchanged)
// =====================================================================
template <int BM, int WM, int WN, int DEPTH>
__global__ __launch_bounds__(256) void gemm_bf16(
    const __bf16* __restrict__ A, const __bf16* __restrict__ W,
    const float* __restrict__ bias, float* __restrict__ Cf, __bf16* __restrict__ Cb,
    int M, int N, int K, int Kc, int relu)
{
    constexpr int MR = BM / WM / 16;
    constexpr int NR = 128 / WN / 16;
    constexpr int CA = BM * 8 / 256;
    __shared__ __bf16 As[DEPTH][BM * 64];
    __shared__ __bf16 Ws[DEPTH][128 * 64];
    const int tid = threadIdx.x;
    const int lane = tid & 63;
    const int wave = tid >> 6;
    const int wm = wave / WN, wn = wave % WN;
    const int m0 = blockIdx.y * BM, n0 = blockIdx.x * 128;
    const int kb = blockIdx.z * Kc;

    f32x4 acc[MR][NR] = {};

    auto stage = [&](int buf, int kt) {
        #pragma unroll
        for (int j = 0; j < CA; ++j) {
            int cb = j * 256 + (wave << 6);
            int c  = cb + lane;
            int row = c >> 3;
            int kcs = (c & 7) ^ (row & 7);
            gload16(A + (size_t)(m0 + row) * K + kb + kt + kcs * 8, &As[buf][cb * 8]);
        }
        #pragma unroll
        for (int j = 0; j < 4; ++j) {
            int cb = j * 256 + (wave << 6);
            int c  = cb + lane;
            int row = c >> 3;
            int kcs = (c & 7) ^ (row & 7);
            gload16(W + (size_t)(n0 + row) * K + kb + kt + kcs * 8, &Ws[buf][cb * 8]);
        }
    };
    auto compute = [&](int buf) {
        #pragma unroll
        for (int ks = 0; ks < 2; ++ks) {
            bf16x8 af[MR], bfr[NR];
            int kc = ks * 4 + (lane >> 4);
            #pragma unroll
            for (int i = 0; i < MR; ++i) {
                int rowA = wm * (BM / WM) + i * 16 + (lane & 15);
                af[i] = *(bf16x8*)&As[buf][rowA * 64 + ((kc ^ (rowA & 7)) * 8)];
            }
            #pragma unroll
            for (int j = 0; j < NR; ++j) {
                int rowB = wn * (128 / WN) + j * 16 + (lane & 15);
                bfr[j] = *(bf16x8*)&Ws[buf][rowB * 64 + ((kc ^ (rowB & 7)) * 8)];
            }
            #pragma unroll
            for (int i = 0; i < MR; ++i)
                #pragma unroll
                for (int j = 0; j < NR; ++j)
                    acc[i][j] = __builtin_amdgcn_mfma_f32_16x16x32_bf16(af[i], bfr[j], acc[i][j], 0, 0, 0);
        }
    };

    const int nt = Kc >> 6;
    if constexpr (DEPTH == 3) {
        stage(0, 0);
        if (nt > 1) stage(1, 64);
        for (int t = 0; t < nt; ++t) {
            if (t < nt - 1) { if constexpr (BM == 64) WAITV(6); else WAITV(8); }
            else            WAITV(0);
            __syncthreads();
            if (t + 2 < nt) stage((t + 2) % 3, (t + 2) << 6);
            compute(t % 3);
        }
    } else {
        stage(0, 0);
        if (nt > 1) stage(1, 64);
        for (int t = 0; t < nt; ++t) {
            if (t < nt - 1) { if constexpr (BM == 64) WAITV(6); else WAITV(8); }
            else            WAITV(0);
            __syncthreads();
            compute(t % 2);
            if (t + 2 <= nt - 1) {
                __syncthreads();
                stage(t % 2, (t + 2) << 6);
            }
        }
    }

    float* Co = Cf ? Cf + (size_t)blockIdx.z * M * N : nullptr;
    #pragma unroll
    for (int j = 0; j < NR; ++j) {
        int col = n0 + wn * (128 / WN) + j * 16 + (lane & 15);
        if (col >= N) continue;
        float bv = (blockIdx.z == 0) ? bias[col] : 0.0f;
        #pragma unroll
        for (int i = 0; i < MR; ++i) {
            #pragma unroll
            for (int r = 0; r < 4; ++r) {
                int rowm = m0 + wm * (BM / WM) + i * 16 + (lane >> 4) * 4 + r;
                float v = acc[i][j][r] + bv;
                if (relu) v = fmaxf(v, 0.0f);
                if (Co) Co[(size_t)rowm * N + col] = v;
                if (Cb) Cb[(size_t)rowm * N + col] = (__bf16)v;
            }
        }
    }
}

// =====================================================================
// embed3 via MFMA (R8, unchanged)
// =====================================================================
__global__ __launch_bounds__(256) void embed3_mfma(
    const __bf16* __restrict__ A, const __bf16* __restrict__ W,
    const float* __restrict__ cb3,
    float* __restrict__ gmax, float* __restrict__ gmin, double* __restrict__ st3)
{
    __shared__ __bf16 As[2][128 * 64];
    __shared__ __bf16 Ws[2][128 * 64];
    const int tid = threadIdx.x;
    const int lane = tid & 63;
    const int wave = tid >> 6;
    const int wm = wave >> 1, wn = wave & 1;
    const int m0 = blockIdx.y * 128, n0 = blockIdx.x * 128;
    const int K = 128;

    f32x4 acc[4][4] = {};

    auto stage = [&](int buf, int kt) {
        #pragma unroll
        for (int j = 0; j < 4; ++j) {
            int cb = j * 256 + (wave << 6);
            int c  = cb + lane;
            int row = c >> 3;
            int kcs = (c & 7) ^ (row & 7);
            gload16(A + (size_t)(m0 + row) * K + kt + kcs * 8, &As[buf][cb * 8]);
            gload16(W + (size_t)(n0 + row) * K + kt + kcs * 8, &Ws[buf][cb * 8]);
        }
    };
    auto compute = [&](int buf) {
        #pragma unroll
        for (int ks = 0; ks < 2; ++ks) {
            bf16x8 af[4], bfr[4];
            int kc = ks * 4 + (lane >> 4);
            #pragma unroll
            for (int i = 0; i < 4; ++i) {
                int rowA = wm * 64 + i * 16 + (lane & 15);
                af[i] = *(bf16x8*)&As[buf][rowA * 64 + ((kc ^ (rowA & 7)) * 8)];
                int rowB = wn * 64 + i * 16 + (lane & 15);
                bfr[i] = *(bf16x8*)&Ws[buf][rowB * 64 + ((kc ^ (rowB & 7)) * 8)];
            }
            #pragma unroll
            for (int i = 0; i < 4; ++i)
                #pragma unroll
                for (int j = 0; j < 4; ++j)
                    acc[i][j] = __builtin_amdgcn_mfma_f32_16x16x32_bf16(af[i], bfr[j], acc[i][j], 0, 0, 0);
        }
    };

    stage(0, 0);
    stage(1, 64);
    WAITV(8);
    __syncthreads();
    compute(0);
    WAITV(0);
    __syncthreads();
    compute(1);

    #pragma unroll
    for (int j = 0; j < 4; ++j) {
        int col = n0 + wn * 64 + j * 16 + (lane & 15);
        float bv = cb3[col];
        float stot = 0.0f, s2tot = 0.0f;
        #pragma unroll
        for (int gi = 0; gi < 2; ++gi) {
            float mx = -1e30f, mn = 1e30f, s = 0.0f, s2 = 0.0f;
            #pragma unroll
            for (int ii = 0; ii < 2; ++ii) {
                f32x4 a = acc[gi * 2 + ii][j];
                #pragma unroll
                for (int r = 0; r < 4; ++r) {
                    float v = a[r] + bv;
                    mx = fmaxf(mx, v); mn = fminf(mn, v);
                    s += v; s2 += v * v;
                }
            }
            #pragma unroll
            for (int d = 16; d < 64; d <<= 1) {
                mx = fmaxf(mx, __shfl_xor(mx, d));
                mn = fminf(mn, __shfl_xor(mn, d));
                s  += __shfl_xor(s, d);
                s2 += __shfl_xor(s2, d);
            }
            stot += s; s2tot += s2;
            if (lane < 16) {
                int g = (m0 >> 5) + wm * 2 + gi;
                gmax[(size_t)g * 768 + col] = mx;
                gmin[(size_t)g * 768 + col] = mn;
            }
        }
        if (lane < 16) {
            double* stp = st3 + (size_t)(blockIdx.y & 31) * 1536;
            atomicAdd(&stp[col], (double)stot);
            atomicAdd(&stp[768 + col], (double)s2tot);
        }
    }
}

__global__ void bn3_finalize(const double* __restrict__ st3, const float* __restrict__ g,
                             const float* __restrict__ be, float* __restrict__ a3,
                             float* __restrict__ c3)
{
    int c = blockIdx.x * 256 + threadIdx.x;
    if (c >= 768) return;
    double s = 0.0, s2 = 0.0;
    for (int p = 0; p < 32; ++p) { s += st3[(size_t)p * 1536 + c]; s2 += st3[(size_t)p * 1536 + 768 + c]; }
    double m = s / 131072.0;
    double var = s2 / 131072.0 - m * m;
    if (var < 0.0) var = 0.0;
    float rs = rsqrtf((float)var + 1e-5f);
    a3[c] = rs * g[c];
    c3[c] = be[c] - (float)m * rs * g[c];
}

__global__ void tokens_pos(const float* __restrict__ gmax, const float* __restrict__ gmin,
                           const float* __restrict__ a3, const float* __restrict__ c3,
                           const float* __restrict__ cxyz, const float* __restrict__ posw,
                           const float* __restrict__ posb, float* __restrict__ x)
{
    int i = blockIdx.x * 256 + threadIdx.x;
    if (i >= 4096 * 768) return;
    int c = i % 768, g = i / 768;
    float a = a3[c];
    float tok = (a >= 0.0f ? a * gmax[i] : a * gmin[i]) + c3[c];
    float px = cxyz[g * 3 + 0], py = cxyz[g * 3 + 1], pz = cxyz[g * 3 + 2];
    x[i] = tok + px * posw[c * 3 + 0] + py * posw[c * 3 + 1] + pz * posw[c * 3 + 2] + posb[c];
}

__global__ void restore_kernel(const int* __restrict__ shuffle, int* __restrict__ restore,
                               float* __restrict__ maskv)
{
    int j = blockIdx.x * 256 + threadIdx.x;
    if (j >= BB * NG) return;
    int b = j / NG, p = j % NG;
    int dst = b * NG + shuffle[j];
    restore[dst] = p;
    maskv[dst] = (p < LK) ? 0.0f : 1.0f;
}

__global__ void gather_xk(const float* __restrict__ xfull, const int* __restrict__ shuffle,
                          float* __restrict__ xe, __bf16* __restrict__ xeb)
{
    int i = blockIdx.x * 256 + threadIdx.x;
    if (i >= BB * LK * DE) return;
    int c = i % DE;
    int s = (i / DE) % LK;
    int b = i / (DE * LK);
    float v = xfull[((size_t)b * NG + shuffle[b * NG + s]) * DE + c];
    xe[i] = v;
    xeb[i] = (__bf16)v;
}

__global__ void yd_build(const float* __restrict__ ykp, const int* __restrict__ restore,
                         const float* __restrict__ mtok, const float* __restrict__ cxyz,
                         const float* __restrict__ dpw, const float* __restrict__ dpb,
                         float* __restrict__ xd, __bf16* __restrict__ xdb)
{
    const size_t PS = (size_t)1024 * DD;
    int i = blockIdx.x * 256 + threadIdx.x;
    if (i >= BB * NG * DD) return;
    int c = i % DD;
    int g = i / DD;
    int b = g / NG;
    int r = restore[g];
    float base;
    if (r < LK) {
        size_t o = (size_t)(b * LK + r) * DD + c;
        base = ykp[o] + ykp[PS + o] + ykp[2 * PS + o] + ykp[3 * PS + o];
    } else {
        base = mtok[c];
    }
    float px = cxyz[g * 3 + 0], py = cxyz[g * 3 + 1], pz = cxyz[g * 3 + 2];
    float v = base + px * dpw[c * 3 + 0] + py * dpw[c * 3 + 1] + pz * dpw[c * 3 + 2] + dpb[c];
    xd[i] = v;
    xdb[i] = (__bf16)v;
}

// =====================================================================
// decoder attention via MFMA: block per (b,h), 256 thr (4 waves).
// S=128, DH=32. Stage Q/K/V bf16 (V transposed); wave w owns 32 q-rows.
// Scores: 2 q-tiles x 8 k-tiles MFMA (K=32 = 1 step). Softmax in-register
// (8 cols/lane + 4-level shfl_xor in 16-lane row group). P -> LDS bf16
// (wave-local). PV: 2x2 tiles x 4 k-steps MFMA.
// =====================================================================
template <int S, int DH, int NH>
__global__ __launch_bounds__(256) void dattn_kernel(const float* __restrict__ qkv,
                                                    __bf16* __restrict__ o, float scale)
{
    constexpr int D = NH * DH;          // 512
    constexpr int SQ = DH + 8;          // 40
    constexpr int SV = S + 8;           // 136
    __shared__ __bf16 Qb[S * SQ];
    __shared__ __bf16 Kb[S * SQ];
    __shared__ __bf16 Vt[DH * SV];
    __shared__ __bf16 Pb[S * SV];
    const int h = blockIdx.x % NH;
    const int b = blockIdx.x / NH;
    const int tid = threadIdx.x;
    const int lane = tid & 63, wv = tid >> 6;
    const float* base = qkv + (size_t)b * S * 3 * D + h * DH;
    for (int i = tid; i < S * (DH / 4); i += 256) {
        int s = i / (DH / 4), c4 = (i % (DH / 4)) * 4;
        const float* rp = base + (size_t)s * 3 * D;
        float4 q = *(const float4*)(rp + c4);
        float4 k = *(const float4*)(rp + D + c4);
        float4 v = *(const float4*)(rp + 2 * D + c4);
        __bf16 q4[4] = {(__bf16)q.x, (__bf16)q.y, (__bf16)q.z, (__bf16)q.w};
        __bf16 k4[4] = {(__bf16)k.x, (__bf16)k.y, (__bf16)k.z, (__bf16)k.w};
        *(ushort4*)&Qb[s * SQ + c4] = *(ushort4*)q4;
        *(ushort4*)&Kb[s * SQ + c4] = *(ushort4*)k4;
        Vt[(c4 + 0) * SV + s] = (__bf16)v.x;
        Vt[(c4 + 1) * SV + s] = (__bf16)v.y;
        Vt[(c4 + 2) * SV + s] = (__bf16)v.z;
        Vt[(c4 + 3) * SV + s] = (__bf16)v.w;
    }
    __syncthreads();
    const int q0 = wv * 32;
    const int arow = lane & 15;
    const int kch = (lane >> 4) * 8;
    const int rrow = (lane >> 4) * 4;
    f32x4 sc[2][8];
    {
        bf16x8 af0 = *(bf16x8*)&Qb[(q0 + arow) * SQ + kch];
        bf16x8 af1 = *(bf16x8*)&Qb[(q0 + 16 + arow) * SQ + kch];
        f32x4 z = {0.0f, 0.0f, 0.0f, 0.0f};
        #pragma unroll
        for (int j = 0; j < 8; ++j) {
            bf16x8 bf_ = *(bf16x8*)&Kb[(j * 16 + arow) * SQ + kch];
            sc[0][j] = __builtin_amdgcn_mfma_f32_16x16x32_bf16(af0, bf_, z, 0, 0, 0);
            sc[1][j] = __builtin_amdgcn_mfma_f32_16x16x32_bf16(af1, bf_, z, 0, 0, 0);
        }
    }
    // softmax (raw max then exp((x-m)*scale)) + write P bf16 (wave-local)
    #pragma unroll
    for (int i = 0; i < 2; ++i) {
        #pragma unroll
        for (int r = 0; r < 4; ++r) {
            float m = -1e30f;
            #pragma unroll
            for (int j = 0; j < 8; ++j) m = fmaxf(m, sc[i][j][r]);
            #pragma unroll
            for (int d = 8; d >= 1; d >>= 1) m = fmaxf(m, __shfl_xor(m, d));
            float sum = 0.0f;
            #pragma unroll
            for (int j = 0; j < 8; ++j) {
                float e = expf((sc[i][j][r] - m) * scale);
                sc[i][j][r] = e;
                sum += e;
            }
            #pragma unroll
            for (int d = 8; d >= 1; d >>= 1) sum += __shfl_xor(sum, d);
            float inv = 1.0f / sum;
            int row = q0 + i * 16 + rrow + r;
            #pragma unroll
            for (int j = 0; j < 8; ++j)
                Pb[row * SV + j * 16 + (lane & 15)] = (__bf16)(sc[i][j][r] * inv);
        }
    }
    // PV (reads own P rows + Vt; no barrier needed)
    #pragma unroll
    for (int i = 0; i < 2; ++i) {
        #pragma unroll
        for (int j2 = 0; j2 < 2; ++j2) {
            f32x4 a2 = {0.0f, 0.0f, 0.0f, 0.0f};
            #pragma unroll
            for (int ks = 0; ks < 4; ++ks) {
                bf16x8 pa = *(bf16x8*)&Pb[(q0 + i * 16 + arow) * SV + ks * 32 + kch];
                bf16x8 vb = *(bf16x8*)&Vt[(j2 * 16 + arow) * SV + ks * 32 + kch];
                a2 = __builtin_amdgcn_mfma_f32_16x16x32_bf16(pa, vb, a2, 0, 0, 0);
            }
            #pragma unroll
            for (int r = 0; r < 4; ++r) {
                int q = q0 + i * 16 + rrow + r;
                o[((size_t)(b * S + q)) * D + h * DH + j2 * 16 + (lane & 15)] = (__bf16)a2[r];
            }
        }
    }
}

// =====================================================================
// encoder attention via MFMA: block per (b,h), 64 thr (1 wave).
// S=32, DH=64. Scores: 2x2 tiles x 2 k-steps; PV: 2x4 tiles x 1 k-step.
// =====================================================================
template <int S, int DH, int NH>
__global__ __launch_bounds__(64) void eattn_kernel(const float* __restrict__ qkv,
                                                   __bf16* __restrict__ o, float scale)
{
    constexpr int D = NH * DH;          // 768
    constexpr int SQ = DH + 8;          // 72
    constexpr int SV = S + 8;           // 40
    __shared__ __bf16 Qb[S * SQ];
    __shared__ __bf16 Kb[S * SQ];
    __shared__ __bf16 Vt[DH * SV];
    __shared__ __bf16 Pb[S * SV];
    const int h = blockIdx.x % NH;
    const int b = blockIdx.x / NH;
    const int lane = threadIdx.x;
    const float* base = qkv + (size_t)b * S * 3 * D + h * DH;
    for (int i = lane; i < S * (DH / 4); i += 64) {
        int s = i / (DH / 4), c4 = (i % (DH / 4)) * 4;
        const float* rp = base + (size_t)s * 3 * D;
        float4 q = *(const float4*)(rp + c4);
        float4 k = *(const float4*)(rp + D + c4);
        float4 v = *(const float4*)(rp + 2 * D + c4);
        __bf16 q4[4] = {(__bf16)q.x, (__bf16)q.y, (__bf16)q.z, (__bf16)q.w};
        __bf16 k4[4] = {(__bf16)k.x, (__bf16)k.y, (__bf16)k.z, (__bf16)k.w};
        *(ushort4*)&Qb[s * SQ + c4] = *(ushort4*)q4;
        *(ushort4*)&Kb[s * SQ + c4] = *(ushort4*)k4;
        Vt[(c4 + 0) * SV + s] = (__bf16)v.x;
        Vt[(c4 + 1) * SV + s] = (__bf16)v.y;
        Vt[(c4 + 2) * SV + s] = (__bf16)v.z;
        Vt[(c4 + 3) * SV + s] = (__bf16)v.w;
    }
    __syncthreads();
    const int arow = lane & 15;
    const int kch = (lane >> 4) * 8;
    const int rrow = (lane >> 4) * 4;
    f32x4 sc[2][2] = {};
    #pragma unroll
    for (int ks = 0; ks < 2; ++ks) {
        bf16x8 af0 = *(bf16x8*)&Qb[(arow) * SQ + ks * 32 + kch];
        bf16x8 af1 = *(bf16x8*)&Qb[(16 + arow) * SQ + ks * 32 + kch];
        #pragma unroll
        for (int j = 0; j < 2; ++j) {
            bf16x8 bf_ = *(bf16x8*)&Kb[(j * 16 + arow) * SQ + ks * 32 + kch];
            sc[0][j] = __builtin_amdgcn_mfma_f32_16x16x32_bf16(af0, bf_, sc[0][j], 0, 0, 0);
            sc[1][j] = __builtin_amdgcn_mfma_f32_16x16x32_bf16(af1, bf_, sc[1][j], 0, 0, 0);
        }
    }
    #pragma unroll
    for (int i = 0; i < 2; ++i) {
        #pragma unroll
        for (int r = 0; r < 4; ++r) {
            float m = fmaxf(sc[i][0][r], sc[i][1][r]);
            #pragma unroll
            for (int d = 8; d >= 1; d >>= 1) m = fmaxf(m, __shfl_xor(m, d));
            float sum = 0.0f;
            #pragma unroll
            for (int j = 0; j < 2; ++j) {
                float e = expf((sc[i][j][r] - m) * scale);
                sc[i][j][r] = e;
                sum += e;
            }
            #pragma unroll
            for (int d = 8; d >= 1; d >>= 1) sum += __shfl_xor(sum, d);
            float inv = 1.0f / sum;
            int row = i * 16 + rrow + r;
            #pragma unroll
            for (int j = 0; j < 2; ++j)
                Pb[row * SV + j * 16 + (lane & 15)] = (__bf16)(sc[i][j][r] * inv);
        }
    }
    __syncthreads();   // single wave: cheap; orders P writes vs frag reads
    #pragma unroll
    for (int i = 0; i < 2; ++i) {
        bf16x8 pa = *(bf16x8*)&Pb[(i * 16 + arow) * SV + kch];
        #pragma unroll
        for (int j2 = 0; j2 < 4; ++j2) {
            bf16x8 vb = *(bf16x8*)&Vt[(j2 * 16 + arow) * SV + kch];
            f32x4 z = {0.0f, 0.0f, 0.0f, 0.0f};
            f32x4 a2 = __builtin_amdgcn_mfma_f32_16x16x32_bf16(pa, vb, z, 0, 0, 0);
            #pragma unroll
            for (int r = 0; r < 4; ++r) {
                int q = i * 16 + rrow + r;
                o[((size_t)(b * S + q)) * D + h * DH + j2 * 16 + (lane & 15)] = (__bf16)a2[r];
            }
        }
    }
}

// =====================================================================
// LayerNorm with residual (+ SK split-K partial sum)
// =====================================================================
template <int D, int SK>
__global__ __launch_bounds__(256) void ln_res(float* __restrict__ x, const float* __restrict__ part,
                                              size_t pstride,
                                              const float* __restrict__ g, const float* __restrict__ b,
                                              __bf16* __restrict__ xb)
{
    constexpr int J = D / 256;
    __shared__ float pr[2][4];
    const size_t off = (size_t)blockIdx.x * D;
    const int tid = threadIdx.x;
    float vals[J];
    float s = 0.0f, s2 = 0.0f;
    #pragma unroll
    for (int j = 0; j < J; ++j) {
        int i = tid + j * 256;
        float v = x[off + i];
        #pragma unroll
        for (int sk = 0; sk < SK; ++sk) v += part[(size_t)sk * pstride + off + i];
        vals[j] = v; s += v; s2 += v * v;
    }
    #pragma unroll
    for (int d = 32; d >= 1; d >>= 1) { s += __shfl_down(s, d); s2 += __shfl_down(s2, d); }
    if ((tid & 63) == 0) { pr[0][tid >> 6] = s; pr[1][tid >> 6] = s2; }
    __syncthreads();
    float st = pr[0][0] + pr[0][1] + pr[0][2] + pr[0][3];
    float s2t = pr[1][0] + pr[1][1] + pr[1][2] + pr[1][3];
    float m = st / D;
    float var = s2t / D - m * m;
    if (var < 0.0f) var = 0.0f;
    float rs = rsqrtf(var + 1e-5f);
    #pragma unroll
    for (int j = 0; j < J; ++j) {
        int i = tid + j * 256;
        float v = (vals[j] - m) * rs * g[i] + b[i];
        x[off + i] = v;
        xb[off + i] = (__bf16)v;
    }
}

// =====================================================================
// loss
// =====================================================================
__global__ __launch_bounds__(128) void loss_l(const float* __restrict__ pred,
                                              const float* __restrict__ target,
                                              const float* __restrict__ maskv,
                                              float* __restrict__ lm)
{
    const int g = blockIdx.x;
    __shared__ float red[128];
    int t = threadIdx.x;
    float s = 0.0f;
    if (t < 96) {
        float d = pred[(size_t)g * 96 + t] - target[(size_t)g * 96 + t];
        s = d * d;
    }
    red[t] = s; __syncthreads();
    for (int st = 64; st > 0; st >>= 1) { if (t < st) red[t] += red[t + st]; __syncthreads(); }
    if (t == 0) lm[g] = (red[0] / 96.0f) * maskv[g];
}

__global__ __launch_bounds__(1024) void loss_final(const float* __restrict__ lm,
                                                   const float* __restrict__ maskv,
                                                   float* __restrict__ out)
{
    __shared__ float r1[1024], r2[1024];
    int t = threadIdx.x;
    float a = 0.0f, b = 0.0f;
    for (int i = t; i < BB * NG; i += 1024) { a += lm[i]; b += maskv[i]; }
    r1[t] = a; r2[t] = b; __syncthreads();
    for (int st = 512; st > 0; st >>= 1) { if (t < st) { r1[t] += r1[t + st]; r2[t] += r2[t + st]; } __syncthreads(); }
    if (t == 0) out[0] = r1[0] / r2[0];
}

// =====================================================================
// host
// =====================================================================
extern "C" void kernel_launch(void* const* d_in, const int* in_sizes, int n_in,
                              void* d_out, int out_size, void* d_ws, size_t ws_size,
                              hipStream_t stream)
{
    (void)in_sizes; (void)n_in; (void)out_size; (void)ws_size;
    const float* xyz        = (const float*)d_in[0];
    const int*   fps_init   = (const int*)d_in[1];
    const int*   ids_shuf   = (const int*)d_in[2];
    const float* cw1 = (const float*)d_in[3];  const float* cb1 = (const float*)d_in[4];
    const float* g1  = (const float*)d_in[5];  const float* be1 = (const float*)d_in[6];
    const float* cw2 = (const float*)d_in[7];  const float* cb2 = (const float*)d_in[8];
    const float* g2  = (const float*)d_in[9];  const float* be2 = (const float*)d_in[10];
    const float* cw3 = (const float*)d_in[11]; const float* cb3 = (const float*)d_in[12];
    const float* g3  = (const float*)d_in[13]; const float* be3 = (const float*)d_in[14];
    const float* posw = (const float*)d_in[15]; const float* posb = (const float*)d_in[16];
    const float* eqw = (const float*)d_in[17]; const float* eqb = (const float*)d_in[18];
    const float* eow = (const float*)d_in[19]; const float* eob = (const float*)d_in[20];
    const float* el1g = (const float*)d_in[21]; const float* el1b = (const float*)d_in[22];
    const float* ef1w = (const float*)d_in[23]; const float* ef1b = (const float*)d_in[24];
    const float* ef2w = (const float*)d_in[25]; const float* ef2b = (const float*)d_in[26];
    const float* el2g = (const float*)d_in[27]; const float* el2b = (const float*)d_in[28];
    const float* dew = (const float*)d_in[29]; const float* deb = (const float*)d_in[30];
    const float* mtok = (const float*)d_in[31];
    const float* dpw = (const float*)d_in[32]; const float* dpb = (const float*)d_in[33];
    const float* dqw = (const float*)d_in[34]; const float* dqb = (const float*)d_in[35];
    const float* dow = (const float*)d_in[36]; const float* dob = (const float*)d_in[37];
    const float* dl1g = (const float*)d_in[38]; const float* dl1b = (const float*)d_in[39];
    const float* df1w = (const float*)d_in[40]; const float* df1b = (const float*)d_in[41];
    const float* df2w = (const float*)d_in[42]; const float* df2b = (const float*)d_in[43];
    const float* dl2g = (const float*)d_in[44]; const float* dl2b = (const float*)d_in[45];
    const float* prw = (const float*)d_in[46]; const float* prb = (const float*)d_in[47];
    float* out = (float*)d_out;
    float* pred = out + 1;
    float* maskv = out + 1 + (size_t)BB * NG * KNB * 3;

    // ---- workspace carve ----
    char* ws = (char*)d_ws;
    size_t off = 0;
    auto alloc = [&](size_t bytes) -> void* {
        void* p = ws + off;
        off = (off + bytes + 255) & ~(size_t)255;
        return p;
    };
    double* st1 = (double*)alloc(128 * 8);
    double* st2 = (double*)alloc(256 * 8);
    double* st3 = (double*)alloc((size_t)32 * 1536 * 8);
    float* sc1 = (float*)alloc(64 * 4);  float* sh1 = (float*)alloc(64 * 4);
    float* sc2 = (float*)alloc(128 * 4); float* sh2 = (float*)alloc(128 * 4);
    float* a3 = (float*)alloc(768 * 4);  float* c3 = (float*)alloc(768 * 4);
    int* restore = (int*)alloc(4096 * 4);
    float* cxyz = (float*)alloc(12288 * 4);
    float* gn   = (float*)alloc((size_t)393216 * 4);
    __bf16* cw2b = (__bf16*)alloc((size_t)128 * 64 * 2);
    __bf16* cw3b = (__bf16*)alloc((size_t)768 * 128 * 2);
    float* xfull = (float*)alloc((size_t)4096 * 768 * 4);   // also 4x(1024x768) partials
    float* xe    = (float*)alloc((size_t)1024 * 768 * 4);
    __bf16* xeb  = (__bf16*)alloc((size_t)1024 * 768 * 2);
    float* qkve  = (float*)alloc((size_t)1024 * 2304 * 4);  // also 4x(1024x512) dew partials
    __bf16* oeb  = (__bf16*)alloc((size_t)1024 * 768 * 2);
    __bf16* fe1b = (__bf16*)alloc((size_t)1024 * 3072 * 2);
    float* xd    = (float*)alloc((size_t)4096 * 512 * 4);
    __bf16* xdb  = (__bf16*)alloc((size_t)4096 * 512 * 2);
    float* qkvd  = (float*)alloc((size_t)4096 * 1536 * 4);  // also 2x(4096x512) partials
    __bf16* odb  = (__bf16*)alloc((size_t)4096 * 512 * 2);
    __bf16* fd1b = (__bf16*)alloc((size_t)4096 * 2048 * 2);
    float* lm    = (float*)alloc(4096 * 4);

    __bf16* eqwb  = (__bf16*)alloc((size_t)NLE * 3 * DE * DE * 2);
    __bf16* eowb  = (__bf16*)alloc((size_t)NLE * DE * DE * 2);
    __bf16* ef1wb = (__bf16*)alloc((size_t)NLE * 4 * DE * DE * 2);
    __bf16* ef2wb = (__bf16*)alloc((size_t)NLE * 4 * DE * DE * 2);
    __bf16* dewb  = (__bf16*)alloc((size_t)DD * DE * 2);
    __bf16* dqwb  = (__bf16*)alloc((size_t)NLD * 3 * DD * DD * 2);
    __bf16* dowb  = (__bf16*)alloc((size_t)NLD * DD * DD * 2);
    __bf16* df1wb = (__bf16*)alloc((size_t)NLD * 4 * DD * DD * 2);
    __bf16* df2wb = (__bf16*)alloc((size_t)NLD * 4 * DD * DD * 2);
    __bf16* prwb  = (__bf16*)alloc((size_t)128 * 512 * 2);

    char* U = (char*)eqwb;
    float*  h1   = (float*)U;
    __bf16* h1b  = (__bf16*)(U + (size_t)33554432);
    float*  h2   = (float*)(U + (size_t)50331648);
    __bf16* h2b  = (__bf16*)(U + (size_t)117440512);
    float*  gmax = (float*)(U + (size_t)150994944);
    float*  gmin = (float*)(U + (size_t)163577856);

    size_t stats_bytes = (size_t)((char*)st3 + (size_t)32 * 1536 * 8 - (char*)st1);
    hipMemsetAsync((void*)st1, 0, stats_bytes, stream);

    auto cvt = [&](const float* src, __bf16* dst, size_t n) {
        int n8 = (int)(n / 8);
        cvt_bf16_kernel<<<(n8 + 255) / 256, 256, 0, stream>>>(src, dst, n8);
    };
    auto gemm = [&](const __bf16* A, const __bf16* Wt, const float* bias,
                    float* Cf, __bf16* Cb, int M, int N, int K, int relu) {
        int nb128 = ((N + 127) / 128) * (M / 128);
        if (nb128 < 256) {
            dim3 grid((N + 127) / 128, M / 64, 1);
            gemm_bf16<64, 1, 4, 3><<<grid, 256, 0, stream>>>(A, Wt, bias, Cf, Cb, M, N, K, K, relu);
        } else {
            dim3 grid((N + 127) / 128, M / 128, 1);
            gemm_bf16<128, 2, 2, 2><<<grid, 256, 0, stream>>>(A, Wt, bias, Cf, Cb, M, N, K, K, relu);
        }
    };
    auto gemmSK = [&](const __bf16* A, const __bf16* Wt, const float* bias,
                      float* Cf, int M, int N, int K, int SK) {
        dim3 grid((N + 127) / 128, M / 64, SK);
        gemm_bf16<64, 1, 4, 3><<<grid, 256, 0, stream>>>(A, Wt, bias, Cf, nullptr, M, N, K, K / SK, 0);
    };

    cvt(cw2, cw2b, 128 * 64);
    cvt(cw3, cw3b, 768 * 128);

    // ---- stage 1: FPS + KNN ----
    fps_kernel<<<BB, 512, 0, stream>>>(xyz, fps_init, cxyz);
    knn_kernel<<<BB * NG, 256, 0, stream>>>(xyz, cxyz, gn);

    // ---- stage 2: mini-PointNet ----
    embed1_kernel<<<(131072 * 64 + 255) / 256, 256, 0, stream>>>(gn, cw1, cb1, h1);
    colstats_kernel<64><<<256, 256, 0, stream>>>(h1, st1, 131072);
    bn_finalize<<<1, 64, 0, stream>>>(st1, g1, be1, sc1, sh1, 64);
    bn_apply_bf16<<<(131072 * 64 + 255) / 256, 256, 0, stream>>>(h1, sc1, sh1, h1b, 131072 * 64, 64);
    gemm(h1b, cw2b, cb2, h2, nullptr, 131072, 128, 64, 0);
    colstats_kernel<128><<<256, 256, 0, stream>>>(h2, st2, 131072);
    bn_finalize<<<2, 64, 0, stream>>>(st2, g2, be2, sc2, sh2, 128);
    bn_apply_bf16<<<(131072 * 128 + 255) / 256, 256, 0, stream>>>(h2, sc2, sh2, h2b, 131072 * 128, 128);
    embed3_mfma<<<dim3(6, 1024), 256, 0, stream>>>(h2b, cw3b, cb3, gmax, gmin, st3);
    bn3_finalize<<<3, 256, 0, stream>>>(st3, g3, be3, a3, c3);
    tokens_pos<<<(4096 * 768 + 255) / 256, 256, 0, stream>>>(gmax, gmin, a3, c3, cxyz, posw, posb, xfull);

    // ---- stage 3: shuffle / mask ----
    restore_kernel<<<16, 256, 0, stream>>>(ids_shuf, restore, maskv);
    gather_xk<<<(BB * LK * DE + 255) / 256, 256, 0, stream>>>(xfull, ids_shuf, xe, xeb);

    // ---- weight conversion: single dispatch ----
    {
        CvtTab t;
        const float* srcs[10] = {eqw, eow, ef1w, ef2w, dew, dqw, dow, df1w, df2w, prw};
        __bf16* dsts[10] = {eqwb, eowb, ef1wb, ef2wb, dewb, dqwb, dowb, df1wb, df2wb, prwb};
        size_t ns[10] = {
            (size_t)NLE * 3 * DE * DE, (size_t)NLE * DE * DE,
            (size_t)NLE * 4 * DE * DE, (size_t)NLE * 4 * DE * DE,
            (size_t)DD * DE,
            (size_t)NLD * 3 * DD * DD, (size_t)NLD * DD * DD,
            (size_t)NLD * 4 * DD * DD, (size_t)NLD * 4 * DD * DD,
            (size_t)96 * 512
        };
        int cum = 0;
        t.cum[0] = 0;
        for (int k = 0; k < 10; ++k) {
            t.src[k] = srcs[k]; t.dst[k] = dsts[k];
            cum += (int)(ns[k] / 8);
            t.cum[k + 1] = cum;
        }
        cvt_multi_kernel<<<(cum + 255) / 256, 256, 0, stream>>>(t);
        hipMemsetAsync((void*)(prwb + (size_t)96 * 512), 0, (size_t)32 * 512 * 2, stream);
    }

    const size_t PSE = (size_t)1024 * DE;
    const size_t PSD = (size_t)4096 * DD;

    // ---- stage 4: encoder (12 layers) ----
    for (int l = 0; l < NLE; ++l) {
        gemm(xeb, eqwb + (size_t)l * 3 * DE * DE, eqb + (size_t)l * 3 * DE, qkve, nullptr, 1024, 3 * DE, DE, 0);
        eattn_kernel<LK, 64, 12><<<BB * 12, 64, 0, stream>>>(qkve, oeb, 0.125f);
        gemmSK(oeb, eowb + (size_t)l * DE * DE, eob + (size_t)l * DE, xfull, 1024, DE, DE, 4);
        ln_res<DE, 4><<<BB * LK, 256, 0, stream>>>(xe, xfull, PSE, el1g + (size_t)l * DE, el1b + (size_t)l * DE, xeb);
        gemm(xeb, ef1wb + (size_t)l * 4 * DE * DE, ef1b + (size_t)l * 4 * DE, nullptr, fe1b, 1024, 4 * DE, DE, 1);
        gemmSK(fe1b, ef2wb + (size_t)l * DE * 4 * DE, ef2b + (size_t)l * DE, xfull, 1024, DE, 4 * DE, 4);
        ln_res<DE, 4><<<BB * LK, 256, 0, stream>>>(xe, xfull, PSE, el2g + (size_t)l * DE, el2b + (size_t)l * DE, xeb);
    }

    // ---- stage 5: decoder embed + mask tokens ----
    gemmSK(xeb, dewb, deb, qkve, 1024, DD, DE, 4);
    yd_build<<<(BB * NG * DD + 255) / 256, 256, 0, stream>>>(qkve, restore, mtok, cxyz, dpw, dpb, xd, xdb);

    // ---- stage 6: decoder (8 layers) ----
    const float dsc = (float)(1.0 / sqrt(32.0));
    for (int l = 0; l < NLD; ++l) {
        gemm(xdb, dqwb + (size_t)l * 3 * DD * DD, dqb + (size_t)l * 3 * DD, qkvd, nullptr, 4096, 3 * DD, DD, 0);
        dattn_kernel<NG, 32, 16><<<BB * 16, 256, 0, stream>>>(qkvd, odb, dsc);
        gemmSK(odb, dowb + (size_t)l * DD * DD, dob + (size_t)l * DD, qkvd, 4096, DD, DD, 2);
        ln_res<DD, 2><<<BB * NG, 256, 0, stream>>>(xd, qkvd, PSD, dl1g + (size_t)l * DD, dl1b + (size_t)l * DD, xdb);
        gemm(xdb, df1wb + (size_t)l * 4 * DD * DD, df1b + (size_t)l * 4 * DD, nullptr, fd1b, 4096, 4 * DD, DD, 1);
        gemmSK(fd1b, df2wb + (size_t)l * DD * 4 * DD, df2b + (size_t)l * DD, qkvd, 4096, DD, 4 * DD, 2);
        ln_res<DD, 2><<<BB * NG, 256, 0, stream>>>(xd, qkvd, PSD, dl2g + (size_t)l * DD, dl2b + (size_t)l * DD, xdb);
    }

    // ---- stage 7: prediction + loss ----
    gemm(xdb, prwb, prb, pred, nullptr, 4096, 96, 512, 0);
    loss_l<<<BB * NG, 128, 0, stream>>>(pred, gn, maskv, lm);
    loss_final<<<1, 1024, 0, stream>>>(lm, maskv, out);
}

// Round 10
// 2375.592 us; speedup vs baseline: 9.7566x; 1.0184x over previous
//
#include <hip/hip_runtime.h>
#include <cmath>

// ---------------- problem constants ----------------
#define BB 32          // batch
#define NPTS 8192      // points per cloud
#define NG 128         // groups
#define KNB 32         // neighbors per group
#define LK 32          // len_keep
#define DE 768         // encoder dim
#define DD 512         // decoder dim
#define NLE 12
#define NLD 8

typedef __bf16 bf16x8 __attribute__((ext_vector_type(8)));
typedef float  f32x4  __attribute__((ext_vector_type(4)));
typedef unsigned long long u64;

#define WAITV(N) asm volatile("s_waitcnt vmcnt(" #N ")" ::: "memory")

static __device__ __forceinline__ bf16x8 pack8(float4 a, float4 b) {
    bf16x8 h;
    h[0] = (__bf16)a.x; h[1] = (__bf16)a.y; h[2] = (__bf16)a.z; h[3] = (__bf16)a.w;
    h[4] = (__bf16)b.x; h[5] = (__bf16)b.y; h[6] = (__bf16)b.z; h[7] = (__bf16)b.w;
    return h;
}

// async global->LDS 16B copy: per-wave, lane l writes ldsbase + l*16
static __device__ __forceinline__ void gload16(const __bf16* g, __bf16* l) {
    __builtin_amdgcn_global_load_lds(
        (const __attribute__((address_space(1))) void*)g,
        (__attribute__((address_space(3))) void*)l,
        16, 0, 0);
}

// monotone float -> uint map (total order preserved, handles negatives)
static __device__ __forceinline__ unsigned fkey(float f) {
    unsigned u = __float_as_uint(f);
    return ((int)u < 0) ? ~u : (u | 0x80000000u);
}

// =====================================================================
// FPS (R9, at latency floor): one block/batch, 512 thr, regs + 1 barrier/step
// =====================================================================
__global__ __launch_bounds__(512, 1) void fps_kernel(
    const float* __restrict__ xyz, const int* __restrict__ init,
    float* __restrict__ cxyz)
{
#pragma clang fp contract(off)
    const int b = blockIdx.x;
    const float* P = xyz + (size_t)b * NPTS * 3;
    __shared__ float pxs[NPTS], pys[NPTS], pzs[NPTS];
    __shared__ u64 red[2][8];
    const int tid = threadIdx.x;
    float x[16], y[16], z[16], dmin[16];
    #pragma unroll
    for (int k = 0; k < 16; ++k) {
        int n = tid + (k << 9);
        float xx = P[n * 3 + 0], yy = P[n * 3 + 1], zz = P[n * 3 + 2];
        x[k] = xx; y[k] = yy; z[k] = zz;
        pxs[n] = xx; pys[n] = yy; pzs[n] = zz;
        dmin[k] = 1e10f;
    }
    int far = init[b];
    __syncthreads();
    for (int t = 0; t < NG; ++t) {
        float cx = pxs[far], cy = pys[far], cz = pzs[far];
        if (tid == 0) {
            cxyz[(b * NG + t) * 3 + 0] = cx;
            cxyz[(b * NG + t) * 3 + 1] = cy;
            cxyz[(b * NG + t) * 3 + 2] = cz;
        }
        float best = -1.0f; int bi = 0;
        #pragma unroll
        for (int k = 0; k < 16; ++k) {
            int n = tid + (k << 9);
            float dx = x[k] - cx, dy = y[k] - cy, dz = z[k] - cz;
            float d = dx * dx + dy * dy + dz * dz;
            float dm = dmin[k];
            if (d < dm) dm = d;
            dmin[k] = dm;
            if (dm > best) { best = dm; bi = n; }   // strict > keeps lowest index
        }
        u64 key = ((u64)__float_as_uint(best) << 32) | (unsigned)(8191 - bi);
        #pragma unroll
        for (int d = 32; d >= 1; d >>= 1) {
            u64 k2 = __shfl_down(key, d);
            if (k2 > key) key = k2;
        }
        if ((tid & 63) == 0) red[t & 1][tid >> 6] = key;
        __syncthreads();
        u64 kb = red[t & 1][0];
        #pragma unroll
        for (int w = 1; w < 8; ++w) {
            u64 k2 = red[t & 1][w];
            if (k2 > kb) kb = k2;
        }
        far = 8191 - (int)(kb & 0xFFFFFFFFu);
    }
}

// =====================================================================
// KNN: threshold + rank selection (R8, unchanged).
// =====================================================================
__global__ __launch_bounds__(256) void knn_kernel(
    const float* __restrict__ xyz, const float* __restrict__ cxyz,
    float* __restrict__ gn)
{
#pragma clang fp contract(off)
    const int bm = blockIdx.x;
    const int b = bm / NG;
    const float* P = xyz + (size_t)b * NPTS * 3;
    __shared__ u64 cand[512];
    __shared__ u64 tmins[4];
    __shared__ int wcnt[4];
    __shared__ int order[KNB];
    const int tid = threadIdx.x;
    const int wv = tid >> 6, lane = tid & 63;
    const float cx = cxyz[bm * 3 + 0], cy = cxyz[bm * 3 + 1], cz = cxyz[bm * 3 + 2];
    const float c2 = cx * cx + cy * cy + cz * cz;
    unsigned fk[32];
    float bestf = 1e31f; int bi = 1 << 30;
    #pragma unroll
    for (int j = 0; j < 32; ++j) {
        int n = tid + (j << 8);
        float x = P[n * 3 + 0], y = P[n * 3 + 1], z = P[n * 3 + 2];
        float x2 = x * x + y * y + z * z;
        float dt = cx * x + cy * y + cz * z;
        float v = (c2 + x2) - 2.0f * dt;
        fk[j] = fkey(v);
        if (v < bestf) { bestf = v; bi = n; }
    }
    u64 mk = ((u64)fkey(bestf) << 32) | (unsigned)bi;
    {
        u64 v = mk;
        #pragma unroll
        for (int k = 2; k <= 64; k <<= 1) {
            #pragma unroll
            for (int j = k >> 1; j > 0; j >>= 1) {
                u64 o = __shfl_xor(v, j);
                bool up = ((lane & k) == 0);
                bool lower = ((lane & j) == 0);
                u64 mn = (v < o) ? v : o;
                u64 mx = (v < o) ? o : v;
                v = (up == lower) ? mn : mx;
            }
        }
        u64 Tw = __shfl(v, 31);
        if (lane == 0) tmins[wv] = Tw;
    }
    __syncthreads();
    u64 T = tmins[0];
    #pragma unroll
    for (int w = 1; w < 4; ++w) { u64 k2 = tmins[w]; if (k2 < T) T = k2; }
    int c = 0;
    #pragma unroll
    for (int j = 0; j < 32; ++j) {
        u64 key = ((u64)fk[j] << 32) | (unsigned)(tid + (j << 8));
        c += (key <= T) ? 1 : 0;
    }
    int s = c;
    #pragma unroll
    for (int d = 1; d < 64; d <<= 1) {
        int t2 = __shfl_up(s, d);
        if (lane >= d) s += t2;
    }
    int excl = s - c;
    if (lane == 63) wcnt[wv] = s;
    __syncthreads();
    int base = 0;
    for (int w = 0; w < wv; ++w) base += wcnt[w];
    int etot = wcnt[0] + wcnt[1] + wcnt[2] + wcnt[3];

    if (etot <= 512) {
        int pos = base + excl;
        #pragma unroll
        for (int j = 0; j < 32; ++j) {
            u64 key = ((u64)fk[j] << 32) | (unsigned)(tid + (j << 8));
            if (key <= T) cand[pos++] = key;
        }
        __syncthreads();
        for (int si = tid; si < etot; si += 256) {
            u64 my = cand[si];
            int r = 0;
            for (int j2 = 0; j2 < etot; ++j2) r += (cand[j2] < my) ? 1 : 0;
            if (r < KNB) order[r] = (int)(my & 0xFFFFFFFFu);
        }
        __syncthreads();
    } else {
        u64 bk = ~0ull;
        #pragma unroll
        for (int j = 0; j < 32; ++j) {
            u64 key = ((u64)fk[j] << 32) | (unsigned)(tid + (j << 8));
            if (key < bk) bk = key;
        }
        for (int r = 0; r < KNB; ++r) {
            u64 kk = bk;
            #pragma unroll
            for (int dd = 32; dd >= 1; dd >>= 1) {
                u64 k2 = __shfl_down(kk, dd);
                if (k2 < kk) kk = k2;
            }
            if (lane == 0) cand[(r & 1) * 4 + wv] = kk;
            __syncthreads();
            u64 kb = cand[(r & 1) * 4 + 0];
            #pragma unroll
            for (int w = 1; w < 4; ++w) { u64 k2 = cand[(r & 1) * 4 + w]; if (k2 < kb) kb = k2; }
            if (tid == 0) order[r] = (int)(kb & 0xFFFFFFFFu);
            if ((int)(kb & 255u) == tid) {
                int sj = (int)((kb & 0xFFFFFFFFu) >> 8);
                #pragma unroll
                for (int j = 0; j < 32; ++j) if (j == sj) fk[j] = 0xFFFFFFFFu;
                bk = ~0ull;
                #pragma unroll
                for (int j = 0; j < 32; ++j) {
                    u64 key = ((u64)fk[j] << 32) | (unsigned)(tid + (j << 8));
                    if (key < bk) bk = key;
                }
            }
            __syncthreads();
        }
    }
    if (tid < KNB) {
        int n = order[tid];
        gn[((size_t)bm * KNB + tid) * 3 + 0] = P[n * 3 + 0] - cx;
        gn[((size_t)bm * KNB + tid) * 3 + 1] = P[n * 3 + 1] - cy;
        gn[((size_t)bm * KNB + tid) * 3 + 2] = P[n * 3 + 2] - cz;
    }
}

// =====================================================================
// f32 -> bf16 bulk convert
// =====================================================================
__global__ void cvt_bf16_kernel(const float* __restrict__ src, __bf16* __restrict__ dst, int n8)
{
    int i = blockIdx.x * 256 + threadIdx.x;
    if (i >= n8) return;
    const float4* p = (const float4*)(src + (size_t)i * 8);
    *(bf16x8*)(dst + (size_t)i * 8) = pack8(p[0], p[1]);
}

struct CvtTab {
    const float* src[10];
    __bf16* dst[10];
    int cum[11];
};
__global__ void cvt_multi_kernel(CvtTab t)
{
    int i = blockIdx.x * 256 + threadIdx.x;
    if (i >= t.cum[10]) return;
    int seg = 0;
    #pragma unroll
    for (int k = 1; k < 10; ++k) seg += (i >= t.cum[k]) ? 1 : 0;
    int local = i - t.cum[seg];
    const float4* p = (const float4*)(t.src[seg] + (size_t)local * 8);
    *(bf16x8*)(t.dst[seg] + (size_t)local * 8) = pack8(p[0], p[1]);
}

// =====================================================================
// embed1
// =====================================================================
__global__ void embed1_kernel(const float* __restrict__ gn, const float* __restrict__ w,
                              const float* __restrict__ bias, float* __restrict__ h1)
{
    int i = blockIdx.x * 256 + threadIdx.x;
    if (i >= 131072 * 64) return;
    int r = i >> 6, c = i & 63;
    const float* p = gn + (size_t)r * 3;
    h1[i] = p[0] * w[c * 3 + 0] + p[1] * w[c * 3 + 1] + p[2] * w[c * 3 + 2] + bias[c];
}

// =====================================================================
// column stats
// =====================================================================
template <int C>
__global__ __launch_bounds__(256) void colstats_kernel(const float* __restrict__ X,
                                                       double* __restrict__ st, int Mrows)
{
    constexpr int RL = 256 / C;
    const int c = threadIdx.x % C;
    const int rl = threadIdx.x / C;
    double s = 0.0, s2 = 0.0;
    int rows_per_block = (Mrows + gridDim.x - 1) / gridDim.x;
    int r0 = blockIdx.x * rows_per_block;
    int r1 = min(r0 + rows_per_block, Mrows);
    for (int r = r0 + rl; r < r1; r += RL) {
        float v = X[(size_t)r * C + c];
        s += v; s2 += (double)v * v;
    }
    __shared__ double sh[2][256];
    sh[0][threadIdx.x] = s; sh[1][threadIdx.x] = s2;
    __syncthreads();
    if (rl == 0) {
        for (int j = 1; j < RL; ++j) { s += sh[0][j * C + c]; s2 += sh[1][j * C + c]; }
        atomicAdd(&st[c], s);
        atomicAdd(&st[C + c], s2);
    }
}

__global__ void bn_finalize(const double* __restrict__ st, const float* __restrict__ g,
                            const float* __restrict__ be, float* __restrict__ sc,
                            float* __restrict__ shb, int C)
{
    int c = blockIdx.x * 64 + threadIdx.x;
    if (c >= C) return;
    double m = st[c] / 131072.0;
    double var = st[C + c] / 131072.0 - m * m;
    if (var < 0.0) var = 0.0;
    float rs = rsqrtf((float)var + 1e-5f);
    sc[c] = rs * g[c];
    shb[c] = be[c] - (float)m * rs * g[c];
}

__global__ void bn_apply_bf16(const float* __restrict__ x, const float* __restrict__ sc,
                              const float* __restrict__ shb, __bf16* __restrict__ y,
                              int total, int C)
{
    int i = blockIdx.x * 256 + threadIdx.x;
    if (i >= total) return;
    int c = i % C;
    float v = x[i] * sc[c] + shb[c];
    v = fmaxf(v, 0.0f);
    y[i] = (__bf16)v;
}

// =====================================================================
// bf16 MFMA GEMM, split-K, unified single-barrier counted-vmcnt pipeline:
// per K-step: WAITV(ahead*L); barrier; stage(t+DEPTH-1); compute(t).
// The barrier at iter t proves all waves finished compute(t-1), so the
// stage overwrite of buf (t+DEPTH-1)%DEPTH is safe.
// =====================================================================
template <int BM, int WM, int WN, int DEPTH>
__global__ __launch_bounds__(256) void gemm_bf16(
    const __bf16* __restrict__ A, const __bf16* __restrict__ W,
    const float* __restrict__ bias, float* __restrict__ Cf, __bf16* __restrict__ Cb,
    int M, int N, int K, int Kc, int relu)
{
    constexpr int MR = BM / WM / 16;
    constexpr int NR = 128 / WN / 16;
    constexpr int CA = BM * 8 / 256;
    __shared__ __bf16 As[DEPTH][BM * 64];
    __shared__ __bf16 Ws[DEPTH][128 * 64];
    const int tid = threadIdx.x;
    const int lane = tid & 63;
    const int wave = tid >> 6;
    const int wm = wave / WN, wn = wave % WN;
    const int m0 = blockIdx.y * BM, n0 = blockIdx.x * 128;
    const int kb = blockIdx.z * Kc;

    f32x4 acc[MR][NR] = {};

    auto stage = [&](int buf, int kt) {
        #pragma unroll
        for (int j = 0; j < CA; ++j) {
            int cb = j * 256 + (wave << 6);
            int c  = cb + lane;
            int row = c >> 3;
            int kcs = (c & 7) ^ (row & 7);
            gload16(A + (size_t)(m0 + row) * K + kb + kt + kcs * 8, &As[buf][cb * 8]);
        }
        #pragma unroll
        for (int j = 0; j < 4; ++j) {
            int cb = j * 256 + (wave << 6);
            int c  = cb + lane;
            int row = c >> 3;
            int kcs = (c & 7) ^ (row & 7);
            gload16(W + (size_t)(n0 + row) * K + kb + kt + kcs * 8, &Ws[buf][cb * 8]);
        }
    };
    auto compute = [&](int buf) {
        #pragma unroll
        for (int ks = 0; ks < 2; ++ks) {
            bf16x8 af[MR], bfr[NR];
            int kc = ks * 4 + (lane >> 4);
            #pragma unroll
            for (int i = 0; i < MR; ++i) {
                int rowA = wm * (BM / WM) + i * 16 + (lane & 15);
                af[i] = *(bf16x8*)&As[buf][rowA * 64 + ((kc ^ (rowA & 7)) * 8)];
            }
            #pragma unroll
            for (int j = 0; j < NR; ++j) {
                int rowB = wn * (128 / WN) + j * 16 + (lane & 15);
                bfr[j] = *(bf16x8*)&Ws[buf][rowB * 64 + ((kc ^ (rowB & 7)) * 8)];
            }
            #pragma unroll
            for (int i = 0; i < MR; ++i)
                #pragma unroll
                for (int j = 0; j < NR; ++j)
                    acc[i][j] = __builtin_amdgcn_mfma_f32_16x16x32_bf16(af[i], bfr[j], acc[i][j], 0, 0, 0);
        }
    };

    const int nt = Kc >> 6;
    stage(0, 0);
    if (DEPTH > 2 && nt > 1) stage(1, 64);
    for (int t = 0; t < nt; ++t) {
        int ahead = min(nt - 1, t + DEPTH - 2) - t;   // stages allowed in flight
        if (ahead >= 1) { if constexpr (BM == 64) WAITV(6); else WAITV(8); }
        else            WAITV(0);
        __syncthreads();
        if (t + DEPTH - 1 < nt) stage((t + DEPTH - 1) % DEPTH, (t + DEPTH - 1) << 6);
        compute(t % DEPTH);
    }

    float* Co = Cf ? Cf + (size_t)blockIdx.z * M * N : nullptr;
    #pragma unroll
    for (int j = 0; j < NR; ++j) {
        int col = n0 + wn * (128 / WN) + j * 16 + (lane & 15);
        if (col >= N) continue;
        float bv = (blockIdx.z == 0) ? bias[col] : 0.0f;
        #pragma unroll
        for (int i = 0; i < MR; ++i) {
            #pragma unroll
            for (int r = 0; r < 4; ++r) {
                int rowm = m0 + wm * (BM / WM) + i * 16 + (lane >> 4) * 4 + r;
                float v = acc[i][j][r] + bv;
                if (relu) v = fmaxf(v, 0.0f);
                if (Co) Co[(size_t)rowm * N + col] = v;
                if (Cb) Cb[(size_t)rowm * N + col] = (__bf16)v;
            }
        }
    }
}

// =====================================================================
// embed3 via MFMA (unchanged)
// =====================================================================
__global__ __launch_bounds__(256) void embed3_mfma(
    const __bf16* __restrict__ A, const __bf16* __restrict__ W,
    const float* __restrict__ cb3,
    float* __restrict__ gmax, float* __restrict__ gmin, double* __restrict__ st3)
{
    __shared__ __bf16 As[2][128 * 64];
    __shared__ __bf16 Ws[2][128 * 64];
    const int tid = threadIdx.x;
    const int lane = tid & 63;
    const int wave = tid >> 6;
    const int wm = wave >> 1, wn = wave & 1;
    const int m0 = blockIdx.y * 128, n0 = blockIdx.x * 128;
    const int K = 128;

    f32x4 acc[4][4] = {};

    auto stage = [&](int buf, int kt) {
        #pragma unroll
        for (int j = 0; j < 4; ++j) {
            int cb = j * 256 + (wave << 6);
            int c  = cb + lane;
            int row = c >> 3;
            int kcs = (c & 7) ^ (row & 7);
            gload16(A + (size_t)(m0 + row) * K + kt + kcs * 8, &As[buf][cb * 8]);
            gload16(W + (size_t)(n0 + row) * K + kt + kcs * 8, &Ws[buf][cb * 8]);
        }
    };
    auto compute = [&](int buf) {
        #pragma unroll
        for (int ks = 0; ks < 2; ++ks) {
            bf16x8 af[4], bfr[4];
            int kc = ks * 4 + (lane >> 4);
            #pragma unroll
            for (int i = 0; i < 4; ++i) {
                int rowA = wm * 64 + i * 16 + (lane & 15);
                af[i] = *(bf16x8*)&As[buf][rowA * 64 + ((kc ^ (rowA & 7)) * 8)];
                int rowB = wn * 64 + i * 16 + (lane & 15);
                bfr[i] = *(bf16x8*)&Ws[buf][rowB * 64 + ((kc ^ (rowB & 7)) * 8)];
            }
            #pragma unroll
            for (int i = 0; i < 4; ++i)
                #pragma unroll
                for (int j = 0; j < 4; ++j)
                    acc[i][j] = __builtin_amdgcn_mfma_f32_16x16x32_bf16(af[i], bfr[j], acc[i][j], 0, 0, 0);
        }
    };

    stage(0, 0);
    stage(1, 64);
    WAITV(8);
    __syncthreads();
    compute(0);
    WAITV(0);
    __syncthreads();
    compute(1);

    #pragma unroll
    for (int j = 0; j < 4; ++j) {
        int col = n0 + wn * 64 + j * 16 + (lane & 15);
        float bv = cb3[col];
        float stot = 0.0f, s2tot = 0.0f;
        #pragma unroll
        for (int gi = 0; gi < 2; ++gi) {
            float mx = -1e30f, mn = 1e30f, s = 0.0f, s2 = 0.0f;
            #pragma unroll
            for (int ii = 0; ii < 2; ++ii) {
                f32x4 a = acc[gi * 2 + ii][j];
                #pragma unroll
                for (int r = 0; r < 4; ++r) {
                    float v = a[r] + bv;
                    mx = fmaxf(mx, v); mn = fminf(mn, v);
                    s += v; s2 += v * v;
                }
            }
            #pragma unroll
            for (int d = 16; d < 64; d <<= 1) {
                mx = fmaxf(mx, __shfl_xor(mx, d));
                mn = fminf(mn, __shfl_xor(mn, d));
                s  += __shfl_xor(s, d);
                s2 += __shfl_xor(s2, d);
            }
            stot += s; s2tot += s2;
            if (lane < 16) {
                int g = (m0 >> 5) + wm * 2 + gi;
                gmax[(size_t)g * 768 + col] = mx;
                gmin[(size_t)g * 768 + col] = mn;
            }
        }
        if (lane < 16) {
            double* stp = st3 + (size_t)(blockIdx.y & 31) * 1536;
            atomicAdd(&stp[col], (double)stot);
            atomicAdd(&stp[768 + col], (double)s2tot);
        }
    }
}

__global__ void bn3_finalize(const double* __restrict__ st3, const float* __restrict__ g,
                             const float* __restrict__ be, float* __restrict__ a3,
                             float* __restrict__ c3)
{
    int c = blockIdx.x * 256 + threadIdx.x;
    if (c >= 768) return;
    double s = 0.0, s2 = 0.0;
    for (int p = 0; p < 32; ++p) { s += st3[(size_t)p * 1536 + c]; s2 += st3[(size_t)p * 1536 + 768 + c]; }
    double m = s / 131072.0;
    double var = s2 / 131072.0 - m * m;
    if (var < 0.0) var = 0.0;
    float rs = rsqrtf((float)var + 1e-5f);
    a3[c] = rs * g[c];
    c3[c] = be[c] - (float)m * rs * g[c];
}

// tokens + pos, FUSED gather: write only kept rows directly into xe/xeb
__global__ void tokens_pos(const float* __restrict__ gmax, const float* __restrict__ gmin,
                           const float* __restrict__ a3, const float* __restrict__ c3,
                           const float* __restrict__ cxyz, const float* __restrict__ posw,
                           const float* __restrict__ posb, const int* __restrict__ restore,
                           float* __restrict__ xe, __bf16* __restrict__ xeb)
{
    int i = blockIdx.x * 256 + threadIdx.x;
    if (i >= 4096 * 768) return;
    int c = i % 768, g = i / 768;
    int r = restore[g];
    if (r >= LK) return;                     // masked-out token: x never used
    float a = a3[c];
    float tok = (a >= 0.0f ? a * gmax[i] : a * gmin[i]) + c3[c];
    float px = cxyz[g * 3 + 0], py = cxyz[g * 3 + 1], pz = cxyz[g * 3 + 2];
    float v = tok + px * posw[c * 3 + 0] + py * posw[c * 3 + 1] + pz * posw[c * 3 + 2] + posb[c];
    int b = g >> 7;
    size_t idx = ((size_t)(b * LK + r)) * DE + c;
    xe[idx] = v;
    xeb[idx] = (__bf16)v;
}

// restore + mask fused
__global__ void restore_kernel(const int* __restrict__ shuffle, int* __restrict__ restore,
                               float* __restrict__ maskv)
{
    int j = blockIdx.x * 256 + threadIdx.x;
    if (j >= BB * NG) return;
    int b = j / NG, p = j % NG;
    int dst = b * NG + shuffle[j];
    restore[dst] = p;
    maskv[dst] = (p < LK) ? 0.0f : 1.0f;
}

// yd = (kept ? sum of 4 yk partials : mtok) + cxyz@dpw^T + dpb
__global__ void yd_build(const float* __restrict__ ykp, const int* __restrict__ restore,
                         const float* __restrict__ mtok, const float* __restrict__ cxyz,
                         const float* __restrict__ dpw, const float* __restrict__ dpb,
                         float* __restrict__ xd, __bf16* __restrict__ xdb)
{
    const size_t PS = (size_t)1024 * DD;
    int i = blockIdx.x * 256 + threadIdx.x;
    if (i >= BB * NG * DD) return;
    int c = i % DD;
    int g = i / DD;
    int b = g / NG;
    int r = restore[g];
    float base;
    if (r < LK) {
        size_t o = (size_t)(b * LK + r) * DD + c;
        base = ykp[o] + ykp[PS + o] + ykp[2 * PS + o] + ykp[3 * PS + o];
    } else {
        base = mtok[c];
    }
    float px = cxyz[g * 3 + 0], py = cxyz[g * 3 + 1], pz = cxyz[g * 3 + 2];
    float v = base + px * dpw[c * 3 + 0] + py * dpw[c * 3 + 1] + pz * dpw[c * 3 + 2] + dpb[c];
    xd[i] = v;
    xdb[i] = (__bf16)v;
}

// =====================================================================
// decoder attention via MFMA: block per (b,h), 256 thr. bf16 qkv input.
// =====================================================================
template <int S, int DH, int NH>
__global__ __launch_bounds__(256) void dattn_kernel(const __bf16* __restrict__ qkv,
                                                    __bf16* __restrict__ o, float scale)
{
    constexpr int D = NH * DH;          // 512
    constexpr int SQ = DH + 8;          // 40
    constexpr int SV = S + 8;           // 136
    __shared__ __bf16 Qb[S * SQ];
    __shared__ __bf16 Kb[S * SQ];
    __shared__ __bf16 Vt[DH * SV];
    __shared__ __bf16 Pb[S * SV];
    const int h = blockIdx.x % NH;
    const int b = blockIdx.x / NH;
    const int tid = threadIdx.x;
    const int lane = tid & 63, wv = tid >> 6;
    const __bf16* base = qkv + (size_t)b * S * 3 * D + h * DH;
    for (int i = tid; i < S * (DH / 8); i += 256) {
        int s = i / (DH / 8), c8 = (i % (DH / 8)) * 8;
        const __bf16* rp = base + (size_t)s * 3 * D;
        bf16x8 q = *(const bf16x8*)(rp + c8);
        bf16x8 k = *(const bf16x8*)(rp + D + c8);
        bf16x8 v = *(const bf16x8*)(rp + 2 * D + c8);
        *(bf16x8*)&Qb[s * SQ + c8] = q;
        *(bf16x8*)&Kb[s * SQ + c8] = k;
        #pragma unroll
        for (int j = 0; j < 8; ++j) Vt[(c8 + j) * SV + s] = v[j];
    }
    __syncthreads();
    const int q0 = wv * 32;
    const int arow = lane & 15;
    const int kch = (lane >> 4) * 8;
    const int rrow = (lane >> 4) * 4;
    f32x4 sc[2][8];
    {
        bf16x8 af0 = *(bf16x8*)&Qb[(q0 + arow) * SQ + kch];
        bf16x8 af1 = *(bf16x8*)&Qb[(q0 + 16 + arow) * SQ + kch];
        f32x4 z = {0.0f, 0.0f, 0.0f, 0.0f};
        #pragma unroll
        for (int j = 0; j < 8; ++j) {
            bf16x8 bf_ = *(bf16x8*)&Kb[(j * 16 + arow) * SQ + kch];
            sc[0][j] = __builtin_amdgcn_mfma_f32_16x16x32_bf16(af0, bf_, z, 0, 0, 0);
            sc[1][j] = __builtin_amdgcn_mfma_f32_16x16x32_bf16(af1, bf_, z, 0, 0, 0);
        }
    }
    #pragma unroll
    for (int i = 0; i < 2; ++i) {
        #pragma unroll
        for (int r = 0; r < 4; ++r) {
            float m = -1e30f;
            #pragma unroll
            for (int j = 0; j < 8; ++j) m = fmaxf(m, sc[i][j][r]);
            #pragma unroll
            for (int d = 8; d >= 1; d >>= 1) m = fmaxf(m, __shfl_xor(m, d));
            float sum = 0.0f;
            #pragma unroll
            for (int j = 0; j < 8; ++j) {
                float e = expf((sc[i][j][r] - m) * scale);
                sc[i][j][r] = e;
                sum += e;
            }
            #pragma unroll
            for (int d = 8; d >= 1; d >>= 1) sum += __shfl_xor(sum, d);
            float inv = 1.0f / sum;
            int row = q0 + i * 16 + rrow + r;
            #pragma unroll
            for (int j = 0; j < 8; ++j)
                Pb[row * SV + j * 16 + (lane & 15)] = (__bf16)(sc[i][j][r] * inv);
        }
    }
    #pragma unroll
    for (int i = 0; i < 2; ++i) {
        #pragma unroll
        for (int j2 = 0; j2 < 2; ++j2) {
            f32x4 a2 = {0.0f, 0.0f, 0.0f, 0.0f};
            #pragma unroll
            for (int ks = 0; ks < 4; ++ks) {
                bf16x8 pa = *(bf16x8*)&Pb[(q0 + i * 16 + arow) * SV + ks * 32 + kch];
                bf16x8 vb = *(bf16x8*)&Vt[(j2 * 16 + arow) * SV + ks * 32 + kch];
                a2 = __builtin_amdgcn_mfma_f32_16x16x32_bf16(pa, vb, a2, 0, 0, 0);
            }
            #pragma unroll
            for (int r = 0; r < 4; ++r) {
                int q = q0 + i * 16 + rrow + r;
                o[((size_t)(b * S + q)) * D + h * DH + j2 * 16 + (lane & 15)] = (__bf16)a2[r];
            }
        }
    }
}

// =====================================================================
// encoder attention via MFMA: block per (b,h), 64 thr. bf16 qkv input.
// =====================================================================
template <int S, int DH, int NH>
__global__ __launch_bounds__(64) void eattn_kernel(const __bf16* __restrict__ qkv,
                                                   __bf16* __restrict__ o, float scale)
{
    constexpr int D = NH * DH;          // 768
    constexpr int SQ = DH + 8;          // 72
    constexpr int SV = S + 8;           // 40
    __shared__ __bf16 Qb[S * SQ];
    __shared__ __bf16 Kb[S * SQ];
    __shared__ __bf16 Vt[DH * SV];
    __shared__ __bf16 Pb[S * SV];
    const int h = blockIdx.x % NH;
    const int b = blockIdx.x / NH;
    const int lane = threadIdx.x;
    const __bf16* base = qkv + (size_t)b * S * 3 * D + h * DH;
    for (int i = lane; i < S * (DH / 8); i += 64) {
        int s = i / (DH / 8), c8 = (i % (DH / 8)) * 8;
        const __bf16* rp = base + (size_t)s * 3 * D;
        bf16x8 q = *(const bf16x8*)(rp + c8);
        bf16x8 k = *(const bf16x8*)(rp + D + c8);
        bf16x8 v = *(const bf16x8*)(rp + 2 * D + c8);
        *(bf16x8*)&Qb[s * SQ + c8] = q;
        *(bf16x8*)&Kb[s * SQ + c8] = k;
        #pragma unroll
        for (int j = 0; j < 8; ++j) Vt[(c8 + j) * SV + s] = v[j];
    }
    __syncthreads();
    const int arow = lane & 15;
    const int kch = (lane >> 4) * 8;
    const int rrow = (lane >> 4) * 4;
    f32x4 sc[2][2] = {};
    #pragma unroll
    for (int ks = 0; ks < 2; ++ks) {
        bf16x8 af0 = *(bf16x8*)&Qb[(arow) * SQ + ks * 32 + kch];
        bf16x8 af1 = *(bf16x8*)&Qb[(16 + arow) * SQ + ks * 32 + kch];
        #pragma unroll
        for (int j = 0; j < 2; ++j) {
            bf16x8 bf_ = *(bf16x8*)&Kb[(j * 16 + arow) * SQ + ks * 32 + kch];
            sc[0][j] = __builtin_amdgcn_mfma_f32_16x16x32_bf16(af0, bf_, sc[0][j], 0, 0, 0);
            sc[1][j] = __builtin_amdgcn_mfma_f32_16x16x32_bf16(af1, bf_, sc[1][j], 0, 0, 0);
        }
    }
    #pragma unroll
    for (int i = 0; i < 2; ++i) {
        #pragma unroll
        for (int r = 0; r < 4; ++r) {
            float m = fmaxf(sc[i][0][r], sc[i][1][r]);
            #pragma unroll
            for (int d = 8; d >= 1; d >>= 1) m = fmaxf(m, __shfl_xor(m, d));
            float sum = 0.0f;
            #pragma unroll
            for (int j = 0; j < 2; ++j) {
                float e = expf((sc[i][j][r] - m) * scale);
                sc[i][j][r] = e;
                sum += e;
            }
            #pragma unroll
            for (int d = 8; d >= 1; d >>= 1) sum += __shfl_xor(sum, d);
            float inv = 1.0f / sum;
            int row = i * 16 + rrow + r;
            #pragma unroll
            for (int j = 0; j < 2; ++j)
                Pb[row * SV + j * 16 + (lane & 15)] = (__bf16)(sc[i][j][r] * inv);
        }
    }
    __syncthreads();
    #pragma unroll
    for (int i = 0; i < 2; ++i) {
        bf16x8 pa = *(bf16x8*)&Pb[(i * 16 + arow) * SV + kch];
        #pragma unroll
        for (int j2 = 0; j2 < 4; ++j2) {
            bf16x8 vb = *(bf16x8*)&Vt[(j2 * 16 + arow) * SV + kch];
            f32x4 z = {0.0f, 0.0f, 0.0f, 0.0f};
            f32x4 a2 = __builtin_amdgcn_mfma_f32_16x16x32_bf16(pa, vb, z, 0, 0, 0);
            #pragma unroll
            for (int r = 0; r < 4; ++r) {
                int q = i * 16 + rrow + r;
                o[((size_t)(b * S + q)) * D + h * DH + j2 * 16 + (lane & 15)] = (__bf16)a2[r];
            }
        }
    }
}

// =====================================================================
// LayerNorm with residual (+ SK split-K partial sum)
// =====================================================================
template <int D, int SK>
__global__ __launch_bounds__(256) void ln_res(float* __restrict__ x, const float* __restrict__ part,
                                              size_t pstride,
                                              const float* __restrict__ g, const float* __restrict__ b,
                                              __bf16* __restrict__ xb)
{
    constexpr int J = D / 256;
    __shared__ float pr[2][4];
    const size_t off = (size_t)blockIdx.x * D;
    const int tid = threadIdx.x;
    float vals[J];
    float s = 0.0f, s2 = 0.0f;
    #pragma unroll
    for (int j = 0; j < J; ++j) {
        int i = tid + j * 256;
        float v = x[off + i];
        #pragma unroll
        for (int sk = 0; sk < SK; ++sk) v += part[(size_t)sk * pstride + off + i];
        vals[j] = v; s += v; s2 += v * v;
    }
    #pragma unroll
    for (int d = 32; d >= 1; d >>= 1) { s += __shfl_down(s, d); s2 += __shfl_down(s2, d); }
    if ((tid & 63) == 0) { pr[0][tid >> 6] = s; pr[1][tid >> 6] = s2; }
    __syncthreads();
    float st = pr[0][0] + pr[0][1] + pr[0][2] + pr[0][3];
    float s2t = pr[1][0] + pr[1][1] + pr[1][2] + pr[1][3];
    float m = st / D;
    float var = s2t / D - m * m;
    if (var < 0.0f) var = 0.0f;
    float rs = rsqrtf(var + 1e-5f);
    #pragma unroll
    for (int j = 0; j < J; ++j) {
        int i = tid + j * 256;
        float v = (vals[j] - m) * rs * g[i] + b[i];
        x[off + i] = v;
        xb[off + i] = (__bf16)v;
    }
}

// =====================================================================
// loss: sum 4 pred split-K partials, write final pred, masked row mse
// =====================================================================
__global__ __launch_bounds__(128) void loss_l(const float* __restrict__ predp,
                                              const float* __restrict__ target,
                                              const float* __restrict__ maskv,
                                              float* __restrict__ pred_out,
                                              float* __restrict__ lm)
{
    const size_t PS = (size_t)4096 * 96;
    const int g = blockIdx.x;
    __shared__ float red[128];
    int t = threadIdx.x;
    float s = 0.0f;
    if (t < 96) {
        size_t o = (size_t)g * 96 + t;
        float v = predp[o] + predp[PS + o] + predp[2 * PS + o] + predp[3 * PS + o];
        pred_out[o] = v;
        float d = v - target[o];
        s = d * d;
    }
    red[t] = s; __syncthreads();
    for (int st = 64; st > 0; st >>= 1) { if (t < st) red[t] += red[t + st]; __syncthreads(); }
    if (t == 0) lm[g] = (red[0] / 96.0f) * maskv[g];
}

__global__ __launch_bounds__(1024) void loss_final(const float* __restrict__ lm,
                                                   const float* __restrict__ maskv,
                                                   float* __restrict__ out)
{
    __shared__ float r1[1024], r2[1024];
    int t = threadIdx.x;
    float a = 0.0f, b = 0.0f;
    for (int i = t; i < BB * NG; i += 1024) { a += lm[i]; b += maskv[i]; }
    r1[t] = a; r2[t] = b; __syncthreads();
    for (int st = 512; st > 0; st >>= 1) { if (t < st) { r1[t] += r1[t + st]; r2[t] += r2[t + st]; } __syncthreads(); }
    if (t == 0) out[0] = r1[0] / r2[0];
}

// =====================================================================
// host
// =====================================================================
extern "C" void kernel_launch(void* const* d_in, const int* in_sizes, int n_in,
                              void* d_out, int out_size, void* d_ws, size_t ws_size,
                              hipStream_t stream)
{
    (void)in_sizes; (void)n_in; (void)out_size; (void)ws_size;
    const float* xyz        = (const float*)d_in[0];
    const int*   fps_init   = (const int*)d_in[1];
    const int*   ids_shuf   = (const int*)d_in[2];
    const float* cw1 = (const float*)d_in[3];  const float* cb1 = (const float*)d_in[4];
    const float* g1  = (const float*)d_in[5];  const float* be1 = (const float*)d_in[6];
    const float* cw2 = (const float*)d_in[7];  const float* cb2 = (const float*)d_in[8];
    const float* g2  = (const float*)d_in[9];  const float* be2 = (const float*)d_in[10];
    const float* cw3 = (const float*)d_in[11]; const float* cb3 = (const float*)d_in[12];
    const float* g3  = (const float*)d_in[13]; const float* be3 = (const float*)d_in[14];
    const float* posw = (const float*)d_in[15]; const float* posb = (const float*)d_in[16];
    const float* eqw = (const float*)d_in[17]; const float* eqb = (const float*)d_in[18];
    const float* eow = (const float*)d_in[19]; const float* eob = (const float*)d_in[20];
    const float* el1g = (const float*)d_in[21]; const float* el1b = (const float*)d_in[22];
    const float* ef1w = (const float*)d_in[23]; const float* ef1b = (const float*)d_in[24];
    const float* ef2w = (const float*)d_in[25]; const float* ef2b = (const float*)d_in[26];
    const float* el2g = (const float*)d_in[27]; const float* el2b = (const float*)d_in[28];
    const float* dew = (const float*)d_in[29]; const float* deb = (const float*)d_in[30];
    const float* mtok = (const float*)d_in[31];
    const float* dpw = (const float*)d_in[32]; const float* dpb = (const float*)d_in[33];
    const float* dqw = (const float*)d_in[34]; const float* dqb = (const float*)d_in[35];
    const float* dow = (const float*)d_in[36]; const float* dob = (const float*)d_in[37];
    const float* dl1g = (const float*)d_in[38]; const float* dl1b = (const float*)d_in[39];
    const float* df1w = (const float*)d_in[40]; const float* df1b = (const float*)d_in[41];
    const float* df2w = (const float*)d_in[42]; const float* df2b = (const float*)d_in[43];
    const float* dl2g = (const float*)d_in[44]; const float* dl2b = (const float*)d_in[45];
    const float* prw = (const float*)d_in[46]; const float* prb = (const float*)d_in[47];
    float* out = (float*)d_out;
    float* pred = out + 1;
    float* maskv = out + 1 + (size_t)BB * NG * KNB * 3;

    // ---- workspace carve ----
    char* ws = (char*)d_ws;
    size_t off = 0;
    auto alloc = [&](size_t bytes) -> void* {
        void* p = ws + off;
        off = (off + bytes + 255) & ~(size_t)255;
        return p;
    };
    double* st1 = (double*)alloc(128 * 8);
    double* st2 = (double*)alloc(256 * 8);
    double* st3 = (double*)alloc((size_t)32 * 1536 * 8);
    float* sc1 = (float*)alloc(64 * 4);  float* sh1 = (float*)alloc(64 * 4);
    float* sc2 = (float*)alloc(128 * 4); float* sh2 = (float*)alloc(128 * 4);
    float* a3 = (float*)alloc(768 * 4);  float* c3 = (float*)alloc(768 * 4);
    int* restore = (int*)alloc(4096 * 4);
    float* cxyz = (float*)alloc(12288 * 4);
    float* gn   = (float*)alloc((size_t)393216 * 4);
    __bf16* cw2b = (__bf16*)alloc((size_t)128 * 64 * 2);
    __bf16* cw3b = (__bf16*)alloc((size_t)768 * 128 * 2);
    float* xfull = (float*)alloc((size_t)4096 * 768 * 4);   // encoder SK partials
    float* xe    = (float*)alloc((size_t)1024 * 768 * 4);
    __bf16* xeb  = (__bf16*)alloc((size_t)1024 * 768 * 2);
    float* qkve  = (float*)alloc((size_t)1024 * 2304 * 4);  // dew SK partials (f32)
    __bf16* qkveb = (__bf16*)alloc((size_t)1024 * 2304 * 2);
    __bf16* oeb  = (__bf16*)alloc((size_t)1024 * 768 * 2);
    __bf16* fe1b = (__bf16*)alloc((size_t)1024 * 3072 * 2);
    float* xd    = (float*)alloc((size_t)4096 * 512 * 4);
    __bf16* xdb  = (__bf16*)alloc((size_t)4096 * 512 * 2);
    float* qkvd  = (float*)alloc((size_t)4096 * 1536 * 4);  // dec SK partials; gmax/gmin alias
    __bf16* qkvdb = (__bf16*)alloc((size_t)4096 * 1536 * 2);
    __bf16* odb  = (__bf16*)alloc((size_t)4096 * 512 * 2);
    __bf16* fd1b = (__bf16*)alloc((size_t)4096 * 2048 * 2); // pred SK partials alias
    float* lm    = (float*)alloc(4096 * 4);

    __bf16* eqwb  = (__bf16*)alloc((size_t)NLE * 3 * DE * DE * 2);
    __bf16* eowb  = (__bf16*)alloc((size_t)NLE * DE * DE * 2);
    __bf16* ef1wb = (__bf16*)alloc((size_t)NLE * 4 * DE * DE * 2);
    __bf16* ef2wb = (__bf16*)alloc((size_t)NLE * 4 * DE * DE * 2);
    __bf16* dewb  = (__bf16*)alloc((size_t)DD * DE * 2);
    __bf16* dqwb  = (__bf16*)alloc((size_t)NLD * 3 * DD * DD * 2);
    __bf16* dowb  = (__bf16*)alloc((size_t)NLD * DD * DD * 2);
    __bf16* df1wb = (__bf16*)alloc((size_t)NLD * 4 * DD * DD * 2);
    __bf16* df2wb = (__bf16*)alloc((size_t)NLD * 4 * DD * DD * 2);
    __bf16* prwb  = (__bf16*)alloc((size_t)128 * 512 * 2);

    // stage-2 temps alias the ENCODER weight region (151MB <= 169.9MB)
    char* U = (char*)eqwb;
    float*  h1   = (float*)U;                                // 33.6MB
    __bf16* h1b  = (__bf16*)(U + (size_t)33554432);          // 16.8MB
    float*  h2   = (float*)(U + (size_t)50331648);           // 67.1MB
    __bf16* h2b  = (__bf16*)(U + (size_t)117440512);         // 33.6MB
    // gmax/gmin alias qkvd (decoder-only buffer, free during stage 2)
    float* gmax = qkvd;
    float* gmin = qkvd + (size_t)3145728;
    // pred split-K partials alias fd1b (free after last decoder ffn2)
    float* predp = (float*)fd1b;

    size_t stats_bytes = (size_t)((char*)st3 + (size_t)32 * 1536 * 8 - (char*)st1);
    hipMemsetAsync((void*)st1, 0, stats_bytes, stream);

    auto cvt = [&](const float* src, __bf16* dst, size_t n) {
        int n8 = (int)(n / 8);
        cvt_bf16_kernel<<<(n8 + 255) / 256, 256, 0, stream>>>(src, dst, n8);
    };
    auto gemm = [&](const __bf16* A, const __bf16* Wt, const float* bias,
                    float* Cf, __bf16* Cb, int M, int N, int K, int relu) {
        int nb128 = ((N + 127) / 128) * (M / 128);
        if (nb128 < 256) {
            dim3 grid((N + 127) / 128, M / 64, 1);
            gemm_bf16<64, 1, 4, 3><<<grid, 256, 0, stream>>>(A, Wt, bias, Cf, Cb, M, N, K, K, relu);
        } else {
            dim3 grid((N + 127) / 128, M / 128, 1);
            gemm_bf16<128, 2, 2, 2><<<grid, 256, 0, stream>>>(A, Wt, bias, Cf, Cb, M, N, K, K, relu);
        }
    };
    auto gemmSK = [&](const __bf16* A, const __bf16* Wt, const float* bias,
                      float* Cf, int M, int N, int K, int SK) {
        dim3 grid((N + 127) / 128, M / 64, SK);
        gemm_bf16<64, 1, 4, 3><<<grid, 256, 0, stream>>>(A, Wt, bias, Cf, nullptr, M, N, K, K / SK, 0);
    };

    cvt(cw2, cw2b, 128 * 64);
    cvt(cw3, cw3b, 768 * 128);

    // ---- stage 1: FPS + KNN ----
    fps_kernel<<<BB, 512, 0, stream>>>(xyz, fps_init, cxyz);
    knn_kernel<<<BB * NG, 256, 0, stream>>>(xyz, cxyz, gn);

    // ---- stage 2: mini-PointNet ----
    embed1_kernel<<<(131072 * 64 + 255) / 256, 256, 0, stream>>>(gn, cw1, cb1, h1);
    colstats_kernel<64><<<256, 256, 0, stream>>>(h1, st1, 131072);
    bn_finalize<<<1, 64, 0, stream>>>(st1, g1, be1, sc1, sh1, 64);
    bn_apply_bf16<<<(131072 * 64 + 255) / 256, 256, 0, stream>>>(h1, sc1, sh1, h1b, 131072 * 64, 64);
    gemm(h1b, cw2b, cb2, h2, nullptr, 131072, 128, 64, 0);
    colstats_kernel<128><<<256, 256, 0, stream>>>(h2, st2, 131072);
    bn_finalize<<<2, 64, 0, stream>>>(st2, g2, be2, sc2, sh2, 128);
    bn_apply_bf16<<<(131072 * 128 + 255) / 256, 256, 0, stream>>>(h2, sc2, sh2, h2b, 131072 * 128, 128);
    embed3_mfma<<<dim3(6, 1024), 256, 0, stream>>>(h2b, cw3b, cb3, gmax, gmin, st3);
    bn3_finalize<<<3, 256, 0, stream>>>(st3, g3, be3, a3, c3);

    // ---- stage 3: shuffle / mask / tokens (gather fused) ----
    restore_kernel<<<16, 256, 0, stream>>>(ids_shuf, restore, maskv);
    tokens_pos<<<(4096 * 768 + 255) / 256, 256, 0, stream>>>(gmax, gmin, a3, c3, cxyz, posw, posb,
                                                             restore, xe, xeb);

    // ---- weight conversion: single dispatch ----
    {
        CvtTab t;
        const float* srcs[10] = {eqw, eow, ef1w, ef2w, dew, dqw, dow, df1w, df2w, prw};
        __bf16* dsts[10] = {eqwb, eowb, ef1wb, ef2wb, dewb, dqwb, dowb, df1wb, df2wb, prwb};
        size_t ns[10] = {
            (size_t)NLE * 3 * DE * DE, (size_t)NLE * DE * DE,
            (size_t)NLE * 4 * DE * DE, (size_t)NLE * 4 * DE * DE,
            (size_t)DD * DE,
            (size_t)NLD * 3 * DD * DD, (size_t)NLD * DD * DD,
            (size_t)NLD * 4 * DD * DD, (size_t)NLD * 4 * DD * DD,
            (size_t)96 * 512
        };
        int cum = 0;
        t.cum[0] = 0;
        for (int k = 0; k < 10; ++k) {
            t.src[k] = srcs[k]; t.dst[k] = dsts[k];
            cum += (int)(ns[k] / 8);
            t.cum[k + 1] = cum;
        }
        cvt_multi_kernel<<<(cum + 255) / 256, 256, 0, stream>>>(t);
        hipMemsetAsync((void*)(prwb + (size_t)96 * 512), 0, (size_t)32 * 512 * 2, stream);
    }

    const size_t PSE = (size_t)1024 * DE;
    const size_t PSD = (size_t)4096 * DD;

    // ---- stage 4: encoder (12 layers) ----
    for (int l = 0; l < NLE; ++l) {
        gemm(xeb, eqwb + (size_t)l * 3 * DE * DE, eqb + (size_t)l * 3 * DE, nullptr, qkveb, 1024, 3 * DE, DE, 0);
        eattn_kernel<LK, 64, 12><<<BB * 12, 64, 0, stream>>>(qkveb, oeb, 0.125f);
        gemmSK(oeb, eowb + (size_t)l * DE * DE, eob + (size_t)l * DE, xfull, 1024, DE, DE, 4);
        ln_res<DE, 4><<<BB * LK, 256, 0, stream>>>(xe, xfull, PSE, el1g + (size_t)l * DE, el1b + (size_t)l * DE, xeb);
        gemm(xeb, ef1wb + (size_t)l * 4 * DE * DE, ef1b + (size_t)l * 4 * DE, nullptr, fe1b, 1024, 4 * DE, DE, 1);
        gemmSK(fe1b, ef2wb + (size_t)l * DE * 4 * DE, ef2b + (size_t)l * DE, xfull, 1024, DE, 4 * DE, 4);
        ln_res<DE, 4><<<BB * LK, 256, 0, stream>>>(xe, xfull, PSE, el2g + (size_t)l * DE, el2b + (size_t)l * DE, xeb);
    }

    // ---- stage 5: decoder embed + mask tokens ----
    gemmSK(xeb, dewb, deb, qkve, 1024, DD, DE, 4);
    yd_build<<<(BB * NG * DD + 255) / 256, 256, 0, stream>>>(qkve, restore, mtok, cxyz, dpw, dpb, xd, xdb);

    // ---- stage 6: decoder (8 layers) ----
    const float dsc = (float)(1.0 / sqrt(32.0));
    for (int l = 0; l < NLD; ++l) {
        gemm(xdb, dqwb + (size_t)l * 3 * DD * DD, dqb + (size_t)l * 3 * DD, nullptr, qkvdb, 4096, 3 * DD, DD, 0);
        dattn_kernel<NG, 32, 16><<<BB * 16, 256, 0, stream>>>(qkvdb, odb, dsc);
        gemmSK(odb, dowb + (size_t)l * DD * DD, dob + (size_t)l * DD, qkvd, 4096, DD, DD, 2);
        ln_res<DD, 2><<<BB * NG, 256, 0, stream>>>(xd, qkvd, PSD, dl1g + (size_t)l * DD, dl1b + (size_t)l * DD, xdb);
        gemm(xdb, df1wb + (size_t)l * 4 * DD * DD, df1b + (size_t)l * 4 * DD, nullptr, fd1b, 4096, 4 * DD, DD, 1);
        gemmSK(fd1b, df2wb + (size_t)l * DD * 4 * DD, df2b + (size_t)l * DD, qkvd, 4096, DD, 4 * DD, 2);
        ln_res<DD, 2><<<BB * NG, 256, 0, stream>>>(xd, qkvd, PSD, dl2g + (size_t)l * DD, dl2b + (size_t)l * DD, xdb);
    }

    // ---- stage 7: prediction (split-K) + loss ----
    gemmSK(xdb, prwb, prb, predp, 4096, 96, 512, 4);
    loss_l<<<BB * NG, 128, 0, stream>>>(predp, gn, maskv, pred, lm);
    loss_final<<<1, 1024, 0, stream>>>(lm, maskv, out);
}